// Round 1
// 1703.100 us; speedup vs baseline: 1.0526x; 1.0526x over previous
//
#include <hip/hip_runtime.h>
#include <hip/hip_bf16.h>

typedef __hip_bfloat16 bf16;
typedef __bf16 bft;
typedef bft bf16x8 __attribute__((ext_vector_type(8)));
typedef bft bf16x4 __attribute__((ext_vector_type(4)));
typedef float f32x4 __attribute__((ext_vector_type(4)));

#define S_LEN 8192
#define HID   2048
#define QKV3  6144
#define NH    16
#define HD    128
#define NFW   4
#define FD    512
#define CHUNK_LEN 2048
#define NCHUNK 4
#define BASE_LR_INV (-6.9072552f)   // log(expm1(0.001))
#define QKP 136                     // attn Q/K LDS stride (128 + 8)
#define VSP 72                      // attn V^T LDS stride (64 + 8)
#define PSP 76                      // attn P LDS stride (64 + 12)

__device__ __forceinline__ float bf2f(bf16 x){ return __bfloat162float(x); }
__device__ __forceinline__ bf16  f2bf(float x){ return __float2bfloat16(x); }
__device__ __forceinline__ float sigm(float x){ return 1.f/(1.f+__expf(-x)); }
__device__ __forceinline__ float siluf(float x){ return x/(1.f+__expf(-x)); }
__device__ __forceinline__ float wave_sum(float v){
  #pragma unroll
  for(int off=32; off; off>>=1) v += __shfl_xor(v, off, 64);
  return v;
}

// ---------------------------------------------------------------------------
// GEMM LDS tile staging, swizzled layout.
// Tile: ROWS x 32 bf16, unpadded [row][32]; physical col-slot c (8 elems)
// holds logical col-group g = c ^ ((row>>1)&3).
// bf16 source: global_load_lds 16B/lane (lane -> row=lane>>2, c=lane&3;
//   LDS dest = wave-uniform base + lane*16 => exactly (row,c) slot).
// fp32 source: VGPR load+convert, write same swizzled layout.
// ---------------------------------------------------------------------------
template<int ROWS, typename T>
__device__ __forceinline__ void stage(const T* __restrict__ src, long ld,
                                      bft* dst, int tid)
{
  if constexpr (sizeof(T) == 2) {
    const int lane = tid & 63, wv = tid >> 6;
    #pragma unroll
    for (int i = 0; i < ROWS/64; ++i) {
      const int r0 = wv*16 + i*64;               // wave-uniform
      const int row = r0 + (lane >> 2);
      const int g = (lane & 3) ^ ((row >> 1) & 3);
      const bft* gp = (const bft*)src + (size_t)row*ld + g*8;
      bft* lp = dst + (size_t)r0*32;
      __builtin_amdgcn_global_load_lds(
          (const __attribute__((address_space(1))) void*)gp,
          (__attribute__((address_space(3))) void*)lp, 16, 0, 0);
    }
  } else {
    #pragma unroll
    for (int i = 0; i < ROWS/64; ++i) {
      const int e = tid + i*256;
      const int row = e >> 2, c = e & 3;
      const int g = c ^ ((row >> 1) & 3);
      const float* sp = (const float*)src + (size_t)row*ld + g*8;
      const float4 v0 = *(const float4*)sp;
      const float4 v1 = *(const float4*)(sp + 4);
      bf16x8 b;
      b[0]=(bft)v0.x; b[1]=(bft)v0.y; b[2]=(bft)v0.z; b[3]=(bft)v0.w;
      b[4]=(bft)v1.x; b[5]=(bft)v1.y; b[6]=(bft)v1.z; b[7]=(bft)v1.w;
      *(bf16x8*)(dst + (size_t)row*32 + c*8) = b;
    }
  }
}

// ---------------------------------------------------------------------------
// MFMA NT GEMM: C[M,N] (+)= A[M,K] * B[N,K]^T, fp32 accumulate.
// EPI: 0 = store bf16, 1 = store fp32, 2 = fp32 C += acc (+ optional
// transposed bf16 shadow Ct). Batched over blockIdx.z.
// ---------------------------------------------------------------------------
template<int BM,int BN,int EPI, typename TA, typename TB>
__global__ __launch_bounds__(256) void mgemm_k(
    const TA* __restrict__ A, const TB* __restrict__ B, void* __restrict__ Cv,
    bft* __restrict__ Ct, int K, long lda, long ldb, long ldc,
    long sA, long sB, long sC)
{
  constexpr int AM = BM/32, AN = BN/32;
  __shared__ __align__(16) bft As[BM*32];
  __shared__ __align__(16) bft Bs[BN*32];
  const int tid = threadIdx.x;
  const int z = blockIdx.z;
  A += (size_t)z * sA;
  B += (size_t)z * sB;
  const size_t m0 = (size_t)blockIdx.y * BM, n0 = (size_t)blockIdx.x * BN;
  const int wv = tid >> 6, lane = tid & 63;
  const int wm = (wv & 1) * (BM/2), wn = (wv >> 1) * (BN/2);
  const int fr = lane & 15;
  const int fsw = ((lane >> 4) ^ ((fr >> 1) & 3)) * 8;   // swizzled frag col

  f32x4 acc[AM][AN];
  #pragma unroll
  for (int i=0;i<AM;i++)
    #pragma unroll
    for (int j=0;j<AN;j++) acc[i][j] = (f32x4){0.f,0.f,0.f,0.f};

  const TA* Ab = A + m0*lda;
  const TB* Bb = B + n0*ldb;
  for (int kt = 0; kt < K; kt += 32) {
    __syncthreads();
    stage<BM>(Ab + kt, lda, As, tid);
    stage<BN>(Bb + kt, ldb, Bs, tid);
    __syncthreads();
    bf16x8 af[AM], bfv[AN];
    #pragma unroll
    for (int mi=0; mi<AM; mi++)
      af[mi] = *(const bf16x8*)(As + (size_t)(wm + mi*16 + fr)*32 + fsw);
    #pragma unroll
    for (int ni=0; ni<AN; ni++)
      bfv[ni] = *(const bf16x8*)(Bs + (size_t)(wn + ni*16 + fr)*32 + fsw);
    #pragma unroll
    for (int mi=0; mi<AM; mi++)
      #pragma unroll
      for (int ni=0; ni<AN; ni++)
        acc[mi][ni] = __builtin_amdgcn_mfma_f32_16x16x32_bf16(af[mi], bfv[ni], acc[mi][ni], 0, 0, 0);
  }

  const int er = (lane >> 4) * 4;   // C/D: row=(lane>>4)*4+reg, col=lane&15
  const int ec = lane & 15;
  #pragma unroll
  for (int mi=0; mi<AM; mi++){
    #pragma unroll
    for (int ni=0; ni<AN; ni++){
      #pragma unroll
      for (int r=0; r<4; r++){
        size_t row = m0 + wm + mi*16 + er + r;
        size_t col = n0 + wn + ni*16 + ec;
        size_t idx = (size_t)z*sC + row*ldc + col;
        float v = acc[mi][ni][r];
        if constexpr (EPI == 0){
          ((bft*)Cv)[idx] = (bft)v;
        } else if constexpr (EPI == 1){
          ((float*)Cv)[idx] = v;
        } else {
          float nv = ((float*)Cv)[idx] + v;
          ((float*)Cv)[idx] = nv;
          if (Ct) Ct[(size_t)z*FD*FD + col*FD + row] = (bft)nv;
        }
      }
    }
  }
}

template<int BM,int BN,int EPI, typename TA, typename TB>
static inline void mgemm(hipStream_t st, const TA* A, const TB* B, void* C, bft* Ct,
    int M, int N, int K, long lda, long ldb, long ldc,
    int batch, long sA, long sB, long sC)
{
  dim3 g(N/BN, M/BM, batch);
  mgemm_k<BM,BN,EPI,TA,TB><<<g, 256, 0, st>>>(A, B, C, Ct, K, lda, ldb, ldc, sA, sB, sC);
}

// ---------------------------------------------------------------------------
// 256x256 MFMA NT GEMM with 4-slot (BK=32) circular LDS pipeline, counted
// vmcnt (never drained to 0 in steady state), raw s_barrier (1 per slot),
// setprio around the MFMA cluster, XCD-aware bijective block swizzle.
// 512 threads = 8 waves (2M x 4N), per-wave 128x64 output. LDS = 128 KiB.
// Race-freedom: slot written at iter s is (s+2)&3; any wave concurrently
// reading is at slot (s-1)&3 or s&3 (distinct mod 4); barrier counting
// guarantees slot s-2 fully consumed before any wave issues into its buffer.
// vmcnt(8) at iter s leaves slots s+1, s+2 (4 loads each) in flight and
// guarantees slot s's 4 global_load_lds have landed.
// ---------------------------------------------------------------------------
__device__ __forceinline__ void stage8(const bft* __restrict__ src, long ld,
                                       bft* dst, int tid)
{
  const int lane = tid & 63, wv = tid >> 6;      // 8 waves
  #pragma unroll
  for (int i = 0; i < 2; ++i) {
    const int r0 = wv*16 + i*128;                // wave-uniform
    const int row = r0 + (lane >> 2);
    const int g = (lane & 3) ^ ((row >> 1) & 3);
    const bft* gp = src + (size_t)row*ld + g*8;
    bft* lp = dst + (size_t)r0*32;
    __builtin_amdgcn_global_load_lds(
        (const __attribute__((address_space(1))) void*)gp,
        (__attribute__((address_space(3))) void*)lp, 16, 0, 0);
  }
}

template<int EPI>
__global__ __launch_bounds__(512, 2) void mgemm8_k(
    const bft* __restrict__ A, const bft* __restrict__ B, void* __restrict__ Cv,
    int K, long lda, long ldb, long ldc)
{
  __shared__ __align__(16) bft As[4][256*32];
  __shared__ __align__(16) bft Bs[4][256*32];
  const int tid = threadIdx.x;

  // XCD-aware bijective swizzle (nwg % 8 == 0 for both call sites)
  const int gx = (int)gridDim.x;
  const int nwg = (int)(gridDim.x * gridDim.y);
  int lin = (int)(blockIdx.y * gridDim.x + blockIdx.x);
  if ((nwg & 7) == 0) lin = (lin & 7) * (nwg >> 3) + (lin >> 3);
  const size_t m0 = (size_t)(lin / gx) * 256;
  const size_t n0 = (size_t)(lin % gx) * 256;

  const int wv = tid >> 6, lane = tid & 63;
  const int wm = (wv & 1) * 128, wn = (wv >> 1) * 64;
  const int fr = lane & 15;
  const int fsw = ((lane >> 4) ^ ((fr >> 1) & 3)) * 8;

  f32x4 acc[8][4];
  #pragma unroll
  for (int i=0;i<8;i++)
    #pragma unroll
    for (int j=0;j<4;j++) acc[i][j] = (f32x4){0.f,0.f,0.f,0.f};

  const bft* Ab = A + m0*lda;
  const bft* Bb = B + n0*ldb;
  const int NS = K >> 5;

  // prologue: slots 0 and 1
  stage8(Ab,      lda, As[0], tid);
  stage8(Bb,      ldb, Bs[0], tid);
  stage8(Ab + 32, lda, As[1], tid);
  stage8(Bb + 32, ldb, Bs[1], tid);

  auto compute = [&](int s){
    const bft* Ap = As[s & 3];
    const bft* Bp = Bs[s & 3];
    bf16x8 af[8], bv[4];
    #pragma unroll
    for (int mi=0; mi<8; mi++)
      af[mi] = *(const bf16x8*)(Ap + (size_t)(wm + mi*16 + fr)*32 + fsw);
    #pragma unroll
    for (int ni=0; ni<4; ni++)
      bv[ni] = *(const bf16x8*)(Bp + (size_t)(wn + ni*16 + fr)*32 + fsw);
    __builtin_amdgcn_s_setprio(1);
    #pragma unroll
    for (int mi=0; mi<8; mi++)
      #pragma unroll
      for (int ni=0; ni<4; ni++)
        acc[mi][ni] = __builtin_amdgcn_mfma_f32_16x16x32_bf16(af[mi], bv[ni], acc[mi][ni], 0, 0, 0);
    __builtin_amdgcn_s_setprio(0);
  };

  for (int s = 0; s < NS - 2; ++s) {
    const int kt = (s + 2) * 32;
    stage8(Ab + kt, lda, As[(s+2)&3], tid);
    stage8(Bb + kt, ldb, Bs[(s+2)&3], tid);
    asm volatile("s_waitcnt vmcnt(8)" ::: "memory");
    __builtin_amdgcn_s_barrier();
    asm volatile("" ::: "memory");
    compute(s);
  }
  asm volatile("s_waitcnt vmcnt(4)" ::: "memory");
  __builtin_amdgcn_s_barrier();
  asm volatile("" ::: "memory");
  compute(NS - 2);
  asm volatile("s_waitcnt vmcnt(0)" ::: "memory");
  __builtin_amdgcn_s_barrier();
  asm volatile("" ::: "memory");
  compute(NS - 1);

  const int er = (lane >> 4) * 4;
  const int ec = lane & 15;
  #pragma unroll
  for (int mi=0; mi<8; mi++){
    #pragma unroll
    for (int ni=0; ni<4; ni++){
      #pragma unroll
      for (int r=0; r<4; r++){
        size_t row = m0 + wm + mi*16 + er + r;
        size_t col = n0 + wn + ni*16 + ec;
        size_t idx = row*ldc + col;
        float v = acc[mi][ni][r];
        if constexpr (EPI == 0) ((bft*)Cv)[idx] = (bft)v;
        else                    ((float*)Cv)[idx] = v;
      }
    }
  }
}

template<int EPI>
static inline void mgemm8(hipStream_t st, const bft* A, const bft* B, void* C,
                          int M, int N, int K, long lda, long ldb, long ldc)
{
  dim3 g(N/256, M/256, 1);
  mgemm8_k<EPI><<<g, 512, 0, st>>>(A, B, C, K, lda, ldb, ldc);
}

// ---------------------------------------------------------------------------
// fp32 -> bf16 bulk convert (8 elems/thread); n must divide 2048.
// ---------------------------------------------------------------------------
__global__ __launch_bounds__(256) void cvt_k(const float* __restrict__ s,
    bft* __restrict__ d)
{
  size_t i = ((size_t)blockIdx.x*256 + threadIdx.x) * 8;
  const float4 v0 = *(const float4*)(s + i);
  const float4 v1 = *(const float4*)(s + i + 4);
  bf16x8 b;
  b[0]=(bft)v0.x; b[1]=(bft)v0.y; b[2]=(bft)v0.z; b[3]=(bft)v0.w;
  b[4]=(bft)v1.x; b[5]=(bft)v1.y; b[6]=(bft)v1.z; b[7]=(bft)v1.w;
  *(bf16x8*)(d + i) = b;
}

// ---------------------------------------------------------------------------
// Batched bf16 transpose: out[z][c][r] = in[z][r][c], R=2048, C=512.
// ---------------------------------------------------------------------------
__global__ __launch_bounds__(256) void tr_k(const bft* __restrict__ in,
    bft* __restrict__ out, long ldin, long sIn, long sOut)
{
  __shared__ __align__(16) bft t[64][72];
  const int c0 = blockIdx.x*64, r0 = blockIdx.y*64;
  in  += (size_t)blockIdx.z * sIn;
  out += (size_t)blockIdx.z * sOut;
  const int tid = threadIdx.x;
  #pragma unroll
  for (int i=0;i<2;i++){
    int e = tid + i*256;
    int r = e >> 3, c8 = (e & 7) * 8;
    *(bf16x8*)&t[r][c8] = *(const bf16x8*)(in + (size_t)(r0+r)*ldin + c0 + c8);
  }
  __syncthreads();
  #pragma unroll
  for (int i=0;i<2;i++){
    int e = tid + i*256;
    int c = e >> 3, r8 = (e & 7) * 8;
    bf16x8 v;
    #pragma unroll
    for (int j=0;j<8;j++) v[j] = t[r8+j][c];
    *(bf16x8*)(out + (size_t)(c0+c)*CHUNK_LEN + r0 + r8) = v;
  }
}

// initial w1^T bf16 shadow: w1tb[z][h][o] = (bf16)w1[z][o][h]
__global__ __launch_bounds__(256) void tcw1_k(const float* __restrict__ w1,
    bft* __restrict__ w1tb)
{
  size_t idx = (size_t)blockIdx.x*256 + threadIdx.x;
  int z = (int)(idx >> 18);
  int h = (int)((idx >> 9) & 511);
  int o = (int)(idx & 511);
  w1tb[idx] = (bft)w1[(size_t)z*FD*FD + (size_t)o*FD + h];
}

// ---------------------------------------------------------------------------
// v^T for attention PV: vT[h][d][s] = v[s][h*128+d] (raw v region of qkv).
// ---------------------------------------------------------------------------
__global__ __launch_bounds__(256) void vt_k(const bf16* __restrict__ qkv,
    bft* __restrict__ vT)
{
  __shared__ __align__(16) bft t[64*QKP];   // [s][d]
  const int s0 = blockIdx.x * 64;
  const int h  = blockIdx.y;
  const int tid = threadIdx.x;
  #pragma unroll
  for (int i=0;i<4;i++){
    int e = tid + i*256;
    int rr = e >> 4, doff = (e & 15) * 8;
    *(bf16x8*)(t + rr*QKP + doff) =
        *(const bf16x8*)((const bft*)qkv + (size_t)(s0+rr)*QKV3 + 2*HID + h*HD + doff);
  }
  __syncthreads();
  #pragma unroll
  for (int it=0; it<4; it++){
    int d = (tid >> 3) + it*32;
    int so8 = (tid & 7) * 8;
    bf16x8 v;
    #pragma unroll
    for (int j=0;j<8;j++) v[j] = t[(so8+j)*QKP + d];
    *(bf16x8*)(vT + ((size_t)(h*HD + d))*S_LEN + s0 + so8) = v;
  }
}

// ---------------------------------------------------------------------------
// RoPE cos/sin tables
// ---------------------------------------------------------------------------
__global__ void rope_k(float* __restrict__ rc, float* __restrict__ rs){
  int pos = blockIdx.x, d = threadIdx.x;
  float inv = 1.f / powf(500000.0f, (float)d * (1.0f/64.0f));
  float ang = (float)pos * inv;
  rc[pos*64+d] = cosf(ang);
  rs[pos*64+d] = sinf(ang);
}

// ---------------------------------------------------------------------------
// per-token learning rates
// ---------------------------------------------------------------------------
__global__ __launch_bounds__(256) void lr_k(const float* __restrict__ hidden,
    const float* __restrict__ lr_w, const float* __restrict__ lr_b,
    float* __restrict__ lro)
{
  __shared__ float hrow[HID];
  __shared__ float red[4][12];
  int s = blockIdx.x, tid = threadIdx.x;
  for(int i=0;i<HID/256;i++) hrow[tid+256*i] = hidden[(size_t)s*HID + tid + 256*i];
  __syncthreads();
  float part[12];
  #pragma unroll
  for(int o=0;o<12;o++) part[o]=0.f;
  for(int i=0;i<HID/256;i++){
    int j = tid + 256*i;
    float h = hrow[j];
    #pragma unroll
    for(int o=0;o<12;o++) part[o] += h * lr_w[o*HID + j];
  }
  int lane = tid & 63, w = tid >> 6;
  #pragma unroll
  for(int o=0;o<12;o++){
    float v = wave_sum(part[o]);
    if(lane==0) red[w][o] = v;
  }
  __syncthreads();
  if(tid < 12){
    float v = red[0][tid]+red[1][tid]+red[2][tid]+red[3][tid] + lr_b[tid] + BASE_LR_INV;
    float sp = (v > 20.f) ? v : log1pf(expf(v));
    lro[s*12 + tid] = sp;
  }
}

// ---------------------------------------------------------------------------
// E2a: per-token rmsnorm(q), rmsnorm(k), in place in qkv (bf16).
// ---------------------------------------------------------------------------
__global__ __launch_bounds__(256) void e2a_k(
    bf16* __restrict__ qkv,
    const float* __restrict__ qnw, const float* __restrict__ knw)
{
  __shared__ float red[8];
  int s = blockIdx.x, tid = threadIdx.x;
  int lane = tid & 63, w = tid >> 6;
  float qv[8], kv[8];
  float sq = 0.f, sk = 0.f;
  size_t base = (size_t)s*QKV3;
  #pragma unroll
  for(int i=0;i<8;i++){
    int j = tid*8 + i;
    qv[i] = bf2f(qkv[base + j]);
    kv[i] = bf2f(qkv[base + HID + j]);
    sq += qv[i]*qv[i]; sk += kv[i]*kv[i];
  }
  sq = wave_sum(sq); sk = wave_sum(sk);
  if(lane==0){ red[w] = sq; red[4+w] = sk; }
  __syncthreads();
  float rq = rsqrtf((red[0]+red[1]+red[2]+red[3])*(1.f/HID) + 1e-6f);
  float rk = rsqrtf((red[4]+red[5]+red[6]+red[7])*(1.f/HID) + 1e-6f);
  #pragma unroll
  for(int i=0;i<8;i++){
    int j = tid*8 + i;
    qkv[base + j]       = f2bf(qv[i]*rq*qnw[j]);
    qkv[base + HID + j] = f2bf(kv[i]*rk*knw[j]);
  }
}

// ---------------------------------------------------------------------------
// E2b (after attention): overwrite q/k/v regions with fq/fk/fv.
// ---------------------------------------------------------------------------
__global__ __launch_bounds__(256) void e2b_k(
    bf16* __restrict__ qkv,
    const float* __restrict__ qks, const float* __restrict__ qko)
{
  int s = blockIdx.x, tid = threadIdx.x;
  size_t base = (size_t)s*QKV3;
  float a[8], b[8], vv[8];
  float ga = 0.f, gb2 = 0.f;
  #pragma unroll
  for(int i=0;i<8;i++){
    int j = tid*8 + i;
    float qn = bf2f(qkv[base + j]);
    float kn = bf2f(qkv[base + HID + j]);
    float v  = bf2f(qkv[base + 2*HID + j]);
    a[i] = siluf(qn*qks[2*j]   + qko[2*j]);
    b[i] = siluf(kn*qks[2*j+1] + qko[2*j+1]);
    vv[i] = siluf(v);
    ga += a[i]*a[i]; gb2 += b[i]*b[i];
  }
  ga = wave_sum(ga); gb2 = wave_sum(gb2);
  float iq = 1.f / fmaxf(sqrtf(ga), 1e-12f);
  float ik = 1.f / fmaxf(sqrtf(gb2), 1e-12f);
  #pragma unroll
  for(int i=0;i<8;i++){
    int j = tid*8 + i;
    qkv[base + j]         = f2bf(a[i]*iq);
    qkv[base + HID + j]   = f2bf(b[i]*ik);
    qkv[base + 2*HID + j] = f2bf(vv[i]);
  }
}

// ---------------------------------------------------------------------------
// MFMA sliding-window attention (window 256 incl self).
// ---------------------------------------------------------------------------
__global__ __launch_bounds__(256) void attn_k(
    const bf16* __restrict__ qkv, const bft* __restrict__ vT,
    const float* __restrict__ rc, const float* __restrict__ rs,
    float* __restrict__ attn)
{
  __shared__ __align__(16) bft Qs[64*QKP];
  __shared__ __align__(16) bft Ks[64*QKP];
  __shared__ __align__(16) bft Vs[128*VSP];
  __shared__ __align__(16) bft Ps[64*PSP];
  const int head = blockIdx.x >> 7;
  const int Q0 = (blockIdx.x & 127) * 64;
  const int tid = threadIdx.x;
  const int hb = head * HD;
  const int lane = tid & 63;
  const int wm = (tid >> 6) * 16;
  const int fr = lane & 15, fko = (lane >> 4) * 8;
  const int rbase = (lane >> 4) * 4;

  #pragma unroll
  for(int i=0;i<16;i++){
    int e = tid + i*256;
    int rr = e >> 6, d = e & 63;
    int qpos = Q0 + rr;
    size_t b = (size_t)qpos*QKV3 + hb;
    float x1 = bf2f(qkv[b + d]);
    float x2 = bf2f(qkv[b + d + 64]);
    float c = rc[qpos*64 + d], sn = rs[qpos*64 + d];
    Qs[rr*QKP + d]      = (bft)(x1*c - x2*sn);
    Qs[rr*QKP + d + 64] = (bft)(x2*c + x1*sn);
  }
  __syncthreads();
  bf16x8 qf[4];
  #pragma unroll
  for (int kk=0;kk<4;kk++)
    qf[kk] = *(const bf16x8*)(Qs + (wm+fr)*QKP + kk*32 + fko);

  f32x4 Ot[8];
  #pragma unroll
  for (int i=0;i<8;i++) Ot[i] = (f32x4){0.f,0.f,0.f,0.f};
  float m4[4], l4[4];
  #pragma unroll
  for (int r=0;r<4;r++){ m4[r] = -INFINITY; l4[r] = 0.f; }

  for (int kt=0; kt<5; kt++){
    const int kb = Q0 - 256 + kt*64;
    if (kb < 0) continue;
    __syncthreads();
    #pragma unroll
    for(int i=0;i<16;i++){
      int e = tid + i*256;
      int rr = e >> 6, d = e & 63;
      int kpos = kb + rr;
      size_t b = (size_t)kpos*QKV3 + HID + hb;
      float x1 = bf2f(qkv[b + d]);
      float x2 = bf2f(qkv[b + d + 64]);
      float c = rc[kpos*64 + d], sn = rs[kpos*64 + d];
      Ks[rr*QKP + d]      = (bft)(x1*c - x2*sn);
      Ks[rr*QKP + d + 64] = (bft)(x2*c + x1*sn);
    }
    {
      int d = tid >> 1, koff = (tid & 1) * 32;
      const bft* vrow = vT + ((size_t)(hb + d))*S_LEN + kb + koff;
      bft* lrow = Vs + d*VSP + koff;
      #pragma unroll
      for (int j8=0;j8<4;j8++)
        *(bf16x8*)(lrow + j8*8) = *(const bf16x8*)(vrow + j8*8);
    }
    __syncthreads();

    f32x4 st[4];
    #pragma unroll
    for (int nt=0;nt<4;nt++){
      f32x4 acc = (f32x4){0.f,0.f,0.f,0.f};
      #pragma unroll
      for (int kk=0;kk<4;kk++){
        bf16x8 kf = *(const bf16x8*)(Ks + (nt*16+fr)*QKP + kk*32 + fko);
        acc = __builtin_amdgcn_mfma_f32_16x16x32_bf16(qf[kk], kf, acc, 0, 0, 0);
      }
      st[nt] = acc;
    }

    float pv[4][4];
    #pragma unroll
    for (int r=0;r<4;r++){
      int qpos = Q0 + wm + rbase + r;
      float sm[4];
      float mx = -INFINITY;
      #pragma unroll
      for (int nt=0;nt<4;nt++){
        int kpos = kb + nt*16 + fr;
        bool valid = (kpos > qpos - 256) && (kpos <= qpos);
        float s = valid ? st[nt][r] * 0.088388347648318447f : -INFINITY;
        sm[nt] = s;
        mx = fmaxf(mx, s);
      }
      mx = fmaxf(mx, __shfl_xor(mx, 1, 64));
      mx = fmaxf(mx, __shfl_xor(mx, 2, 64));
      mx = fmaxf(mx, __shfl_xor(mx, 4, 64));
      mx = fmaxf(mx, __shfl_xor(mx, 8, 64));
      float mnew = fmaxf(m4[r], mx);
      float alpha = (mnew == -INFINITY) ? 1.f : __expf(m4[r] - mnew);
      float ps = 0.f;
      #pragma unroll
      for (int nt=0;nt<4;nt++){
        float p = (sm[nt] == -INFINITY) ? 0.f : __expf(sm[nt] - mnew);
        pv[nt][r] = p;
        ps += p;
      }
      ps += __shfl_xor(ps, 1, 64);
      ps += __shfl_xor(ps, 2, 64);
      ps += __shfl_xor(ps, 4, 64);
      ps += __shfl_xor(ps, 8, 64);
      l4[r] = l4[r]*alpha + ps;
      m4[r] = mnew;
      #pragma unroll
      for (int ct=0;ct<8;ct++) Ot[ct][r] *= alpha;
    }

    #pragma unroll
    for (int r=0;r<4;r++){
      int row = wm + rbase + r;
      #pragma unroll
      for (int nt=0;nt<4;nt++)
        Ps[row*PSP + nt*16 + fr] = (bft)pv[nt][r];
    }
    bf16x8 af[2];
    #pragma unroll
    for (int kk=0;kk<2;kk++){
      const bft* pp = Ps + (wm+fr)*PSP + kk*32 + fko;
      bf16x4 lo = *(const bf16x4*)pp;
      bf16x4 hi = *(const bf16x4*)(pp+4);
      bf16x8 a;
      #pragma unroll
      for (int j=0;j<4;j++){ a[j]=lo[j]; a[j+4]=hi[j]; }
      af[kk]=a;
    }
    #pragma unroll
    for (int ct=0;ct<8;ct++)
      #pragma unroll
      for (int kk=0;kk<2;kk++){
        bf16x8 bv = *(const bf16x8*)(Vs + (ct*16+fr)*VSP + kk*32 + fko);
        Ot[ct] = __builtin_amdgcn_mfma_f32_16x16x32_bf16(af[kk], bv, Ot[ct], 0, 0, 0);
      }
  }

  #pragma unroll
  for (int r=0;r<4;r++){
    float invl = 1.f / l4[r];
    int qpos = Q0 + wm + rbase + r;
    size_t ob = (size_t)qpos*HID + hb;
    #pragma unroll
    for (int ct=0;ct<8;ct++)
      attn[ob + ct*16 + fr] = Ot[ct][r] * invl;
  }
}

// ---------------------------------------------------------------------------
// TTT elementwise fwd: hid = silu(g)*hm ; opre = silu(qg)*qm (opre -> qg buf)
// ---------------------------------------------------------------------------
__global__ __launch_bounds__(256) void e3_k(
    const bf16* __restrict__ g, const bf16* __restrict__ hm,
    bf16* __restrict__ qg, const bf16* __restrict__ qm,
    bf16* __restrict__ hid)
{
  size_t idx = (size_t)blockIdx.x*256 + threadIdx.x;
  float opre = siluf(bf2f(qg[idx])) * bf2f(qm[idx]);
  hid[idx] = f2bf(siluf(bf2f(g[idx])) * bf2f(hm[idx]));
  qg[idx]  = f2bf(opre);
}

// ---------------------------------------------------------------------------
// TTT backprop elementwise (in place): a0->g, a2->hm, a1->dhid buffer.
// ---------------------------------------------------------------------------
__global__ __launch_bounds__(256) void e4_k(
    bf16* __restrict__ g, bf16* __restrict__ hm, bf16* __restrict__ dhid,
    const bf16* __restrict__ qkv, const float* __restrict__ lrb, int cbase)
{
  size_t idx = (size_t)blockIdx.x*256 + threadIdx.x;
  int h  = (int)(idx >> 20);
  int ci = (int)((idx >> 9) & 2047);
  int d  = (int)(idx & 511);
  int s  = cbase + ci;
  float l0  = lrb[s*12 + h];
  float l1  = lrb[s*12 + 4 + h];
  float l2v = lrb[s*12 + 8 + h];
  float gg = bf2f(g[idx]), hv = bf2f(hm[idx]), dh = bf2f(dhid[idx]);
  float sg = sigm(gg);
  float silu_g = gg * sg;
  float dhm = dh * silu_g;
  float dg  = dh * hv;
  float dgp = dg * (sg * (1.f + gg * (1.f - sg)));
  float fvv = bf2f(qkv[(size_t)s*QKV3 + 2*HID + h*FD + d]);
  g[idx]    = f2bf(dgp * l0);
  hm[idx]   = f2bf(dhm * l2v);
  dhid[idx] = f2bf(fvv * l1);
}

// ---------------------------------------------------------------------------
// E5 (per chunk): X = attn + rmsnorm(ofc)*ttt_norm_w -> q region of qkv
// ---------------------------------------------------------------------------
__global__ __launch_bounds__(256) void e5_k(const float* __restrict__ attn,
    const bf16* __restrict__ ofc, const float* __restrict__ tnw,
    bf16* __restrict__ qkv, int cbase)
{
  int ci = blockIdx.x, tid = threadIdx.x;
  int s = cbase + ci;
  int lane = tid & 63, w = tid >> 6;
  float o[8]; float ss = 0.f;
  size_t ob = ((size_t)w*CHUNK_LEN + ci)*FD + (size_t)lane*8;
  #pragma unroll
  for(int i=0;i<8;i++){ o[i] = bf2f(ofc[ob+i]); ss += o[i]*o[i]; }
  ss = wave_sum(ss);
  float inv = rsqrtf(ss*(1.f/FD) + 1e-6f);
  size_t xb = (size_t)s*QKV3 + w*FD + (size_t)lane*8;
  size_t ab = (size_t)s*HID  + w*FD + (size_t)lane*8;
  #pragma unroll
  for(int i=0;i<8;i++){
    int d = lane*8 + i;
    qkv[xb+i] = f2bf(attn[ab+i] + o[i]*inv*tnw[d]);
  }
}

// ---------------------------------------------------------------------------
extern "C" void kernel_launch(void* const* d_in, const int* in_sizes, int n_in,
                              void* d_out, int out_size, void* d_ws, size_t ws_size,
                              hipStream_t stream)
{
  (void)in_sizes; (void)n_in; (void)out_size;
  const float* hidden   = (const float*)d_in[0];
  const float* qkv_w    = (const float*)d_in[1];
  const float* q_norm_w = (const float*)d_in[2];
  const float* k_norm_w = (const float*)d_in[3];
  const float* qk_scale = (const float*)d_in[4];
  const float* qk_off   = (const float*)d_in[5];
  const float* lr_w     = (const float*)d_in[6];
  const float* lr_b     = (const float*)d_in[7];
  const float* w0_in    = (const float*)d_in[8];
  const float* w1_in    = (const float*)d_in[9];
  const float* w2_in    = (const float*)d_in[10];
  const float* ttt_nw   = (const float*)d_in[11];
  const float* o_proj   = (const float*)d_in[12];
  float* out = (float*)d_out;

  char* p = (char*)d_ws;
  auto alloc = [&](size_t n){ char* r = p; p += (n + 255) & ~(size_t)255; return (void*)r; };

  bf16*  qkv   = (bf16*) alloc((size_t)S_LEN*QKV3*sizeof(bf16));
  float* lrb   = (float*)alloc((size_t)S_LEN*12*sizeof(float));
  float* rc    = (float*)alloc((size_t)S_LEN*64*sizeof(float));
  float* rs    = (float*)alloc((size_t)S_LEN*64*sizeof(float));
  float* w0s   = (float*)alloc((size_t)NFW*FD*FD*sizeof(float));
  float* w1s   = (float*)alloc((size_t)NFW*FD*FD*sizeof(float));
  float* w2s   = (float*)alloc((size_t)NFW*FD*FD*sizeof(float));
  bft*   w1tb  = (bft*)  alloc((size_t)NFW*FD*FD*sizeof(bft));
  bf16*  gb    = (bf16*) alloc((size_t)NFW*CHUNK_LEN*FD*sizeof(bf16));
  bf16*  hmb   = (bf16*) alloc((size_t)NFW*CHUNK_LEN*FD*sizeof(bf16));
  bf16*  qgb   = (bf16*) alloc((size_t)NFW*CHUNK_LEN*FD*sizeof(bf16));
  bf16*  qmb   = (bf16*) alloc((size_t)NFW*CHUNK_LEN*FD*sizeof(bf16));
  bf16*  hidb  = (bf16*) alloc((size_t)NFW*CHUNK_LEN*FD*sizeof(bf16));
  bf16*  ofc   = (bf16*) alloc((size_t)NFW*CHUNK_LEN*FD*sizeof(bf16));
  bft*   fkT   = (bft*)  alloc((size_t)NFW*FD*CHUNK_LEN*sizeof(bft));
  bft*   hidT  = (bft*)  alloc((size_t)NFW*FD*CHUNK_LEN*sizeof(bft));
  bft*   a2T   = (bft*)  alloc((size_t)NFW*FD*CHUNK_LEN*sizeof(bft));
  bft*   a1T   = (bft*)  alloc((size_t)NFW*FD*CHUNK_LEN*sizeof(bft));

  if ((size_t)(p - (char*)d_ws) > ws_size) return;

  // Liveness aliases (no extra workspace):
  // hidden_bf (33.55 MB) = gb..qmb  — dead before chunk loop writes gb.
  // qkvw_bf   (25.17 MB) = fkT..a2T — dead before vt_k writes vT.
  // vT        (33.55 MB) = fkT..a1T — dead before chunk loop's tr_k.
  // opw_bf    ( 8.39 MB) = hidb..   — converted after last e5, before o_proj.
  bft* hidden_bf = (bft*)gb;
  bft* qkvw_bf   = (bft*)fkT;
  bft* vT        = (bft*)fkT;
  bft* opw_bf    = (bft*)hidb;

  float* attn = out;   // attn lives in d_out until the final projection

  hipMemcpyAsync(w0s, w0_in, (size_t)NFW*FD*FD*sizeof(float), hipMemcpyDeviceToDevice, stream);
  hipMemcpyAsync(w1s, w1_in, (size_t)NFW*FD*FD*sizeof(float), hipMemcpyDeviceToDevice, stream);
  hipMemcpyAsync(w2s, w2_in, (size_t)NFW*FD*FD*sizeof(float), hipMemcpyDeviceToDevice, stream);

  rope_k<<<S_LEN, 64, 0, stream>>>(rc, rs);
  lr_k<<<S_LEN, 256, 0, stream>>>(hidden, lr_w, lr_b, lrb);
  tcw1_k<<<NFW*FD*FD/256, 256, 0, stream>>>(w1_in, w1tb);
  cvt_k<<<(S_LEN*HID)/2048, 256, 0, stream>>>(hidden, hidden_bf);
  cvt_k<<<(QKV3*HID)/2048, 256, 0, stream>>>(qkv_w, qkvw_bf);

  // qkv = hidden @ qkv_w^T -> bf16   (256^2 pipelined GEMM)
  mgemm8<0>(stream, hidden_bf, qkvw_bf, (void*)qkv, S_LEN, QKV3, HID, HID, HID, QKV3);

  e2a_k<<<S_LEN, 256, 0, stream>>>(qkv, q_norm_w, k_norm_w);
  vt_k<<<dim3(S_LEN/64, NH), 256, 0, stream>>>(qkv, vT);
  attn_k<<<NH*128, 256, 0, stream>>>(qkv, vT, rc, rs, attn);
  e2b_k<<<S_LEN, 256, 0, stream>>>(qkv, qk_scale, qk_off);

  const long sW  = (long)FD*FD;
  const long sCh = (long)CHUNK_LEN*FD;
  const long sT  = (long)FD*CHUNK_LEN;
  const int  NEL = NFW*CHUNK_LEN*FD/256;
  const dim3 tg(FD/64, CHUNK_LEN/64, NFW);

  for(int c=0; c<NCHUNK; c++){
    const bft* fqc = (const bft*)qkv + (size_t)c*CHUNK_LEN*QKV3;
    const bft* fkc = fqc + HID;
    const bft* fvc = fqc + 2*HID;
    mgemm<128,128,0>(stream, fkc, w0s, gb,  (bft*)nullptr, CHUNK_LEN, FD, FD, QKV3, FD, FD, NFW, FD, sW, sCh);
    mgemm<128,128,0>(stream, fkc, w2s, hmb, (bft*)nullptr, CHUNK_LEN, FD, FD, QKV3, FD, FD, NFW, FD, sW, sCh);
    mgemm<128,128,0>(stream, fqc, w0s, qgb, (bft*)nullptr, CHUNK_LEN, FD, FD, QKV3, FD, FD, NFW, FD, sW, sCh);
    mgemm<128,128,0>(stream, fqc, w2s, qmb, (bft*)nullptr, CHUNK_LEN, FD, FD, QKV3, FD, FD, NFW, FD, sW, sCh);
    e3_k<<<NEL, 256, 0, stream>>>(gb, hmb, qgb, qmb, hidb);
    mgemm<128,128,0>(stream, (const bft*)qgb, w1s, ofc, (bft*)nullptr, CHUNK_LEN, FD, FD, FD, FD, FD, NFW, sCh, sW, sCh);
    mgemm<128,128,0>(stream, fvc, (const bft*)w1tb, qmb, (bft*)nullptr, CHUNK_LEN, FD, FD, QKV3, FD, FD, NFW, FD, sW, sCh);
    e4_k<<<NEL, 256, 0, stream>>>(gb, hmb, qmb, qkv, lrb, c*CHUNK_LEN);
    tr_k<<<tg, 256, 0, stream>>>(fkc,              fkT,        QKV3, FD,  sT);
    tr_k<<<tg, 256, 0, stream>>>((const bft*)hidb, hidT,       FD,   sCh, sT);
    tr_k<<<tg, 256, 0, stream>>>((const bft*)gb,   (bft*)qgb,  FD,   sCh, sT);
    tr_k<<<tg, 256, 0, stream>>>((const bft*)hmb,  a2T,        FD,   sCh, sT);
    tr_k<<<tg, 256, 0, stream>>>((const bft*)qmb,  a1T,        FD,   sCh, sT);
    mgemm<64,64,2>(stream, (const bft*)qgb, fkT,  w0s, (bft*)nullptr, FD, FD, CHUNK_LEN, CHUNK_LEN, CHUNK_LEN, FD, NFW, sT, sT, sW);
    mgemm<64,64,2>(stream, a2T,             fkT,  w2s, (bft*)nullptr, FD, FD, CHUNK_LEN, CHUNK_LEN, CHUNK_LEN, FD, NFW, sT, sT, sW);
    mgemm<64,64,2>(stream, a1T,             hidT, w1s, w1tb,          FD, FD, CHUNK_LEN, CHUNK_LEN, CHUNK_LEN, FD, NFW, sT, sT, sW);
    e5_k<<<CHUNK_LEN, 256, 0, stream>>>(attn, ofc, ttt_nw, qkv, c*CHUNK_LEN);
  }

  // bf16 copy of o_proj (hidb/ofc are dead now), then final projection
  cvt_k<<<(HID*HID)/2048, 256, 0, stream>>>(o_proj, opw_bf);
  mgemm8<1>(stream, (const bft*)qkv, opw_bf, out, S_LEN, HID, HID, QKV3, HID, HID);
}

// Round 2
// 1578.328 us; speedup vs baseline: 1.1358x; 1.0791x over previous
//
#include <hip/hip_runtime.h>
#include <hip/hip_bf16.h>

typedef __hip_bfloat16 bf16;
typedef __bf16 bft;
typedef bft bf16x8 __attribute__((ext_vector_type(8)));
typedef bft bf16x4 __attribute__((ext_vector_type(4)));
typedef float f32x4 __attribute__((ext_vector_type(4)));

#define S_LEN 8192
#define HID   2048
#define QKV3  6144
#define NH    16
#define HD    128
#define NFW   4
#define FD    512
#define CHUNK_LEN 2048
#define NCHUNK 4
#define BASE_LR_INV (-6.9072552f)   // log(expm1(0.001))
#define QKP 136                     // attn Q/K LDS stride (128 + 8)
#define VSP 72                      // attn V^T LDS stride (64 + 8)
#define PSP 76                      // attn P LDS stride (64 + 12)

__device__ __forceinline__ float bf2f(bf16 x){ return __bfloat162float(x); }
__device__ __forceinline__ bf16  f2bf(float x){ return __float2bfloat16(x); }
__device__ __forceinline__ float sigm(float x){ return 1.f/(1.f+__expf(-x)); }
__device__ __forceinline__ float siluf(float x){ return x/(1.f+__expf(-x)); }
__device__ __forceinline__ float wave_sum(float v){
  #pragma unroll
  for(int off=32; off; off>>=1) v += __shfl_xor(v, off, 64);
  return v;
}

template<int N>
__device__ __forceinline__ void waitcnt_vm(){
  static_assert(N==0||N==2||N==4||N==8, "unsupported vmcnt");
  if constexpr (N==0)      asm volatile("s_waitcnt vmcnt(0)" ::: "memory");
  else if constexpr (N==2) asm volatile("s_waitcnt vmcnt(2)" ::: "memory");
  else if constexpr (N==4) asm volatile("s_waitcnt vmcnt(4)" ::: "memory");
  else                     asm volatile("s_waitcnt vmcnt(8)" ::: "memory");
}

// ---------------------------------------------------------------------------
// GEMM LDS tile staging (bf16 only), swizzled layout.
// Tile: ROWS x 32 bf16, unpadded [row][32]; physical col-slot c (8 elems)
// holds logical col-group g = c ^ ((row>>1)&3).
// global_load_lds 16B/lane (lane -> row=lane>>2, c=lane&3;
//   LDS dest = wave-uniform base + lane*16 => exactly (row,c) slot).
// 4 waves (256 threads): issues ROWS/64 loads per wave.
// ---------------------------------------------------------------------------
template<int ROWS>
__device__ __forceinline__ void stage(const bft* __restrict__ src, long ld,
                                      bft* dst, int tid)
{
  const int lane = tid & 63, wv = tid >> 6;
  #pragma unroll
  for (int i = 0; i < ROWS/64; ++i) {
    const int r0 = wv*16 + i*64;               // wave-uniform
    const int row = r0 + (lane >> 2);
    const int g = (lane & 3) ^ ((row >> 1) & 3);
    const bft* gp = src + (size_t)row*ld + g*8;
    bft* lp = dst + (size_t)r0*32;
    __builtin_amdgcn_global_load_lds(
        (const __attribute__((address_space(1))) void*)gp,
        (__attribute__((address_space(3))) void*)lp, 16, 0, 0);
  }
}

// ---------------------------------------------------------------------------
// MFMA NT GEMM: C[M,N] (+)= A[M,K] * B[N,K]^T, fp32 accumulate, 256 threads.
// 4-slot circular LDS pipeline (BK=32), counted vmcnt (never drained to 0
// in steady state), raw s_barrier (1 per slot), setprio around MFMA cluster.
// Race-freedom: slot written at iter s is (s+2)&3; concurrent readers touch
// (s-1)&3 and s&3 (distinct mod 4); per-wave program order + barrier counting
// guarantees slot s-2 fully consumed before any wave issues into its buffer.
// EPI: 0 = store bf16, 1 = store fp32, 2 = fp32 C += acc, bf16 direct shadow
// Cd, optional transposed bf16 shadow Ct. Batched over blockIdx.z.
// ---------------------------------------------------------------------------
template<int BM,int BN,int EPI>
__global__ __launch_bounds__(256) void mgemm_k(
    const bft* __restrict__ A, const bft* __restrict__ B, void* __restrict__ Cv,
    bft* __restrict__ Cd, bft* __restrict__ Ct, int K,
    long lda, long ldb, long ldc, long sA, long sB, long sC)
{
  constexpr int AM = BM/32, AN = BN/32;
  constexpr int LPS = BM/64 + BN/64;           // global_load_lds per wave/slot
  __shared__ __align__(16) bft As[4][BM*32];
  __shared__ __align__(16) bft Bs[4][BN*32];
  const int tid = threadIdx.x;
  const int z = blockIdx.z;
  A += (size_t)z * sA;
  B += (size_t)z * sB;
  const size_t m0 = (size_t)blockIdx.y * BM, n0 = (size_t)blockIdx.x * BN;
  const int wv = tid >> 6, lane = tid & 63;
  const int wm = (wv & 1) * (BM/2), wn = (wv >> 1) * (BN/2);
  const int fr = lane & 15;
  const int fsw = ((lane >> 4) ^ ((fr >> 1) & 3)) * 8;   // swizzled frag col

  f32x4 acc[AM][AN];
  #pragma unroll
  for (int i=0;i<AM;i++)
    #pragma unroll
    for (int j=0;j<AN;j++) acc[i][j] = (f32x4){0.f,0.f,0.f,0.f};

  const bft* Ab = A + m0*lda;
  const bft* Bb = B + n0*ldb;
  const int NS = K >> 5;

  // prologue: slots 0 and 1
  stage<BM>(Ab,      lda, As[0], tid);
  stage<BN>(Bb,      ldb, Bs[0], tid);
  stage<BM>(Ab + 32, lda, As[1], tid);
  stage<BN>(Bb + 32, ldb, Bs[1], tid);

  auto compute = [&](int s){
    const bft* Ap = As[s & 3];
    const bft* Bp = Bs[s & 3];
    bf16x8 af[AM], bfv[AN];
    #pragma unroll
    for (int mi=0; mi<AM; mi++)
      af[mi] = *(const bf16x8*)(Ap + (size_t)(wm + mi*16 + fr)*32 + fsw);
    #pragma unroll
    for (int ni=0; ni<AN; ni++)
      bfv[ni] = *(const bf16x8*)(Bp + (size_t)(wn + ni*16 + fr)*32 + fsw);
    __builtin_amdgcn_s_setprio(1);
    #pragma unroll
    for (int mi=0; mi<AM; mi++)
      #pragma unroll
      for (int ni=0; ni<AN; ni++)
        acc[mi][ni] = __builtin_amdgcn_mfma_f32_16x16x32_bf16(af[mi], bfv[ni], acc[mi][ni], 0, 0, 0);
    __builtin_amdgcn_s_setprio(0);
  };

  for (int s = 0; s < NS - 2; ++s) {
    const int kt = (s + 2) * 32;
    stage<BM>(Ab + kt, lda, As[(s+2)&3], tid);
    stage<BN>(Bb + kt, ldb, Bs[(s+2)&3], tid);
    waitcnt_vm<2*LPS>();
    __builtin_amdgcn_s_barrier();
    asm volatile("" ::: "memory");
    compute(s);
  }
  waitcnt_vm<LPS>();
  __builtin_amdgcn_s_barrier();
  asm volatile("" ::: "memory");
  compute(NS - 2);
  waitcnt_vm<0>();
  __builtin_amdgcn_s_barrier();
  asm volatile("" ::: "memory");
  compute(NS - 1);

  const int er = (lane >> 4) * 4;   // C/D: row=(lane>>4)*4+reg, col=lane&15
  const int ec = lane & 15;
  #pragma unroll
  for (int mi=0; mi<AM; mi++){
    #pragma unroll
    for (int ni=0; ni<AN; ni++){
      #pragma unroll
      for (int r=0; r<4; r++){
        size_t row = m0 + wm + mi*16 + er + r;
        size_t col = n0 + wn + ni*16 + ec;
        size_t idx = (size_t)z*sC + row*ldc + col;
        float v = acc[mi][ni][r];
        if constexpr (EPI == 0){
          ((bft*)Cv)[idx] = (bft)v;
        } else if constexpr (EPI == 1){
          ((float*)Cv)[idx] = v;
        } else {
          float nv = ((float*)Cv)[idx] + v;
          ((float*)Cv)[idx] = nv;
          Cd[idx] = (bft)nv;
          if (Ct) Ct[(size_t)z*FD*FD + col*FD + row] = (bft)nv;
        }
      }
    }
  }
}

template<int BM,int BN,int EPI>
static inline void mgemm(hipStream_t st, const bft* A, const bft* B, void* C,
    bft* Cd, bft* Ct, int M, int N, int K, long lda, long ldb, long ldc,
    int batch, long sA, long sB, long sC)
{
  dim3 g(N/BN, M/BM, batch);
  mgemm_k<BM,BN,EPI><<<g, 256, 0, st>>>(A, B, C, Cd, Ct, K, lda, ldb, ldc, sA, sB, sC);
}

// ---------------------------------------------------------------------------
// 256x256 MFMA NT GEMM, same 4-slot pipeline, 512 threads = 8 waves (2Mx4N),
// per-wave 128x64 output. LDS = 128 KiB. XCD-aware bijective block swizzle.
// ---------------------------------------------------------------------------
__device__ __forceinline__ void stage8(const bft* __restrict__ src, long ld,
                                       bft* dst, int tid)
{
  const int lane = tid & 63, wv = tid >> 6;      // 8 waves
  #pragma unroll
  for (int i = 0; i < 2; ++i) {
    const int r0 = wv*16 + i*128;                // wave-uniform
    const int row = r0 + (lane >> 2);
    const int g = (lane & 3) ^ ((row >> 1) & 3);
    const bft* gp = src + (size_t)row*ld + g*8;
    bft* lp = dst + (size_t)r0*32;
    __builtin_amdgcn_global_load_lds(
        (const __attribute__((address_space(1))) void*)gp,
        (__attribute__((address_space(3))) void*)lp, 16, 0, 0);
  }
}

template<int EPI>
__global__ __launch_bounds__(512, 2) void mgemm8_k(
    const bft* __restrict__ A, const bft* __restrict__ B, void* __restrict__ Cv,
    int K, long lda, long ldb, long ldc)
{
  __shared__ __align__(16) bft As[4][256*32];
  __shared__ __align__(16) bft Bs[4][256*32];
  const int tid = threadIdx.x;

  // XCD-aware bijective swizzle (nwg % 8 == 0 for both call sites)
  const int gx = (int)gridDim.x;
  const int nwg = (int)(gridDim.x * gridDim.y);
  int lin = (int)(blockIdx.y * gridDim.x + blockIdx.x);
  if ((nwg & 7) == 0) lin = (lin & 7) * (nwg >> 3) + (lin >> 3);
  const size_t m0 = (size_t)(lin / gx) * 256;
  const size_t n0 = (size_t)(lin % gx) * 256;

  const int wv = tid >> 6, lane = tid & 63;
  const int wm = (wv & 1) * 128, wn = (wv >> 1) * 64;
  const int fr = lane & 15;
  const int fsw = ((lane >> 4) ^ ((fr >> 1) & 3)) * 8;

  f32x4 acc[8][4];
  #pragma unroll
  for (int i=0;i<8;i++)
    #pragma unroll
    for (int j=0;j<4;j++) acc[i][j] = (f32x4){0.f,0.f,0.f,0.f};

  const bft* Ab = A + m0*lda;
  const bft* Bb = B + n0*ldb;
  const int NS = K >> 5;

  // prologue: slots 0 and 1
  stage8(Ab,      lda, As[0], tid);
  stage8(Bb,      ldb, Bs[0], tid);
  stage8(Ab + 32, lda, As[1], tid);
  stage8(Bb + 32, ldb, Bs[1], tid);

  auto compute = [&](int s){
    const bft* Ap = As[s & 3];
    const bft* Bp = Bs[s & 3];
    bf16x8 af[8], bv[4];
    #pragma unroll
    for (int mi=0; mi<8; mi++)
      af[mi] = *(const bf16x8*)(Ap + (size_t)(wm + mi*16 + fr)*32 + fsw);
    #pragma unroll
    for (int ni=0; ni<4; ni++)
      bv[ni] = *(const bf16x8*)(Bp + (size_t)(wn + ni*16 + fr)*32 + fsw);
    __builtin_amdgcn_s_setprio(1);
    #pragma unroll
    for (int mi=0; mi<8; mi++)
      #pragma unroll
      for (int ni=0; ni<4; ni++)
        acc[mi][ni] = __builtin_amdgcn_mfma_f32_16x16x32_bf16(af[mi], bv[ni], acc[mi][ni], 0, 0, 0);
    __builtin_amdgcn_s_setprio(0);
  };

  for (int s = 0; s < NS - 2; ++s) {
    const int kt = (s + 2) * 32;
    stage8(Ab + kt, lda, As[(s+2)&3], tid);
    stage8(Bb + kt, ldb, Bs[(s+2)&3], tid);
    asm volatile("s_waitcnt vmcnt(8)" ::: "memory");
    __builtin_amdgcn_s_barrier();
    asm volatile("" ::: "memory");
    compute(s);
  }
  asm volatile("s_waitcnt vmcnt(4)" ::: "memory");
  __builtin_amdgcn_s_barrier();
  asm volatile("" ::: "memory");
  compute(NS - 2);
  asm volatile("s_waitcnt vmcnt(0)" ::: "memory");
  __builtin_amdgcn_s_barrier();
  asm volatile("" ::: "memory");
  compute(NS - 1);

  const int er = (lane >> 4) * 4;
  const int ec = lane & 15;
  #pragma unroll
  for (int mi=0; mi<8; mi++){
    #pragma unroll
    for (int ni=0; ni<4; ni++){
      #pragma unroll
      for (int r=0; r<4; r++){
        size_t row = m0 + wm + mi*16 + er + r;
        size_t col = n0 + wn + ni*16 + ec;
        size_t idx = row*ldc + col;
        float v = acc[mi][ni][r];
        if constexpr (EPI == 0) ((bft*)Cv)[idx] = (bft)v;
        else                    ((float*)Cv)[idx] = v;
      }
    }
  }
}

template<int EPI>
static inline void mgemm8(hipStream_t st, const bft* A, const bft* B, void* C,
                          int M, int N, int K, long lda, long ldb, long ldc)
{
  dim3 g(N/256, M/256, 1);
  mgemm8_k<EPI><<<g, 512, 0, st>>>(A, B, C, K, lda, ldb, ldc);
}

// ---------------------------------------------------------------------------
// fp32 -> bf16 bulk convert (8 elems/thread); n must divide 2048.
// ---------------------------------------------------------------------------
__global__ __launch_bounds__(256) void cvt_k(const float* __restrict__ s,
    bft* __restrict__ d)
{
  size_t i = ((size_t)blockIdx.x*256 + threadIdx.x) * 8;
  const float4 v0 = *(const float4*)(s + i);
  const float4 v1 = *(const float4*)(s + i + 4);
  bf16x8 b;
  b[0]=(bft)v0.x; b[1]=(bft)v0.y; b[2]=(bft)v0.z; b[3]=(bft)v0.w;
  b[4]=(bft)v1.x; b[5]=(bft)v1.y; b[6]=(bft)v1.z; b[7]=(bft)v1.w;
  *(bf16x8*)(d + i) = b;
}

// ---------------------------------------------------------------------------
// Batched bf16 transpose: out[z][c][r] = in[z][r][c], R=2048, C=512.
// ---------------------------------------------------------------------------
__global__ __launch_bounds__(256) void tr_k(const bft* __restrict__ in,
    bft* __restrict__ out, long ldin, long sIn, long sOut)
{
  __shared__ __align__(16) bft t[64][72];
  const int c0 = blockIdx.x*64, r0 = blockIdx.y*64;
  in  += (size_t)blockIdx.z * sIn;
  out += (size_t)blockIdx.z * sOut;
  const int tid = threadIdx.x;
  #pragma unroll
  for (int i=0;i<2;i++){
    int e = tid + i*256;
    int r = e >> 3, c8 = (e & 7) * 8;
    *(bf16x8*)&t[r][c8] = *(const bf16x8*)(in + (size_t)(r0+r)*ldin + c0 + c8);
  }
  __syncthreads();
  #pragma unroll
  for (int i=0;i<2;i++){
    int e = tid + i*256;
    int c = e >> 3, r8 = (e & 7) * 8;
    bf16x8 v;
    #pragma unroll
    for (int j=0;j<8;j++) v[j] = t[r8+j][c];
    *(bf16x8*)(out + (size_t)(c0+c)*CHUNK_LEN + r0 + r8) = v;
  }
}

// initial w1^T bf16 shadow: w1tb[z][h][o] = (bf16)w1[z][o][h]
__global__ __launch_bounds__(256) void tcw1_k(const float* __restrict__ w1,
    bft* __restrict__ w1tb)
{
  size_t idx = (size_t)blockIdx.x*256 + threadIdx.x;
  int z = (int)(idx >> 18);
  int h = (int)((idx >> 9) & 511);
  int o = (int)(idx & 511);
  w1tb[idx] = (bft)w1[(size_t)z*FD*FD + (size_t)o*FD + h];
}

// ---------------------------------------------------------------------------
// v^T for attention PV: vT[h][d][s] = v[s][h*128+d] (raw v region of qkv).
// ---------------------------------------------------------------------------
__global__ __launch_bounds__(256) void vt_k(const bf16* __restrict__ qkv,
    bft* __restrict__ vT)
{
  __shared__ __align__(16) bft t[64*QKP];   // [s][d]
  const int s0 = blockIdx.x * 64;
  const int h  = blockIdx.y;
  const int tid = threadIdx.x;
  #pragma unroll
  for (int i=0;i<4;i++){
    int e = tid + i*256;
    int rr = e >> 4, doff = (e & 15) * 8;
    *(bf16x8*)(t + rr*QKP + doff) =
        *(const bf16x8*)((const bft*)qkv + (size_t)(s0+rr)*QKV3 + 2*HID + h*HD + doff);
  }
  __syncthreads();
  #pragma unroll
  for (int it=0; it<4; it++){
    int d = (tid >> 3) + it*32;
    int so8 = (tid & 7) * 8;
    bf16x8 v;
    #pragma unroll
    for (int j=0;j<8;j++) v[j] = t[(so8+j)*QKP + d];
    *(bf16x8*)(vT + ((size_t)(h*HD + d))*S_LEN + s0 + so8) = v;
  }
}

// ---------------------------------------------------------------------------
// RoPE cos/sin tables
// ---------------------------------------------------------------------------
__global__ void rope_k(float* __restrict__ rc, float* __restrict__ rs){
  int pos = blockIdx.x, d = threadIdx.x;
  float inv = 1.f / powf(500000.0f, (float)d * (1.0f/64.0f));
  float ang = (float)pos * inv;
  rc[pos*64+d] = cosf(ang);
  rs[pos*64+d] = sinf(ang);
}

// ---------------------------------------------------------------------------
// per-token learning rates
// ---------------------------------------------------------------------------
__global__ __launch_bounds__(256) void lr_k(const float* __restrict__ hidden,
    const float* __restrict__ lr_w, const float* __restrict__ lr_b,
    float* __restrict__ lro)
{
  __shared__ float hrow[HID];
  __shared__ float red[4][12];
  int s = blockIdx.x, tid = threadIdx.x;
  for(int i=0;i<HID/256;i++) hrow[tid+256*i] = hidden[(size_t)s*HID + tid + 256*i];
  __syncthreads();
  float part[12];
  #pragma unroll
  for(int o=0;o<12;o++) part[o]=0.f;
  for(int i=0;i<HID/256;i++){
    int j = tid + 256*i;
    float h = hrow[j];
    #pragma unroll
    for(int o=0;o<12;o++) part[o] += h * lr_w[o*HID + j];
  }
  int lane = tid & 63, w = tid >> 6;
  #pragma unroll
  for(int o=0;o<12;o++){
    float v = wave_sum(part[o]);
    if(lane==0) red[w][o] = v;
  }
  __syncthreads();
  if(tid < 12){
    float v = red[0][tid]+red[1][tid]+red[2][tid]+red[3][tid] + lr_b[tid] + BASE_LR_INV;
    float sp = (v > 20.f) ? v : log1pf(expf(v));
    lro[s*12 + tid] = sp;
  }
}

// ---------------------------------------------------------------------------
// E2a: per-token rmsnorm(q), rmsnorm(k), in place in qkv (bf16).
// ---------------------------------------------------------------------------
__global__ __launch_bounds__(256) void e2a_k(
    bf16* __restrict__ qkv,
    const float* __restrict__ qnw, const float* __restrict__ knw)
{
  __shared__ float red[8];
  int s = blockIdx.x, tid = threadIdx.x;
  int lane = tid & 63, w = tid >> 6;
  float qv[8], kv[8];
  float sq = 0.f, sk = 0.f;
  size_t base = (size_t)s*QKV3;
  #pragma unroll
  for(int i=0;i<8;i++){
    int j = tid*8 + i;
    qv[i] = bf2f(qkv[base + j]);
    kv[i] = bf2f(qkv[base + HID + j]);
    sq += qv[i]*qv[i]; sk += kv[i]*kv[i];
  }
  sq = wave_sum(sq); sk = wave_sum(sk);
  if(lane==0){ red[w] = sq; red[4+w] = sk; }
  __syncthreads();
  float rq = rsqrtf((red[0]+red[1]+red[2]+red[3])*(1.f/HID) + 1e-6f);
  float rk = rsqrtf((red[4]+red[5]+red[6]+red[7])*(1.f/HID) + 1e-6f);
  #pragma unroll
  for(int i=0;i<8;i++){
    int j = tid*8 + i;
    qkv[base + j]       = f2bf(qv[i]*rq*qnw[j]);
    qkv[base + HID + j] = f2bf(kv[i]*rk*knw[j]);
  }
}

// ---------------------------------------------------------------------------
// E2b (after attention): overwrite q/k/v regions with fq/fk/fv.
// ---------------------------------------------------------------------------
__global__ __launch_bounds__(256) void e2b_k(
    bf16* __restrict__ qkv,
    const float* __restrict__ qks, const float* __restrict__ qko)
{
  int s = blockIdx.x, tid = threadIdx.x;
  size_t base = (size_t)s*QKV3;
  float a[8], b[8], vv[8];
  float ga = 0.f, gb2 = 0.f;
  #pragma unroll
  for(int i=0;i<8;i++){
    int j = tid*8 + i;
    float qn = bf2f(qkv[base + j]);
    float kn = bf2f(qkv[base + HID + j]);
    float v  = bf2f(qkv[base + 2*HID + j]);
    a[i] = siluf(qn*qks[2*j]   + qko[2*j]);
    b[i] = siluf(kn*qks[2*j+1] + qko[2*j+1]);
    vv[i] = siluf(v);
    ga += a[i]*a[i]; gb2 += b[i]*b[i];
  }
  ga = wave_sum(ga); gb2 = wave_sum(gb2);
  float iq = 1.f / fmaxf(sqrtf(ga), 1e-12f);
  float ik = 1.f / fmaxf(sqrtf(gb2), 1e-12f);
  #pragma unroll
  for(int i=0;i<8;i++){
    int j = tid*8 + i;
    qkv[base + j]         = f2bf(a[i]*iq);
    qkv[base + HID + j]   = f2bf(b[i]*ik);
    qkv[base + 2*HID + j] = f2bf(vv[i]);
  }
}

// ---------------------------------------------------------------------------
// MFMA sliding-window attention (window 256 incl self).
// ---------------------------------------------------------------------------
__global__ __launch_bounds__(256) void attn_k(
    const bf16* __restrict__ qkv, const bft* __restrict__ vT,
    const float* __restrict__ rc, const float* __restrict__ rs,
    float* __restrict__ attn)
{
  __shared__ __align__(16) bft Qs[64*QKP];
  __shared__ __align__(16) bft Ks[64*QKP];
  __shared__ __align__(16) bft Vs[128*VSP];
  __shared__ __align__(16) bft Ps[64*PSP];
  const int head = blockIdx.x >> 7;
  const int Q0 = (blockIdx.x & 127) * 64;
  const int tid = threadIdx.x;
  const int hb = head * HD;
  const int lane = tid & 63;
  const int wm = (tid >> 6) * 16;
  const int fr = lane & 15, fko = (lane >> 4) * 8;
  const int rbase = (lane >> 4) * 4;

  #pragma unroll
  for(int i=0;i<16;i++){
    int e = tid + i*256;
    int rr = e >> 6, d = e & 63;
    int qpos = Q0 + rr;
    size_t b = (size_t)qpos*QKV3 + hb;
    float x1 = bf2f(qkv[b + d]);
    float x2 = bf2f(qkv[b + d + 64]);
    float c = rc[qpos*64 + d], sn = rs[qpos*64 + d];
    Qs[rr*QKP + d]      = (bft)(x1*c - x2*sn);
    Qs[rr*QKP + d + 64] = (bft)(x2*c + x1*sn);
  }
  __syncthreads();
  bf16x8 qf[4];
  #pragma unroll
  for (int kk=0;kk<4;kk++)
    qf[kk] = *(const bf16x8*)(Qs + (wm+fr)*QKP + kk*32 + fko);

  f32x4 Ot[8];
  #pragma unroll
  for (int i=0;i<8;i++) Ot[i] = (f32x4){0.f,0.f,0.f,0.f};
  float m4[4], l4[4];
  #pragma unroll
  for (int r=0;r<4;r++){ m4[r] = -INFINITY; l4[r] = 0.f; }

  for (int kt=0; kt<5; kt++){
    const int kb = Q0 - 256 + kt*64;
    if (kb < 0) continue;
    __syncthreads();
    #pragma unroll
    for(int i=0;i<16;i++){
      int e = tid + i*256;
      int rr = e >> 6, d = e & 63;
      int kpos = kb + rr;
      size_t b = (size_t)kpos*QKV3 + HID + hb;
      float x1 = bf2f(qkv[b + d]);
      float x2 = bf2f(qkv[b + d + 64]);
      float c = rc[kpos*64 + d], sn = rs[kpos*64 + d];
      Ks[rr*QKP + d]      = (bft)(x1*c - x2*sn);
      Ks[rr*QKP + d + 64] = (bft)(x2*c + x1*sn);
    }
    {
      int d = tid >> 1, koff = (tid & 1) * 32;
      const bft* vrow = vT + ((size_t)(hb + d))*S_LEN + kb + koff;
      bft* lrow = Vs + d*VSP + koff;
      #pragma unroll
      for (int j8=0;j8<4;j8++)
        *(bf16x8*)(lrow + j8*8) = *(const bf16x8*)(vrow + j8*8);
    }
    __syncthreads();

    f32x4 st[4];
    #pragma unroll
    for (int nt=0;nt<4;nt++){
      f32x4 acc = (f32x4){0.f,0.f,0.f,0.f};
      #pragma unroll
      for (int kk=0;kk<4;kk++){
        bf16x8 kf = *(const bf16x8*)(Ks + (nt*16+fr)*QKP + kk*32 + fko);
        acc = __builtin_amdgcn_mfma_f32_16x16x32_bf16(qf[kk], kf, acc, 0, 0, 0);
      }
      st[nt] = acc;
    }

    float pv[4][4];
    #pragma unroll
    for (int r=0;r<4;r++){
      int qpos = Q0 + wm + rbase + r;
      float sm[4];
      float mx = -INFINITY;
      #pragma unroll
      for (int nt=0;nt<4;nt++){
        int kpos = kb + nt*16 + fr;
        bool valid = (kpos > qpos - 256) && (kpos <= qpos);
        float s = valid ? st[nt][r] * 0.088388347648318447f : -INFINITY;
        sm[nt] = s;
        mx = fmaxf(mx, s);
      }
      mx = fmaxf(mx, __shfl_xor(mx, 1, 64));
      mx = fmaxf(mx, __shfl_xor(mx, 2, 64));
      mx = fmaxf(mx, __shfl_xor(mx, 4, 64));
      mx = fmaxf(mx, __shfl_xor(mx, 8, 64));
      float mnew = fmaxf(m4[r], mx);
      float alpha = (mnew == -INFINITY) ? 1.f : __expf(m4[r] - mnew);
      float ps = 0.f;
      #pragma unroll
      for (int nt=0;nt<4;nt++){
        float p = (sm[nt] == -INFINITY) ? 0.f : __expf(sm[nt] - mnew);
        pv[nt][r] = p;
        ps += p;
      }
      ps += __shfl_xor(ps, 1, 64);
      ps += __shfl_xor(ps, 2, 64);
      ps += __shfl_xor(ps, 4, 64);
      ps += __shfl_xor(ps, 8, 64);
      l4[r] = l4[r]*alpha + ps;
      m4[r] = mnew;
      #pragma unroll
      for (int ct=0;ct<8;ct++) Ot[ct][r] *= alpha;
    }

    #pragma unroll
    for (int r=0;r<4;r++){
      int row = wm + rbase + r;
      #pragma unroll
      for (int nt=0;nt<4;nt++)
        Ps[row*PSP + nt*16 + fr] = (bft)pv[nt][r];
    }
    bf16x8 af[2];
    #pragma unroll
    for (int kk=0;kk<2;kk++){
      const bft* pp = Ps + (wm+fr)*PSP + kk*32 + fko;
      bf16x4 lo = *(const bf16x4*)pp;
      bf16x4 hi = *(const bf16x4*)(pp+4);
      bf16x8 a;
      #pragma unroll
      for (int j=0;j<4;j++){ a[j]=lo[j]; a[j+4]=hi[j]; }
      af[kk]=a;
    }
    #pragma unroll
    for (int ct=0;ct<8;ct++)
      #pragma unroll
      for (int kk=0;kk<2;kk++){
        bf16x8 bv = *(const bf16x8*)(Vs + (ct*16+fr)*VSP + kk*32 + fko);
        Ot[ct] = __builtin_amdgcn_mfma_f32_16x16x32_bf16(af[kk], bv, Ot[ct], 0, 0, 0);
      }
  }

  #pragma unroll
  for (int r=0;r<4;r++){
    float invl = 1.f / l4[r];
    int qpos = Q0 + wm + rbase + r;
    size_t ob = (size_t)qpos*HID + hb;
    #pragma unroll
    for (int ct=0;ct<8;ct++)
      attn[ob + ct*16 + fr] = Ot[ct][r] * invl;
  }
}

// ---------------------------------------------------------------------------
// TTT elementwise fwd: hid = silu(g)*hm ; opre = silu(qg)*qm (opre -> qg buf)
// ---------------------------------------------------------------------------
__global__ __launch_bounds__(256) void e3_k(
    const bf16* __restrict__ g, const bf16* __restrict__ hm,
    bf16* __restrict__ qg, const bf16* __restrict__ qm,
    bf16* __restrict__ hid)
{
  size_t idx = (size_t)blockIdx.x*256 + threadIdx.x;
  float opre = siluf(bf2f(qg[idx])) * bf2f(qm[idx]);
  hid[idx] = f2bf(siluf(bf2f(g[idx])) * bf2f(hm[idx]));
  qg[idx]  = f2bf(opre);
}

// ---------------------------------------------------------------------------
// TTT backprop elementwise (in place): a0->g, a2->hm, a1->dhid buffer.
// ---------------------------------------------------------------------------
__global__ __launch_bounds__(256) void e4_k(
    bf16* __restrict__ g, bf16* __restrict__ hm, bf16* __restrict__ dhid,
    const bf16* __restrict__ qkv, const float* __restrict__ lrb, int cbase)
{
  size_t idx = (size_t)blockIdx.x*256 + threadIdx.x;
  int h  = (int)(idx >> 20);
  int ci = (int)((idx >> 9) & 2047);
  int d  = (int)(idx & 511);
  int s  = cbase + ci;
  float l0  = lrb[s*12 + h];
  float l1  = lrb[s*12 + 4 + h];
  float l2v = lrb[s*12 + 8 + h];
  float gg = bf2f(g[idx]), hv = bf2f(hm[idx]), dh = bf2f(dhid[idx]);
  float sg = sigm(gg);
  float silu_g = gg * sg;
  float dhm = dh * silu_g;
  float dg  = dh * hv;
  float dgp = dg * (sg * (1.f + gg * (1.f - sg)));
  float fvv = bf2f(qkv[(size_t)s*QKV3 + 2*HID + h*FD + d]);
  g[idx]    = f2bf(dgp * l0);
  hm[idx]   = f2bf(dhm * l2v);
  dhid[idx] = f2bf(fvv * l1);
}

// ---------------------------------------------------------------------------
// E5 (per chunk): X = attn + rmsnorm(ofc)*ttt_norm_w -> q region of qkv
// ---------------------------------------------------------------------------
__global__ __launch_bounds__(256) void e5_k(const float* __restrict__ attn,
    const bf16* __restrict__ ofc, const float* __restrict__ tnw,
    bf16* __restrict__ qkv, int cbase)
{
  int ci = blockIdx.x, tid = threadIdx.x;
  int s = cbase + ci;
  int lane = tid & 63, w = tid >> 6;
  float o[8]; float ss = 0.f;
  size_t ob = ((size_t)w*CHUNK_LEN + ci)*FD + (size_t)lane*8;
  #pragma unroll
  for(int i=0;i<8;i++){ o[i] = bf2f(ofc[ob+i]); ss += o[i]*o[i]; }
  ss = wave_sum(ss);
  float inv = rsqrtf(ss*(1.f/FD) + 1e-6f);
  size_t xb = (size_t)s*QKV3 + w*FD + (size_t)lane*8;
  size_t ab = (size_t)s*HID  + w*FD + (size_t)lane*8;
  #pragma unroll
  for(int i=0;i<8;i++){
    int d = lane*8 + i;
    qkv[xb+i] = f2bf(attn[ab+i] + o[i]*inv*tnw[d]);
  }
}

// ---------------------------------------------------------------------------
extern "C" void kernel_launch(void* const* d_in, const int* in_sizes, int n_in,
                              void* d_out, int out_size, void* d_ws, size_t ws_size,
                              hipStream_t stream)
{
  (void)in_sizes; (void)n_in; (void)out_size;
  const float* hidden   = (const float*)d_in[0];
  const float* qkv_w    = (const float*)d_in[1];
  const float* q_norm_w = (const float*)d_in[2];
  const float* k_norm_w = (const float*)d_in[3];
  const float* qk_scale = (const float*)d_in[4];
  const float* qk_off   = (const float*)d_in[5];
  const float* lr_w     = (const float*)d_in[6];
  const float* lr_b     = (const float*)d_in[7];
  const float* w0_in    = (const float*)d_in[8];
  const float* w1_in    = (const float*)d_in[9];
  const float* w2_in    = (const float*)d_in[10];
  const float* ttt_nw   = (const float*)d_in[11];
  const float* o_proj   = (const float*)d_in[12];
  float* out = (float*)d_out;

  char* p = (char*)d_ws;
  auto alloc = [&](size_t n){ char* r = p; p += (n + 255) & ~(size_t)255; return (void*)r; };

  bf16*  qkv   = (bf16*) alloc((size_t)S_LEN*QKV3*sizeof(bf16));
  float* lrb   = (float*)alloc((size_t)S_LEN*12*sizeof(float));
  float* rc    = (float*)alloc((size_t)S_LEN*64*sizeof(float));
  float* rs    = (float*)alloc((size_t)S_LEN*64*sizeof(float));
  float* w0s   = (float*)alloc((size_t)NFW*FD*FD*sizeof(float));
  float* w1s   = (float*)alloc((size_t)NFW*FD*FD*sizeof(float));
  float* w2s   = (float*)alloc((size_t)NFW*FD*FD*sizeof(float));
  bft*   w1tb  = (bft*)  alloc((size_t)NFW*FD*FD*sizeof(bft));
  bft*   w0b   = (bft*)  alloc((size_t)NFW*FD*FD*sizeof(bft));
  bft*   w1b   = (bft*)  alloc((size_t)NFW*FD*FD*sizeof(bft));
  bft*   w2b   = (bft*)  alloc((size_t)NFW*FD*FD*sizeof(bft));
  bf16*  gb    = (bf16*) alloc((size_t)NFW*CHUNK_LEN*FD*sizeof(bf16));
  bf16*  hmb   = (bf16*) alloc((size_t)NFW*CHUNK_LEN*FD*sizeof(bf16));
  bf16*  qgb   = (bf16*) alloc((size_t)NFW*CHUNK_LEN*FD*sizeof(bf16));
  bf16*  qmb   = (bf16*) alloc((size_t)NFW*CHUNK_LEN*FD*sizeof(bf16));
  bf16*  hidb  = (bf16*) alloc((size_t)NFW*CHUNK_LEN*FD*sizeof(bf16));
  bf16*  ofc   = (bf16*) alloc((size_t)NFW*CHUNK_LEN*FD*sizeof(bf16));
  bft*   fkT   = (bft*)  alloc((size_t)NFW*FD*CHUNK_LEN*sizeof(bft));
  bft*   hidT  = (bft*)  alloc((size_t)NFW*FD*CHUNK_LEN*sizeof(bft));
  bft*   a2T   = (bft*)  alloc((size_t)NFW*FD*CHUNK_LEN*sizeof(bft));
  bft*   a1T   = (bft*)  alloc((size_t)NFW*FD*CHUNK_LEN*sizeof(bft));

  if ((size_t)(p - (char*)d_ws) > ws_size) return;

  // Liveness aliases (no extra workspace):
  // hidden_bf (33.55 MB) = gb..qmb  — dead before chunk loop writes gb.
  // qkvw_bf   (25.17 MB) = fkT..a2T — dead before vt_k writes vT.
  // vT        (33.55 MB) = fkT..a1T — dead before chunk loop's tr_k.
  // opw_bf    ( 8.39 MB) = hidb..   — converted after last e5, before o_proj.
  bft* hidden_bf = (bft*)gb;
  bft* qkvw_bf   = (bft*)fkT;
  bft* vT        = (bft*)fkT;
  bft* opw_bf    = (bft*)hidb;

  float* attn = out;   // attn lives in d_out until the final projection

  hipMemcpyAsync(w0s, w0_in, (size_t)NFW*FD*FD*sizeof(float), hipMemcpyDeviceToDevice, stream);
  hipMemcpyAsync(w1s, w1_in, (size_t)NFW*FD*FD*sizeof(float), hipMemcpyDeviceToDevice, stream);
  hipMemcpyAsync(w2s, w2_in, (size_t)NFW*FD*FD*sizeof(float), hipMemcpyDeviceToDevice, stream);

  rope_k<<<S_LEN, 64, 0, stream>>>(rc, rs);
  lr_k<<<S_LEN, 256, 0, stream>>>(hidden, lr_w, lr_b, lrb);
  tcw1_k<<<NFW*FD*FD/256, 256, 0, stream>>>(w1_in, w1tb);
  cvt_k<<<(NFW*FD*FD)/2048, 256, 0, stream>>>(w0_in, w0b);
  cvt_k<<<(NFW*FD*FD)/2048, 256, 0, stream>>>(w1_in, w1b);
  cvt_k<<<(NFW*FD*FD)/2048, 256, 0, stream>>>(w2_in, w2b);
  cvt_k<<<(S_LEN*HID)/2048, 256, 0, stream>>>(hidden, hidden_bf);
  cvt_k<<<(QKV3*HID)/2048, 256, 0, stream>>>(qkv_w, qkvw_bf);

  // qkv = hidden @ qkv_w^T -> bf16   (256^2 pipelined GEMM)
  mgemm8<0>(stream, hidden_bf, qkvw_bf, (void*)qkv, S_LEN, QKV3, HID, HID, HID, QKV3);

  e2a_k<<<S_LEN, 256, 0, stream>>>(qkv, q_norm_w, k_norm_w);
  vt_k<<<dim3(S_LEN/64, NH), 256, 0, stream>>>(qkv, vT);
  attn_k<<<NH*128, 256, 0, stream>>>(qkv, vT, rc, rs, attn);
  e2b_k<<<S_LEN, 256, 0, stream>>>(qkv, qk_scale, qk_off);

  const long sW  = (long)FD*FD;
  const long sCh = (long)CHUNK_LEN*FD;
  const long sT  = (long)FD*CHUNK_LEN;
  const int  NEL = NFW*CHUNK_LEN*FD/256;
  const dim3 tg(FD/64, CHUNK_LEN/64, NFW);

  for(int c=0; c<NCHUNK; c++){
    const bft* fqc = (const bft*)qkv + (size_t)c*CHUNK_LEN*QKV3;
    const bft* fkc = fqc + HID;
    const bft* fvc = fqc + 2*HID;
    mgemm<128,128,0>(stream, fkc, w0b, gb,  nullptr, nullptr, CHUNK_LEN, FD, FD, QKV3, FD, FD, NFW, FD, sW, sCh);
    mgemm<128,128,0>(stream, fkc, w2b, hmb, nullptr, nullptr, CHUNK_LEN, FD, FD, QKV3, FD, FD, NFW, FD, sW, sCh);
    mgemm<128,128,0>(stream, fqc, w0b, qgb, nullptr, nullptr, CHUNK_LEN, FD, FD, QKV3, FD, FD, NFW, FD, sW, sCh);
    mgemm<128,128,0>(stream, fqc, w2b, qmb, nullptr, nullptr, CHUNK_LEN, FD, FD, QKV3, FD, FD, NFW, FD, sW, sCh);
    e3_k<<<NEL, 256, 0, stream>>>(gb, hmb, qgb, qmb, hidb);
    mgemm<128,128,0>(stream, (const bft*)qgb, w1b, ofc, nullptr, nullptr, CHUNK_LEN, FD, FD, FD, FD, FD, NFW, sCh, sW, sCh);
    mgemm<128,128,0>(stream, fvc, (const bft*)w1tb, qmb, nullptr, nullptr, CHUNK_LEN, FD, FD, QKV3, FD, FD, NFW, FD, sW, sCh);
    e4_k<<<NEL, 256, 0, stream>>>(gb, hmb, qmb, qkv, lrb, c*CHUNK_LEN);
    tr_k<<<tg, 256, 0, stream>>>(fkc,              fkT,        QKV3, FD,  sT);
    tr_k<<<tg, 256, 0, stream>>>((const bft*)hidb, hidT,       FD,   sCh, sT);
    tr_k<<<tg, 256, 0, stream>>>((const bft*)gb,   (bft*)qgb,  FD,   sCh, sT);
    tr_k<<<tg, 256, 0, stream>>>((const bft*)hmb,  a2T,        FD,   sCh, sT);
    tr_k<<<tg, 256, 0, stream>>>((const bft*)qmb,  a1T,        FD,   sCh, sT);
    mgemm<64,64,2>(stream, (const bft*)qgb, fkT,  w0s, w0b, nullptr, FD, FD, CHUNK_LEN, CHUNK_LEN, CHUNK_LEN, FD, NFW, sT, sT, sW);
    mgemm<64,64,2>(stream, a2T,             fkT,  w2s, w2b, nullptr, FD, FD, CHUNK_LEN, CHUNK_LEN, CHUNK_LEN, FD, NFW, sT, sT, sW);
    mgemm<64,64,2>(stream, a1T,             hidT, w1s, w1b, w1tb,    FD, FD, CHUNK_LEN, CHUNK_LEN, CHUNK_LEN, FD, NFW, sT, sT, sW);
    e5_k<<<CHUNK_LEN, 256, 0, stream>>>(attn, ofc, ttt_nw, qkv, c*CHUNK_LEN);
  }

  // bf16 copy of o_proj (hidb/ofc are dead now), then final projection
  cvt_k<<<(HID*HID)/2048, 256, 0, stream>>>(o_proj, opw_bf);
  mgemm8<1>(stream, (const bft*)qkv, opw_bf, out, S_LEN, HID, HID, QKV3, HID, HID);
}

// Round 3
// 1563.498 us; speedup vs baseline: 1.1465x; 1.0095x over previous
//
#include <hip/hip_runtime.h>
#include <hip/hip_bf16.h>

typedef __hip_bfloat16 bf16;
typedef __bf16 bft;
typedef bft bf16x8 __attribute__((ext_vector_type(8)));
typedef bft bf16x4 __attribute__((ext_vector_type(4)));
typedef float f32x4 __attribute__((ext_vector_type(4)));

#define S_LEN 8192
#define HID   2048
#define QKV3  6144
#define NH    16
#define HD    128
#define NFW   4
#define FD    512
#define CHUNK_LEN 2048
#define NCHUNK 4
#define BASE_LR_INV (-6.9072552f)   // log(expm1(0.001))
#define QKP 136                     // attn Q/K LDS stride (128 + 8)
#define VSP 72                      // attn V^T LDS stride (64 + 8)
#define PSP 76                      // attn P LDS stride (64 + 12)

__device__ __forceinline__ float bf2f(bf16 x){ return __bfloat162float(x); }
__device__ __forceinline__ bf16  f2bf(float x){ return __float2bfloat16(x); }
__device__ __forceinline__ float sigm(float x){ return 1.f/(1.f+__expf(-x)); }
__device__ __forceinline__ float siluf(float x){ return x/(1.f+__expf(-x)); }
__device__ __forceinline__ float wave_sum(float v){
  #pragma unroll
  for(int off=32; off; off>>=1) v += __shfl_xor(v, off, 64);
  return v;
}

template<int N>
__device__ __forceinline__ void waitcnt_vm(){
  static_assert(N==0||N==2||N==4||N==8, "unsupported vmcnt");
  if constexpr (N==0)      asm volatile("s_waitcnt vmcnt(0)" ::: "memory");
  else if constexpr (N==2) asm volatile("s_waitcnt vmcnt(2)" ::: "memory");
  else if constexpr (N==4) asm volatile("s_waitcnt vmcnt(4)" ::: "memory");
  else                     asm volatile("s_waitcnt vmcnt(8)" ::: "memory");
}

__device__ __forceinline__ void phase_edge(){
  __builtin_amdgcn_sched_barrier(0);
  __builtin_amdgcn_s_barrier();
  asm volatile("" ::: "memory");
  __builtin_amdgcn_sched_barrier(0);
}

// ---------------------------------------------------------------------------
// GEMM LDS tile staging (bf16 only), swizzled layout.
// Tile: ROWS x 32 bf16, unpadded [row][32]; physical col-slot c (8 elems)
// holds logical col-group g = c ^ ((row>>1)&3).
// global_load_lds 16B/lane (lane -> row=lane>>2, c=lane&3;
//   LDS dest = wave-uniform base + lane*16 => exactly (row,c) slot).
// 4 waves (256 threads): issues ROWS/64 loads per wave.
// ---------------------------------------------------------------------------
template<int ROWS>
__device__ __forceinline__ void stage(const bft* __restrict__ src, long ld,
                                      bft* dst, int tid)
{
  const int lane = tid & 63, wv = tid >> 6;
  #pragma unroll
  for (int i = 0; i < ROWS/64; ++i) {
    const int r0 = wv*16 + i*64;               // wave-uniform
    const int row = r0 + (lane >> 2);
    const int g = (lane & 3) ^ ((row >> 1) & 3);
    const bft* gp = src + (size_t)row*ld + g*8;
    bft* lp = dst + (size_t)r0*32;
    __builtin_amdgcn_global_load_lds(
        (const __attribute__((address_space(1))) void*)gp,
        (__attribute__((address_space(3))) void*)lp, 16, 0, 0);
  }
}

// ---------------------------------------------------------------------------
// MFMA NT GEMM: C[M,N] (+)= A[M,K] * B[N,K]^T, fp32 accumulate, 256 threads.
// 4-slot circular LDS pipeline (BK=32), counted vmcnt (never drained to 0
// in steady state), phase-split compute (barrier-delimited ds_read/stage/MFMA
// interleave), setprio around MFMA clusters.
// Race-freedom: slot written at iter s is (s+2)&3; concurrent readers touch
// (s-1)&3 and s&3 (distinct mod 4); per-wave program order + barrier counting
// guarantees slot s-2 fully consumed before any wave issues into its buffer.
// vmcnt ladder: steady-state wait leaves exactly slot s+2's LPT loads in
// flight, guaranteeing slot s+1 is landed before its reads begin.
// EPI: 0 = store bf16, 1 = store fp32, 2 = fp32 C += acc, bf16 direct shadow
// Cd, optional transposed bf16 shadow Ct. Batched over blockIdx.z.
// ---------------------------------------------------------------------------
template<int BM,int BN,int EPI>
__global__ __launch_bounds__(256) void mgemm_k(
    const bft* __restrict__ A, const bft* __restrict__ B, void* __restrict__ Cv,
    bft* __restrict__ Cd, bft* __restrict__ Ct, int K,
    long lda, long ldb, long ldc, long sA, long sB, long sC)
{
  constexpr int AM = BM/32, AN = BN/32;
  constexpr int LPT = BM/64 + BN/64;           // global_load_lds per wave/slot
  constexpr int NPH = (AM >= 4) ? 2 : 1;       // compute phases per slot
  constexpr int MH  = AM / NPH;                // mi rows per phase
  __shared__ __align__(16) bft As[4][BM*32];
  __shared__ __align__(16) bft Bs[4][BN*32];
  const int tid = threadIdx.x;
  const int z = blockIdx.z;
  A += (size_t)z * sA;
  B += (size_t)z * sB;
  const size_t m0 = (size_t)blockIdx.y * BM, n0 = (size_t)blockIdx.x * BN;
  const int wv = tid >> 6, lane = tid & 63;
  const int wm = (wv & 1) * (BM/2), wn = (wv >> 1) * (BN/2);
  const int fr = lane & 15;
  const int fsw = ((lane >> 4) ^ ((fr >> 1) & 3)) * 8;   // swizzled frag col

  f32x4 acc[AM][AN];
  #pragma unroll
  for (int i=0;i<AM;i++)
    #pragma unroll
    for (int j=0;j<AN;j++) acc[i][j] = (f32x4){0.f,0.f,0.f,0.f};

  const bft* Ab = A + m0*lda;
  const bft* Bb = B + n0*ldb;
  const int NS = K >> 5;

  // prologue: slots 0 and 1; then guarantee slot 0 landed.
  stage<BM>(Ab,      lda, As[0], tid);
  stage<BN>(Bb,      ldb, Bs[0], tid);
  stage<BM>(Ab + 32, lda, As[1], tid);
  stage<BN>(Bb + 32, ldb, Bs[1], tid);
  waitcnt_vm<LPT>();
  __builtin_amdgcn_s_barrier();
  asm volatile("" ::: "memory");

  for (int s = 0; s < NS; ++s) {
    const bft* Ap = As[s & 3];
    const bft* Bp = Bs[s & 3];
    const int kt = (s + 2) * 32;
    const bool st = (s + 2 < NS);

    bf16x8 bvv[AN], afv[MH];
    // ---- phase 0: all B-frags + first mi half; stage next A-tile ----
    #pragma unroll
    for (int ni=0; ni<AN; ni++)
      bvv[ni] = *(const bf16x8*)(Bp + (size_t)(wn + ni*16 + fr)*32 + fsw);
    #pragma unroll
    for (int i=0; i<MH; i++)
      afv[i] = *(const bf16x8*)(Ap + (size_t)(wm + i*16 + fr)*32 + fsw);
    if (st) stage<BM>(Ab + kt, lda, As[(s+2)&3], tid);
    if constexpr (NPH == 1) {
      if (st) { stage<BN>(Bb + kt, ldb, Bs[(s+2)&3], tid); waitcnt_vm<LPT>(); }
      else waitcnt_vm<0>();
    }
    phase_edge();
    __builtin_amdgcn_s_setprio(1);
    #pragma unroll
    for (int i=0; i<MH; i++)
      #pragma unroll
      for (int ni=0; ni<AN; ni++)
        acc[i][ni] = __builtin_amdgcn_mfma_f32_16x16x32_bf16(afv[i], bvv[ni], acc[i][ni], 0, 0, 0);
    __builtin_amdgcn_s_setprio(0);

    if constexpr (NPH == 2) {
      // ---- phase 1: second mi half; stage next B-tile; vm ladder ----
      #pragma unroll
      for (int i=0; i<MH; i++)
        afv[i] = *(const bf16x8*)(Ap + (size_t)(wm + (MH+i)*16 + fr)*32 + fsw);
      if (st) { stage<BN>(Bb + kt, ldb, Bs[(s+2)&3], tid); waitcnt_vm<LPT>(); }
      else waitcnt_vm<0>();
      phase_edge();
      __builtin_amdgcn_s_setprio(1);
      #pragma unroll
      for (int i=0; i<MH; i++)
        #pragma unroll
        for (int ni=0; ni<AN; ni++)
          acc[MH+i][ni] = __builtin_amdgcn_mfma_f32_16x16x32_bf16(afv[i], bvv[ni], acc[MH+i][ni], 0, 0, 0);
      __builtin_amdgcn_s_setprio(0);
    }
  }

  const int er = (lane >> 4) * 4;   // C/D: row=(lane>>4)*4+reg, col=lane&15
  const int ec = lane & 15;
  #pragma unroll
  for (int mi=0; mi<AM; mi++){
    #pragma unroll
    for (int ni=0; ni<AN; ni++){
      #pragma unroll
      for (int r=0; r<4; r++){
        size_t row = m0 + wm + mi*16 + er + r;
        size_t col = n0 + wn + ni*16 + ec;
        size_t idx = (size_t)z*sC + row*ldc + col;
        float v = acc[mi][ni][r];
        if constexpr (EPI == 0){
          ((bft*)Cv)[idx] = (bft)v;
        } else if constexpr (EPI == 1){
          ((float*)Cv)[idx] = v;
        } else {
          float nv = ((float*)Cv)[idx] + v;
          ((float*)Cv)[idx] = nv;
          Cd[idx] = (bft)nv;
          if (Ct) Ct[(size_t)z*FD*FD + col*FD + row] = (bft)nv;
        }
      }
    }
  }
}

template<int BM,int BN,int EPI>
static inline void mgemm(hipStream_t st, const bft* A, const bft* B, void* C,
    bft* Cd, bft* Ct, int M, int N, int K, long lda, long ldb, long ldc,
    int batch, long sA, long sB, long sC)
{
  dim3 g(N/BN, M/BM, batch);
  mgemm_k<BM,BN,EPI><<<g, 256, 0, st>>>(A, B, C, Cd, Ct, K, lda, ldb, ldc, sA, sB, sC);
}

// ---------------------------------------------------------------------------
// 256x256 MFMA NT GEMM, 4-slot pipeline, 512 threads = 8 waves (2Mx4N),
// per-wave 128x64 output, 4-phase compute interleave. LDS = 128 KiB.
// XCD-aware bijective block swizzle.
// ---------------------------------------------------------------------------
__device__ __forceinline__ void stage8(const bft* __restrict__ src, long ld,
                                       bft* dst, int tid)
{
  const int lane = tid & 63, wv = tid >> 6;      // 8 waves
  #pragma unroll
  for (int i = 0; i < 2; ++i) {
    const int r0 = wv*16 + i*128;                // wave-uniform
    const int row = r0 + (lane >> 2);
    const int g = (lane & 3) ^ ((row >> 1) & 3);
    const bft* gp = src + (size_t)row*ld + g*8;
    bft* lp = dst + (size_t)r0*32;
    __builtin_amdgcn_global_load_lds(
        (const __attribute__((address_space(1))) void*)gp,
        (__attribute__((address_space(3))) void*)lp, 16, 0, 0);
  }
}

#define M8_ROW(mi, a) { \
    acc[mi][0]=__builtin_amdgcn_mfma_f32_16x16x32_bf16(a,bv[0],acc[mi][0],0,0,0); \
    acc[mi][1]=__builtin_amdgcn_mfma_f32_16x16x32_bf16(a,bv[1],acc[mi][1],0,0,0); \
    acc[mi][2]=__builtin_amdgcn_mfma_f32_16x16x32_bf16(a,bv[2],acc[mi][2],0,0,0); \
    acc[mi][3]=__builtin_amdgcn_mfma_f32_16x16x32_bf16(a,bv[3],acc[mi][3],0,0,0); }

template<int EPI>
__global__ __launch_bounds__(512, 2) void mgemm8_k(
    const bft* __restrict__ A, const bft* __restrict__ B, void* __restrict__ Cv,
    int K, long lda, long ldb, long ldc)
{
  __shared__ __align__(16) bft As[4][256*32];
  __shared__ __align__(16) bft Bs[4][256*32];
  const int tid = threadIdx.x;

  // XCD-aware bijective swizzle (nwg % 8 == 0 for both call sites)
  const int gx = (int)gridDim.x;
  const int nwg = (int)(gridDim.x * gridDim.y);
  int lin = (int)(blockIdx.y * gridDim.x + blockIdx.x);
  if ((nwg & 7) == 0) lin = (lin & 7) * (nwg >> 3) + (lin >> 3);
  const size_t m0 = (size_t)(lin / gx) * 256;
  const size_t n0 = (size_t)(lin % gx) * 256;

  const int wv = tid >> 6, lane = tid & 63;
  const int wm = (wv & 1) * 128, wn = (wv >> 1) * 64;
  const int fr = lane & 15;
  const int fsw = ((lane >> 4) ^ ((fr >> 1) & 3)) * 8;

  f32x4 acc[8][4];
  #pragma unroll
  for (int i=0;i<8;i++)
    #pragma unroll
    for (int j=0;j<4;j++) acc[i][j] = (f32x4){0.f,0.f,0.f,0.f};

  const bft* Ab = A + m0*lda;
  const bft* Bb = B + n0*ldb;
  const int NS = K >> 5;

  // prologue: slots 0 and 1; then guarantee slot 0 landed (newest 4 = slot1).
  stage8(Ab,      lda, As[0], tid);
  stage8(Bb,      ldb, Bs[0], tid);
  stage8(Ab + 32, lda, As[1], tid);
  stage8(Bb + 32, ldb, Bs[1], tid);
  waitcnt_vm<4>();
  __builtin_amdgcn_s_barrier();
  asm volatile("" ::: "memory");

  for (int s = 0; s < NS; ++s) {
    const bft* Ap = As[s & 3];
    const bft* Bp = Bs[s & 3];
    const int kt = (s + 2) * 32;
    const bool st = (s + 2 < NS);
    bf16x8 bv[4], a0, a1;

    // ---- phase A: B-frags + af0,1; stage next A-tile ----
    bv[0] = *(const bf16x8*)(Bp + (size_t)(wn +  0 + fr)*32 + fsw);
    bv[1] = *(const bf16x8*)(Bp + (size_t)(wn + 16 + fr)*32 + fsw);
    bv[2] = *(const bf16x8*)(Bp + (size_t)(wn + 32 + fr)*32 + fsw);
    bv[3] = *(const bf16x8*)(Bp + (size_t)(wn + 48 + fr)*32 + fsw);
    a0 = *(const bf16x8*)(Ap + (size_t)(wm +  0 + fr)*32 + fsw);
    a1 = *(const bf16x8*)(Ap + (size_t)(wm + 16 + fr)*32 + fsw);
    if (st) stage8(Ab + kt, lda, As[(s+2)&3], tid);
    phase_edge();
    __builtin_amdgcn_s_setprio(1);
    M8_ROW(0, a0); M8_ROW(1, a1);
    __builtin_amdgcn_s_setprio(0);

    // ---- phase B: af2,3; stage next B-tile ----
    a0 = *(const bf16x8*)(Ap + (size_t)(wm + 32 + fr)*32 + fsw);
    a1 = *(const bf16x8*)(Ap + (size_t)(wm + 48 + fr)*32 + fsw);
    if (st) stage8(Bb + kt, ldb, Bs[(s+2)&3], tid);
    phase_edge();
    __builtin_amdgcn_s_setprio(1);
    M8_ROW(2, a0); M8_ROW(3, a1);
    __builtin_amdgcn_s_setprio(0);

    // ---- phase C: af4,5 ----
    a0 = *(const bf16x8*)(Ap + (size_t)(wm + 64 + fr)*32 + fsw);
    a1 = *(const bf16x8*)(Ap + (size_t)(wm + 80 + fr)*32 + fsw);
    phase_edge();
    __builtin_amdgcn_s_setprio(1);
    M8_ROW(4, a0); M8_ROW(5, a1);
    __builtin_amdgcn_s_setprio(0);

    // ---- phase D: af6,7; vm ladder (slot s+1 guaranteed after) ----
    a0 = *(const bf16x8*)(Ap + (size_t)(wm +  96 + fr)*32 + fsw);
    a1 = *(const bf16x8*)(Ap + (size_t)(wm + 112 + fr)*32 + fsw);
    if (st) waitcnt_vm<4>(); else waitcnt_vm<0>();
    phase_edge();
    __builtin_amdgcn_s_setprio(1);
    M8_ROW(6, a0); M8_ROW(7, a1);
    __builtin_amdgcn_s_setprio(0);
  }

  const int er = (lane >> 4) * 4;
  const int ec = lane & 15;
  #pragma unroll
  for (int mi=0; mi<8; mi++){
    #pragma unroll
    for (int ni=0; ni<4; ni++){
      #pragma unroll
      for (int r=0; r<4; r++){
        size_t row = m0 + wm + mi*16 + er + r;
        size_t col = n0 + wn + ni*16 + ec;
        size_t idx = row*ldc + col;
        float v = acc[mi][ni][r];
        if constexpr (EPI == 0) ((bft*)Cv)[idx] = (bft)v;
        else                    ((float*)Cv)[idx] = v;
      }
    }
  }
}

template<int EPI>
static inline void mgemm8(hipStream_t st, const bft* A, const bft* B, void* C,
                          int M, int N, int K, long lda, long ldb, long ldc)
{
  dim3 g(N/256, M/256, 1);
  mgemm8_k<EPI><<<g, 512, 0, st>>>(A, B, C, K, lda, ldb, ldc);
}

// ---------------------------------------------------------------------------
// fp32 -> bf16 bulk convert (8 elems/thread); n must divide 2048.
// ---------------------------------------------------------------------------
__global__ __launch_bounds__(256) void cvt_k(const float* __restrict__ s,
    bft* __restrict__ d)
{
  size_t i = ((size_t)blockIdx.x*256 + threadIdx.x) * 8;
  const float4 v0 = *(const float4*)(s + i);
  const float4 v1 = *(const float4*)(s + i + 4);
  bf16x8 b;
  b[0]=(bft)v0.x; b[1]=(bft)v0.y; b[2]=(bft)v0.z; b[3]=(bft)v0.w;
  b[4]=(bft)v1.x; b[5]=(bft)v1.y; b[6]=(bft)v1.z; b[7]=(bft)v1.w;
  *(bf16x8*)(d + i) = b;
}

// ---------------------------------------------------------------------------
// Batched bf16 transpose: out[z][c][r] = in[z][r][c], R=2048, C=512.
// ---------------------------------------------------------------------------
__global__ __launch_bounds__(256) void tr_k(const bft* __restrict__ in,
    bft* __restrict__ out, long ldin, long sIn, long sOut)
{
  __shared__ __align__(16) bft t[64][72];
  const int c0 = blockIdx.x*64, r0 = blockIdx.y*64;
  in  += (size_t)blockIdx.z * sIn;
  out += (size_t)blockIdx.z * sOut;
  const int tid = threadIdx.x;
  #pragma unroll
  for (int i=0;i<2;i++){
    int e = tid + i*256;
    int r = e >> 3, c8 = (e & 7) * 8;
    *(bf16x8*)&t[r][c8] = *(const bf16x8*)(in + (size_t)(r0+r)*ldin + c0 + c8);
  }
  __syncthreads();
  #pragma unroll
  for (int i=0;i<2;i++){
    int e = tid + i*256;
    int c = e >> 3, r8 = (e & 7) * 8;
    bf16x8 v;
    #pragma unroll
    for (int j=0;j<8;j++) v[j] = t[r8+j][c];
    *(bf16x8*)(out + (size_t)(c0+c)*CHUNK_LEN + r0 + r8) = v;
  }
}

// initial w1^T bf16 shadow: w1tb[z][h][o] = (bf16)w1[z][o][h]
__global__ __launch_bounds__(256) void tcw1_k(const float* __restrict__ w1,
    bft* __restrict__ w1tb)
{
  size_t idx = (size_t)blockIdx.x*256 + threadIdx.x;
  int z = (int)(idx >> 18);
  int h = (int)((idx >> 9) & 511);
  int o = (int)(idx & 511);
  w1tb[idx] = (bft)w1[(size_t)z*FD*FD + (size_t)o*FD + h];
}

// ---------------------------------------------------------------------------
// v^T for attention PV: vT[h][d][s] = v[s][h*128+d] (raw v region of qkv).
// ---------------------------------------------------------------------------
__global__ __launch_bounds__(256) void vt_k(const bf16* __restrict__ qkv,
    bft* __restrict__ vT)
{
  __shared__ __align__(16) bft t[64*QKP];   // [s][d]
  const int s0 = blockIdx.x * 64;
  const int h  = blockIdx.y;
  const int tid = threadIdx.x;
  #pragma unroll
  for (int i=0;i<4;i++){
    int e = tid + i*256;
    int rr = e >> 4, doff = (e & 15) * 8;
    *(bf16x8*)(t + rr*QKP + doff) =
        *(const bf16x8*)((const bft*)qkv + (size_t)(s0+rr)*QKV3 + 2*HID + h*HD + doff);
  }
  __syncthreads();
  #pragma unroll
  for (int it=0; it<4; it++){
    int d = (tid >> 3) + it*32;
    int so8 = (tid & 7) * 8;
    bf16x8 v;
    #pragma unroll
    for (int j=0;j<8;j++) v[j] = t[(so8+j)*QKP + d];
    *(bf16x8*)(vT + ((size_t)(h*HD + d))*S_LEN + s0 + so8) = v;
  }
}

// ---------------------------------------------------------------------------
// RoPE cos/sin tables
// ---------------------------------------------------------------------------
__global__ void rope_k(float* __restrict__ rc, float* __restrict__ rs){
  int pos = blockIdx.x, d = threadIdx.x;
  float inv = 1.f / powf(500000.0f, (float)d * (1.0f/64.0f));
  float ang = (float)pos * inv;
  rc[pos*64+d] = cosf(ang);
  rs[pos*64+d] = sinf(ang);
}

// ---------------------------------------------------------------------------
// per-token learning rates
// ---------------------------------------------------------------------------
__global__ __launch_bounds__(256) void lr_k(const float* __restrict__ hidden,
    const float* __restrict__ lr_w, const float* __restrict__ lr_b,
    float* __restrict__ lro)
{
  __shared__ float hrow[HID];
  __shared__ float red[4][12];
  int s = blockIdx.x, tid = threadIdx.x;
  for(int i=0;i<HID/256;i++) hrow[tid+256*i] = hidden[(size_t)s*HID + tid + 256*i];
  __syncthreads();
  float part[12];
  #pragma unroll
  for(int o=0;o<12;o++) part[o]=0.f;
  for(int i=0;i<HID/256;i++){
    int j = tid + 256*i;
    float h = hrow[j];
    #pragma unroll
    for(int o=0;o<12;o++) part[o] += h * lr_w[o*HID + j];
  }
  int lane = tid & 63, w = tid >> 6;
  #pragma unroll
  for(int o=0;o<12;o++){
    float v = wave_sum(part[o]);
    if(lane==0) red[w][o] = v;
  }
  __syncthreads();
  if(tid < 12){
    float v = red[0][tid]+red[1][tid]+red[2][tid]+red[3][tid] + lr_b[tid] + BASE_LR_INV;
    float sp = (v > 20.f) ? v : log1pf(expf(v));
    lro[s*12 + tid] = sp;
  }
}

// ---------------------------------------------------------------------------
// E2a: per-token rmsnorm(q), rmsnorm(k), in place in qkv (bf16).
// ---------------------------------------------------------------------------
__global__ __launch_bounds__(256) void e2a_k(
    bf16* __restrict__ qkv,
    const float* __restrict__ qnw, const float* __restrict__ knw)
{
  __shared__ float red[8];
  int s = blockIdx.x, tid = threadIdx.x;
  int lane = tid & 63, w = tid >> 6;
  float qv[8], kv[8];
  float sq = 0.f, sk = 0.f;
  size_t base = (size_t)s*QKV3;
  #pragma unroll
  for(int i=0;i<8;i++){
    int j = tid*8 + i;
    qv[i] = bf2f(qkv[base + j]);
    kv[i] = bf2f(qkv[base + HID + j]);
    sq += qv[i]*qv[i]; sk += kv[i]*kv[i];
  }
  sq = wave_sum(sq); sk = wave_sum(sk);
  if(lane==0){ red[w] = sq; red[4+w] = sk; }
  __syncthreads();
  float rq = rsqrtf((red[0]+red[1]+red[2]+red[3])*(1.f/HID) + 1e-6f);
  float rk = rsqrtf((red[4]+red[5]+red[6]+red[7])*(1.f/HID) + 1e-6f);
  #pragma unroll
  for(int i=0;i<8;i++){
    int j = tid*8 + i;
    qkv[base + j]       = f2bf(qv[i]*rq*qnw[j]);
    qkv[base + HID + j] = f2bf(kv[i]*rk*knw[j]);
  }
}

// ---------------------------------------------------------------------------
// E2b (after attention): overwrite q/k/v regions with fq/fk/fv.
// ---------------------------------------------------------------------------
__global__ __launch_bounds__(256) void e2b_k(
    bf16* __restrict__ qkv,
    const float* __restrict__ qks, const float* __restrict__ qko)
{
  int s = blockIdx.x, tid = threadIdx.x;
  size_t base = (size_t)s*QKV3;
  float a[8], b[8], vv[8];
  float ga = 0.f, gb2 = 0.f;
  #pragma unroll
  for(int i=0;i<8;i++){
    int j = tid*8 + i;
    float qn = bf2f(qkv[base + j]);
    float kn = bf2f(qkv[base + HID + j]);
    float v  = bf2f(qkv[base + 2*HID + j]);
    a[i] = siluf(qn*qks[2*j]   + qko[2*j]);
    b[i] = siluf(kn*qks[2*j+1] + qko[2*j+1]);
    vv[i] = siluf(v);
    ga += a[i]*a[i]; gb2 += b[i]*b[i];
  }
  ga = wave_sum(ga); gb2 = wave_sum(gb2);
  float iq = 1.f / fmaxf(sqrtf(ga), 1e-12f);
  float ik = 1.f / fmaxf(sqrtf(gb2), 1e-12f);
  #pragma unroll
  for(int i=0;i<8;i++){
    int j = tid*8 + i;
    qkv[base + j]         = f2bf(a[i]*iq);
    qkv[base + HID + j]   = f2bf(b[i]*ik);
    qkv[base + 2*HID + j] = f2bf(vv[i]);
  }
}

// ---------------------------------------------------------------------------
// MFMA sliding-window attention (window 256 incl self).
// ---------------------------------------------------------------------------
__global__ __launch_bounds__(256) void attn_k(
    const bf16* __restrict__ qkv, const bft* __restrict__ vT,
    const float* __restrict__ rc, const float* __restrict__ rs,
    float* __restrict__ attn)
{
  __shared__ __align__(16) bft Qs[64*QKP];
  __shared__ __align__(16) bft Ks[64*QKP];
  __shared__ __align__(16) bft Vs[128*VSP];
  __shared__ __align__(16) bft Ps[64*PSP];
  const int head = blockIdx.x >> 7;
  const int Q0 = (blockIdx.x & 127) * 64;
  const int tid = threadIdx.x;
  const int hb = head * HD;
  const int lane = tid & 63;
  const int wm = (tid >> 6) * 16;
  const int fr = lane & 15, fko = (lane >> 4) * 8;
  const int rbase = (lane >> 4) * 4;

  #pragma unroll
  for(int i=0;i<16;i++){
    int e = tid + i*256;
    int rr = e >> 6, d = e & 63;
    int qpos = Q0 + rr;
    size_t b = (size_t)qpos*QKV3 + hb;
    float x1 = bf2f(qkv[b + d]);
    float x2 = bf2f(qkv[b + d + 64]);
    float c = rc[qpos*64 + d], sn = rs[qpos*64 + d];
    Qs[rr*QKP + d]      = (bft)(x1*c - x2*sn);
    Qs[rr*QKP + d + 64] = (bft)(x2*c + x1*sn);
  }
  __syncthreads();
  bf16x8 qf[4];
  #pragma unroll
  for (int kk=0;kk<4;kk++)
    qf[kk] = *(const bf16x8*)(Qs + (wm+fr)*QKP + kk*32 + fko);

  f32x4 Ot[8];
  #pragma unroll
  for (int i=0;i<8;i++) Ot[i] = (f32x4){0.f,0.f,0.f,0.f};
  float m4[4], l4[4];
  #pragma unroll
  for (int r=0;r<4;r++){ m4[r] = -INFINITY; l4[r] = 0.f; }

  for (int kt=0; kt<5; kt++){
    const int kb = Q0 - 256 + kt*64;
    if (kb < 0) continue;
    __syncthreads();
    #pragma unroll
    for(int i=0;i<16;i++){
      int e = tid + i*256;
      int rr = e >> 6, d = e & 63;
      int kpos = kb + rr;
      size_t b = (size_t)kpos*QKV3 + HID + hb;
      float x1 = bf2f(qkv[b + d]);
      float x2 = bf2f(qkv[b + d + 64]);
      float c = rc[kpos*64 + d], sn = rs[kpos*64 + d];
      Ks[rr*QKP + d]      = (bft)(x1*c - x2*sn);
      Ks[rr*QKP + d + 64] = (bft)(x2*c + x1*sn);
    }
    {
      int d = tid >> 1, koff = (tid & 1) * 32;
      const bft* vrow = vT + ((size_t)(hb + d))*S_LEN + kb + koff;
      bft* lrow = Vs + d*VSP + koff;
      #pragma unroll
      for (int j8=0;j8<4;j8++)
        *(bf16x8*)(lrow + j8*8) = *(const bf16x8*)(vrow + j8*8);
    }
    __syncthreads();

    f32x4 st[4];
    #pragma unroll
    for (int nt=0;nt<4;nt++){
      f32x4 acc = (f32x4){0.f,0.f,0.f,0.f};
      #pragma unroll
      for (int kk=0;kk<4;kk++){
        bf16x8 kf = *(const bf16x8*)(Ks + (nt*16+fr)*QKP + kk*32 + fko);
        acc = __builtin_amdgcn_mfma_f32_16x16x32_bf16(qf[kk], kf, acc, 0, 0, 0);
      }
      st[nt] = acc;
    }

    float pv[4][4];
    #pragma unroll
    for (int r=0;r<4;r++){
      int qpos = Q0 + wm + rbase + r;
      float sm[4];
      float mx = -INFINITY;
      #pragma unroll
      for (int nt=0;nt<4;nt++){
        int kpos = kb + nt*16 + fr;
        bool valid = (kpos > qpos - 256) && (kpos <= qpos);
        float s = valid ? st[nt][r] * 0.088388347648318447f : -INFINITY;
        sm[nt] = s;
        mx = fmaxf(mx, s);
      }
      mx = fmaxf(mx, __shfl_xor(mx, 1, 64));
      mx = fmaxf(mx, __shfl_xor(mx, 2, 64));
      mx = fmaxf(mx, __shfl_xor(mx, 4, 64));
      mx = fmaxf(mx, __shfl_xor(mx, 8, 64));
      float mnew = fmaxf(m4[r], mx);
      float alpha = (mnew == -INFINITY) ? 1.f : __expf(m4[r] - mnew);
      float ps = 0.f;
      #pragma unroll
      for (int nt=0;nt<4;nt++){
        float p = (sm[nt] == -INFINITY) ? 0.f : __expf(sm[nt] - mnew);
        pv[nt][r] = p;
        ps += p;
      }
      ps += __shfl_xor(ps, 1, 64);
      ps += __shfl_xor(ps, 2, 64);
      ps += __shfl_xor(ps, 4, 64);
      ps += __shfl_xor(ps, 8, 64);
      l4[r] = l4[r]*alpha + ps;
      m4[r] = mnew;
      #pragma unroll
      for (int ct=0;ct<8;ct++) Ot[ct][r] *= alpha;
    }

    #pragma unroll
    for (int r=0;r<4;r++){
      int row = wm + rbase + r;
      #pragma unroll
      for (int nt=0;nt<4;nt++)
        Ps[row*PSP + nt*16 + fr] = (bft)pv[nt][r];
    }
    bf16x8 af[2];
    #pragma unroll
    for (int kk=0;kk<2;kk++){
      const bft* pp = Ps + (wm+fr)*PSP + kk*32 + fko;
      bf16x4 lo = *(const bf16x4*)pp;
      bf16x4 hi = *(const bf16x4*)(pp+4);
      bf16x8 a;
      #pragma unroll
      for (int j=0;j<4;j++){ a[j]=lo[j]; a[j+4]=hi[j]; }
      af[kk]=a;
    }
    #pragma unroll
    for (int ct=0;ct<8;ct++)
      #pragma unroll
      for (int kk=0;kk<2;kk++){
        bf16x8 bv = *(const bf16x8*)(Vs + (ct*16+fr)*VSP + kk*32 + fko);
        Ot[ct] = __builtin_amdgcn_mfma_f32_16x16x32_bf16(af[kk], bv, Ot[ct], 0, 0, 0);
      }
  }

  #pragma unroll
  for (int r=0;r<4;r++){
    float invl = 1.f / l4[r];
    int qpos = Q0 + wm + rbase + r;
    size_t ob = (size_t)qpos*HID + hb;
    #pragma unroll
    for (int ct=0;ct<8;ct++)
      attn[ob + ct*16 + fr] = Ot[ct][r] * invl;
  }
}

// ---------------------------------------------------------------------------
// TTT elementwise fwd: hid = silu(g)*hm ; opre = silu(qg)*qm (opre -> qg buf)
// ---------------------------------------------------------------------------
__global__ __launch_bounds__(256) void e3_k(
    const bf16* __restrict__ g, const bf16* __restrict__ hm,
    bf16* __restrict__ qg, const bf16* __restrict__ qm,
    bf16* __restrict__ hid)
{
  size_t idx = (size_t)blockIdx.x*256 + threadIdx.x;
  float opre = siluf(bf2f(qg[idx])) * bf2f(qm[idx]);
  hid[idx] = f2bf(siluf(bf2f(g[idx])) * bf2f(hm[idx]));
  qg[idx]  = f2bf(opre);
}

// ---------------------------------------------------------------------------
// TTT backprop elementwise (in place): a0->g, a2->hm, a1->dhid buffer.
// ---------------------------------------------------------------------------
__global__ __launch_bounds__(256) void e4_k(
    bf16* __restrict__ g, bf16* __restrict__ hm, bf16* __restrict__ dhid,
    const bf16* __restrict__ qkv, const float* __restrict__ lrb, int cbase)
{
  size_t idx = (size_t)blockIdx.x*256 + threadIdx.x;
  int h  = (int)(idx >> 20);
  int ci = (int)((idx >> 9) & 2047);
  int d  = (int)(idx & 511);
  int s  = cbase + ci;
  float l0  = lrb[s*12 + h];
  float l1  = lrb[s*12 + 4 + h];
  float l2v = lrb[s*12 + 8 + h];
  float gg = bf2f(g[idx]), hv = bf2f(hm[idx]), dh = bf2f(dhid[idx]);
  float sg = sigm(gg);
  float silu_g = gg * sg;
  float dhm = dh * silu_g;
  float dg  = dh * hv;
  float dgp = dg * (sg * (1.f + gg * (1.f - sg)));
  float fvv = bf2f(qkv[(size_t)s*QKV3 + 2*HID + h*FD + d]);
  g[idx]    = f2bf(dgp * l0);
  hm[idx]   = f2bf(dhm * l2v);
  dhid[idx] = f2bf(fvv * l1);
}

// ---------------------------------------------------------------------------
// E5 (per chunk): X = attn + rmsnorm(ofc)*ttt_norm_w -> q region of qkv
// ---------------------------------------------------------------------------
__global__ __launch_bounds__(256) void e5_k(const float* __restrict__ attn,
    const bf16* __restrict__ ofc, const float* __restrict__ tnw,
    bf16* __restrict__ qkv, int cbase)
{
  int ci = blockIdx.x, tid = threadIdx.x;
  int s = cbase + ci;
  int lane = tid & 63, w = tid >> 6;
  float o[8]; float ss = 0.f;
  size_t ob = ((size_t)w*CHUNK_LEN + ci)*FD + (size_t)lane*8;
  #pragma unroll
  for(int i=0;i<8;i++){ o[i] = bf2f(ofc[ob+i]); ss += o[i]*o[i]; }
  ss = wave_sum(ss);
  float inv = rsqrtf(ss*(1.f/FD) + 1e-6f);
  size_t xb = (size_t)s*QKV3 + w*FD + (size_t)lane*8;
  size_t ab = (size_t)s*HID  + w*FD + (size_t)lane*8;
  #pragma unroll
  for(int i=0;i<8;i++){
    int d = lane*8 + i;
    qkv[xb+i] = f2bf(attn[ab+i] + o[i]*inv*tnw[d]);
  }
}

// ---------------------------------------------------------------------------
extern "C" void kernel_launch(void* const* d_in, const int* in_sizes, int n_in,
                              void* d_out, int out_size, void* d_ws, size_t ws_size,
                              hipStream_t stream)
{
  (void)in_sizes; (void)n_in; (void)out_size;
  const float* hidden   = (const float*)d_in[0];
  const float* qkv_w    = (const float*)d_in[1];
  const float* q_norm_w = (const float*)d_in[2];
  const float* k_norm_w = (const float*)d_in[3];
  const float* qk_scale = (const float*)d_in[4];
  const float* qk_off   = (const float*)d_in[5];
  const float* lr_w     = (const float*)d_in[6];
  const float* lr_b     = (const float*)d_in[7];
  const float* w0_in    = (const float*)d_in[8];
  const float* w1_in    = (const float*)d_in[9];
  const float* w2_in    = (const float*)d_in[10];
  const float* ttt_nw   = (const float*)d_in[11];
  const float* o_proj   = (const float*)d_in[12];
  float* out = (float*)d_out;

  char* p = (char*)d_ws;
  auto alloc = [&](size_t n){ char* r = p; p += (n + 255) & ~(size_t)255; return (void*)r; };

  bf16*  qkv   = (bf16*) alloc((size_t)S_LEN*QKV3*sizeof(bf16));
  float* lrb   = (float*)alloc((size_t)S_LEN*12*sizeof(float));
  float* rc    = (float*)alloc((size_t)S_LEN*64*sizeof(float));
  float* rs    = (float*)alloc((size_t)S_LEN*64*sizeof(float));
  float* w0s   = (float*)alloc((size_t)NFW*FD*FD*sizeof(float));
  float* w1s   = (float*)alloc((size_t)NFW*FD*FD*sizeof(float));
  float* w2s   = (float*)alloc((size_t)NFW*FD*FD*sizeof(float));
  bft*   w1tb  = (bft*)  alloc((size_t)NFW*FD*FD*sizeof(bft));
  bft*   w0b   = (bft*)  alloc((size_t)NFW*FD*FD*sizeof(bft));
  bft*   w1b   = (bft*)  alloc((size_t)NFW*FD*FD*sizeof(bft));
  bft*   w2b   = (bft*)  alloc((size_t)NFW*FD*FD*sizeof(bft));
  bf16*  gb    = (bf16*) alloc((size_t)NFW*CHUNK_LEN*FD*sizeof(bf16));
  bf16*  hmb   = (bf16*) alloc((size_t)NFW*CHUNK_LEN*FD*sizeof(bf16));
  bf16*  qgb   = (bf16*) alloc((size_t)NFW*CHUNK_LEN*FD*sizeof(bf16));
  bf16*  qmb   = (bf16*) alloc((size_t)NFW*CHUNK_LEN*FD*sizeof(bf16));
  bf16*  hidb  = (bf16*) alloc((size_t)NFW*CHUNK_LEN*FD*sizeof(bf16));
  bf16*  ofc   = (bf16*) alloc((size_t)NFW*CHUNK_LEN*FD*sizeof(bf16));
  bft*   fkT   = (bft*)  alloc((size_t)NFW*FD*CHUNK_LEN*sizeof(bft));
  bft*   hidT  = (bft*)  alloc((size_t)NFW*FD*CHUNK_LEN*sizeof(bft));
  bft*   a2T   = (bft*)  alloc((size_t)NFW*FD*CHUNK_LEN*sizeof(bft));
  bft*   a1T   = (bft*)  alloc((size_t)NFW*FD*CHUNK_LEN*sizeof(bft));

  if ((size_t)(p - (char*)d_ws) > ws_size) return;

  // Liveness aliases (no extra workspace):
  // hidden_bf (33.55 MB) = gb..qmb  — dead before chunk loop writes gb.
  // qkvw_bf   (25.17 MB) = fkT..a2T — dead before vt_k writes vT.
  // vT        (33.55 MB) = fkT..a1T — dead before chunk loop's tr_k.
  // opw_bf    ( 8.39 MB) = hidb..   — converted after last e5, before o_proj.
  bft* hidden_bf = (bft*)gb;
  bft* qkvw_bf   = (bft*)fkT;
  bft* vT        = (bft*)fkT;
  bft* opw_bf    = (bft*)hidb;

  float* attn = out;   // attn lives in d_out until the final projection

  hipMemcpyAsync(w0s, w0_in, (size_t)NFW*FD*FD*sizeof(float), hipMemcpyDeviceToDevice, stream);
  hipMemcpyAsync(w1s, w1_in, (size_t)NFW*FD*FD*sizeof(float), hipMemcpyDeviceToDevice, stream);
  hipMemcpyAsync(w2s, w2_in, (size_t)NFW*FD*FD*sizeof(float), hipMemcpyDeviceToDevice, stream);

  rope_k<<<S_LEN, 64, 0, stream>>>(rc, rs);
  lr_k<<<S_LEN, 256, 0, stream>>>(hidden, lr_w, lr_b, lrb);
  tcw1_k<<<NFW*FD*FD/256, 256, 0, stream>>>(w1_in, w1tb);
  cvt_k<<<(NFW*FD*FD)/2048, 256, 0, stream>>>(w0_in, w0b);
  cvt_k<<<(NFW*FD*FD)/2048, 256, 0, stream>>>(w1_in, w1b);
  cvt_k<<<(NFW*FD*FD)/2048, 256, 0, stream>>>(w2_in, w2b);
  cvt_k<<<(S_LEN*HID)/2048, 256, 0, stream>>>(hidden, hidden_bf);
  cvt_k<<<(QKV3*HID)/2048, 256, 0, stream>>>(qkv_w, qkvw_bf);

  // qkv = hidden @ qkv_w^T -> bf16   (256^2 pipelined GEMM)
  mgemm8<0>(stream, hidden_bf, qkvw_bf, (void*)qkv, S_LEN, QKV3, HID, HID, HID, QKV3);

  e2a_k<<<S_LEN, 256, 0, stream>>>(qkv, q_norm_w, k_norm_w);
  vt_k<<<dim3(S_LEN/64, NH), 256, 0, stream>>>(qkv, vT);
  attn_k<<<NH*128, 256, 0, stream>>>(qkv, vT, rc, rs, attn);
  e2b_k<<<S_LEN, 256, 0, stream>>>(qkv, qk_scale, qk_off);

  const long sW  = (long)FD*FD;
  const long sCh = (long)CHUNK_LEN*FD;
  const long sT  = (long)FD*CHUNK_LEN;
  const int  NEL = NFW*CHUNK_LEN*FD/256;
  const dim3 tg(FD/64, CHUNK_LEN/64, NFW);

  for(int c=0; c<NCHUNK; c++){
    const bft* fqc = (const bft*)qkv + (size_t)c*CHUNK_LEN*QKV3;
    const bft* fkc = fqc + HID;
    const bft* fvc = fqc + 2*HID;
    mgemm<128,128,0>(stream, fkc, w0b, gb,  nullptr, nullptr, CHUNK_LEN, FD, FD, QKV3, FD, FD, NFW, FD, sW, sCh);
    mgemm<128,128,0>(stream, fkc, w2b, hmb, nullptr, nullptr, CHUNK_LEN, FD, FD, QKV3, FD, FD, NFW, FD, sW, sCh);
    mgemm<128,128,0>(stream, fqc, w0b, qgb, nullptr, nullptr, CHUNK_LEN, FD, FD, QKV3, FD, FD, NFW, FD, sW, sCh);
    mgemm<128,128,0>(stream, fqc, w2b, qmb, nullptr, nullptr, CHUNK_LEN, FD, FD, QKV3, FD, FD, NFW, FD, sW, sCh);
    e3_k<<<NEL, 256, 0, stream>>>(gb, hmb, qgb, qmb, hidb);
    mgemm<128,128,0>(stream, (const bft*)qgb, w1b, ofc, nullptr, nullptr, CHUNK_LEN, FD, FD, FD, FD, FD, NFW, sCh, sW, sCh);
    mgemm<128,128,0>(stream, fvc, (const bft*)w1tb, qmb, nullptr, nullptr, CHUNK_LEN, FD, FD, QKV3, FD, FD, NFW, FD, sW, sCh);
    e4_k<<<NEL, 256, 0, stream>>>(gb, hmb, qmb, qkv, lrb, c*CHUNK_LEN);
    tr_k<<<tg, 256, 0, stream>>>(fkc,              fkT,        QKV3, FD,  sT);
    tr_k<<<tg, 256, 0, stream>>>((const bft*)hidb, hidT,       FD,   sCh, sT);
    tr_k<<<tg, 256, 0, stream>>>((const bft*)gb,   (bft*)qgb,  FD,   sCh, sT);
    tr_k<<<tg, 256, 0, stream>>>((const bft*)hmb,  a2T,        FD,   sCh, sT);
    tr_k<<<tg, 256, 0, stream>>>((const bft*)qmb,  a1T,        FD,   sCh, sT);
    mgemm<64,64,2>(stream, (const bft*)qgb, fkT,  w0s, w0b, nullptr, FD, FD, CHUNK_LEN, CHUNK_LEN, CHUNK_LEN, FD, NFW, sT, sT, sW);
    mgemm<64,64,2>(stream, a2T,             fkT,  w2s, w2b, nullptr, FD, FD, CHUNK_LEN, CHUNK_LEN, CHUNK_LEN, FD, NFW, sT, sT, sW);
    mgemm<64,64,2>(stream, a1T,             hidT, w1s, w1b, w1tb,    FD, FD, CHUNK_LEN, CHUNK_LEN, CHUNK_LEN, FD, NFW, sT, sT, sW);
    e5_k<<<CHUNK_LEN, 256, 0, stream>>>(attn, ofc, ttt_nw, qkv, c*CHUNK_LEN);
  }

  // bf16 copy of o_proj (hidb/ofc are dead now), then final projection
  cvt_k<<<(HID*HID)/2048, 256, 0, stream>>>(o_proj, opw_bf);
  mgemm8<1>(stream, (const bft*)qkv, opw_bf, out, S_LEN, HID, HID, QKV3, HID, HID);
}

// Round 4
// 1547.901 us; speedup vs baseline: 1.1581x; 1.0101x over previous
//
#include <hip/hip_runtime.h>
#include <hip/hip_bf16.h>

typedef __hip_bfloat16 bf16;
typedef __bf16 bft;
typedef bft bf16x8 __attribute__((ext_vector_type(8)));
typedef bft bf16x4 __attribute__((ext_vector_type(4)));
typedef float f32x4 __attribute__((ext_vector_type(4)));

#define S_LEN 8192
#define HID   2048
#define QKV3  6144
#define NH    16
#define HD    128
#define NFW   4
#define FD    512
#define CHUNK_LEN 2048
#define NCHUNK 4
#define BASE_LR_INV (-6.9072552f)   // log(expm1(0.001))
#define QKP 136                     // attn Q/K LDS stride (128 + 8)
#define VSP 72                      // attn V^T LDS stride (64 + 8)
#define PSP 76                      // attn P LDS stride (64 + 12)

__device__ __forceinline__ float bf2f(bf16 x){ return __bfloat162float(x); }
__device__ __forceinline__ bf16  f2bf(float x){ return __float2bfloat16(x); }
__device__ __forceinline__ float sigm(float x){ return 1.f/(1.f+__expf(-x)); }
__device__ __forceinline__ float siluf(float x){ return x/(1.f+__expf(-x)); }
__device__ __forceinline__ float wave_sum(float v){
  #pragma unroll
  for(int off=32; off; off>>=1) v += __shfl_xor(v, off, 64);
  return v;
}

template<int N>
__device__ __forceinline__ void waitcnt_vm(){
  static_assert(N==0||N==2||N==4||N==8, "unsupported vmcnt");
  if constexpr (N==0)      asm volatile("s_waitcnt vmcnt(0)" ::: "memory");
  else if constexpr (N==2) asm volatile("s_waitcnt vmcnt(2)" ::: "memory");
  else if constexpr (N==4) asm volatile("s_waitcnt vmcnt(4)" ::: "memory");
  else                     asm volatile("s_waitcnt vmcnt(8)" ::: "memory");
}

// Raw barrier, NO sched_barrier pinning (m141: pinning defeats the
// compiler's own lgkmcnt scheduling and costs ~40%).
__device__ __forceinline__ void bar(){
  __builtin_amdgcn_s_barrier();
  asm volatile("" ::: "memory");
}

// ---------------------------------------------------------------------------
// GEMM LDS tile staging (bf16 only), swizzled layout.
// Tile: ROWS x 32 bf16, unpadded [row][32]; physical col-slot c (8 elems)
// holds logical col-group g = c ^ ((row>>1)&3).
// global_load_lds 16B/lane (lane -> row=lane>>2, c=lane&3;
//   LDS dest = wave-uniform base + lane*16 => exactly (row,c) slot).
// 4 waves (256 threads): issues ROWS/64 loads per wave.
// ---------------------------------------------------------------------------
template<int ROWS>
__device__ __forceinline__ void stage(const bft* __restrict__ src, long ld,
                                      bft* dst, int tid)
{
  const int lane = tid & 63, wv = tid >> 6;
  #pragma unroll
  for (int i = 0; i < ROWS/64; ++i) {
    const int r0 = wv*16 + i*64;               // wave-uniform
    const int row = r0 + (lane >> 2);
    const int g = (lane & 3) ^ ((row >> 1) & 3);
    const bft* gp = src + (size_t)row*ld + g*8;
    bft* lp = dst + (size_t)r0*32;
    __builtin_amdgcn_global_load_lds(
        (const __attribute__((address_space(1))) void*)gp,
        (__attribute__((address_space(3))) void*)lp, 16, 0, 0);
  }
}

// ---------------------------------------------------------------------------
// MFMA NT GEMM: C[M,N] (+)= A[M,K] * B[N,K]^T, fp32 accumulate, 256 threads.
// 4-slot circular LDS pipeline (BK=32), counted vmcnt (never drained to 0
// in steady state). m201-style phase skeleton: per phase
// {ds_read subtile | stage issue -> barrier -> setprio(1) -> MFMA cluster
//  -> setprio(0) -> barrier}; compiler schedules freely inside phases.
// Race-freedom: slot written at iter s is (s+2)&3; concurrent readers touch
// s&3 (distinct mod 4); reads of the overwritten buffer (slot s-2) completed
// before that wave's iter-(s-2) MFMA cluster, >=1 barrier earlier.
// vmcnt ladder: wait leaves exactly slot s+2's LPT loads in flight,
// guaranteeing slot s+1 is landed before its reads begin.
// EPI: 0 = store bf16, 1 = store fp32, 2 = fp32 C += acc, bf16 direct shadow
// Cd, optional transposed bf16 shadow Ct. Batched over blockIdx.z.
// ---------------------------------------------------------------------------
template<int BM,int BN,int EPI>
__global__ __launch_bounds__(256) void mgemm_k(
    const bft* __restrict__ A, const bft* __restrict__ B, void* __restrict__ Cv,
    bft* __restrict__ Cd, bft* __restrict__ Ct, int K,
    long lda, long ldb, long ldc, long sA, long sB, long sC)
{
  constexpr int AM = BM/32, AN = BN/32;
  constexpr int LPT = BM/64 + BN/64;           // global_load_lds per wave/slot
  constexpr int NPH = (AM >= 4) ? 2 : 1;       // compute phases per slot
  constexpr int MH  = AM / NPH;                // mi rows per phase
  __shared__ __align__(16) bft As[4][BM*32];
  __shared__ __align__(16) bft Bs[4][BN*32];
  const int tid = threadIdx.x;
  const int z = blockIdx.z;
  A += (size_t)z * sA;
  B += (size_t)z * sB;
  const size_t m0 = (size_t)blockIdx.y * BM, n0 = (size_t)blockIdx.x * BN;
  const int wv = tid >> 6, lane = tid & 63;
  const int wm = (wv & 1) * (BM/2), wn = (wv >> 1) * (BN/2);
  const int fr = lane & 15;
  const int fsw = ((lane >> 4) ^ ((fr >> 1) & 3)) * 8;   // swizzled frag col

  f32x4 acc[AM][AN];
  #pragma unroll
  for (int i=0;i<AM;i++)
    #pragma unroll
    for (int j=0;j<AN;j++) acc[i][j] = (f32x4){0.f,0.f,0.f,0.f};

  const bft* Ab = A + m0*lda;
  const bft* Bb = B + n0*ldb;
  const int NS = K >> 5;

  // prologue: slots 0 and 1; then guarantee slot 0 landed.
  stage<BM>(Ab,      lda, As[0], tid);
  stage<BN>(Bb,      ldb, Bs[0], tid);
  stage<BM>(Ab + 32, lda, As[1], tid);
  stage<BN>(Bb + 32, ldb, Bs[1], tid);
  waitcnt_vm<LPT>();
  bar();

  for (int s = 0; s < NS; ++s) {
    const bft* Ap = As[s & 3];
    const bft* Bp = Bs[s & 3];
    const int kt = (s + 2) * 32;
    const bool st = (s + 2 < NS);

    bf16x8 bvv[AN], afv[MH];
    // ---- phase A: all B-frags + first mi half; stage next A-tile ----
    #pragma unroll
    for (int ni=0; ni<AN; ni++)
      bvv[ni] = *(const bf16x8*)(Bp + (size_t)(wn + ni*16 + fr)*32 + fsw);
    #pragma unroll
    for (int i=0; i<MH; i++)
      afv[i] = *(const bf16x8*)(Ap + (size_t)(wm + i*16 + fr)*32 + fsw);
    if (st) stage<BM>(Ab + kt, lda, As[(s+2)&3], tid);
    if constexpr (NPH == 1) {
      if (st) { stage<BN>(Bb + kt, ldb, Bs[(s+2)&3], tid); waitcnt_vm<LPT>(); }
      else waitcnt_vm<0>();
    }
    bar();
    __builtin_amdgcn_s_setprio(1);
    #pragma unroll
    for (int i=0; i<MH; i++)
      #pragma unroll
      for (int ni=0; ni<AN; ni++)
        acc[i][ni] = __builtin_amdgcn_mfma_f32_16x16x32_bf16(afv[i], bvv[ni], acc[i][ni], 0, 0, 0);
    __builtin_amdgcn_s_setprio(0);

    if constexpr (NPH == 2) {
      bar();
      // ---- phase B: second mi half; stage next B-tile; vm ladder ----
      #pragma unroll
      for (int i=0; i<MH; i++)
        afv[i] = *(const bf16x8*)(Ap + (size_t)(wm + (MH+i)*16 + fr)*32 + fsw);
      if (st) { stage<BN>(Bb + kt, ldb, Bs[(s+2)&3], tid); waitcnt_vm<LPT>(); }
      else waitcnt_vm<0>();
      bar();
      __builtin_amdgcn_s_setprio(1);
      #pragma unroll
      for (int i=0; i<MH; i++)
        #pragma unroll
        for (int ni=0; ni<AN; ni++)
          acc[MH+i][ni] = __builtin_amdgcn_mfma_f32_16x16x32_bf16(afv[i], bvv[ni], acc[MH+i][ni], 0, 0, 0);
      __builtin_amdgcn_s_setprio(0);
      bar();
    }
  }

  const int er = (lane >> 4) * 4;   // C/D: row=(lane>>4)*4+reg, col=lane&15
  const int ec = lane & 15;
  #pragma unroll
  for (int mi=0; mi<AM; mi++){
    #pragma unroll
    for (int ni=0; ni<AN; ni++){
      #pragma unroll
      for (int r=0; r<4; r++){
        size_t row = m0 + wm + mi*16 + er + r;
        size_t col = n0 + wn + ni*16 + ec;
        size_t idx = (size_t)z*sC + row*ldc + col;
        float v = acc[mi][ni][r];
        if constexpr (EPI == 0){
          ((bft*)Cv)[idx] = (bft)v;
        } else if constexpr (EPI == 1){
          ((float*)Cv)[idx] = v;
        } else {
          float nv = ((float*)Cv)[idx] + v;
          ((float*)Cv)[idx] = nv;
          Cd[idx] = (bft)nv;
          if (Ct) Ct[(size_t)z*FD*FD + col*FD + row] = (bft)nv;
        }
      }
    }
  }
}

template<int BM,int BN,int EPI>
static inline void mgemm(hipStream_t st, const bft* A, const bft* B, void* C,
    bft* Cd, bft* Ct, int M, int N, int K, long lda, long ldb, long ldc,
    int batch, long sA, long sB, long sC)
{
  dim3 g(N/BN, M/BM, batch);
  mgemm_k<BM,BN,EPI><<<g, 256, 0, st>>>(A, B, C, Cd, Ct, K, lda, ldb, ldc, sA, sB, sC);
}

// ---------------------------------------------------------------------------
// 256x256 MFMA NT GEMM, 4-slot pipeline, 512 threads = 8 waves (2Mx4N),
// per-wave 128x64 output. 2 phases/slot x 16 MFMA, double-barrier bracket
// (m201 skeleton), counted vmcnt. LDS = 128 KiB. XCD-aware bijective swizzle.
// ---------------------------------------------------------------------------
__device__ __forceinline__ void stage8(const bft* __restrict__ src, long ld,
                                       bft* dst, int tid)
{
  const int lane = tid & 63, wv = tid >> 6;      // 8 waves
  #pragma unroll
  for (int i = 0; i < 2; ++i) {
    const int r0 = wv*16 + i*128;                // wave-uniform
    const int row = r0 + (lane >> 2);
    const int g = (lane & 3) ^ ((row >> 1) & 3);
    const bft* gp = src + (size_t)row*ld + g*8;
    bft* lp = dst + (size_t)r0*32;
    __builtin_amdgcn_global_load_lds(
        (const __attribute__((address_space(1))) void*)gp,
        (__attribute__((address_space(3))) void*)lp, 16, 0, 0);
  }
}

#define M8_ROW(mi, a) { \
    acc[mi][0]=__builtin_amdgcn_mfma_f32_16x16x32_bf16(a,bv[0],acc[mi][0],0,0,0); \
    acc[mi][1]=__builtin_amdgcn_mfma_f32_16x16x32_bf16(a,bv[1],acc[mi][1],0,0,0); \
    acc[mi][2]=__builtin_amdgcn_mfma_f32_16x16x32_bf16(a,bv[2],acc[mi][2],0,0,0); \
    acc[mi][3]=__builtin_amdgcn_mfma_f32_16x16x32_bf16(a,bv[3],acc[mi][3],0,0,0); }

template<int EPI>
__global__ __launch_bounds__(512, 2) void mgemm8_k(
    const bft* __restrict__ A, const bft* __restrict__ B, void* __restrict__ Cv,
    int K, long lda, long ldb, long ldc)
{
  __shared__ __align__(16) bft As[4][256*32];
  __shared__ __align__(16) bft Bs[4][256*32];
  const int tid = threadIdx.x;

  // XCD-aware bijective swizzle (nwg % 8 == 0 for both call sites)
  const int gx = (int)gridDim.x;
  const int nwg = (int)(gridDim.x * gridDim.y);
  int lin = (int)(blockIdx.y * gridDim.x + blockIdx.x);
  if ((nwg & 7) == 0) lin = (lin & 7) * (nwg >> 3) + (lin >> 3);
  const size_t m0 = (size_t)(lin / gx) * 256;
  const size_t n0 = (size_t)(lin % gx) * 256;

  const int wv = tid >> 6, lane = tid & 63;
  const int wm = (wv & 1) * 128, wn = (wv >> 1) * 64;
  const int fr = lane & 15;
  const int fsw = ((lane >> 4) ^ ((fr >> 1) & 3)) * 8;

  f32x4 acc[8][4];
  #pragma unroll
  for (int i=0;i<8;i++)
    #pragma unroll
    for (int j=0;j<4;j++) acc[i][j] = (f32x4){0.f,0.f,0.f,0.f};

  const bft* Ab = A + m0*lda;
  const bft* Bb = B + n0*ldb;
  const int NS = K >> 5;

  // prologue: slots 0 and 1; then guarantee slot 0 landed (newest 4 = slot1).
  stage8(Ab,      lda, As[0], tid);
  stage8(Bb,      ldb, Bs[0], tid);
  stage8(Ab + 32, lda, As[1], tid);
  stage8(Bb + 32, ldb, Bs[1], tid);
  waitcnt_vm<4>();
  bar();

  for (int s = 0; s < NS; ++s) {
    const bft* Ap = As[s & 3];
    const bft* Bp = Bs[s & 3];
    const int kt = (s + 2) * 32;
    const bool st = (s + 2 < NS);
    bf16x8 bv[4], a0, a1, a2, a3;

    // ---- phase A: B-frags + A rows 0-3; stage next A-tile ----
    bv[0] = *(const bf16x8*)(Bp + (size_t)(wn +  0 + fr)*32 + fsw);
    bv[1] = *(const bf16x8*)(Bp + (size_t)(wn + 16 + fr)*32 + fsw);
    bv[2] = *(const bf16x8*)(Bp + (size_t)(wn + 32 + fr)*32 + fsw);
    bv[3] = *(const bf16x8*)(Bp + (size_t)(wn + 48 + fr)*32 + fsw);
    a0 = *(const bf16x8*)(Ap + (size_t)(wm +  0 + fr)*32 + fsw);
    a1 = *(const bf16x8*)(Ap + (size_t)(wm + 16 + fr)*32 + fsw);
    a2 = *(const bf16x8*)(Ap + (size_t)(wm + 32 + fr)*32 + fsw);
    a3 = *(const bf16x8*)(Ap + (size_t)(wm + 48 + fr)*32 + fsw);
    if (st) stage8(Ab + kt, lda, As[(s+2)&3], tid);
    bar();
    __builtin_amdgcn_s_setprio(1);
    M8_ROW(0, a0); M8_ROW(1, a1); M8_ROW(2, a2); M8_ROW(3, a3);
    __builtin_amdgcn_s_setprio(0);
    bar();

    // ---- phase B: A rows 4-7; stage next B-tile; vm ladder ----
    a0 = *(const bf16x8*)(Ap + (size_t)(wm +  64 + fr)*32 + fsw);
    a1 = *(const bf16x8*)(Ap + (size_t)(wm +  80 + fr)*32 + fsw);
    a2 = *(const bf16x8*)(Ap + (size_t)(wm +  96 + fr)*32 + fsw);
    a3 = *(const bf16x8*)(Ap + (size_t)(wm + 112 + fr)*32 + fsw);
    if (st) { stage8(Bb + kt, ldb, Bs[(s+2)&3], tid); waitcnt_vm<4>(); }
    else waitcnt_vm<0>();
    bar();
    __builtin_amdgcn_s_setprio(1);
    M8_ROW(4, a0); M8_ROW(5, a1); M8_ROW(6, a2); M8_ROW(7, a3);
    __builtin_amdgcn_s_setprio(0);
    bar();
  }

  const int er = (lane >> 4) * 4;
  const int ec = lane & 15;
  #pragma unroll
  for (int mi=0; mi<8; mi++){
    #pragma unroll
    for (int ni=0; ni<4; ni++){
      #pragma unroll
      for (int r=0; r<4; r++){
        size_t row = m0 + wm + mi*16 + er + r;
        size_t col = n0 + wn + ni*16 + ec;
        size_t idx = row*ldc + col;
        float v = acc[mi][ni][r];
        if constexpr (EPI == 0) ((bft*)Cv)[idx] = (bft)v;
        else                    ((float*)Cv)[idx] = v;
      }
    }
  }
}

template<int EPI>
static inline void mgemm8(hipStream_t st, const bft* A, const bft* B, void* C,
                          int M, int N, int K, long lda, long ldb, long ldc)
{
  dim3 g(N/256, M/256, 1);
  mgemm8_k<EPI><<<g, 512, 0, st>>>(A, B, C, K, lda, ldb, ldc);
}

// ---------------------------------------------------------------------------
// fp32 -> bf16 bulk convert (8 elems/thread); n must divide 2048.
// ---------------------------------------------------------------------------
__global__ __launch_bounds__(256) void cvt_k(const float* __restrict__ s,
    bft* __restrict__ d)
{
  size_t i = ((size_t)blockIdx.x*256 + threadIdx.x) * 8;
  const float4 v0 = *(const float4*)(s + i);
  const float4 v1 = *(const float4*)(s + i + 4);
  bf16x8 b;
  b[0]=(bft)v0.x; b[1]=(bft)v0.y; b[2]=(bft)v0.z; b[3]=(bft)v0.w;
  b[4]=(bft)v1.x; b[5]=(bft)v1.y; b[6]=(bft)v1.z; b[7]=(bft)v1.w;
  *(bf16x8*)(d + i) = b;
}

// ---------------------------------------------------------------------------
// Batched bf16 transpose: out[z][c][r] = in[z][r][c], R=2048, C=512.
// ---------------------------------------------------------------------------
__global__ __launch_bounds__(256) void tr_k(const bft* __restrict__ in,
    bft* __restrict__ out, long ldin, long sIn, long sOut)
{
  __shared__ __align__(16) bft t[64][72];
  const int c0 = blockIdx.x*64, r0 = blockIdx.y*64;
  in  += (size_t)blockIdx.z * sIn;
  out += (size_t)blockIdx.z * sOut;
  const int tid = threadIdx.x;
  #pragma unroll
  for (int i=0;i<2;i++){
    int e = tid + i*256;
    int r = e >> 3, c8 = (e & 7) * 8;
    *(bf16x8*)&t[r][c8] = *(const bf16x8*)(in + (size_t)(r0+r)*ldin + c0 + c8);
  }
  __syncthreads();
  #pragma unroll
  for (int i=0;i<2;i++){
    int e = tid + i*256;
    int c = e >> 3, r8 = (e & 7) * 8;
    bf16x8 v;
    #pragma unroll
    for (int j=0;j<8;j++) v[j] = t[r8+j][c];
    *(bf16x8*)(out + (size_t)(c0+c)*CHUNK_LEN + r0 + r8) = v;
  }
}

// initial w1^T bf16 shadow: w1tb[z][h][o] = (bf16)w1[z][o][h]
__global__ __launch_bounds__(256) void tcw1_k(const float* __restrict__ w1,
    bft* __restrict__ w1tb)
{
  size_t idx = (size_t)blockIdx.x*256 + threadIdx.x;
  int z = (int)(idx >> 18);
  int h = (int)((idx >> 9) & 511);
  int o = (int)(idx & 511);
  w1tb[idx] = (bft)w1[(size_t)z*FD*FD + (size_t)o*FD + h];
}

// ---------------------------------------------------------------------------
// v^T for attention PV: vT[h][d][s] = v[s][h*128+d] (raw v region of qkv).
// ---------------------------------------------------------------------------
__global__ __launch_bounds__(256) void vt_k(const bf16* __restrict__ qkv,
    bft* __restrict__ vT)
{
  __shared__ __align__(16) bft t[64*QKP];   // [s][d]
  const int s0 = blockIdx.x * 64;
  const int h  = blockIdx.y;
  const int tid = threadIdx.x;
  #pragma unroll
  for (int i=0;i<4;i++){
    int e = tid + i*256;
    int rr = e >> 4, doff = (e & 15) * 8;
    *(bf16x8*)(t + rr*QKP + doff) =
        *(const bf16x8*)((const bft*)qkv + (size_t)(s0+rr)*QKV3 + 2*HID + h*HD + doff);
  }
  __syncthreads();
  #pragma unroll
  for (int it=0; it<4; it++){
    int d = (tid >> 3) + it*32;
    int so8 = (tid & 7) * 8;
    bf16x8 v;
    #pragma unroll
    for (int j=0;j<8;j++) v[j] = t[(so8+j)*QKP + d];
    *(bf16x8*)(vT + ((size_t)(h*HD + d))*S_LEN + s0 + so8) = v;
  }
}

// ---------------------------------------------------------------------------
// RoPE cos/sin tables
// ---------------------------------------------------------------------------
__global__ void rope_k(float* __restrict__ rc, float* __restrict__ rs){
  int pos = blockIdx.x, d = threadIdx.x;
  float inv = 1.f / powf(500000.0f, (float)d * (1.0f/64.0f));
  float ang = (float)pos * inv;
  rc[pos*64+d] = cosf(ang);
  rs[pos*64+d] = sinf(ang);
}

// ---------------------------------------------------------------------------
// per-token learning rates
// ---------------------------------------------------------------------------
__global__ __launch_bounds__(256) void lr_k(const float* __restrict__ hidden,
    const float* __restrict__ lr_w, const float* __restrict__ lr_b,
    float* __restrict__ lro)
{
  __shared__ float hrow[HID];
  __shared__ float red[4][12];
  int s = blockIdx.x, tid = threadIdx.x;
  for(int i=0;i<HID/256;i++) hrow[tid+256*i] = hidden[(size_t)s*HID + tid + 256*i];
  __syncthreads();
  float part[12];
  #pragma unroll
  for(int o=0;o<12;o++) part[o]=0.f;
  for(int i=0;i<HID/256;i++){
    int j = tid + 256*i;
    float h = hrow[j];
    #pragma unroll
    for(int o=0;o<12;o++) part[o] += h * lr_w[o*HID + j];
  }
  int lane = tid & 63, w = tid >> 6;
  #pragma unroll
  for(int o=0;o<12;o++){
    float v = wave_sum(part[o]);
    if(lane==0) red[w][o] = v;
  }
  __syncthreads();
  if(tid < 12){
    float v = red[0][tid]+red[1][tid]+red[2][tid]+red[3][tid] + lr_b[tid] + BASE_LR_INV;
    float sp = (v > 20.f) ? v : log1pf(expf(v));
    lro[s*12 + tid] = sp;
  }
}

// ---------------------------------------------------------------------------
// E2a: per-token rmsnorm(q), rmsnorm(k), in place in qkv (bf16).
// ---------------------------------------------------------------------------
__global__ __launch_bounds__(256) void e2a_k(
    bf16* __restrict__ qkv,
    const float* __restrict__ qnw, const float* __restrict__ knw)
{
  __shared__ float red[8];
  int s = blockIdx.x, tid = threadIdx.x;
  int lane = tid & 63, w = tid >> 6;
  float qv[8], kv[8];
  float sq = 0.f, sk = 0.f;
  size_t base = (size_t)s*QKV3;
  #pragma unroll
  for(int i=0;i<8;i++){
    int j = tid*8 + i;
    qv[i] = bf2f(qkv[base + j]);
    kv[i] = bf2f(qkv[base + HID + j]);
    sq += qv[i]*qv[i]; sk += kv[i]*kv[i];
  }
  sq = wave_sum(sq); sk = wave_sum(sk);
  if(lane==0){ red[w] = sq; red[4+w] = sk; }
  __syncthreads();
  float rq = rsqrtf((red[0]+red[1]+red[2]+red[3])*(1.f/HID) + 1e-6f);
  float rk = rsqrtf((red[4]+red[5]+red[6]+red[7])*(1.f/HID) + 1e-6f);
  #pragma unroll
  for(int i=0;i<8;i++){
    int j = tid*8 + i;
    qkv[base + j]       = f2bf(qv[i]*rq*qnw[j]);
    qkv[base + HID + j] = f2bf(kv[i]*rk*knw[j]);
  }
}

// ---------------------------------------------------------------------------
// E2b (after attention): overwrite q/k/v regions with fq/fk/fv.
// ---------------------------------------------------------------------------
__global__ __launch_bounds__(256) void e2b_k(
    bf16* __restrict__ qkv,
    const float* __restrict__ qks, const float* __restrict__ qko)
{
  int s = blockIdx.x, tid = threadIdx.x;
  size_t base = (size_t)s*QKV3;
  float a[8], b[8], vv[8];
  float ga = 0.f, gb2 = 0.f;
  #pragma unroll
  for(int i=0;i<8;i++){
    int j = tid*8 + i;
    float qn = bf2f(qkv[base + j]);
    float kn = bf2f(qkv[base + HID + j]);
    float v  = bf2f(qkv[base + 2*HID + j]);
    a[i] = siluf(qn*qks[2*j]   + qko[2*j]);
    b[i] = siluf(kn*qks[2*j+1] + qko[2*j+1]);
    vv[i] = siluf(v);
    ga += a[i]*a[i]; gb2 += b[i]*b[i];
  }
  ga = wave_sum(ga); gb2 = wave_sum(gb2);
  float iq = 1.f / fmaxf(sqrtf(ga), 1e-12f);
  float ik = 1.f / fmaxf(sqrtf(gb2), 1e-12f);
  #pragma unroll
  for(int i=0;i<8;i++){
    int j = tid*8 + i;
    qkv[base + j]         = f2bf(a[i]*iq);
    qkv[base + HID + j]   = f2bf(b[i]*ik);
    qkv[base + 2*HID + j] = f2bf(vv[i]);
  }
}

// ---------------------------------------------------------------------------
// MFMA sliding-window attention (window 256 incl self).
// ---------------------------------------------------------------------------
__global__ __launch_bounds__(256) void attn_k(
    const bf16* __restrict__ qkv, const bft* __restrict__ vT,
    const float* __restrict__ rc, const float* __restrict__ rs,
    float* __restrict__ attn)
{
  __shared__ __align__(16) bft Qs[64*QKP];
  __shared__ __align__(16) bft Ks[64*QKP];
  __shared__ __align__(16) bft Vs[128*VSP];
  __shared__ __align__(16) bft Ps[64*PSP];
  const int head = blockIdx.x >> 7;
  const int Q0 = (blockIdx.x & 127) * 64;
  const int tid = threadIdx.x;
  const int hb = head * HD;
  const int lane = tid & 63;
  const int wm = (tid >> 6) * 16;
  const int fr = lane & 15, fko = (lane >> 4) * 8;
  const int rbase = (lane >> 4) * 4;

  #pragma unroll
  for(int i=0;i<16;i++){
    int e = tid + i*256;
    int rr = e >> 6, d = e & 63;
    int qpos = Q0 + rr;
    size_t b = (size_t)qpos*QKV3 + hb;
    float x1 = bf2f(qkv[b + d]);
    float x2 = bf2f(qkv[b + d + 64]);
    float c = rc[qpos*64 + d], sn = rs[qpos*64 + d];
    Qs[rr*QKP + d]      = (bft)(x1*c - x2*sn);
    Qs[rr*QKP + d + 64] = (bft)(x2*c + x1*sn);
  }
  __syncthreads();
  bf16x8 qf[4];
  #pragma unroll
  for (int kk=0;kk<4;kk++)
    qf[kk] = *(const bf16x8*)(Qs + (wm+fr)*QKP + kk*32 + fko);

  f32x4 Ot[8];
  #pragma unroll
  for (int i=0;i<8;i++) Ot[i] = (f32x4){0.f,0.f,0.f,0.f};
  float m4[4], l4[4];
  #pragma unroll
  for (int r=0;r<4;r++){ m4[r] = -INFINITY; l4[r] = 0.f; }

  for (int kt=0; kt<5; kt++){
    const int kb = Q0 - 256 + kt*64;
    if (kb < 0) continue;
    __syncthreads();
    #pragma unroll
    for(int i=0;i<16;i++){
      int e = tid + i*256;
      int rr = e >> 6, d = e & 63;
      int kpos = kb + rr;
      size_t b = (size_t)kpos*QKV3 + HID + hb;
      float x1 = bf2f(qkv[b + d]);
      float x2 = bf2f(qkv[b + d + 64]);
      float c = rc[kpos*64 + d], sn = rs[kpos*64 + d];
      Ks[rr*QKP + d]      = (bft)(x1*c - x2*sn);
      Ks[rr*QKP + d + 64] = (bft)(x2*c + x1*sn);
    }
    {
      int d = tid >> 1, koff = (tid & 1) * 32;
      const bft* vrow = vT + ((size_t)(hb + d))*S_LEN + kb + koff;
      bft* lrow = Vs + d*VSP + koff;
      #pragma unroll
      for (int j8=0;j8<4;j8++)
        *(bf16x8*)(lrow + j8*8) = *(const bf16x8*)(vrow + j8*8);
    }
    __syncthreads();

    f32x4 st[4];
    #pragma unroll
    for (int nt=0;nt<4;nt++){
      f32x4 acc = (f32x4){0.f,0.f,0.f,0.f};
      #pragma unroll
      for (int kk=0;kk<4;kk++){
        bf16x8 kf = *(const bf16x8*)(Ks + (nt*16+fr)*QKP + kk*32 + fko);
        acc = __builtin_amdgcn_mfma_f32_16x16x32_bf16(qf[kk], kf, acc, 0, 0, 0);
      }
      st[nt] = acc;
    }

    float pv[4][4];
    #pragma unroll
    for (int r=0;r<4;r++){
      int qpos = Q0 + wm + rbase + r;
      float sm[4];
      float mx = -INFINITY;
      #pragma unroll
      for (int nt=0;nt<4;nt++){
        int kpos = kb + nt*16 + fr;
        bool valid = (kpos > qpos - 256) && (kpos <= qpos);
        float s = valid ? st[nt][r] * 0.088388347648318447f : -INFINITY;
        sm[nt] = s;
        mx = fmaxf(mx, s);
      }
      mx = fmaxf(mx, __shfl_xor(mx, 1, 64));
      mx = fmaxf(mx, __shfl_xor(mx, 2, 64));
      mx = fmaxf(mx, __shfl_xor(mx, 4, 64));
      mx = fmaxf(mx, __shfl_xor(mx, 8, 64));
      float mnew = fmaxf(m4[r], mx);
      float alpha = (mnew == -INFINITY) ? 1.f : __expf(m4[r] - mnew);
      float ps = 0.f;
      #pragma unroll
      for (int nt=0;nt<4;nt++){
        float p = (sm[nt] == -INFINITY) ? 0.f : __expf(sm[nt] - mnew);
        pv[nt][r] = p;
        ps += p;
      }
      ps += __shfl_xor(ps, 1, 64);
      ps += __shfl_xor(ps, 2, 64);
      ps += __shfl_xor(ps, 4, 64);
      ps += __shfl_xor(ps, 8, 64);
      l4[r] = l4[r]*alpha + ps;
      m4[r] = mnew;
      #pragma unroll
      for (int ct=0;ct<8;ct++) Ot[ct][r] *= alpha;
    }

    #pragma unroll
    for (int r=0;r<4;r++){
      int row = wm + rbase + r;
      #pragma unroll
      for (int nt=0;nt<4;nt++)
        Ps[row*PSP + nt*16 + fr] = (bft)pv[nt][r];
    }
    bf16x8 af[2];
    #pragma unroll
    for (int kk=0;kk<2;kk++){
      const bft* pp = Ps + (wm+fr)*PSP + kk*32 + fko;
      bf16x4 lo = *(const bf16x4*)pp;
      bf16x4 hi = *(const bf16x4*)(pp+4);
      bf16x8 a;
      #pragma unroll
      for (int j=0;j<4;j++){ a[j]=lo[j]; a[j+4]=hi[j]; }
      af[kk]=a;
    }
    #pragma unroll
    for (int ct=0;ct<8;ct++)
      #pragma unroll
      for (int kk=0;kk<2;kk++){
        bf16x8 bv = *(const bf16x8*)(Vs + (ct*16+fr)*VSP + kk*32 + fko);
        Ot[ct] = __builtin_amdgcn_mfma_f32_16x16x32_bf16(af[kk], bv, Ot[ct], 0, 0, 0);
      }
  }

  #pragma unroll
  for (int r=0;r<4;r++){
    float invl = 1.f / l4[r];
    int qpos = Q0 + wm + rbase + r;
    size_t ob = (size_t)qpos*HID + hb;
    #pragma unroll
    for (int ct=0;ct<8;ct++)
      attn[ob + ct*16 + fr] = Ot[ct][r] * invl;
  }
}

// ---------------------------------------------------------------------------
// TTT elementwise fwd: hid = silu(g)*hm ; opre = silu(qg)*qm (opre -> qg buf)
// ---------------------------------------------------------------------------
__global__ __launch_bounds__(256) void e3_k(
    const bf16* __restrict__ g, const bf16* __restrict__ hm,
    bf16* __restrict__ qg, const bf16* __restrict__ qm,
    bf16* __restrict__ hid)
{
  size_t idx = (size_t)blockIdx.x*256 + threadIdx.x;
  float opre = siluf(bf2f(qg[idx])) * bf2f(qm[idx]);
  hid[idx] = f2bf(siluf(bf2f(g[idx])) * bf2f(hm[idx]));
  qg[idx]  = f2bf(opre);
}

// ---------------------------------------------------------------------------
// TTT backprop elementwise (in place): a0->g, a2->hm, a1->dhid buffer.
// ---------------------------------------------------------------------------
__global__ __launch_bounds__(256) void e4_k(
    bf16* __restrict__ g, bf16* __restrict__ hm, bf16* __restrict__ dhid,
    const bf16* __restrict__ qkv, const float* __restrict__ lrb, int cbase)
{
  size_t idx = (size_t)blockIdx.x*256 + threadIdx.x;
  int h  = (int)(idx >> 20);
  int ci = (int)((idx >> 9) & 2047);
  int d  = (int)(idx & 511);
  int s  = cbase + ci;
  float l0  = lrb[s*12 + h];
  float l1  = lrb[s*12 + 4 + h];
  float l2v = lrb[s*12 + 8 + h];
  float gg = bf2f(g[idx]), hv = bf2f(hm[idx]), dh = bf2f(dhid[idx]);
  float sg = sigm(gg);
  float silu_g = gg * sg;
  float dhm = dh * silu_g;
  float dg  = dh * hv;
  float dgp = dg * (sg * (1.f + gg * (1.f - sg)));
  float fvv = bf2f(qkv[(size_t)s*QKV3 + 2*HID + h*FD + d]);
  g[idx]    = f2bf(dgp * l0);
  hm[idx]   = f2bf(dhm * l2v);
  dhid[idx] = f2bf(fvv * l1);
}

// ---------------------------------------------------------------------------
// E5 (per chunk): X = attn + rmsnorm(ofc)*ttt_norm_w -> q region of qkv
// ---------------------------------------------------------------------------
__global__ __launch_bounds__(256) void e5_k(const float* __restrict__ attn,
    const bf16* __restrict__ ofc, const float* __restrict__ tnw,
    bf16* __restrict__ qkv, int cbase)
{
  int ci = blockIdx.x, tid = threadIdx.x;
  int s = cbase + ci;
  int lane = tid & 63, w = tid >> 6;
  float o[8]; float ss = 0.f;
  size_t ob = ((size_t)w*CHUNK_LEN + ci)*FD + (size_t)lane*8;
  #pragma unroll
  for(int i=0;i<8;i++){ o[i] = bf2f(ofc[ob+i]); ss += o[i]*o[i]; }
  ss = wave_sum(ss);
  float inv = rsqrtf(ss*(1.f/FD) + 1e-6f);
  size_t xb = (size_t)s*QKV3 + w*FD + (size_t)lane*8;
  size_t ab = (size_t)s*HID  + w*FD + (size_t)lane*8;
  #pragma unroll
  for(int i=0;i<8;i++){
    int d = lane*8 + i;
    qkv[xb+i] = f2bf(attn[ab+i] + o[i]*inv*tnw[d]);
  }
}

// ---------------------------------------------------------------------------
extern "C" void kernel_launch(void* const* d_in, const int* in_sizes, int n_in,
                              void* d_out, int out_size, void* d_ws, size_t ws_size,
                              hipStream_t stream)
{
  (void)in_sizes; (void)n_in; (void)out_size;
  const float* hidden   = (const float*)d_in[0];
  const float* qkv_w    = (const float*)d_in[1];
  const float* q_norm_w = (const float*)d_in[2];
  const float* k_norm_w = (const float*)d_in[3];
  const float* qk_scale = (const float*)d_in[4];
  const float* qk_off   = (const float*)d_in[5];
  const float* lr_w     = (const float*)d_in[6];
  const float* lr_b     = (const float*)d_in[7];
  const float* w0_in    = (const float*)d_in[8];
  const float* w1_in    = (const float*)d_in[9];
  const float* w2_in    = (const float*)d_in[10];
  const float* ttt_nw   = (const float*)d_in[11];
  const float* o_proj   = (const float*)d_in[12];
  float* out = (float*)d_out;

  char* p = (char*)d_ws;
  auto alloc = [&](size_t n){ char* r = p; p += (n + 255) & ~(size_t)255; return (void*)r; };

  bf16*  qkv   = (bf16*) alloc((size_t)S_LEN*QKV3*sizeof(bf16));
  float* lrb   = (float*)alloc((size_t)S_LEN*12*sizeof(float));
  float* rc    = (float*)alloc((size_t)S_LEN*64*sizeof(float));
  float* rs    = (float*)alloc((size_t)S_LEN*64*sizeof(float));
  float* w0s   = (float*)alloc((size_t)NFW*FD*FD*sizeof(float));
  float* w1s   = (float*)alloc((size_t)NFW*FD*FD*sizeof(float));
  float* w2s   = (float*)alloc((size_t)NFW*FD*FD*sizeof(float));
  bft*   w1tb  = (bft*)  alloc((size_t)NFW*FD*FD*sizeof(bft));
  bft*   w0b   = (bft*)  alloc((size_t)NFW*FD*FD*sizeof(bft));
  bft*   w1b   = (bft*)  alloc((size_t)NFW*FD*FD*sizeof(bft));
  bft*   w2b   = (bft*)  alloc((size_t)NFW*FD*FD*sizeof(bft));
  bf16*  gb    = (bf16*) alloc((size_t)NFW*CHUNK_LEN*FD*sizeof(bf16));
  bf16*  hmb   = (bf16*) alloc((size_t)NFW*CHUNK_LEN*FD*sizeof(bf16));
  bf16*  qgb   = (bf16*) alloc((size_t)NFW*CHUNK_LEN*FD*sizeof(bf16));
  bf16*  qmb   = (bf16*) alloc((size_t)NFW*CHUNK_LEN*FD*sizeof(bf16));
  bf16*  hidb  = (bf16*) alloc((size_t)NFW*CHUNK_LEN*FD*sizeof(bf16));
  bf16*  ofc   = (bf16*) alloc((size_t)NFW*CHUNK_LEN*FD*sizeof(bf16));
  bft*   fkT   = (bft*)  alloc((size_t)NFW*FD*CHUNK_LEN*sizeof(bft));
  bft*   hidT  = (bft*)  alloc((size_t)NFW*FD*CHUNK_LEN*sizeof(bft));
  bft*   a2T   = (bft*)  alloc((size_t)NFW*FD*CHUNK_LEN*sizeof(bft));
  bft*   a1T   = (bft*)  alloc((size_t)NFW*FD*CHUNK_LEN*sizeof(bft));

  if ((size_t)(p - (char*)d_ws) > ws_size) return;

  // Liveness aliases (no extra workspace):
  // hidden_bf (33.55 MB) = gb..qmb  — dead before chunk loop writes gb.
  // qkvw_bf   (25.17 MB) = fkT..a2T — dead before vt_k writes vT.
  // vT        (33.55 MB) = fkT..a1T — dead before chunk loop's tr_k.
  // opw_bf    ( 8.39 MB) = hidb..   — converted after last e5, before o_proj.
  bft* hidden_bf = (bft*)gb;
  bft* qkvw_bf   = (bft*)fkT;
  bft* vT        = (bft*)fkT;
  bft* opw_bf    = (bft*)hidb;

  float* attn = out;   // attn lives in d_out until the final projection

  hipMemcpyAsync(w0s, w0_in, (size_t)NFW*FD*FD*sizeof(float), hipMemcpyDeviceToDevice, stream);
  hipMemcpyAsync(w1s, w1_in, (size_t)NFW*FD*FD*sizeof(float), hipMemcpyDeviceToDevice, stream);
  hipMemcpyAsync(w2s, w2_in, (size_t)NFW*FD*FD*sizeof(float), hipMemcpyDeviceToDevice, stream);

  rope_k<<<S_LEN, 64, 0, stream>>>(rc, rs);
  lr_k<<<S_LEN, 256, 0, stream>>>(hidden, lr_w, lr_b, lrb);
  tcw1_k<<<NFW*FD*FD/256, 256, 0, stream>>>(w1_in, w1tb);
  cvt_k<<<(NFW*FD*FD)/2048, 256, 0, stream>>>(w0_in, w0b);
  cvt_k<<<(NFW*FD*FD)/2048, 256, 0, stream>>>(w1_in, w1b);
  cvt_k<<<(NFW*FD*FD)/2048, 256, 0, stream>>>(w2_in, w2b);
  cvt_k<<<(S_LEN*HID)/2048, 256, 0, stream>>>(hidden, hidden_bf);
  cvt_k<<<(QKV3*HID)/2048, 256, 0, stream>>>(qkv_w, qkvw_bf);

  // qkv = hidden @ qkv_w^T -> bf16   (256^2 pipelined GEMM)
  mgemm8<0>(stream, hidden_bf, qkvw_bf, (void*)qkv, S_LEN, QKV3, HID, HID, HID, QKV3);

  e2a_k<<<S_LEN, 256, 0, stream>>>(qkv, q_norm_w, k_norm_w);
  vt_k<<<dim3(S_LEN/64, NH), 256, 0, stream>>>(qkv, vT);
  attn_k<<<NH*128, 256, 0, stream>>>(qkv, vT, rc, rs, attn);
  e2b_k<<<S_LEN, 256, 0, stream>>>(qkv, qk_scale, qk_off);

  const long sW  = (long)FD*FD;
  const long sCh = (long)CHUNK_LEN*FD;
  const long sT  = (long)FD*CHUNK_LEN;
  const int  NEL = NFW*CHUNK_LEN*FD/256;
  const dim3 tg(FD/64, CHUNK_LEN/64, NFW);

  for(int c=0; c<NCHUNK; c++){
    const bft* fqc = (const bft*)qkv + (size_t)c*CHUNK_LEN*QKV3;
    const bft* fkc = fqc + HID;
    const bft* fvc = fqc + 2*HID;
    mgemm<128,128,0>(stream, fkc, w0b, gb,  nullptr, nullptr, CHUNK_LEN, FD, FD, QKV3, FD, FD, NFW, FD, sW, sCh);
    mgemm<128,128,0>(stream, fkc, w2b, hmb, nullptr, nullptr, CHUNK_LEN, FD, FD, QKV3, FD, FD, NFW, FD, sW, sCh);
    mgemm<128,128,0>(stream, fqc, w0b, qgb, nullptr, nullptr, CHUNK_LEN, FD, FD, QKV3, FD, FD, NFW, FD, sW, sCh);
    mgemm<128,128,0>(stream, fqc, w2b, qmb, nullptr, nullptr, CHUNK_LEN, FD, FD, QKV3, FD, FD, NFW, FD, sW, sCh);
    e3_k<<<NEL, 256, 0, stream>>>(gb, hmb, qgb, qmb, hidb);
    mgemm<128,128,0>(stream, (const bft*)qgb, w1b, ofc, nullptr, nullptr, CHUNK_LEN, FD, FD, FD, FD, FD, NFW, sCh, sW, sCh);
    mgemm<128,128,0>(stream, fvc, (const bft*)w1tb, qmb, nullptr, nullptr, CHUNK_LEN, FD, FD, QKV3, FD, FD, NFW, FD, sW, sCh);
    e4_k<<<NEL, 256, 0, stream>>>(gb, hmb, qmb, qkv, lrb, c*CHUNK_LEN);
    tr_k<<<tg, 256, 0, stream>>>(fkc,              fkT,        QKV3, FD,  sT);
    tr_k<<<tg, 256, 0, stream>>>((const bft*)hidb, hidT,       FD,   sCh, sT);
    tr_k<<<tg, 256, 0, stream>>>((const bft*)gb,   (bft*)qgb,  FD,   sCh, sT);
    tr_k<<<tg, 256, 0, stream>>>((const bft*)hmb,  a2T,        FD,   sCh, sT);
    tr_k<<<tg, 256, 0, stream>>>((const bft*)qmb,  a1T,        FD,   sCh, sT);
    mgemm<64,64,2>(stream, (const bft*)qgb, fkT,  w0s, w0b, nullptr, FD, FD, CHUNK_LEN, CHUNK_LEN, CHUNK_LEN, FD, NFW, sT, sT, sW);
    mgemm<64,64,2>(stream, a2T,             fkT,  w2s, w2b, nullptr, FD, FD, CHUNK_LEN, CHUNK_LEN, CHUNK_LEN, FD, NFW, sT, sT, sW);
    mgemm<64,64,2>(stream, a1T,             hidT, w1s, w1b, w1tb,    FD, FD, CHUNK_LEN, CHUNK_LEN, CHUNK_LEN, FD, NFW, sT, sT, sW);
    e5_k<<<CHUNK_LEN, 256, 0, stream>>>(attn, ofc, ttt_nw, qkv, c*CHUNK_LEN);
  }

  // bf16 copy of o_proj (hidb/ofc are dead now), then final projection
  cvt_k<<<(HID*HID)/2048, 256, 0, stream>>>(o_proj, opw_bf);
  mgemm8<1>(stream, (const bft*)qkv, opw_bf, out, S_LEN, HID, HID, QKV3, HID, HID);
}

// Round 5
// 1506.767 us; speedup vs baseline: 1.1897x; 1.0273x over previous
//
#include <hip/hip_runtime.h>
#include <hip/hip_bf16.h>

typedef __hip_bfloat16 bf16;
typedef __bf16 bft;
typedef bft bf16x8 __attribute__((ext_vector_type(8)));
typedef bft bf16x4 __attribute__((ext_vector_type(4)));
typedef float f32x4 __attribute__((ext_vector_type(4)));

#define S_LEN 8192
#define HID   2048
#define QKV3  6144
#define NH    16
#define HD    128
#define NFW   4
#define FD    512
#define CHUNK_LEN 2048
#define NCHUNK 4
#define BASE_LR_INV (-6.9072552f)   // log(expm1(0.001))
#define QKP 136                     // attn Q/K LDS stride (128 + 8)
#define VSP 72                      // attn V^T LDS stride (64 + 8)
#define PSP 76                      // attn P LDS stride (64 + 12)

__device__ __forceinline__ float bf2f(bf16 x){ return __bfloat162float(x); }
__device__ __forceinline__ bf16  f2bf(float x){ return __float2bfloat16(x); }
__device__ __forceinline__ float sigm(float x){ return 1.f/(1.f+__expf(-x)); }
__device__ __forceinline__ float siluf(float x){ return x/(1.f+__expf(-x)); }
__device__ __forceinline__ float wave_sum(float v){
  #pragma unroll
  for(int off=32; off; off>>=1) v += __shfl_xor(v, off, 64);
  return v;
}

template<int N>
__device__ __forceinline__ void waitcnt_vm(){
  static_assert(N==0||N==2||N==4||N==8, "unsupported vmcnt");
  if constexpr (N==0)      asm volatile("s_waitcnt vmcnt(0)" ::: "memory");
  else if constexpr (N==2) asm volatile("s_waitcnt vmcnt(2)" ::: "memory");
  else if constexpr (N==4) asm volatile("s_waitcnt vmcnt(4)" ::: "memory");
  else                     asm volatile("s_waitcnt vmcnt(8)" ::: "memory");
}

// Raw barrier, NO sched_barrier pinning (m141: pinning defeats the
// compiler's own lgkmcnt scheduling).
__device__ __forceinline__ void bar(){
  __builtin_amdgcn_s_barrier();
  asm volatile("" ::: "memory");
}

// ---------------------------------------------------------------------------
// GEMM LDS tile staging (bf16 only), swizzled layout.
// Tile: ROWS x 32 bf16, unpadded [row][32]; physical col-slot c (8 elems)
// holds logical col-group g = c ^ ((row>>1)&3).
// global_load_lds 16B/lane; LDS dest = wave-uniform base + lane*16.
// ---------------------------------------------------------------------------
template<int ROWS>
__device__ __forceinline__ void stage(const bft* __restrict__ src, long ld,
                                      bft* dst, int tid)
{
  const int lane = tid & 63, wv = tid >> 6;
  #pragma unroll
  for (int i = 0; i < ROWS/64; ++i) {
    const int r0 = wv*16 + i*64;               // wave-uniform
    const int row = r0 + (lane >> 2);
    const int g = (lane & 3) ^ ((row >> 1) & 3);
    const bft* gp = src + (size_t)row*ld + g*8;
    bft* lp = dst + (size_t)r0*32;
    __builtin_amdgcn_global_load_lds(
        (const __attribute__((address_space(1))) void*)gp,
        (__attribute__((address_space(3))) void*)lp, 16, 0, 0);
  }
}

// ---------------------------------------------------------------------------
// MFMA NT GEMM: C[M,N] (+)= A[M,K] * B[N,K]^T, fp32 accumulate, 256 threads.
// 4-slot circular LDS pipeline (BK=32), counted vmcnt (never drained to 0
// in steady state), m201-style phase skeleton.
// Race-freedom: slot written at iter s is (s+2)&3; concurrent readers touch
// s&3 (distinct mod 4); reads of the overwritten buffer finished >=1 barrier
// earlier. vmcnt ladder leaves slot s+2's LPT loads in flight.
// EPI: 0 = store bf16, 1 = store fp32, 2 = fp32 C += acc, bf16 direct shadow
// Cd (z-stride sCd, row stride ldc), optional transposed shadow Ct.
// ---------------------------------------------------------------------------
template<int BM,int BN,int EPI>
__global__ __launch_bounds__(256) void mgemm_k(
    const bft* __restrict__ A, const bft* __restrict__ B, void* __restrict__ Cv,
    bft* __restrict__ Cd, bft* __restrict__ Ct, int K,
    long lda, long ldb, long ldc, long sA, long sB, long sC, long sCd)
{
  constexpr int AM = BM/32, AN = BN/32;
  constexpr int LPT = BM/64 + BN/64;           // global_load_lds per wave/slot
  constexpr int NPH = (AM >= 4) ? 2 : 1;       // compute phases per slot
  constexpr int MH  = AM / NPH;                // mi rows per phase
  __shared__ __align__(16) bft As[4][BM*32];
  __shared__ __align__(16) bft Bs[4][BN*32];
  const int tid = threadIdx.x;
  const int z = blockIdx.z;
  A += (size_t)z * sA;
  B += (size_t)z * sB;
  const size_t m0 = (size_t)blockIdx.y * BM, n0 = (size_t)blockIdx.x * BN;
  const int wv = tid >> 6, lane = tid & 63;
  const int wm = (wv & 1) * (BM/2), wn = (wv >> 1) * (BN/2);
  const int fr = lane & 15;
  const int fsw = ((lane >> 4) ^ ((fr >> 1) & 3)) * 8;   // swizzled frag col

  f32x4 acc[AM][AN];
  #pragma unroll
  for (int i=0;i<AM;i++)
    #pragma unroll
    for (int j=0;j<AN;j++) acc[i][j] = (f32x4){0.f,0.f,0.f,0.f};

  const bft* Ab = A + m0*lda;
  const bft* Bb = B + n0*ldb;
  const int NS = K >> 5;

  stage<BM>(Ab,      lda, As[0], tid);
  stage<BN>(Bb,      ldb, Bs[0], tid);
  stage<BM>(Ab + 32, lda, As[1], tid);
  stage<BN>(Bb + 32, ldb, Bs[1], tid);
  waitcnt_vm<LPT>();
  bar();

  for (int s = 0; s < NS; ++s) {
    const bft* Ap = As[s & 3];
    const bft* Bp = Bs[s & 3];
    const int kt = (s + 2) * 32;
    const bool st = (s + 2 < NS);

    bf16x8 bvv[AN], afv[MH];
    // ---- phase A: all B-frags + first mi half; stage next A-tile ----
    #pragma unroll
    for (int ni=0; ni<AN; ni++)
      bvv[ni] = *(const bf16x8*)(Bp + (size_t)(wn + ni*16 + fr)*32 + fsw);
    #pragma unroll
    for (int i=0; i<MH; i++)
      afv[i] = *(const bf16x8*)(Ap + (size_t)(wm + i*16 + fr)*32 + fsw);
    if (st) stage<BM>(Ab + kt, lda, As[(s+2)&3], tid);
    if constexpr (NPH == 1) {
      if (st) { stage<BN>(Bb + kt, ldb, Bs[(s+2)&3], tid); waitcnt_vm<LPT>(); }
      else waitcnt_vm<0>();
    }
    bar();
    __builtin_amdgcn_s_setprio(1);
    #pragma unroll
    for (int i=0; i<MH; i++)
      #pragma unroll
      for (int ni=0; ni<AN; ni++)
        acc[i][ni] = __builtin_amdgcn_mfma_f32_16x16x32_bf16(afv[i], bvv[ni], acc[i][ni], 0, 0, 0);
    __builtin_amdgcn_s_setprio(0);

    if constexpr (NPH == 2) {
      bar();
      // ---- phase B: second mi half; stage next B-tile; vm ladder ----
      #pragma unroll
      for (int i=0; i<MH; i++)
        afv[i] = *(const bf16x8*)(Ap + (size_t)(wm + (MH+i)*16 + fr)*32 + fsw);
      if (st) { stage<BN>(Bb + kt, ldb, Bs[(s+2)&3], tid); waitcnt_vm<LPT>(); }
      else waitcnt_vm<0>();
      bar();
      __builtin_amdgcn_s_setprio(1);
      #pragma unroll
      for (int i=0; i<MH; i++)
        #pragma unroll
        for (int ni=0; ni<AN; ni++)
          acc[MH+i][ni] = __builtin_amdgcn_mfma_f32_16x16x32_bf16(afv[i], bvv[ni], acc[MH+i][ni], 0, 0, 0);
      __builtin_amdgcn_s_setprio(0);
      bar();
    }
  }

  const int er = (lane >> 4) * 4;   // C/D: row=(lane>>4)*4+reg, col=lane&15
  const int ec = lane & 15;
  #pragma unroll
  for (int mi=0; mi<AM; mi++){
    #pragma unroll
    for (int ni=0; ni<AN; ni++){
      #pragma unroll
      for (int r=0; r<4; r++){
        size_t row = m0 + wm + mi*16 + er + r;
        size_t col = n0 + wn + ni*16 + ec;
        size_t idx = (size_t)z*sC + row*ldc + col;
        float v = acc[mi][ni][r];
        if constexpr (EPI == 0){
          ((bft*)Cv)[idx] = (bft)v;
        } else if constexpr (EPI == 1){
          ((float*)Cv)[idx] = v;
        } else {
          float nv = ((float*)Cv)[idx] + v;
          ((float*)Cv)[idx] = nv;
          Cd[(size_t)z*sCd + row*ldc + col] = (bft)nv;
          if (Ct) Ct[(size_t)z*FD*FD + col*FD + row] = (bft)nv;
        }
      }
    }
  }
}

template<int BM,int BN,int EPI>
static inline void mgemm(hipStream_t st, const bft* A, const bft* B, void* C,
    bft* Cd, bft* Ct, int M, int N, int K, long lda, long ldb, long ldc,
    int batch, long sA, long sB, long sC, long sCd)
{
  dim3 g(N/BN, M/BM, batch);
  mgemm_k<BM,BN,EPI><<<g, 256, 0, st>>>(A, B, C, Cd, Ct, K, lda, ldb, ldc, sA, sB, sC, sCd);
}

// ---------------------------------------------------------------------------
// 256x256 MFMA NT GEMM, 4-slot pipeline, 512 threads = 8 waves (2Mx4N),
// per-wave 128x64 output. 2 phases/slot x 16 MFMA, counted vmcnt.
// LDS = 128 KiB. XCD-aware bijective block swizzle.
// ---------------------------------------------------------------------------
__device__ __forceinline__ void stage8(const bft* __restrict__ src, long ld,
                                       bft* dst, int tid)
{
  const int lane = tid & 63, wv = tid >> 6;      // 8 waves
  #pragma unroll
  for (int i = 0; i < 2; ++i) {
    const int r0 = wv*16 + i*128;                // wave-uniform
    const int row = r0 + (lane >> 2);
    const int g = (lane & 3) ^ ((row >> 1) & 3);
    const bft* gp = src + (size_t)row*ld + g*8;
    bft* lp = dst + (size_t)r0*32;
    __builtin_amdgcn_global_load_lds(
        (const __attribute__((address_space(1))) void*)gp,
        (__attribute__((address_space(3))) void*)lp, 16, 0, 0);
  }
}

#define M8_ROW(mi, a) { \
    acc[mi][0]=__builtin_amdgcn_mfma_f32_16x16x32_bf16(a,bv[0],acc[mi][0],0,0,0); \
    acc[mi][1]=__builtin_amdgcn_mfma_f32_16x16x32_bf16(a,bv[1],acc[mi][1],0,0,0); \
    acc[mi][2]=__builtin_amdgcn_mfma_f32_16x16x32_bf16(a,bv[2],acc[mi][2],0,0,0); \
    acc[mi][3]=__builtin_amdgcn_mfma_f32_16x16x32_bf16(a,bv[3],acc[mi][3],0,0,0); }

template<int EPI>
__global__ __launch_bounds__(512, 2) void mgemm8_k(
    const bft* __restrict__ A, const bft* __restrict__ B, void* __restrict__ Cv,
    int K, long lda, long ldb, long ldc)
{
  __shared__ __align__(16) bft As[4][256*32];
  __shared__ __align__(16) bft Bs[4][256*32];
  const int tid = threadIdx.x;

  const int gx = (int)gridDim.x;
  const int nwg = (int)(gridDim.x * gridDim.y);
  int lin = (int)(blockIdx.y * gridDim.x + blockIdx.x);
  if ((nwg & 7) == 0) lin = (lin & 7) * (nwg >> 3) + (lin >> 3);
  const size_t m0 = (size_t)(lin / gx) * 256;
  const size_t n0 = (size_t)(lin % gx) * 256;

  const int wv = tid >> 6, lane = tid & 63;
  const int wm = (wv & 1) * 128, wn = (wv >> 1) * 64;
  const int fr = lane & 15;
  const int fsw = ((lane >> 4) ^ ((fr >> 1) & 3)) * 8;

  f32x4 acc[8][4];
  #pragma unroll
  for (int i=0;i<8;i++)
    #pragma unroll
    for (int j=0;j<4;j++) acc[i][j] = (f32x4){0.f,0.f,0.f,0.f};

  const bft* Ab = A + m0*lda;
  const bft* Bb = B + n0*ldb;
  const int NS = K >> 5;

  stage8(Ab,      lda, As[0], tid);
  stage8(Bb,      ldb, Bs[0], tid);
  stage8(Ab + 32, lda, As[1], tid);
  stage8(Bb + 32, ldb, Bs[1], tid);
  waitcnt_vm<4>();
  bar();

  for (int s = 0; s < NS; ++s) {
    const bft* Ap = As[s & 3];
    const bft* Bp = Bs[s & 3];
    const int kt = (s + 2) * 32;
    const bool st = (s + 2 < NS);
    bf16x8 bv[4], a0, a1, a2, a3;

    // ---- phase A: B-frags + A rows 0-3; stage next A-tile ----
    bv[0] = *(const bf16x8*)(Bp + (size_t)(wn +  0 + fr)*32 + fsw);
    bv[1] = *(const bf16x8*)(Bp + (size_t)(wn + 16 + fr)*32 + fsw);
    bv[2] = *(const bf16x8*)(Bp + (size_t)(wn + 32 + fr)*32 + fsw);
    bv[3] = *(const bf16x8*)(Bp + (size_t)(wn + 48 + fr)*32 + fsw);
    a0 = *(const bf16x8*)(Ap + (size_t)(wm +  0 + fr)*32 + fsw);
    a1 = *(const bf16x8*)(Ap + (size_t)(wm + 16 + fr)*32 + fsw);
    a2 = *(const bf16x8*)(Ap + (size_t)(wm + 32 + fr)*32 + fsw);
    a3 = *(const bf16x8*)(Ap + (size_t)(wm + 48 + fr)*32 + fsw);
    if (st) stage8(Ab + kt, lda, As[(s+2)&3], tid);
    bar();
    __builtin_amdgcn_s_setprio(1);
    M8_ROW(0, a0); M8_ROW(1, a1); M8_ROW(2, a2); M8_ROW(3, a3);
    __builtin_amdgcn_s_setprio(0);
    bar();

    // ---- phase B: A rows 4-7; stage next B-tile; vm ladder ----
    a0 = *(const bf16x8*)(Ap + (size_t)(wm +  64 + fr)*32 + fsw);
    a1 = *(const bf16x8*)(Ap + (size_t)(wm +  80 + fr)*32 + fsw);
    a2 = *(const bf16x8*)(Ap + (size_t)(wm +  96 + fr)*32 + fsw);
    a3 = *(const bf16x8*)(Ap + (size_t)(wm + 112 + fr)*32 + fsw);
    if (st) { stage8(Bb + kt, ldb, Bs[(s+2)&3], tid); waitcnt_vm<4>(); }
    else waitcnt_vm<0>();
    bar();
    __builtin_amdgcn_s_setprio(1);
    M8_ROW(4, a0); M8_ROW(5, a1); M8_ROW(6, a2); M8_ROW(7, a3);
    __builtin_amdgcn_s_setprio(0);
    bar();
  }

  const int er = (lane >> 4) * 4;
  const int ec = lane & 15;
  #pragma unroll
  for (int mi=0; mi<8; mi++){
    #pragma unroll
    for (int ni=0; ni<4; ni++){
      #pragma unroll
      for (int r=0; r<4; r++){
        size_t row = m0 + wm + mi*16 + er + r;
        size_t col = n0 + wn + ni*16 + ec;
        size_t idx = row*ldc + col;
        float v = acc[mi][ni][r];
        if constexpr (EPI == 0) ((bft*)Cv)[idx] = (bft)v;
        else                    ((float*)Cv)[idx] = v;
      }
    }
  }
}

template<int EPI>
static inline void mgemm8(hipStream_t st, const bft* A, const bft* B, void* C,
                          int M, int N, int K, long lda, long ldb, long ldc)
{
  dim3 g(N/256, M/256, 1);
  mgemm8_k<EPI><<<g, 512, 0, st>>>(A, B, C, K, lda, ldb, ldc);
}

// ---------------------------------------------------------------------------
// fp32 -> bf16 bulk convert (8 elems/thread); n must divide 2048.
// ---------------------------------------------------------------------------
__global__ __launch_bounds__(256) void cvt_k(const float* __restrict__ s,
    bft* __restrict__ d)
{
  size_t i = ((size_t)blockIdx.x*256 + threadIdx.x) * 8;
  const float4 v0 = *(const float4*)(s + i);
  const float4 v1 = *(const float4*)(s + i + 4);
  bf16x8 b;
  b[0]=(bft)v0.x; b[1]=(bft)v0.y; b[2]=(bft)v0.z; b[3]=(bft)v0.w;
  b[4]=(bft)v1.x; b[5]=(bft)v1.y; b[6]=(bft)v1.z; b[7]=(bft)v1.w;
  *(bf16x8*)(d + i) = b;
}

// ---------------------------------------------------------------------------
// Batched bf16 transpose: out[z][c][r] = in[z][r][c]; arbitrary ldin/sIn.
// ---------------------------------------------------------------------------
__global__ __launch_bounds__(256) void tr_k(const bft* __restrict__ in,
    bft* __restrict__ out, long ldin, long sIn, long sOut)
{
  __shared__ __align__(16) bft t[64][72];
  const int c0 = blockIdx.x*64, r0 = blockIdx.y*64;
  in  += (size_t)blockIdx.z * sIn;
  out += (size_t)blockIdx.z * sOut;
  const int tid = threadIdx.x;
  #pragma unroll
  for (int i=0;i<2;i++){
    int e = tid + i*256;
    int r = e >> 3, c8 = (e & 7) * 8;
    *(bf16x8*)&t[r][c8] = *(const bf16x8*)(in + (size_t)(r0+r)*ldin + c0 + c8);
  }
  __syncthreads();
  #pragma unroll
  for (int i=0;i<2;i++){
    int e = tid + i*256;
    int c = e >> 3, r8 = (e & 7) * 8;
    bf16x8 v;
    #pragma unroll
    for (int j=0;j<8;j++) v[j] = t[r8+j][c];
    *(bf16x8*)(out + (size_t)(c0+c)*CHUNK_LEN + r0 + r8) = v;
  }
}

// initial w1^T bf16 shadow: w1tb[z][h][o] = (bf16)w1[z][o][h]
__global__ __launch_bounds__(256) void tcw1_k(const float* __restrict__ w1,
    bft* __restrict__ w1tb)
{
  size_t idx = (size_t)blockIdx.x*256 + threadIdx.x;
  int z = (int)(idx >> 18);
  int h = (int)((idx >> 9) & 511);
  int o = (int)(idx & 511);
  w1tb[idx] = (bft)w1[(size_t)z*FD*FD + (size_t)o*FD + h];
}

// ---------------------------------------------------------------------------
// v^T for attention PV: vT[h][d][s] = v[s][h*128+d] (raw v region of qkv).
// ---------------------------------------------------------------------------
__global__ __launch_bounds__(256) void vt_k(const bf16* __restrict__ qkv,
    bft* __restrict__ vT)
{
  __shared__ __align__(16) bft t[64*QKP];   // [s][d]
  const int s0 = blockIdx.x * 64;
  const int h  = blockIdx.y;
  const int tid = threadIdx.x;
  #pragma unroll
  for (int i=0;i<4;i++){
    int e = tid + i*256;
    int rr = e >> 4, doff = (e & 15) * 8;
    *(bf16x8*)(t + rr*QKP + doff) =
        *(const bf16x8*)((const bft*)qkv + (size_t)(s0+rr)*QKV3 + 2*HID + h*HD + doff);
  }
  __syncthreads();
  #pragma unroll
  for (int it=0; it<4; it++){
    int d = (tid >> 3) + it*32;
    int so8 = (tid & 7) * 8;
    bf16x8 v;
    #pragma unroll
    for (int j=0;j<8;j++) v[j] = t[(so8+j)*QKP + d];
    *(bf16x8*)(vT + ((size_t)(h*HD + d))*S_LEN + s0 + so8) = v;
  }
}

// ---------------------------------------------------------------------------
// RoPE cos/sin tables
// ---------------------------------------------------------------------------
__global__ void rope_k(float* __restrict__ rc, float* __restrict__ rs){
  int pos = blockIdx.x, d = threadIdx.x;
  float inv = 1.f / powf(500000.0f, (float)d * (1.0f/64.0f));
  float ang = (float)pos * inv;
  rc[pos*64+d] = cosf(ang);
  rs[pos*64+d] = sinf(ang);
}

// ---------------------------------------------------------------------------
// per-token learning rates
// ---------------------------------------------------------------------------
__global__ __launch_bounds__(256) void lr_k(const float* __restrict__ hidden,
    const float* __restrict__ lr_w, const float* __restrict__ lr_b,
    float* __restrict__ lro)
{
  __shared__ float hrow[HID];
  __shared__ float red[4][12];
  int s = blockIdx.x, tid = threadIdx.x;
  for(int i=0;i<HID/256;i++) hrow[tid+256*i] = hidden[(size_t)s*HID + tid + 256*i];
  __syncthreads();
  float part[12];
  #pragma unroll
  for(int o=0;o<12;o++) part[o]=0.f;
  for(int i=0;i<HID/256;i++){
    int j = tid + 256*i;
    float h = hrow[j];
    #pragma unroll
    for(int o=0;o<12;o++) part[o] += h * lr_w[o*HID + j];
  }
  int lane = tid & 63, w = tid >> 6;
  #pragma unroll
  for(int o=0;o<12;o++){
    float v = wave_sum(part[o]);
    if(lane==0) red[w][o] = v;
  }
  __syncthreads();
  if(tid < 12){
    float v = red[0][tid]+red[1][tid]+red[2][tid]+red[3][tid] + lr_b[tid] + BASE_LR_INV;
    float sp = (v > 20.f) ? v : log1pf(expf(v));
    lro[s*12 + tid] = sp;
  }
}

// ---------------------------------------------------------------------------
// E2a: per-token rmsnorm(q), rmsnorm(k), in place in qkv (bf16).
// ---------------------------------------------------------------------------
__global__ __launch_bounds__(256) void e2a_k(
    bf16* __restrict__ qkv,
    const float* __restrict__ qnw, const float* __restrict__ knw)
{
  __shared__ float red[8];
  int s = blockIdx.x, tid = threadIdx.x;
  int lane = tid & 63, w = tid >> 6;
  float qv[8], kv[8];
  float sq = 0.f, sk = 0.f;
  size_t base = (size_t)s*QKV3;
  #pragma unroll
  for(int i=0;i<8;i++){
    int j = tid*8 + i;
    qv[i] = bf2f(qkv[base + j]);
    kv[i] = bf2f(qkv[base + HID + j]);
    sq += qv[i]*qv[i]; sk += kv[i]*kv[i];
  }
  sq = wave_sum(sq); sk = wave_sum(sk);
  if(lane==0){ red[w] = sq; red[4+w] = sk; }
  __syncthreads();
  float rq = rsqrtf((red[0]+red[1]+red[2]+red[3])*(1.f/HID) + 1e-6f);
  float rk = rsqrtf((red[4]+red[5]+red[6]+red[7])*(1.f/HID) + 1e-6f);
  #pragma unroll
  for(int i=0;i<8;i++){
    int j = tid*8 + i;
    qkv[base + j]       = f2bf(qv[i]*rq*qnw[j]);
    qkv[base + HID + j] = f2bf(kv[i]*rk*knw[j]);
  }
}

// ---------------------------------------------------------------------------
// E2b (after attention): overwrite q/k/v regions with fq/fk/fv.
// ---------------------------------------------------------------------------
__global__ __launch_bounds__(256) void e2b_k(
    bf16* __restrict__ qkv,
    const float* __restrict__ qks, const float* __restrict__ qko)
{
  int s = blockIdx.x, tid = threadIdx.x;
  size_t base = (size_t)s*QKV3;
  float a[8], b[8], vv[8];
  float ga = 0.f, gb2 = 0.f;
  #pragma unroll
  for(int i=0;i<8;i++){
    int j = tid*8 + i;
    float qn = bf2f(qkv[base + j]);
    float kn = bf2f(qkv[base + HID + j]);
    float v  = bf2f(qkv[base + 2*HID + j]);
    a[i] = siluf(qn*qks[2*j]   + qko[2*j]);
    b[i] = siluf(kn*qks[2*j+1] + qko[2*j+1]);
    vv[i] = siluf(v);
    ga += a[i]*a[i]; gb2 += b[i]*b[i];
  }
  ga = wave_sum(ga); gb2 = wave_sum(gb2);
  float iq = 1.f / fmaxf(sqrtf(ga), 1e-12f);
  float ik = 1.f / fmaxf(sqrtf(gb2), 1e-12f);
  #pragma unroll
  for(int i=0;i<8;i++){
    int j = tid*8 + i;
    qkv[base + j]         = f2bf(a[i]*iq);
    qkv[base + HID + j]   = f2bf(b[i]*ik);
    qkv[base + 2*HID + j] = f2bf(vv[i]);
  }
}

// ---------------------------------------------------------------------------
// MFMA sliding-window attention (window 256 incl self).
// ---------------------------------------------------------------------------
__global__ __launch_bounds__(256) void attn_k(
    const bf16* __restrict__ qkv, const bft* __restrict__ vT,
    const float* __restrict__ rc, const float* __restrict__ rs,
    float* __restrict__ attn)
{
  __shared__ __align__(16) bft Qs[64*QKP];
  __shared__ __align__(16) bft Ks[64*QKP];
  __shared__ __align__(16) bft Vs[128*VSP];
  __shared__ __align__(16) bft Ps[64*PSP];
  const int head = blockIdx.x >> 7;
  const int Q0 = (blockIdx.x & 127) * 64;
  const int tid = threadIdx.x;
  const int hb = head * HD;
  const int lane = tid & 63;
  const int wm = (tid >> 6) * 16;
  const int fr = lane & 15, fko = (lane >> 4) * 8;
  const int rbase = (lane >> 4) * 4;

  #pragma unroll
  for(int i=0;i<16;i++){
    int e = tid + i*256;
    int rr = e >> 6, d = e & 63;
    int qpos = Q0 + rr;
    size_t b = (size_t)qpos*QKV3 + hb;
    float x1 = bf2f(qkv[b + d]);
    float x2 = bf2f(qkv[b + d + 64]);
    float c = rc[qpos*64 + d], sn = rs[qpos*64 + d];
    Qs[rr*QKP + d]      = (bft)(x1*c - x2*sn);
    Qs[rr*QKP + d + 64] = (bft)(x2*c + x1*sn);
  }
  __syncthreads();
  bf16x8 qf[4];
  #pragma unroll
  for (int kk=0;kk<4;kk++)
    qf[kk] = *(const bf16x8*)(Qs + (wm+fr)*QKP + kk*32 + fko);

  f32x4 Ot[8];
  #pragma unroll
  for (int i=0;i<8;i++) Ot[i] = (f32x4){0.f,0.f,0.f,0.f};
  float m4[4], l4[4];
  #pragma unroll
  for (int r=0;r<4;r++){ m4[r] = -INFINITY; l4[r] = 0.f; }

  for (int kt=0; kt<5; kt++){
    const int kb = Q0 - 256 + kt*64;
    if (kb < 0) continue;
    __syncthreads();
    #pragma unroll
    for(int i=0;i<16;i++){
      int e = tid + i*256;
      int rr = e >> 6, d = e & 63;
      int kpos = kb + rr;
      size_t b = (size_t)kpos*QKV3 + HID + hb;
      float x1 = bf2f(qkv[b + d]);
      float x2 = bf2f(qkv[b + d + 64]);
      float c = rc[kpos*64 + d], sn = rs[kpos*64 + d];
      Ks[rr*QKP + d]      = (bft)(x1*c - x2*sn);
      Ks[rr*QKP + d + 64] = (bft)(x2*c + x1*sn);
    }
    {
      int d = tid >> 1, koff = (tid & 1) * 32;
      const bft* vrow = vT + ((size_t)(hb + d))*S_LEN + kb + koff;
      bft* lrow = Vs + d*VSP + koff;
      #pragma unroll
      for (int j8=0;j8<4;j8++)
        *(bf16x8*)(lrow + j8*8) = *(const bf16x8*)(vrow + j8*8);
    }
    __syncthreads();

    f32x4 st[4];
    #pragma unroll
    for (int nt=0;nt<4;nt++){
      f32x4 acc = (f32x4){0.f,0.f,0.f,0.f};
      #pragma unroll
      for (int kk=0;kk<4;kk++){
        bf16x8 kf = *(const bf16x8*)(Ks + (nt*16+fr)*QKP + kk*32 + fko);
        acc = __builtin_amdgcn_mfma_f32_16x16x32_bf16(qf[kk], kf, acc, 0, 0, 0);
      }
      st[nt] = acc;
    }

    float pv[4][4];
    #pragma unroll
    for (int r=0;r<4;r++){
      int qpos = Q0 + wm + rbase + r;
      float sm[4];
      float mx = -INFINITY;
      #pragma unroll
      for (int nt=0;nt<4;nt++){
        int kpos = kb + nt*16 + fr;
        bool valid = (kpos > qpos - 256) && (kpos <= qpos);
        float s = valid ? st[nt][r] * 0.088388347648318447f : -INFINITY;
        sm[nt] = s;
        mx = fmaxf(mx, s);
      }
      mx = fmaxf(mx, __shfl_xor(mx, 1, 64));
      mx = fmaxf(mx, __shfl_xor(mx, 2, 64));
      mx = fmaxf(mx, __shfl_xor(mx, 4, 64));
      mx = fmaxf(mx, __shfl_xor(mx, 8, 64));
      float mnew = fmaxf(m4[r], mx);
      float alpha = (mnew == -INFINITY) ? 1.f : __expf(m4[r] - mnew);
      float ps = 0.f;
      #pragma unroll
      for (int nt=0;nt<4;nt++){
        float p = (sm[nt] == -INFINITY) ? 0.f : __expf(sm[nt] - mnew);
        pv[nt][r] = p;
        ps += p;
      }
      ps += __shfl_xor(ps, 1, 64);
      ps += __shfl_xor(ps, 2, 64);
      ps += __shfl_xor(ps, 4, 64);
      ps += __shfl_xor(ps, 8, 64);
      l4[r] = l4[r]*alpha + ps;
      m4[r] = mnew;
      #pragma unroll
      for (int ct=0;ct<8;ct++) Ot[ct][r] *= alpha;
    }

    #pragma unroll
    for (int r=0;r<4;r++){
      int row = wm + rbase + r;
      #pragma unroll
      for (int nt=0;nt<4;nt++)
        Ps[row*PSP + nt*16 + fr] = (bft)pv[nt][r];
    }
    bf16x8 af[2];
    #pragma unroll
    for (int kk=0;kk<2;kk++){
      const bft* pp = Ps + (wm+fr)*PSP + kk*32 + fko;
      bf16x4 lo = *(const bf16x4*)pp;
      bf16x4 hi = *(const bf16x4*)(pp+4);
      bf16x8 a;
      #pragma unroll
      for (int j=0;j<4;j++){ a[j]=lo[j]; a[j+4]=hi[j]; }
      af[kk]=a;
    }
    #pragma unroll
    for (int ct=0;ct<8;ct++)
      #pragma unroll
      for (int kk=0;kk<2;kk++){
        bf16x8 bv = *(const bf16x8*)(Vs + (ct*16+fr)*VSP + kk*32 + fko);
        Ot[ct] = __builtin_amdgcn_mfma_f32_16x16x32_bf16(af[kk], bv, Ot[ct], 0, 0, 0);
      }
  }

  #pragma unroll
  for (int r=0;r<4;r++){
    float invl = 1.f / l4[r];
    int qpos = Q0 + wm + rbase + r;
    size_t ob = (size_t)qpos*HID + hb;
    #pragma unroll
    for (int ct=0;ct<8;ct++)
      attn[ob + ct*16 + fr] = Ot[ct][r] * invl;
  }
}

// ---------------------------------------------------------------------------
// TTT elementwise fwd on FUSED buffers:
// gh = [z][ci][ g(0:512) | hm(512:1024) ], qgm = [z][ci][ qg | qm ].
// hid = silu(g)*hm (separate [z][ci][512]); opre = silu(qg)*qm -> qgm col 0.
// ---------------------------------------------------------------------------
__global__ __launch_bounds__(256) void e3f_k(
    bft* __restrict__ gh, bft* __restrict__ qgm, bft* __restrict__ hid)
{
  size_t idx = (size_t)blockIdx.x*256 + threadIdx.x;   // over NFW*CHUNK*FD
  int z  = (int)(idx >> 20);
  int ci = (int)((idx >> 9) & 2047);
  int d  = (int)(idx & 511);
  size_t b = ((size_t)z*CHUNK_LEN + ci)*1024 + d;
  float opre = siluf((float)qgm[b]) * (float)qgm[b + 512];
  hid[idx] = (bft)(siluf((float)gh[b]) * (float)gh[b + 512]);
  qgm[b]   = (bft)opre;
}

// ---------------------------------------------------------------------------
// TTT backprop elementwise on fused buffers (in place):
// gh col0 -> dgp*l0 (a0), gh col512 -> dhm*l2 (a2), qgm col512 -> fv*l1 (a1).
// dhid was written into qgm col512 by the fv@w1tb GEMM.
// ---------------------------------------------------------------------------
__global__ __launch_bounds__(256) void e4f_k(
    bft* __restrict__ gh, bft* __restrict__ qgm,
    const bf16* __restrict__ qkv, const float* __restrict__ lrb, int cbase)
{
  size_t idx = (size_t)blockIdx.x*256 + threadIdx.x;
  int z  = (int)(idx >> 20);
  int ci = (int)((idx >> 9) & 2047);
  int d  = (int)(idx & 511);
  int s  = cbase + ci;
  float l0  = lrb[s*12 + z];
  float l1  = lrb[s*12 + 4 + z];
  float l2v = lrb[s*12 + 8 + z];
  size_t b = ((size_t)z*CHUNK_LEN + ci)*1024 + d;
  float gg = (float)gh[b], hv = (float)gh[b + 512], dh = (float)qgm[b + 512];
  float sg = sigm(gg);
  float silu_g = gg * sg;
  float dhm = dh * silu_g;
  float dg  = dh * hv;
  float dgp = dg * (sg * (1.f + gg * (1.f - sg)));
  float fvv = bf2f(qkv[(size_t)s*QKV3 + 2*HID + z*FD + d]);
  gh[b]        = (bft)(dgp * l0);
  gh[b + 512]  = (bft)(dhm * l2v);
  qgm[b + 512] = (bft)(fvv * l1);
}

// ---------------------------------------------------------------------------
// E5 (per chunk): X = attn + rmsnorm(ofc)*ttt_norm_w -> q region of qkv
// ---------------------------------------------------------------------------
__global__ __launch_bounds__(256) void e5_k(const float* __restrict__ attn,
    const bf16* __restrict__ ofc, const float* __restrict__ tnw,
    bf16* __restrict__ qkv, int cbase)
{
  int ci = blockIdx.x, tid = threadIdx.x;
  int s = cbase + ci;
  int lane = tid & 63, w = tid >> 6;
  float o[8]; float ss = 0.f;
  size_t ob = ((size_t)w*CHUNK_LEN + ci)*FD + (size_t)lane*8;
  #pragma unroll
  for(int i=0;i<8;i++){ o[i] = bf2f(ofc[ob+i]); ss += o[i]*o[i]; }
  ss = wave_sum(ss);
  float inv = rsqrtf(ss*(1.f/FD) + 1e-6f);
  size_t xb = (size_t)s*QKV3 + w*FD + (size_t)lane*8;
  size_t ab = (size_t)s*HID  + w*FD + (size_t)lane*8;
  #pragma unroll
  for(int i=0;i<8;i++){
    int d = lane*8 + i;
    qkv[xb+i] = f2bf(attn[ab+i] + o[i]*inv*tnw[d]);
  }
}

// ---------------------------------------------------------------------------
extern "C" void kernel_launch(void* const* d_in, const int* in_sizes, int n_in,
                              void* d_out, int out_size, void* d_ws, size_t ws_size,
                              hipStream_t stream)
{
  (void)in_sizes; (void)n_in; (void)out_size;
  const float* hidden   = (const float*)d_in[0];
  const float* qkv_w    = (const float*)d_in[1];
  const float* q_norm_w = (const float*)d_in[2];
  const float* k_norm_w = (const float*)d_in[3];
  const float* qk_scale = (const float*)d_in[4];
  const float* qk_off   = (const float*)d_in[5];
  const float* lr_w     = (const float*)d_in[6];
  const float* lr_b     = (const float*)d_in[7];
  const float* w0_in    = (const float*)d_in[8];
  const float* w1_in    = (const float*)d_in[9];
  const float* w2_in    = (const float*)d_in[10];
  const float* ttt_nw   = (const float*)d_in[11];
  const float* o_proj   = (const float*)d_in[12];
  float* out = (float*)d_out;

  char* p = (char*)d_ws;
  auto alloc = [&](size_t n){ char* r = p; p += (n + 255) & ~(size_t)255; return (void*)r; };

  bf16*  qkv   = (bf16*) alloc((size_t)S_LEN*QKV3*sizeof(bf16));
  float* lrb   = (float*)alloc((size_t)S_LEN*12*sizeof(float));
  float* rc    = (float*)alloc((size_t)S_LEN*64*sizeof(float));
  float* rs    = (float*)alloc((size_t)S_LEN*64*sizeof(float));
  float* w0s   = (float*)alloc((size_t)NFW*FD*FD*sizeof(float));
  float* w1s   = (float*)alloc((size_t)NFW*FD*FD*sizeof(float));
  float* w2s   = (float*)alloc((size_t)NFW*FD*FD*sizeof(float));
  bft*   w1tb  = (bft*)  alloc((size_t)NFW*FD*FD*sizeof(bft));
  bft*   w02b  = (bft*)  alloc((size_t)NFW*1024*FD*sizeof(bft));  // w0 rows 0-511, w2 rows 512-1023
  bft*   w1b   = (bft*)  alloc((size_t)NFW*FD*FD*sizeof(bft));
  bf16*  gb    = (bf16*) alloc((size_t)NFW*CHUNK_LEN*FD*sizeof(bf16));
  bf16*  hmb   = (bf16*) alloc((size_t)NFW*CHUNK_LEN*FD*sizeof(bf16));
  bf16*  qgb   = (bf16*) alloc((size_t)NFW*CHUNK_LEN*FD*sizeof(bf16));
  bf16*  qmb   = (bf16*) alloc((size_t)NFW*CHUNK_LEN*FD*sizeof(bf16));
  bf16*  hidb  = (bf16*) alloc((size_t)NFW*CHUNK_LEN*FD*sizeof(bf16));
  bf16*  ofc   = (bf16*) alloc((size_t)NFW*CHUNK_LEN*FD*sizeof(bf16));
  bft*   fkT   = (bft*)  alloc((size_t)NFW*FD*CHUNK_LEN*sizeof(bft));
  bft*   hidT  = (bft*)  alloc((size_t)NFW*FD*CHUNK_LEN*sizeof(bft));
  bft*   a2T   = (bft*)  alloc((size_t)NFW*FD*CHUNK_LEN*sizeof(bft));

  if ((size_t)(p - (char*)d_ws) > ws_size) return;

  // Fused-buffer views (allocations are 8MB each, 256B-aligned-exact, so
  // gb..qmb are contiguous):
  //   ghb = gb..hmb  : [z][ci][ g | hm ]  (16 MB)
  //   qgm = qgb..qmb : [z][ci][ qg | qm ] (16 MB)
  bft* ghb = (bft*)gb;
  bft* qgm = (bft*)qgb;
  // Liveness aliases:
  //   hidden_bf (33.55 MB) = gb..qmb  — dead before chunk loop.
  //   qkvw_bf   (25.17 MB) = fkT..hidT — dead before vt_k writes vT.
  //   vT        (33.55 MB) = fkT..a2T — dead before chunk loop's tr_k.
  //   opw_bf    ( 8.39 MB) = hidb     — converted after last e5.
  bft* hidden_bf = (bft*)gb;
  bft* qkvw_bf   = (bft*)fkT;
  bft* vT        = (bft*)fkT;
  bft* opw_bf    = (bft*)hidb;

  float* attn = out;   // attn lives in d_out until the final projection

  const long sW  = (long)FD*FD;
  const long sW2 = (long)1024*FD;
  const long sCh = (long)CHUNK_LEN*FD;
  const long sGH = (long)CHUNK_LEN*1024;
  const long sT  = (long)FD*CHUNK_LEN;

  hipMemcpyAsync(w0s, w0_in, (size_t)NFW*FD*FD*sizeof(float), hipMemcpyDeviceToDevice, stream);
  hipMemcpyAsync(w1s, w1_in, (size_t)NFW*FD*FD*sizeof(float), hipMemcpyDeviceToDevice, stream);
  hipMemcpyAsync(w2s, w2_in, (size_t)NFW*FD*FD*sizeof(float), hipMemcpyDeviceToDevice, stream);

  rope_k<<<S_LEN, 64, 0, stream>>>(rc, rs);
  lr_k<<<S_LEN, 256, 0, stream>>>(hidden, lr_w, lr_b, lrb);
  tcw1_k<<<NFW*FD*FD/256, 256, 0, stream>>>(w1_in, w1tb);
  cvt_k<<<(NFW*FD*FD)/2048, 256, 0, stream>>>(w1_in, w1b);
  for (int z = 0; z < NFW; ++z) {
    cvt_k<<<(FD*FD)/2048, 256, 0, stream>>>(w0_in + (size_t)z*sW, w02b + (size_t)z*sW2);
    cvt_k<<<(FD*FD)/2048, 256, 0, stream>>>(w2_in + (size_t)z*sW, w02b + (size_t)z*sW2 + (size_t)512*FD);
  }
  cvt_k<<<(S_LEN*HID)/2048, 256, 0, stream>>>(hidden, hidden_bf);
  cvt_k<<<(QKV3*HID)/2048, 256, 0, stream>>>(qkv_w, qkvw_bf);

  // qkv = hidden @ qkv_w^T -> bf16   (256^2 pipelined GEMM)
  mgemm8<0>(stream, hidden_bf, qkvw_bf, (void*)qkv, S_LEN, QKV3, HID, HID, HID, QKV3);

  e2a_k<<<S_LEN, 256, 0, stream>>>(qkv, q_norm_w, k_norm_w);
  vt_k<<<dim3(S_LEN/64, NH), 256, 0, stream>>>(qkv, vT);
  attn_k<<<NH*128, 256, 0, stream>>>(qkv, vT, rc, rs, attn);
  e2b_k<<<S_LEN, 256, 0, stream>>>(qkv, qk_scale, qk_off);

  const int  NEL = NFW*CHUNK_LEN*FD/256;
  const dim3 tg(FD/64, CHUNK_LEN/64, NFW);

  for(int c=0; c<NCHUNK; c++){
    const bft* fqc = (const bft*)qkv + (size_t)c*CHUNK_LEN*QKV3;
    const bft* fkc = fqc + HID;
    const bft* fvc = fqc + 2*HID;
    // fused forward: [g|hm] = fk @ [w0|w2]^T ; [qg|qm] = fq @ [w0|w2]^T
    mgemm<128,128,0>(stream, fkc, w02b, ghb, nullptr, nullptr,
        CHUNK_LEN, 1024, FD, QKV3, FD, 1024, NFW, FD, sW2, sGH, 0);
    mgemm<128,128,0>(stream, fqc, w02b, qgm, nullptr, nullptr,
        CHUNK_LEN, 1024, FD, QKV3, FD, 1024, NFW, FD, sW2, sGH, 0);
    e3f_k<<<NEL, 256, 0, stream>>>(ghb, qgm, (bft*)hidb);
    // ofc = opre @ w1^T   (opre = qgm col 0-511, lda=1024)
    mgemm<128,128,0>(stream, (const bft*)qgm, w1b, ofc, nullptr, nullptr,
        CHUNK_LEN, FD, FD, 1024, FD, FD, NFW, sGH, sW, sCh, 0);
    // dhid = fv @ w1  (-> qgm col 512-1023; qm is dead after e3f)
    mgemm<128,128,0>(stream, fvc, (const bft*)w1tb, qgm + 512, nullptr, nullptr,
        CHUNK_LEN, FD, FD, QKV3, FD, 1024, NFW, FD, sW, sGH, 0);
    e4f_k<<<NEL, 256, 0, stream>>>(ghb, qgm, qkv, lrb, c*CHUNK_LEN);
    tr_k<<<tg, 256, 0, stream>>>(fkc,              fkT,  QKV3, FD,  sT);
    tr_k<<<tg, 256, 0, stream>>>((const bft*)hidb, hidT, FD,   sCh, sT);
    // interleave transpose -> update (a2T reused as the scratch T buffer)
    tr_k<<<tg, 256, 0, stream>>>(ghb,       a2T, 1024, sGH, sT);   // a0^T
    mgemm<64,64,2>(stream, a2T, fkT,  w0s, w02b, nullptr,
        FD, FD, CHUNK_LEN, CHUNK_LEN, CHUNK_LEN, FD, NFW, sT, sT, sW, sW2);
    tr_k<<<tg, 256, 0, stream>>>(ghb + 512, a2T, 1024, sGH, sT);   // a2^T
    mgemm<64,64,2>(stream, a2T, fkT,  w2s, w02b + (size_t)512*FD, nullptr,
        FD, FD, CHUNK_LEN, CHUNK_LEN, CHUNK_LEN, FD, NFW, sT, sT, sW, sW2);
    tr_k<<<tg, 256, 0, stream>>>(qgm + 512, a2T, 1024, sGH, sT);   // a1^T
    mgemm<64,64,2>(stream, a2T, hidT, w1s, w1b, w1tb,
        FD, FD, CHUNK_LEN, CHUNK_LEN, CHUNK_LEN, FD, NFW, sT, sT, sW, sW);
    e5_k<<<CHUNK_LEN, 256, 0, stream>>>(attn, ofc, ttt_nw, qkv, c*CHUNK_LEN);
  }

  // bf16 copy of o_proj (hidb/ofc are dead now), then final projection
  cvt_k<<<(HID*HID)/2048, 256, 0, stream>>>(o_proj, opw_bf);
  mgemm8<1>(stream, (const bft*)qkv, opw_bf, out, S_LEN, HID, HID, QKV3, HID, HID);
}

// Round 6
// 1506.019 us; speedup vs baseline: 1.1903x; 1.0005x over previous
//
#include <hip/hip_runtime.h>
#include <hip/hip_bf16.h>

typedef __hip_bfloat16 bf16;
typedef __bf16 bft;
typedef bft bf16x8 __attribute__((ext_vector_type(8)));
typedef bft bf16x4 __attribute__((ext_vector_type(4)));
typedef float f32x4 __attribute__((ext_vector_type(4)));

#define S_LEN 8192
#define HID   2048
#define QKV3  6144
#define NH    16
#define HD    128
#define NFW   4
#define FD    512
#define CHUNK_LEN 2048
#define NCHUNK 4
#define BASE_LR_INV (-6.9072552f)   // log(expm1(0.001))
#define QKP 136                     // attn Q/K LDS stride (128 + 8)
#define VSP 72                      // attn V^T LDS stride (64 + 8)
#define PSP 76                      // attn P LDS stride (64 + 12)

__device__ __forceinline__ float bf2f(bf16 x){ return __bfloat162float(x); }
__device__ __forceinline__ bf16  f2bf(float x){ return __float2bfloat16(x); }
__device__ __forceinline__ float sigm(float x){ return 1.f/(1.f+__expf(-x)); }
__device__ __forceinline__ float siluf(float x){ return x/(1.f+__expf(-x)); }
__device__ __forceinline__ float wave_sum(float v){
  #pragma unroll
  for(int off=32; off; off>>=1) v += __shfl_xor(v, off, 64);
  return v;
}

template<int N>
__device__ __forceinline__ void waitcnt_vm(){
  static_assert(N==0||N==2||N==4||N==8, "unsupported vmcnt");
  if constexpr (N==0)      asm volatile("s_waitcnt vmcnt(0)" ::: "memory");
  else if constexpr (N==2) asm volatile("s_waitcnt vmcnt(2)" ::: "memory");
  else if constexpr (N==4) asm volatile("s_waitcnt vmcnt(4)" ::: "memory");
  else                     asm volatile("s_waitcnt vmcnt(8)" ::: "memory");
}

// Raw barrier, NO sched_barrier pinning (m141).
__device__ __forceinline__ void bar(){
  __builtin_amdgcn_s_barrier();
  asm volatile("" ::: "memory");
}

// ---------------------------------------------------------------------------
// GEMM LDS tile staging (bf16 only), swizzled layout.
// Tile: ROWS x 32 bf16, unpadded [row][32]; physical col-slot c (8 elems)
// holds logical col-group g = c ^ ((row>>1)&3).
// global_load_lds 16B/lane; LDS dest = wave-uniform base + lane*16.
// ---------------------------------------------------------------------------
template<int ROWS>
__device__ __forceinline__ void stage(const bft* __restrict__ src, long ld,
                                      bft* dst, int tid)
{
  const int lane = tid & 63, wv = tid >> 6;
  #pragma unroll
  for (int i = 0; i < ROWS/64; ++i) {
    const int r0 = wv*16 + i*64;               // wave-uniform
    const int row = r0 + (lane >> 2);
    const int g = (lane & 3) ^ ((row >> 1) & 3);
    const bft* gp = src + (size_t)row*ld + g*8;
    bft* lp = dst + (size_t)r0*32;
    __builtin_amdgcn_global_load_lds(
        (const __attribute__((address_space(1))) void*)gp,
        (__attribute__((address_space(3))) void*)lp, 16, 0, 0);
  }
}

// ---------------------------------------------------------------------------
// MFMA NT GEMM: C[M,N] (+)= A[M,K] * B[N,K]^T, fp32 accumulate, 256 threads.
// 4-slot circular LDS ring (BK=32) with CROSS-SLOT REGISTER DOUBLE-BUFFER:
// per slot s each wave issues stage(s+2), vmcnt(LPT), one barrier, then the
// ds_reads of slot s+1 into the ALTERNATE register set, then the full MFMA
// cluster on the CURRENT set. Reads (regNext) and MFMAs (regCur) are
// register-independent -> LDS pipe and MFMA pipe overlap within the wave;
// compiler's auto-lgkmcnt drains reads at next iteration's first use.
// Race-freedom (1 barrier/slot): stage at iter s targets buffer (s+2)&3;
// last reads of that buffer (slot s-2, issued iter s-3) are drained by the
// lgkmcnt before MFMA(s-2), which precedes bar(s-1) in program order -- so
// every wave's reads finished >=1 barrier before the overwrite. vmcnt(LPT)
// + barrier at iter s guarantee all waves' stage(s+1) landed before reads.
// EPI: 0 = store bf16, 1 = store fp32, 2 = fp32 C += acc, bf16 direct shadow
// Cd (z-stride sCd, row stride ldc), optional transposed shadow Ct.
// NS must be even (all call sites: K multiple of 64).
// ---------------------------------------------------------------------------
template<int BM,int BN,int EPI>
__global__ __launch_bounds__(256) void mgemm_k(
    const bft* __restrict__ A, const bft* __restrict__ B, void* __restrict__ Cv,
    bft* __restrict__ Cd, bft* __restrict__ Ct, int K,
    long lda, long ldb, long ldc, long sA, long sB, long sC, long sCd)
{
  constexpr int AM = BM/32, AN = BN/32;
  constexpr int LPT = BM/64 + BN/64;           // global_load_lds per wave/slot
  __shared__ __align__(16) bft As[4][BM*32];
  __shared__ __align__(16) bft Bs[4][BN*32];
  const int tid = threadIdx.x;
  const int z = blockIdx.z;
  A += (size_t)z * sA;
  B += (size_t)z * sB;
  const size_t m0 = (size_t)blockIdx.y * BM, n0 = (size_t)blockIdx.x * BN;
  const int wv = tid >> 6, lane = tid & 63;
  const int wm = (wv & 1) * (BM/2), wn = (wv >> 1) * (BN/2);
  const int fr = lane & 15;
  const int fsw = ((lane >> 4) ^ ((fr >> 1) & 3)) * 8;   // swizzled frag col

  f32x4 acc[AM][AN];
  #pragma unroll
  for (int i=0;i<AM;i++)
    #pragma unroll
    for (int j=0;j<AN;j++) acc[i][j] = (f32x4){0.f,0.f,0.f,0.f};

  const bft* Ab = A + m0*lda;
  const bft* Bb = B + n0*ldb;
  const int NS = K >> 5;

  // prologue: stage slots 0,1; wait slot 0; read slot 0 frags.
  stage<BM>(Ab,      lda, As[0], tid);
  stage<BN>(Bb,      ldb, Bs[0], tid);
  stage<BM>(Ab + 32, lda, As[1], tid);
  stage<BN>(Bb + 32, ldb, Bs[1], tid);
  waitcnt_vm<LPT>();
  bar();

  bf16x8 aP[AM], bP[AN], aQ[AM], bQ[AN];
  #pragma unroll
  for (int mi=0; mi<AM; mi++)
    aP[mi] = *(const bf16x8*)(As[0] + (size_t)(wm + mi*16 + fr)*32 + fsw);
  #pragma unroll
  for (int ni=0; ni<AN; ni++)
    bP[ni] = *(const bf16x8*)(Bs[0] + (size_t)(wn + ni*16 + fr)*32 + fsw);

  auto body = [&](bf16x8 (&ac)[AM], bf16x8 (&bc)[AN],
                  bf16x8 (&an)[AM], bf16x8 (&bn)[AN], int s){
    const int kt = (s + 2) * 32;
    const bool st2 = (s + 2 < NS);
    const bool rd  = (s + 1 < NS);
    if (st2) {
      stage<BM>(Ab + kt, lda, As[(s+2)&3], tid);
      stage<BN>(Bb + kt, ldb, Bs[(s+2)&3], tid);
    }
    if (rd) {
      if (st2) waitcnt_vm<LPT>(); else waitcnt_vm<0>();
      bar();
      const bft* An = As[(s+1)&3];
      const bft* Bn = Bs[(s+1)&3];
      #pragma unroll
      for (int mi=0; mi<AM; mi++)
        an[mi] = *(const bf16x8*)(An + (size_t)(wm + mi*16 + fr)*32 + fsw);
      #pragma unroll
      for (int ni=0; ni<AN; ni++)
        bn[ni] = *(const bf16x8*)(Bn + (size_t)(wn + ni*16 + fr)*32 + fsw);
    }
    __builtin_amdgcn_s_setprio(1);
    #pragma unroll
    for (int mi=0; mi<AM; mi++)
      #pragma unroll
      for (int ni=0; ni<AN; ni++)
        acc[mi][ni] = __builtin_amdgcn_mfma_f32_16x16x32_bf16(ac[mi], bc[ni], acc[mi][ni], 0, 0, 0);
    __builtin_amdgcn_s_setprio(0);
  };

  for (int s = 0; s < NS; s += 2) {
    body(aP, bP, aQ, bQ, s);
    body(aQ, bQ, aP, bP, s + 1);
  }

  const int er = (lane >> 4) * 4;   // C/D: row=(lane>>4)*4+reg, col=lane&15
  const int ec = lane & 15;
  #pragma unroll
  for (int mi=0; mi<AM; mi++){
    #pragma unroll
    for (int ni=0; ni<AN; ni++){
      #pragma unroll
      for (int r=0; r<4; r++){
        size_t row = m0 + wm + mi*16 + er + r;
        size_t col = n0 + wn + ni*16 + ec;
        size_t idx = (size_t)z*sC + row*ldc + col;
        float v = acc[mi][ni][r];
        if constexpr (EPI == 0){
          ((bft*)Cv)[idx] = (bft)v;
        } else if constexpr (EPI == 1){
          ((float*)Cv)[idx] = v;
        } else {
          float nv = ((float*)Cv)[idx] + v;
          ((float*)Cv)[idx] = nv;
          Cd[(size_t)z*sCd + row*ldc + col] = (bft)nv;
          if (Ct) Ct[(size_t)z*FD*FD + col*FD + row] = (bft)nv;
        }
      }
    }
  }
}

template<int BM,int BN,int EPI>
static inline void mgemm(hipStream_t st, const bft* A, const bft* B, void* C,
    bft* Cd, bft* Ct, int M, int N, int K, long lda, long ldb, long ldc,
    int batch, long sA, long sB, long sC, long sCd)
{
  dim3 g(N/BN, M/BM, batch);
  mgemm_k<BM,BN,EPI><<<g, 256, 0, st>>>(A, B, C, Cd, Ct, K, lda, ldb, ldc, sA, sB, sC, sCd);
}

// ---------------------------------------------------------------------------
// 256x256 MFMA NT GEMM, 4-slot ring, 512 threads = 8 waves (2Mx4N),
// per-wave 128x64 output, cross-slot register double-buffer (same proof as
// mgemm_k). LDS = 128 KiB. XCD-aware bijective block swizzle.
// ---------------------------------------------------------------------------
__device__ __forceinline__ void stage8(const bft* __restrict__ src, long ld,
                                       bft* dst, int tid)
{
  const int lane = tid & 63, wv = tid >> 6;      // 8 waves
  #pragma unroll
  for (int i = 0; i < 2; ++i) {
    const int r0 = wv*16 + i*128;                // wave-uniform
    const int row = r0 + (lane >> 2);
    const int g = (lane & 3) ^ ((row >> 1) & 3);
    const bft* gp = src + (size_t)row*ld + g*8;
    bft* lp = dst + (size_t)r0*32;
    __builtin_amdgcn_global_load_lds(
        (const __attribute__((address_space(1))) void*)gp,
        (__attribute__((address_space(3))) void*)lp, 16, 0, 0);
  }
}

template<int EPI>
__global__ __launch_bounds__(512, 2) void mgemm8_k(
    const bft* __restrict__ A, const bft* __restrict__ B, void* __restrict__ Cv,
    int K, long lda, long ldb, long ldc)
{
  __shared__ __align__(16) bft As[4][256*32];
  __shared__ __align__(16) bft Bs[4][256*32];
  const int tid = threadIdx.x;

  const int gx = (int)gridDim.x;
  const int nwg = (int)(gridDim.x * gridDim.y);
  int lin = (int)(blockIdx.y * gridDim.x + blockIdx.x);
  if ((nwg & 7) == 0) lin = (lin & 7) * (nwg >> 3) + (lin >> 3);
  const size_t m0 = (size_t)(lin / gx) * 256;
  const size_t n0 = (size_t)(lin % gx) * 256;

  const int wv = tid >> 6, lane = tid & 63;
  const int wm = (wv & 1) * 128, wn = (wv >> 1) * 64;
  const int fr = lane & 15;
  const int fsw = ((lane >> 4) ^ ((fr >> 1) & 3)) * 8;

  f32x4 acc[8][4];
  #pragma unroll
  for (int i=0;i<8;i++)
    #pragma unroll
    for (int j=0;j<4;j++) acc[i][j] = (f32x4){0.f,0.f,0.f,0.f};

  const bft* Ab = A + m0*lda;
  const bft* Bb = B + n0*ldb;
  const int NS = K >> 5;

  stage8(Ab,      lda, As[0], tid);
  stage8(Bb,      ldb, Bs[0], tid);
  stage8(Ab + 32, lda, As[1], tid);
  stage8(Bb + 32, ldb, Bs[1], tid);
  waitcnt_vm<4>();
  bar();

  bf16x8 aP[8], bP[4], aQ[8], bQ[4];
  #pragma unroll
  for (int mi=0; mi<8; mi++)
    aP[mi] = *(const bf16x8*)(As[0] + (size_t)(wm + mi*16 + fr)*32 + fsw);
  #pragma unroll
  for (int ni=0; ni<4; ni++)
    bP[ni] = *(const bf16x8*)(Bs[0] + (size_t)(wn + ni*16 + fr)*32 + fsw);

  auto body = [&](bf16x8 (&ac)[8], bf16x8 (&bc)[4],
                  bf16x8 (&an)[8], bf16x8 (&bn)[4], int s){
    const int kt = (s + 2) * 32;
    const bool st2 = (s + 2 < NS);
    const bool rd  = (s + 1 < NS);
    if (st2) {
      stage8(Ab + kt, lda, As[(s+2)&3], tid);
      stage8(Bb + kt, ldb, Bs[(s+2)&3], tid);
    }
    if (rd) {
      if (st2) waitcnt_vm<4>(); else waitcnt_vm<0>();
      bar();
      const bft* An = As[(s+1)&3];
      const bft* Bn = Bs[(s+1)&3];
      #pragma unroll
      for (int mi=0; mi<8; mi++)
        an[mi] = *(const bf16x8*)(An + (size_t)(wm + mi*16 + fr)*32 + fsw);
      #pragma unroll
      for (int ni=0; ni<4; ni++)
        bn[ni] = *(const bf16x8*)(Bn + (size_t)(wn + ni*16 + fr)*32 + fsw);
    }
    __builtin_amdgcn_s_setprio(1);
    #pragma unroll
    for (int mi=0; mi<8; mi++)
      #pragma unroll
      for (int ni=0; ni<4; ni++)
        acc[mi][ni] = __builtin_amdgcn_mfma_f32_16x16x32_bf16(ac[mi], bc[ni], acc[mi][ni], 0, 0, 0);
    __builtin_amdgcn_s_setprio(0);
  };

  for (int s = 0; s < NS; s += 2) {
    body(aP, bP, aQ, bQ, s);
    body(aQ, bQ, aP, bP, s + 1);
  }

  const int er = (lane >> 4) * 4;
  const int ec = lane & 15;
  #pragma unroll
  for (int mi=0; mi<8; mi++){
    #pragma unroll
    for (int ni=0; ni<4; ni++){
      #pragma unroll
      for (int r=0; r<4; r++){
        size_t row = m0 + wm + mi*16 + er + r;
        size_t col = n0 + wn + ni*16 + ec;
        size_t idx = row*ldc + col;
        float v = acc[mi][ni][r];
        if constexpr (EPI == 0) ((bft*)Cv)[idx] = (bft)v;
        else                    ((float*)Cv)[idx] = v;
      }
    }
  }
}

template<int EPI>
static inline void mgemm8(hipStream_t st, const bft* A, const bft* B, void* C,
                          int M, int N, int K, long lda, long ldb, long ldc)
{
  dim3 g(N/256, M/256, 1);
  mgemm8_k<EPI><<<g, 512, 0, st>>>(A, B, C, K, lda, ldb, ldc);
}

// ---------------------------------------------------------------------------
// fp32 -> bf16 bulk convert (8 elems/thread); n must divide 2048.
// ---------------------------------------------------------------------------
__global__ __launch_bounds__(256) void cvt_k(const float* __restrict__ s,
    bft* __restrict__ d)
{
  size_t i = ((size_t)blockIdx.x*256 + threadIdx.x) * 8;
  const float4 v0 = *(const float4*)(s + i);
  const float4 v1 = *(const float4*)(s + i + 4);
  bf16x8 b;
  b[0]=(bft)v0.x; b[1]=(bft)v0.y; b[2]=(bft)v0.z; b[3]=(bft)v0.w;
  b[4]=(bft)v1.x; b[5]=(bft)v1.y; b[6]=(bft)v1.z; b[7]=(bft)v1.w;
  *(bf16x8*)(d + i) = b;
}

// ---------------------------------------------------------------------------
// Batched bf16 transpose: out[z][c][r] = in[z][r][c]; arbitrary ldin/sIn.
// ---------------------------------------------------------------------------
__global__ __launch_bounds__(256) void tr_k(const bft* __restrict__ in,
    bft* __restrict__ out, long ldin, long sIn, long sOut)
{
  __shared__ __align__(16) bft t[64][72];
  const int c0 = blockIdx.x*64, r0 = blockIdx.y*64;
  in  += (size_t)blockIdx.z * sIn;
  out += (size_t)blockIdx.z * sOut;
  const int tid = threadIdx.x;
  #pragma unroll
  for (int i=0;i<2;i++){
    int e = tid + i*256;
    int r = e >> 3, c8 = (e & 7) * 8;
    *(bf16x8*)&t[r][c8] = *(const bf16x8*)(in + (size_t)(r0+r)*ldin + c0 + c8);
  }
  __syncthreads();
  #pragma unroll
  for (int i=0;i<2;i++){
    int e = tid + i*256;
    int c = e >> 3, r8 = (e & 7) * 8;
    bf16x8 v;
    #pragma unroll
    for (int j=0;j<8;j++) v[j] = t[r8+j][c];
    *(bf16x8*)(out + (size_t)(c0+c)*CHUNK_LEN + r0 + r8) = v;
  }
}

// initial w1^T bf16 shadow: w1tb[z][h][o] = (bf16)w1[z][o][h]
__global__ __launch_bounds__(256) void tcw1_k(const float* __restrict__ w1,
    bft* __restrict__ w1tb)
{
  size_t idx = (size_t)blockIdx.x*256 + threadIdx.x;
  int z = (int)(idx >> 18);
  int h = (int)((idx >> 9) & 511);
  int o = (int)(idx & 511);
  w1tb[idx] = (bft)w1[(size_t)z*FD*FD + (size_t)o*FD + h];
}

// ---------------------------------------------------------------------------
// v^T for attention PV: vT[h][d][s] = v[s][h*128+d] (raw v region of qkv).
// ---------------------------------------------------------------------------
__global__ __launch_bounds__(256) void vt_k(const bf16* __restrict__ qkv,
    bft* __restrict__ vT)
{
  __shared__ __align__(16) bft t[64*QKP];   // [s][d]
  const int s0 = blockIdx.x * 64;
  const int h  = blockIdx.y;
  const int tid = threadIdx.x;
  #pragma unroll
  for (int i=0;i<4;i++){
    int e = tid + i*256;
    int rr = e >> 4, doff = (e & 15) * 8;
    *(bf16x8*)(t + rr*QKP + doff) =
        *(const bf16x8*)((const bft*)qkv + (size_t)(s0+rr)*QKV3 + 2*HID + h*HD + doff);
  }
  __syncthreads();
  #pragma unroll
  for (int it=0; it<4; it++){
    int d = (tid >> 3) + it*32;
    int so8 = (tid & 7) * 8;
    bf16x8 v;
    #pragma unroll
    for (int j=0;j<8;j++) v[j] = t[(so8+j)*QKP + d];
    *(bf16x8*)(vT + ((size_t)(h*HD + d))*S_LEN + s0 + so8) = v;
  }
}

// ---------------------------------------------------------------------------
// RoPE cos/sin tables
// ---------------------------------------------------------------------------
__global__ void rope_k(float* __restrict__ rc, float* __restrict__ rs){
  int pos = blockIdx.x, d = threadIdx.x;
  float inv = 1.f / powf(500000.0f, (float)d * (1.0f/64.0f));
  float ang = (float)pos * inv;
  rc[pos*64+d] = cosf(ang);
  rs[pos*64+d] = sinf(ang);
}

// ---------------------------------------------------------------------------
// per-token learning rates
// ---------------------------------------------------------------------------
__global__ __launch_bounds__(256) void lr_k(const float* __restrict__ hidden,
    const float* __restrict__ lr_w, const float* __restrict__ lr_b,
    float* __restrict__ lro)
{
  __shared__ float hrow[HID];
  __shared__ float red[4][12];
  int s = blockIdx.x, tid = threadIdx.x;
  for(int i=0;i<HID/256;i++) hrow[tid+256*i] = hidden[(size_t)s*HID + tid + 256*i];
  __syncthreads();
  float part[12];
  #pragma unroll
  for(int o=0;o<12;o++) part[o]=0.f;
  for(int i=0;i<HID/256;i++){
    int j = tid + 256*i;
    float h = hrow[j];
    #pragma unroll
    for(int o=0;o<12;o++) part[o] += h * lr_w[o*HID + j];
  }
  int lane = tid & 63, w = tid >> 6;
  #pragma unroll
  for(int o=0;o<12;o++){
    float v = wave_sum(part[o]);
    if(lane==0) red[w][o] = v;
  }
  __syncthreads();
  if(tid < 12){
    float v = red[0][tid]+red[1][tid]+red[2][tid]+red[3][tid] + lr_b[tid] + BASE_LR_INV;
    float sp = (v > 20.f) ? v : log1pf(expf(v));
    lro[s*12 + tid] = sp;
  }
}

// ---------------------------------------------------------------------------
// E2a: per-token rmsnorm(q), rmsnorm(k), in place in qkv (bf16).
// ---------------------------------------------------------------------------
__global__ __launch_bounds__(256) void e2a_k(
    bf16* __restrict__ qkv,
    const float* __restrict__ qnw, const float* __restrict__ knw)
{
  __shared__ float red[8];
  int s = blockIdx.x, tid = threadIdx.x;
  int lane = tid & 63, w = tid >> 6;
  float qv[8], kv[8];
  float sq = 0.f, sk = 0.f;
  size_t base = (size_t)s*QKV3;
  #pragma unroll
  for(int i=0;i<8;i++){
    int j = tid*8 + i;
    qv[i] = bf2f(qkv[base + j]);
    kv[i] = bf2f(qkv[base + HID + j]);
    sq += qv[i]*qv[i]; sk += kv[i]*kv[i];
  }
  sq = wave_sum(sq); sk = wave_sum(sk);
  if(lane==0){ red[w] = sq; red[4+w] = sk; }
  __syncthreads();
  float rq = rsqrtf((red[0]+red[1]+red[2]+red[3])*(1.f/HID) + 1e-6f);
  float rk = rsqrtf((red[4]+red[5]+red[6]+red[7])*(1.f/HID) + 1e-6f);
  #pragma unroll
  for(int i=0;i<8;i++){
    int j = tid*8 + i;
    qkv[base + j]       = f2bf(qv[i]*rq*qnw[j]);
    qkv[base + HID + j] = f2bf(kv[i]*rk*knw[j]);
  }
}

// ---------------------------------------------------------------------------
// E2b (after attention): overwrite q/k/v regions with fq/fk/fv.
// ---------------------------------------------------------------------------
__global__ __launch_bounds__(256) void e2b_k(
    bf16* __restrict__ qkv,
    const float* __restrict__ qks, const float* __restrict__ qko)
{
  int s = blockIdx.x, tid = threadIdx.x;
  size_t base = (size_t)s*QKV3;
  float a[8], b[8], vv[8];
  float ga = 0.f, gb2 = 0.f;
  #pragma unroll
  for(int i=0;i<8;i++){
    int j = tid*8 + i;
    float qn = bf2f(qkv[base + j]);
    float kn = bf2f(qkv[base + HID + j]);
    float v  = bf2f(qkv[base + 2*HID + j]);
    a[i] = siluf(qn*qks[2*j]   + qko[2*j]);
    b[i] = siluf(kn*qks[2*j+1] + qko[2*j+1]);
    vv[i] = siluf(v);
    ga += a[i]*a[i]; gb2 += b[i]*b[i];
  }
  ga = wave_sum(ga); gb2 = wave_sum(gb2);
  float iq = 1.f / fmaxf(sqrtf(ga), 1e-12f);
  float ik = 1.f / fmaxf(sqrtf(gb2), 1e-12f);
  #pragma unroll
  for(int i=0;i<8;i++){
    int j = tid*8 + i;
    qkv[base + j]         = f2bf(a[i]*iq);
    qkv[base + HID + j]   = f2bf(b[i]*ik);
    qkv[base + 2*HID + j] = f2bf(vv[i]);
  }
}

// ---------------------------------------------------------------------------
// MFMA sliding-window attention (window 256 incl self).
// ---------------------------------------------------------------------------
__global__ __launch_bounds__(256) void attn_k(
    const bf16* __restrict__ qkv, const bft* __restrict__ vT,
    const float* __restrict__ rc, const float* __restrict__ rs,
    float* __restrict__ attn)
{
  __shared__ __align__(16) bft Qs[64*QKP];
  __shared__ __align__(16) bft Ks[64*QKP];
  __shared__ __align__(16) bft Vs[128*VSP];
  __shared__ __align__(16) bft Ps[64*PSP];
  const int head = blockIdx.x >> 7;
  const int Q0 = (blockIdx.x & 127) * 64;
  const int tid = threadIdx.x;
  const int hb = head * HD;
  const int lane = tid & 63;
  const int wm = (tid >> 6) * 16;
  const int fr = lane & 15, fko = (lane >> 4) * 8;
  const int rbase = (lane >> 4) * 4;

  #pragma unroll
  for(int i=0;i<16;i++){
    int e = tid + i*256;
    int rr = e >> 6, d = e & 63;
    int qpos = Q0 + rr;
    size_t b = (size_t)qpos*QKV3 + hb;
    float x1 = bf2f(qkv[b + d]);
    float x2 = bf2f(qkv[b + d + 64]);
    float c = rc[qpos*64 + d], sn = rs[qpos*64 + d];
    Qs[rr*QKP + d]      = (bft)(x1*c - x2*sn);
    Qs[rr*QKP + d + 64] = (bft)(x2*c + x1*sn);
  }
  __syncthreads();
  bf16x8 qf[4];
  #pragma unroll
  for (int kk=0;kk<4;kk++)
    qf[kk] = *(const bf16x8*)(Qs + (wm+fr)*QKP + kk*32 + fko);

  f32x4 Ot[8];
  #pragma unroll
  for (int i=0;i<8;i++) Ot[i] = (f32x4){0.f,0.f,0.f,0.f};
  float m4[4], l4[4];
  #pragma unroll
  for (int r=0;r<4;r++){ m4[r] = -INFINITY; l4[r] = 0.f; }

  for (int kt=0; kt<5; kt++){
    const int kb = Q0 - 256 + kt*64;
    if (kb < 0) continue;
    __syncthreads();
    #pragma unroll
    for(int i=0;i<16;i++){
      int e = tid + i*256;
      int rr = e >> 6, d = e & 63;
      int kpos = kb + rr;
      size_t b = (size_t)kpos*QKV3 + HID + hb;
      float x1 = bf2f(qkv[b + d]);
      float x2 = bf2f(qkv[b + d + 64]);
      float c = rc[kpos*64 + d], sn = rs[kpos*64 + d];
      Ks[rr*QKP + d]      = (bft)(x1*c - x2*sn);
      Ks[rr*QKP + d + 64] = (bft)(x2*c + x1*sn);
    }
    {
      int d = tid >> 1, koff = (tid & 1) * 32;
      const bft* vrow = vT + ((size_t)(hb + d))*S_LEN + kb + koff;
      bft* lrow = Vs + d*VSP + koff;
      #pragma unroll
      for (int j8=0;j8<4;j8++)
        *(bf16x8*)(lrow + j8*8) = *(const bf16x8*)(vrow + j8*8);
    }
    __syncthreads();

    f32x4 st[4];
    #pragma unroll
    for (int nt=0;nt<4;nt++){
      f32x4 acc = (f32x4){0.f,0.f,0.f,0.f};
      #pragma unroll
      for (int kk=0;kk<4;kk++){
        bf16x8 kf = *(const bf16x8*)(Ks + (nt*16+fr)*QKP + kk*32 + fko);
        acc = __builtin_amdgcn_mfma_f32_16x16x32_bf16(qf[kk], kf, acc, 0, 0, 0);
      }
      st[nt] = acc;
    }

    float pv[4][4];
    #pragma unroll
    for (int r=0;r<4;r++){
      int qpos = Q0 + wm + rbase + r;
      float sm[4];
      float mx = -INFINITY;
      #pragma unroll
      for (int nt=0;nt<4;nt++){
        int kpos = kb + nt*16 + fr;
        bool valid = (kpos > qpos - 256) && (kpos <= qpos);
        float s = valid ? st[nt][r] * 0.088388347648318447f : -INFINITY;
        sm[nt] = s;
        mx = fmaxf(mx, s);
      }
      mx = fmaxf(mx, __shfl_xor(mx, 1, 64));
      mx = fmaxf(mx, __shfl_xor(mx, 2, 64));
      mx = fmaxf(mx, __shfl_xor(mx, 4, 64));
      mx = fmaxf(mx, __shfl_xor(mx, 8, 64));
      float mnew = fmaxf(m4[r], mx);
      float alpha = (mnew == -INFINITY) ? 1.f : __expf(m4[r] - mnew);
      float ps = 0.f;
      #pragma unroll
      for (int nt=0;nt<4;nt++){
        float p = (sm[nt] == -INFINITY) ? 0.f : __expf(sm[nt] - mnew);
        pv[nt][r] = p;
        ps += p;
      }
      ps += __shfl_xor(ps, 1, 64);
      ps += __shfl_xor(ps, 2, 64);
      ps += __shfl_xor(ps, 4, 64);
      ps += __shfl_xor(ps, 8, 64);
      l4[r] = l4[r]*alpha + ps;
      m4[r] = mnew;
      #pragma unroll
      for (int ct=0;ct<8;ct++) Ot[ct][r] *= alpha;
    }

    #pragma unroll
    for (int r=0;r<4;r++){
      int row = wm + rbase + r;
      #pragma unroll
      for (int nt=0;nt<4;nt++)
        Ps[row*PSP + nt*16 + fr] = (bft)pv[nt][r];
    }
    bf16x8 af[2];
    #pragma unroll
    for (int kk=0;kk<2;kk++){
      const bft* pp = Ps + (wm+fr)*PSP + kk*32 + fko;
      bf16x4 lo = *(const bf16x4*)pp;
      bf16x4 hi = *(const bf16x4*)(pp+4);
      bf16x8 a;
      #pragma unroll
      for (int j=0;j<4;j++){ a[j]=lo[j]; a[j+4]=hi[j]; }
      af[kk]=a;
    }
    #pragma unroll
    for (int ct=0;ct<8;ct++)
      #pragma unroll
      for (int kk=0;kk<2;kk++){
        bf16x8 bv = *(const bf16x8*)(Vs + (ct*16+fr)*VSP + kk*32 + fko);
        Ot[ct] = __builtin_amdgcn_mfma_f32_16x16x32_bf16(af[kk], bv, Ot[ct], 0, 0, 0);
      }
  }

  #pragma unroll
  for (int r=0;r<4;r++){
    float invl = 1.f / l4[r];
    int qpos = Q0 + wm + rbase + r;
    size_t ob = (size_t)qpos*HID + hb;
    #pragma unroll
    for (int ct=0;ct<8;ct++)
      attn[ob + ct*16 + fr] = Ot[ct][r] * invl;
  }
}

// ---------------------------------------------------------------------------
// TTT elementwise fwd on FUSED buffers:
// gh = [z][ci][ g(0:512) | hm(512:1024) ], qgm = [z][ci][ qg | qm ].
// hid = silu(g)*hm (separate [z][ci][512]); opre = silu(qg)*qm -> qgm col 0.
// ---------------------------------------------------------------------------
__global__ __launch_bounds__(256) void e3f_k(
    bft* __restrict__ gh, bft* __restrict__ qgm, bft* __restrict__ hid)
{
  size_t idx = (size_t)blockIdx.x*256 + threadIdx.x;   // over NFW*CHUNK*FD
  int z  = (int)(idx >> 20);
  int ci = (int)((idx >> 9) & 2047);
  int d  = (int)(idx & 511);
  size_t b = ((size_t)z*CHUNK_LEN + ci)*1024 + d;
  float opre = siluf((float)qgm[b]) * (float)qgm[b + 512];
  hid[idx] = (bft)(siluf((float)gh[b]) * (float)gh[b + 512]);
  qgm[b]   = (bft)opre;
}

// ---------------------------------------------------------------------------
// TTT backprop elementwise on fused buffers (in place):
// gh col0 -> dgp*l0 (a0), gh col512 -> dhm*l2 (a2), qgm col512 -> fv*l1 (a1).
// dhid was written into qgm col512 by the fv@w1tb GEMM.
// ---------------------------------------------------------------------------
__global__ __launch_bounds__(256) void e4f_k(
    bft* __restrict__ gh, bft* __restrict__ qgm,
    const bf16* __restrict__ qkv, const float* __restrict__ lrb, int cbase)
{
  size_t idx = (size_t)blockIdx.x*256 + threadIdx.x;
  int z  = (int)(idx >> 20);
  int ci = (int)((idx >> 9) & 2047);
  int d  = (int)(idx & 511);
  int s  = cbase + ci;
  float l0  = lrb[s*12 + z];
  float l1  = lrb[s*12 + 4 + z];
  float l2v = lrb[s*12 + 8 + z];
  size_t b = ((size_t)z*CHUNK_LEN + ci)*1024 + d;
  float gg = (float)gh[b], hv = (float)gh[b + 512], dh = (float)qgm[b + 512];
  float sg = sigm(gg);
  float silu_g = gg * sg;
  float dhm = dh * silu_g;
  float dg  = dh * hv;
  float dgp = dg * (sg * (1.f + gg * (1.f - sg)));
  float fvv = bf2f(qkv[(size_t)s*QKV3 + 2*HID + z*FD + d]);
  gh[b]        = (bft)(dgp * l0);
  gh[b + 512]  = (bft)(dhm * l2v);
  qgm[b + 512] = (bft)(fvv * l1);
}

// ---------------------------------------------------------------------------
// E5 (per chunk): X = attn + rmsnorm(ofc)*ttt_norm_w -> q region of qkv
// ---------------------------------------------------------------------------
__global__ __launch_bounds__(256) void e5_k(const float* __restrict__ attn,
    const bf16* __restrict__ ofc, const float* __restrict__ tnw,
    bf16* __restrict__ qkv, int cbase)
{
  int ci = blockIdx.x, tid = threadIdx.x;
  int s = cbase + ci;
  int lane = tid & 63, w = tid >> 6;
  float o[8]; float ss = 0.f;
  size_t ob = ((size_t)w*CHUNK_LEN + ci)*FD + (size_t)lane*8;
  #pragma unroll
  for(int i=0;i<8;i++){ o[i] = bf2f(ofc[ob+i]); ss += o[i]*o[i]; }
  ss = wave_sum(ss);
  float inv = rsqrtf(ss*(1.f/FD) + 1e-6f);
  size_t xb = (size_t)s*QKV3 + w*FD + (size_t)lane*8;
  size_t ab = (size_t)s*HID  + w*FD + (size_t)lane*8;
  #pragma unroll
  for(int i=0;i<8;i++){
    int d = lane*8 + i;
    qkv[xb+i] = f2bf(attn[ab+i] + o[i]*inv*tnw[d]);
  }
}

// ---------------------------------------------------------------------------
extern "C" void kernel_launch(void* const* d_in, const int* in_sizes, int n_in,
                              void* d_out, int out_size, void* d_ws, size_t ws_size,
                              hipStream_t stream)
{
  (void)in_sizes; (void)n_in; (void)out_size;
  const float* hidden   = (const float*)d_in[0];
  const float* qkv_w    = (const float*)d_in[1];
  const float* q_norm_w = (const float*)d_in[2];
  const float* k_norm_w = (const float*)d_in[3];
  const float* qk_scale = (const float*)d_in[4];
  const float* qk_off   = (const float*)d_in[5];
  const float* lr_w     = (const float*)d_in[6];
  const float* lr_b     = (const float*)d_in[7];
  const float* w0_in    = (const float*)d_in[8];
  const float* w1_in    = (const float*)d_in[9];
  const float* w2_in    = (const float*)d_in[10];
  const float* ttt_nw   = (const float*)d_in[11];
  const float* o_proj   = (const float*)d_in[12];
  float* out = (float*)d_out;

  char* p = (char*)d_ws;
  auto alloc = [&](size_t n){ char* r = p; p += (n + 255) & ~(size_t)255; return (void*)r; };

  bf16*  qkv   = (bf16*) alloc((size_t)S_LEN*QKV3*sizeof(bf16));
  float* lrb   = (float*)alloc((size_t)S_LEN*12*sizeof(float));
  float* rc    = (float*)alloc((size_t)S_LEN*64*sizeof(float));
  float* rs    = (float*)alloc((size_t)S_LEN*64*sizeof(float));
  float* w0s   = (float*)alloc((size_t)NFW*FD*FD*sizeof(float));
  float* w1s   = (float*)alloc((size_t)NFW*FD*FD*sizeof(float));
  float* w2s   = (float*)alloc((size_t)NFW*FD*FD*sizeof(float));
  bft*   w1tb  = (bft*)  alloc((size_t)NFW*FD*FD*sizeof(bft));
  bft*   w02b  = (bft*)  alloc((size_t)NFW*1024*FD*sizeof(bft));  // w0 rows 0-511, w2 rows 512-1023
  bft*   w1b   = (bft*)  alloc((size_t)NFW*FD*FD*sizeof(bft));
  bf16*  gb    = (bf16*) alloc((size_t)NFW*CHUNK_LEN*FD*sizeof(bf16));
  bf16*  hmb   = (bf16*) alloc((size_t)NFW*CHUNK_LEN*FD*sizeof(bf16));
  bf16*  qgb   = (bf16*) alloc((size_t)NFW*CHUNK_LEN*FD*sizeof(bf16));
  bf16*  qmb   = (bf16*) alloc((size_t)NFW*CHUNK_LEN*FD*sizeof(bf16));
  bf16*  hidb  = (bf16*) alloc((size_t)NFW*CHUNK_LEN*FD*sizeof(bf16));
  bf16*  ofc   = (bf16*) alloc((size_t)NFW*CHUNK_LEN*FD*sizeof(bf16));
  bft*   fkT   = (bft*)  alloc((size_t)NFW*FD*CHUNK_LEN*sizeof(bft));
  bft*   hidT  = (bft*)  alloc((size_t)NFW*FD*CHUNK_LEN*sizeof(bft));
  bft*   a2T   = (bft*)  alloc((size_t)NFW*FD*CHUNK_LEN*sizeof(bft));

  if ((size_t)(p - (char*)d_ws) > ws_size) return;

  // Fused-buffer views (gb..qmb contiguous):
  //   ghb = gb..hmb  : [z][ci][ g | hm ]  (16 MB)
  //   qgm = qgb..qmb : [z][ci][ qg | qm ] (16 MB)
  bft* ghb = (bft*)gb;
  bft* qgm = (bft*)qgb;
  // Liveness aliases:
  //   hidden_bf (33.55 MB) = gb..qmb  — dead before chunk loop.
  //   qkvw_bf   (25.17 MB) = fkT..hidT — dead before vt_k writes vT.
  //   vT        (33.55 MB) = fkT..a2T — dead before chunk loop's tr_k.
  //   opw_bf    ( 8.39 MB) = hidb     — converted after last e5.
  bft* hidden_bf = (bft*)gb;
  bft* qkvw_bf   = (bft*)fkT;
  bft* vT        = (bft*)fkT;
  bft* opw_bf    = (bft*)hidb;

  float* attn = out;   // attn lives in d_out until the final projection

  const long sW  = (long)FD*FD;
  const long sW2 = (long)1024*FD;
  const long sCh = (long)CHUNK_LEN*FD;
  const long sGH = (long)CHUNK_LEN*1024;
  const long sT  = (long)FD*CHUNK_LEN;

  hipMemcpyAsync(w0s, w0_in, (size_t)NFW*FD*FD*sizeof(float), hipMemcpyDeviceToDevice, stream);
  hipMemcpyAsync(w1s, w1_in, (size_t)NFW*FD*FD*sizeof(float), hipMemcpyDeviceToDevice, stream);
  hipMemcpyAsync(w2s, w2_in, (size_t)NFW*FD*FD*sizeof(float), hipMemcpyDeviceToDevice, stream);

  rope_k<<<S_LEN, 64, 0, stream>>>(rc, rs);
  lr_k<<<S_LEN, 256, 0, stream>>>(hidden, lr_w, lr_b, lrb);
  tcw1_k<<<NFW*FD*FD/256, 256, 0, stream>>>(w1_in, w1tb);
  cvt_k<<<(NFW*FD*FD)/2048, 256, 0, stream>>>(w1_in, w1b);
  for (int z = 0; z < NFW; ++z) {
    cvt_k<<<(FD*FD)/2048, 256, 0, stream>>>(w0_in + (size_t)z*sW, w02b + (size_t)z*sW2);
    cvt_k<<<(FD*FD)/2048, 256, 0, stream>>>(w2_in + (size_t)z*sW, w02b + (size_t)z*sW2 + (size_t)512*FD);
  }
  cvt_k<<<(S_LEN*HID)/2048, 256, 0, stream>>>(hidden, hidden_bf);
  cvt_k<<<(QKV3*HID)/2048, 256, 0, stream>>>(qkv_w, qkvw_bf);

  // qkv = hidden @ qkv_w^T -> bf16   (256^2 pipelined GEMM)
  mgemm8<0>(stream, hidden_bf, qkvw_bf, (void*)qkv, S_LEN, QKV3, HID, HID, HID, QKV3);

  e2a_k<<<S_LEN, 256, 0, stream>>>(qkv, q_norm_w, k_norm_w);
  vt_k<<<dim3(S_LEN/64, NH), 256, 0, stream>>>(qkv, vT);
  attn_k<<<NH*128, 256, 0, stream>>>(qkv, vT, rc, rs, attn);
  e2b_k<<<S_LEN, 256, 0, stream>>>(qkv, qk_scale, qk_off);

  const int  NEL = NFW*CHUNK_LEN*FD/256;
  const dim3 tg(FD/64, CHUNK_LEN/64, NFW);

  for(int c=0; c<NCHUNK; c++){
    const bft* fqc = (const bft*)qkv + (size_t)c*CHUNK_LEN*QKV3;
    const bft* fkc = fqc + HID;
    const bft* fvc = fqc + 2*HID;
    // fused forward: [g|hm] = fk @ [w0|w2]^T ; [qg|qm] = fq @ [w0|w2]^T
    mgemm<128,128,0>(stream, fkc, w02b, ghb, nullptr, nullptr,
        CHUNK_LEN, 1024, FD, QKV3, FD, 1024, NFW, FD, sW2, sGH, 0);
    mgemm<128,128,0>(stream, fqc, w02b, qgm, nullptr, nullptr,
        CHUNK_LEN, 1024, FD, QKV3, FD, 1024, NFW, FD, sW2, sGH, 0);
    e3f_k<<<NEL, 256, 0, stream>>>(ghb, qgm, (bft*)hidb);
    // ofc = opre @ w1^T   (opre = qgm col 0-511, lda=1024)
    mgemm<128,128,0>(stream, (const bft*)qgm, w1b, ofc, nullptr, nullptr,
        CHUNK_LEN, FD, FD, 1024, FD, FD, NFW, sGH, sW, sCh, 0);
    // dhid = fv @ w1  (-> qgm col 512-1023; qm is dead after e3f)
    mgemm<128,128,0>(stream, fvc, (const bft*)w1tb, qgm + 512, nullptr, nullptr,
        CHUNK_LEN, FD, FD, QKV3, FD, 1024, NFW, FD, sW, sGH, 0);
    e4f_k<<<NEL, 256, 0, stream>>>(ghb, qgm, qkv, lrb, c*CHUNK_LEN);
    tr_k<<<tg, 256, 0, stream>>>(fkc,              fkT,  QKV3, FD,  sT);
    tr_k<<<tg, 256, 0, stream>>>((const bft*)hidb, hidT, FD,   sCh, sT);
    // interleave transpose -> update (a2T reused as the scratch T buffer)
    tr_k<<<tg, 256, 0, stream>>>(ghb,       a2T, 1024, sGH, sT);   // a0^T
    mgemm<64,64,2>(stream, a2T, fkT,  w0s, w02b, nullptr,
        FD, FD, CHUNK_LEN, CHUNK_LEN, CHUNK_LEN, FD, NFW, sT, sT, sW, sW2);
    tr_k<<<tg, 256, 0, stream>>>(ghb + 512, a2T, 1024, sGH, sT);   // a2^T
    mgemm<64,64,2>(stream, a2T, fkT,  w2s, w02b + (size_t)512*FD, nullptr,
        FD, FD, CHUNK_LEN, CHUNK_LEN, CHUNK_LEN, FD, NFW, sT, sT, sW, sW2);
    tr_k<<<tg, 256, 0, stream>>>(qgm + 512, a2T, 1024, sGH, sT);   // a1^T
    mgemm<64,64,2>(stream, a2T, hidT, w1s, w1b, w1tb,
        FD, FD, CHUNK_LEN, CHUNK_LEN, CHUNK_LEN, FD, NFW, sT, sT, sW, sW);
    e5_k<<<CHUNK_LEN, 256, 0, stream>>>(attn, ofc, ttt_nw, qkv, c*CHUNK_LEN);
  }

  // bf16 copy of o_proj (hidb/ofc are dead now), then final projection
  cvt_k<<<(HID*HID)/2048, 256, 0, stream>>>(o_proj, opw_bf);
  mgemm8<1>(stream, (const bft*)qkv, opw_bf, out, S_LEN, HID, HID, QKV3, HID, HID);
}

// Round 7
// 1499.164 us; speedup vs baseline: 1.1958x; 1.0046x over previous
//
#include <hip/hip_runtime.h>
#include <hip/hip_bf16.h>

typedef __hip_bfloat16 bf16;
typedef __bf16 bft;
typedef bft bf16x8 __attribute__((ext_vector_type(8)));
typedef bft bf16x4 __attribute__((ext_vector_type(4)));
typedef float f32x4 __attribute__((ext_vector_type(4)));

#define S_LEN 8192
#define HID   2048
#define QKV3  6144
#define NH    16
#define HD    128
#define NFW   4
#define FD    512
#define CHUNK_LEN 2048
#define NCHUNK 4
#define BASE_LR_INV (-6.9072552f)   // log(expm1(0.001))
#define QKP 136                     // attn Q/K LDS stride (128 + 8)
#define VSP 72                      // attn V^T LDS stride (64 + 8)
#define PSP 76                      // attn P LDS stride (64 + 12)

__device__ __forceinline__ float bf2f(bf16 x){ return __bfloat162float(x); }
__device__ __forceinline__ bf16  f2bf(float x){ return __float2bfloat16(x); }
__device__ __forceinline__ float sigm(float x){ return 1.f/(1.f+__expf(-x)); }
__device__ __forceinline__ float siluf(float x){ return x/(1.f+__expf(-x)); }
__device__ __forceinline__ float wave_sum(float v){
  #pragma unroll
  for(int off=32; off; off>>=1) v += __shfl_xor(v, off, 64);
  return v;
}

template<int N>
__device__ __forceinline__ void waitcnt_vm(){
  static_assert(N==0||N==2||N==4||N==8, "unsupported vmcnt");
  if constexpr (N==0)      asm volatile("s_waitcnt vmcnt(0)" ::: "memory");
  else if constexpr (N==2) asm volatile("s_waitcnt vmcnt(2)" ::: "memory");
  else if constexpr (N==4) asm volatile("s_waitcnt vmcnt(4)" ::: "memory");
  else                     asm volatile("s_waitcnt vmcnt(8)" ::: "memory");
}

// Raw barrier, NO sched_barrier pinning (m141).
__device__ __forceinline__ void bar(){
  __builtin_amdgcn_s_barrier();
  asm volatile("" ::: "memory");
}

// ---------------------------------------------------------------------------
// GEMM LDS tile staging (bf16 only), swizzled layout.
// Tile: ROWS x 32 bf16, unpadded [row][32]; physical col-slot c (8 elems)
// holds logical col-group g = c ^ ((row>>1)&3).
// global_load_lds 16B/lane; LDS dest = wave-uniform base + lane*16.
// ---------------------------------------------------------------------------
template<int ROWS>
__device__ __forceinline__ void stage(const bft* __restrict__ src, long ld,
                                      bft* dst, int tid)
{
  const int lane = tid & 63, wv = tid >> 6;
  #pragma unroll
  for (int i = 0; i < ROWS/64; ++i) {
    const int r0 = wv*16 + i*64;               // wave-uniform
    const int row = r0 + (lane >> 2);
    const int g = (lane & 3) ^ ((row >> 1) & 3);
    const bft* gp = src + (size_t)row*ld + g*8;
    bft* lp = dst + (size_t)r0*32;
    __builtin_amdgcn_global_load_lds(
        (const __attribute__((address_space(1))) void*)gp,
        (__attribute__((address_space(3))) void*)lp, 16, 0, 0);
  }
}

// ---------------------------------------------------------------------------
// MFMA NT GEMM: C[M,N] (+)= A[M,K] * B[N,K]^T, fp32 accumulate, 256 threads.
// 4-slot circular LDS pipeline (BK=32), counted vmcnt (never drained to 0
// in steady state), m201-style phase skeleton (round-5 structure: keeps
// VGPR ~100 so 512-block chunk grids stay 2-blocks/CU co-resident).
// Race-freedom: slot written at iter s is (s+2)&3; concurrent readers touch
// s&3 (distinct mod 4); reads of the overwritten buffer finished >=1 barrier
// earlier. vmcnt ladder leaves slot s+2's LPT loads in flight.
// EPI: 0 = store bf16, 1 = store fp32, 2 = fp32 C += acc, bf16 direct shadow
// Cd (z-stride sCd, row stride ldc), optional transposed shadow Ct.
// ---------------------------------------------------------------------------
template<int BM,int BN,int EPI>
__global__ __launch_bounds__(256) void mgemm_k(
    const bft* __restrict__ A, const bft* __restrict__ B, void* __restrict__ Cv,
    bft* __restrict__ Cd, bft* __restrict__ Ct, int K,
    long lda, long ldb, long ldc, long sA, long sB, long sC, long sCd)
{
  constexpr int AM = BM/32, AN = BN/32;
  constexpr int LPT = BM/64 + BN/64;           // global_load_lds per wave/slot
  constexpr int NPH = (AM >= 4) ? 2 : 1;       // compute phases per slot
  constexpr int MH  = AM / NPH;                // mi rows per phase
  __shared__ __align__(16) bft As[4][BM*32];
  __shared__ __align__(16) bft Bs[4][BN*32];
  const int tid = threadIdx.x;
  const int z = blockIdx.z;
  A += (size_t)z * sA;
  B += (size_t)z * sB;
  const size_t m0 = (size_t)blockIdx.y * BM, n0 = (size_t)blockIdx.x * BN;
  const int wv = tid >> 6, lane = tid & 63;
  const int wm = (wv & 1) * (BM/2), wn = (wv >> 1) * (BN/2);
  const int fr = lane & 15;
  const int fsw = ((lane >> 4) ^ ((fr >> 1) & 3)) * 8;   // swizzled frag col

  f32x4 acc[AM][AN];
  #pragma unroll
  for (int i=0;i<AM;i++)
    #pragma unroll
    for (int j=0;j<AN;j++) acc[i][j] = (f32x4){0.f,0.f,0.f,0.f};

  const bft* Ab = A + m0*lda;
  const bft* Bb = B + n0*ldb;
  const int NS = K >> 5;

  stage<BM>(Ab,      lda, As[0], tid);
  stage<BN>(Bb,      ldb, Bs[0], tid);
  stage<BM>(Ab + 32, lda, As[1], tid);
  stage<BN>(Bb + 32, ldb, Bs[1], tid);
  waitcnt_vm<LPT>();
  bar();

  for (int s = 0; s < NS; ++s) {
    const bft* Ap = As[s & 3];
    const bft* Bp = Bs[s & 3];
    const int kt = (s + 2) * 32;
    const bool st = (s + 2 < NS);

    bf16x8 bvv[AN], afv[MH];
    // ---- phase A: all B-frags + first mi half; stage next A-tile ----
    #pragma unroll
    for (int ni=0; ni<AN; ni++)
      bvv[ni] = *(const bf16x8*)(Bp + (size_t)(wn + ni*16 + fr)*32 + fsw);
    #pragma unroll
    for (int i=0; i<MH; i++)
      afv[i] = *(const bf16x8*)(Ap + (size_t)(wm + i*16 + fr)*32 + fsw);
    if (st) stage<BM>(Ab + kt, lda, As[(s+2)&3], tid);
    if constexpr (NPH == 1) {
      if (st) { stage<BN>(Bb + kt, ldb, Bs[(s+2)&3], tid); waitcnt_vm<LPT>(); }
      else waitcnt_vm<0>();
    }
    bar();
    __builtin_amdgcn_s_setprio(1);
    #pragma unroll
    for (int i=0; i<MH; i++)
      #pragma unroll
      for (int ni=0; ni<AN; ni++)
        acc[i][ni] = __builtin_amdgcn_mfma_f32_16x16x32_bf16(afv[i], bvv[ni], acc[i][ni], 0, 0, 0);
    __builtin_amdgcn_s_setprio(0);

    if constexpr (NPH == 2) {
      bar();
      // ---- phase B: second mi half; stage next B-tile; vm ladder ----
      #pragma unroll
      for (int i=0; i<MH; i++)
        afv[i] = *(const bf16x8*)(Ap + (size_t)(wm + (MH+i)*16 + fr)*32 + fsw);
      if (st) { stage<BN>(Bb + kt, ldb, Bs[(s+2)&3], tid); waitcnt_vm<LPT>(); }
      else waitcnt_vm<0>();
      bar();
      __builtin_amdgcn_s_setprio(1);
      #pragma unroll
      for (int i=0; i<MH; i++)
        #pragma unroll
        for (int ni=0; ni<AN; ni++)
          acc[MH+i][ni] = __builtin_amdgcn_mfma_f32_16x16x32_bf16(afv[i], bvv[ni], acc[MH+i][ni], 0, 0, 0);
      __builtin_amdgcn_s_setprio(0);
      bar();
    }
  }

  const int er = (lane >> 4) * 4;   // C/D: row=(lane>>4)*4+reg, col=lane&15
  const int ec = lane & 15;
  #pragma unroll
  for (int mi=0; mi<AM; mi++){
    #pragma unroll
    for (int ni=0; ni<AN; ni++){
      #pragma unroll
      for (int r=0; r<4; r++){
        size_t row = m0 + wm + mi*16 + er + r;
        size_t col = n0 + wn + ni*16 + ec;
        size_t idx = (size_t)z*sC + row*ldc + col;
        float v = acc[mi][ni][r];
        if constexpr (EPI == 0){
          ((bft*)Cv)[idx] = (bft)v;
        } else if constexpr (EPI == 1){
          ((float*)Cv)[idx] = v;
        } else {
          float nv = ((float*)Cv)[idx] + v;
          ((float*)Cv)[idx] = nv;
          Cd[(size_t)z*sCd + row*ldc + col] = (bft)nv;
          if (Ct) Ct[(size_t)z*FD*FD + col*FD + row] = (bft)nv;
        }
      }
    }
  }
}

template<int BM,int BN,int EPI>
static inline void mgemm(hipStream_t st, const bft* A, const bft* B, void* C,
    bft* Cd, bft* Ct, int M, int N, int K, long lda, long ldb, long ldc,
    int batch, long sA, long sB, long sC, long sCd)
{
  dim3 g(N/BN, M/BM, batch);
  mgemm_k<BM,BN,EPI><<<g, 256, 0, st>>>(A, B, C, Cd, Ct, K, lda, ldb, ldc, sA, sB, sC, sCd);
}

// ---------------------------------------------------------------------------
// 256x256 MFMA NT GEMM, 4-slot ring, 512 threads = 8 waves (2Mx4N),
// per-wave 128x64 output, cross-slot register double-buffer.
// One sched_barrier(0) between the next-slot frag reads and the MFMA
// cluster: forbids the scheduler from sinking the (consumer-less until next
// iteration) ds_reads below the MFMAs, which would re-serialize the LDS and
// matrix pipes. Inside each region scheduling stays free (NOT m141's
// every-edge pinning). Race proof as before: 1 barrier/slot; stage at iter
// s targets buffer (s+2)&3 whose last reads drained >=1 barrier earlier;
// vmcnt(4)+barrier guarantee slot s+1 landed before its reads.
// ---------------------------------------------------------------------------
__device__ __forceinline__ void stage8(const bft* __restrict__ src, long ld,
                                       bft* dst, int tid)
{
  const int lane = tid & 63, wv = tid >> 6;      // 8 waves
  #pragma unroll
  for (int i = 0; i < 2; ++i) {
    const int r0 = wv*16 + i*128;                // wave-uniform
    const int row = r0 + (lane >> 2);
    const int g = (lane & 3) ^ ((row >> 1) & 3);
    const bft* gp = src + (size_t)row*ld + g*8;
    bft* lp = dst + (size_t)r0*32;
    __builtin_amdgcn_global_load_lds(
        (const __attribute__((address_space(1))) void*)gp,
        (__attribute__((address_space(3))) void*)lp, 16, 0, 0);
  }
}

template<int EPI>
__global__ __launch_bounds__(512, 2) void mgemm8_k(
    const bft* __restrict__ A, const bft* __restrict__ B, void* __restrict__ Cv,
    int K, long lda, long ldb, long ldc)
{
  __shared__ __align__(16) bft As[4][256*32];
  __shared__ __align__(16) bft Bs[4][256*32];
  const int tid = threadIdx.x;

  const int gx = (int)gridDim.x;
  const int nwg = (int)(gridDim.x * gridDim.y);
  int lin = (int)(blockIdx.y * gridDim.x + blockIdx.x);
  if ((nwg & 7) == 0) lin = (lin & 7) * (nwg >> 3) + (lin >> 3);
  const size_t m0 = (size_t)(lin / gx) * 256;
  const size_t n0 = (size_t)(lin % gx) * 256;

  const int wv = tid >> 6, lane = tid & 63;
  const int wm = (wv & 1) * 128, wn = (wv >> 1) * 64;
  const int fr = lane & 15;
  const int fsw = ((lane >> 4) ^ ((fr >> 1) & 3)) * 8;

  f32x4 acc[8][4];
  #pragma unroll
  for (int i=0;i<8;i++)
    #pragma unroll
    for (int j=0;j<4;j++) acc[i][j] = (f32x4){0.f,0.f,0.f,0.f};

  const bft* Ab = A + m0*lda;
  const bft* Bb = B + n0*ldb;
  const int NS = K >> 5;

  stage8(Ab,      lda, As[0], tid);
  stage8(Bb,      ldb, Bs[0], tid);
  stage8(Ab + 32, lda, As[1], tid);
  stage8(Bb + 32, ldb, Bs[1], tid);
  waitcnt_vm<4>();
  bar();

  bf16x8 aP[8], bP[4], aQ[8], bQ[4];
  #pragma unroll
  for (int mi=0; mi<8; mi++)
    aP[mi] = *(const bf16x8*)(As[0] + (size_t)(wm + mi*16 + fr)*32 + fsw);
  #pragma unroll
  for (int ni=0; ni<4; ni++)
    bP[ni] = *(const bf16x8*)(Bs[0] + (size_t)(wn + ni*16 + fr)*32 + fsw);

  auto body = [&](bf16x8 (&ac)[8], bf16x8 (&bc)[4],
                  bf16x8 (&an)[8], bf16x8 (&bn)[4], int s){
    const int kt = (s + 2) * 32;
    const bool st2 = (s + 2 < NS);
    const bool rd  = (s + 1 < NS);
    if (st2) {
      stage8(Ab + kt, lda, As[(s+2)&3], tid);
      stage8(Bb + kt, ldb, Bs[(s+2)&3], tid);
    }
    if (rd) {
      if (st2) waitcnt_vm<4>(); else waitcnt_vm<0>();
      bar();
      const bft* An = As[(s+1)&3];
      const bft* Bn = Bs[(s+1)&3];
      #pragma unroll
      for (int mi=0; mi<8; mi++)
        an[mi] = *(const bf16x8*)(An + (size_t)(wm + mi*16 + fr)*32 + fsw);
      #pragma unroll
      for (int ni=0; ni<4; ni++)
        bn[ni] = *(const bf16x8*)(Bn + (size_t)(wn + ni*16 + fr)*32 + fsw);
    }
    // Pin the next-slot reads BEFORE the MFMA cluster so the LDS pipe
    // drains them underneath the matrix work (single fence, regions free).
    __builtin_amdgcn_sched_barrier(0);
    __builtin_amdgcn_s_setprio(1);
    #pragma unroll
    for (int mi=0; mi<8; mi++)
      #pragma unroll
      for (int ni=0; ni<4; ni++)
        acc[mi][ni] = __builtin_amdgcn_mfma_f32_16x16x32_bf16(ac[mi], bc[ni], acc[mi][ni], 0, 0, 0);
    __builtin_amdgcn_s_setprio(0);
  };

  for (int s = 0; s < NS; s += 2) {
    body(aP, bP, aQ, bQ, s);
    body(aQ, bQ, aP, bP, s + 1);
  }

  const int er = (lane >> 4) * 4;
  const int ec = lane & 15;
  #pragma unroll
  for (int mi=0; mi<8; mi++){
    #pragma unroll
    for (int ni=0; ni<4; ni++){
      #pragma unroll
      for (int r=0; r<4; r++){
        size_t row = m0 + wm + mi*16 + er + r;
        size_t col = n0 + wn + ni*16 + ec;
        size_t idx = row*ldc + col;
        float v = acc[mi][ni][r];
        if constexpr (EPI == 0) ((bft*)Cv)[idx] = (bft)v;
        else                    ((float*)Cv)[idx] = v;
      }
    }
  }
}

template<int EPI>
static inline void mgemm8(hipStream_t st, const bft* A, const bft* B, void* C,
                          int M, int N, int K, long lda, long ldb, long ldc)
{
  dim3 g(N/256, M/256, 1);
  mgemm8_k<EPI><<<g, 512, 0, st>>>(A, B, C, K, lda, ldb, ldc);
}

// ---------------------------------------------------------------------------
// fp32 -> bf16 bulk convert (8 elems/thread); n must divide 2048.
// ---------------------------------------------------------------------------
__global__ __launch_bounds__(256) void cvt_k(const float* __restrict__ s,
    bft* __restrict__ d)
{
  size_t i = ((size_t)blockIdx.x*256 + threadIdx.x) * 8;
  const float4 v0 = *(const float4*)(s + i);
  const float4 v1 = *(const float4*)(s + i + 4);
  bf16x8 b;
  b[0]=(bft)v0.x; b[1]=(bft)v0.y; b[2]=(bft)v0.z; b[3]=(bft)v0.w;
  b[4]=(bft)v1.x; b[5]=(bft)v1.y; b[6]=(bft)v1.z; b[7]=(bft)v1.w;
  *(bf16x8*)(d + i) = b;
}

// ---------------------------------------------------------------------------
// Batched bf16 transpose: out[z][c][r] = in[z][r][c]; arbitrary ldin/sIn.
// ---------------------------------------------------------------------------
__global__ __launch_bounds__(256) void tr_k(const bft* __restrict__ in,
    bft* __restrict__ out, long ldin, long sIn, long sOut)
{
  __shared__ __align__(16) bft t[64][72];
  const int c0 = blockIdx.x*64, r0 = blockIdx.y*64;
  in  += (size_t)blockIdx.z * sIn;
  out += (size_t)blockIdx.z * sOut;
  const int tid = threadIdx.x;
  #pragma unroll
  for (int i=0;i<2;i++){
    int e = tid + i*256;
    int r = e >> 3, c8 = (e & 7) * 8;
    *(bf16x8*)&t[r][c8] = *(const bf16x8*)(in + (size_t)(r0+r)*ldin + c0 + c8);
  }
  __syncthreads();
  #pragma unroll
  for (int i=0;i<2;i++){
    int e = tid + i*256;
    int c = e >> 3, r8 = (e & 7) * 8;
    bf16x8 v;
    #pragma unroll
    for (int j=0;j<8;j++) v[j] = t[r8+j][c];
    *(bf16x8*)(out + (size_t)(c0+c)*CHUNK_LEN + r0 + r8) = v;
  }
}

// initial w1^T bf16 shadow: w1tb[z][h][o] = (bf16)w1[z][o][h]
__global__ __launch_bounds__(256) void tcw1_k(const float* __restrict__ w1,
    bft* __restrict__ w1tb)
{
  size_t idx = (size_t)blockIdx.x*256 + threadIdx.x;
  int z = (int)(idx >> 18);
  int h = (int)((idx >> 9) & 511);
  int o = (int)(idx & 511);
  w1tb[idx] = (bft)w1[(size_t)z*FD*FD + (size_t)o*FD + h];
}

// ---------------------------------------------------------------------------
// v^T for attention PV: vT[h][d][s] = v[s][h*128+d] (raw v region of qkv).
// ---------------------------------------------------------------------------
__global__ __launch_bounds__(256) void vt_k(const bf16* __restrict__ qkv,
    bft* __restrict__ vT)
{
  __shared__ __align__(16) bft t[64*QKP];   // [s][d]
  const int s0 = blockIdx.x * 64;
  const int h  = blockIdx.y;
  const int tid = threadIdx.x;
  #pragma unroll
  for (int i=0;i<4;i++){
    int e = tid + i*256;
    int rr = e >> 4, doff = (e & 15) * 8;
    *(bf16x8*)(t + rr*QKP + doff) =
        *(const bf16x8*)((const bft*)qkv + (size_t)(s0+rr)*QKV3 + 2*HID + h*HD + doff);
  }
  __syncthreads();
  #pragma unroll
  for (int it=0; it<4; it++){
    int d = (tid >> 3) + it*32;
    int so8 = (tid & 7) * 8;
    bf16x8 v;
    #pragma unroll
    for (int j=0;j<8;j++) v[j] = t[(so8+j)*QKP + d];
    *(bf16x8*)(vT + ((size_t)(h*HD + d))*S_LEN + s0 + so8) = v;
  }
}

// ---------------------------------------------------------------------------
// RoPE cos/sin tables
// ---------------------------------------------------------------------------
__global__ void rope_k(float* __restrict__ rc, float* __restrict__ rs){
  int pos = blockIdx.x, d = threadIdx.x;
  float inv = 1.f / powf(500000.0f, (float)d * (1.0f/64.0f));
  float ang = (float)pos * inv;
  rc[pos*64+d] = cosf(ang);
  rs[pos*64+d] = sinf(ang);
}

// ---------------------------------------------------------------------------
// per-token learning rates
// ---------------------------------------------------------------------------
__global__ __launch_bounds__(256) void lr_k(const float* __restrict__ hidden,
    const float* __restrict__ lr_w, const float* __restrict__ lr_b,
    float* __restrict__ lro)
{
  __shared__ float hrow[HID];
  __shared__ float red[4][12];
  int s = blockIdx.x, tid = threadIdx.x;
  for(int i=0;i<HID/256;i++) hrow[tid+256*i] = hidden[(size_t)s*HID + tid + 256*i];
  __syncthreads();
  float part[12];
  #pragma unroll
  for(int o=0;o<12;o++) part[o]=0.f;
  for(int i=0;i<HID/256;i++){
    int j = tid + 256*i;
    float h = hrow[j];
    #pragma unroll
    for(int o=0;o<12;o++) part[o] += h * lr_w[o*HID + j];
  }
  int lane = tid & 63, w = tid >> 6;
  #pragma unroll
  for(int o=0;o<12;o++){
    float v = wave_sum(part[o]);
    if(lane==0) red[w][o] = v;
  }
  __syncthreads();
  if(tid < 12){
    float v = red[0][tid]+red[1][tid]+red[2][tid]+red[3][tid] + lr_b[tid] + BASE_LR_INV;
    float sp = (v > 20.f) ? v : log1pf(expf(v));
    lro[s*12 + tid] = sp;
  }
}

// ---------------------------------------------------------------------------
// E2a: per-token rmsnorm(q), rmsnorm(k), in place in qkv (bf16).
// ---------------------------------------------------------------------------
__global__ __launch_bounds__(256) void e2a_k(
    bf16* __restrict__ qkv,
    const float* __restrict__ qnw, const float* __restrict__ knw)
{
  __shared__ float red[8];
  int s = blockIdx.x, tid = threadIdx.x;
  int lane = tid & 63, w = tid >> 6;
  float qv[8], kv[8];
  float sq = 0.f, sk = 0.f;
  size_t base = (size_t)s*QKV3;
  #pragma unroll
  for(int i=0;i<8;i++){
    int j = tid*8 + i;
    qv[i] = bf2f(qkv[base + j]);
    kv[i] = bf2f(qkv[base + HID + j]);
    sq += qv[i]*qv[i]; sk += kv[i]*kv[i];
  }
  sq = wave_sum(sq); sk = wave_sum(sk);
  if(lane==0){ red[w] = sq; red[4+w] = sk; }
  __syncthreads();
  float rq = rsqrtf((red[0]+red[1]+red[2]+red[3])*(1.f/HID) + 1e-6f);
  float rk = rsqrtf((red[4]+red[5]+red[6]+red[7])*(1.f/HID) + 1e-6f);
  #pragma unroll
  for(int i=0;i<8;i++){
    int j = tid*8 + i;
    qkv[base + j]       = f2bf(qv[i]*rq*qnw[j]);
    qkv[base + HID + j] = f2bf(kv[i]*rk*knw[j]);
  }
}

// ---------------------------------------------------------------------------
// E2b (after attention): overwrite q/k/v regions with fq/fk/fv.
// ---------------------------------------------------------------------------
__global__ __launch_bounds__(256) void e2b_k(
    bf16* __restrict__ qkv,
    const float* __restrict__ qks, const float* __restrict__ qko)
{
  int s = blockIdx.x, tid = threadIdx.x;
  size_t base = (size_t)s*QKV3;
  float a[8], b[8], vv[8];
  float ga = 0.f, gb2 = 0.f;
  #pragma unroll
  for(int i=0;i<8;i++){
    int j = tid*8 + i;
    float qn = bf2f(qkv[base + j]);
    float kn = bf2f(qkv[base + HID + j]);
    float v  = bf2f(qkv[base + 2*HID + j]);
    a[i] = siluf(qn*qks[2*j]   + qko[2*j]);
    b[i] = siluf(kn*qks[2*j+1] + qko[2*j+1]);
    vv[i] = siluf(v);
    ga += a[i]*a[i]; gb2 += b[i]*b[i];
  }
  ga = wave_sum(ga); gb2 = wave_sum(gb2);
  float iq = 1.f / fmaxf(sqrtf(ga), 1e-12f);
  float ik = 1.f / fmaxf(sqrtf(gb2), 1e-12f);
  #pragma unroll
  for(int i=0;i<8;i++){
    int j = tid*8 + i;
    qkv[base + j]         = f2bf(a[i]*iq);
    qkv[base + HID + j]   = f2bf(b[i]*ik);
    qkv[base + 2*HID + j] = f2bf(vv[i]);
  }
}

// ---------------------------------------------------------------------------
// MFMA sliding-window attention (window 256 incl self).
// ---------------------------------------------------------------------------
__global__ __launch_bounds__(256) void attn_k(
    const bf16* __restrict__ qkv, const bft* __restrict__ vT,
    const float* __restrict__ rc, const float* __restrict__ rs,
    float* __restrict__ attn)
{
  __shared__ __align__(16) bft Qs[64*QKP];
  __shared__ __align__(16) bft Ks[64*QKP];
  __shared__ __align__(16) bft Vs[128*VSP];
  __shared__ __align__(16) bft Ps[64*PSP];
  const int head = blockIdx.x >> 7;
  const int Q0 = (blockIdx.x & 127) * 64;
  const int tid = threadIdx.x;
  const int hb = head * HD;
  const int lane = tid & 63;
  const int wm = (tid >> 6) * 16;
  const int fr = lane & 15, fko = (lane >> 4) * 8;
  const int rbase = (lane >> 4) * 4;

  #pragma unroll
  for(int i=0;i<16;i++){
    int e = tid + i*256;
    int rr = e >> 6, d = e & 63;
    int qpos = Q0 + rr;
    size_t b = (size_t)qpos*QKV3 + hb;
    float x1 = bf2f(qkv[b + d]);
    float x2 = bf2f(qkv[b + d + 64]);
    float c = rc[qpos*64 + d], sn = rs[qpos*64 + d];
    Qs[rr*QKP + d]      = (bft)(x1*c - x2*sn);
    Qs[rr*QKP + d + 64] = (bft)(x2*c + x1*sn);
  }
  __syncthreads();
  bf16x8 qf[4];
  #pragma unroll
  for (int kk=0;kk<4;kk++)
    qf[kk] = *(const bf16x8*)(Qs + (wm+fr)*QKP + kk*32 + fko);

  f32x4 Ot[8];
  #pragma unroll
  for (int i=0;i<8;i++) Ot[i] = (f32x4){0.f,0.f,0.f,0.f};
  float m4[4], l4[4];
  #pragma unroll
  for (int r=0;r<4;r++){ m4[r] = -INFINITY; l4[r] = 0.f; }

  for (int kt=0; kt<5; kt++){
    const int kb = Q0 - 256 + kt*64;
    if (kb < 0) continue;
    __syncthreads();
    #pragma unroll
    for(int i=0;i<16;i++){
      int e = tid + i*256;
      int rr = e >> 6, d = e & 63;
      int kpos = kb + rr;
      size_t b = (size_t)kpos*QKV3 + HID + hb;
      float x1 = bf2f(qkv[b + d]);
      float x2 = bf2f(qkv[b + d + 64]);
      float c = rc[kpos*64 + d], sn = rs[kpos*64 + d];
      Ks[rr*QKP + d]      = (bft)(x1*c - x2*sn);
      Ks[rr*QKP + d + 64] = (bft)(x2*c + x1*sn);
    }
    {
      int d = tid >> 1, koff = (tid & 1) * 32;
      const bft* vrow = vT + ((size_t)(hb + d))*S_LEN + kb + koff;
      bft* lrow = Vs + d*VSP + koff;
      #pragma unroll
      for (int j8=0;j8<4;j8++)
        *(bf16x8*)(lrow + j8*8) = *(const bf16x8*)(vrow + j8*8);
    }
    __syncthreads();

    f32x4 st[4];
    #pragma unroll
    for (int nt=0;nt<4;nt++){
      f32x4 acc = (f32x4){0.f,0.f,0.f,0.f};
      #pragma unroll
      for (int kk=0;kk<4;kk++){
        bf16x8 kf = *(const bf16x8*)(Ks + (nt*16+fr)*QKP + kk*32 + fko);
        acc = __builtin_amdgcn_mfma_f32_16x16x32_bf16(qf[kk], kf, acc, 0, 0, 0);
      }
      st[nt] = acc;
    }

    float pv[4][4];
    #pragma unroll
    for (int r=0;r<4;r++){
      int qpos = Q0 + wm + rbase + r;
      float sm[4];
      float mx = -INFINITY;
      #pragma unroll
      for (int nt=0;nt<4;nt++){
        int kpos = kb + nt*16 + fr;
        bool valid = (kpos > qpos - 256) && (kpos <= qpos);
        float s = valid ? st[nt][r] * 0.088388347648318447f : -INFINITY;
        sm[nt] = s;
        mx = fmaxf(mx, s);
      }
      mx = fmaxf(mx, __shfl_xor(mx, 1, 64));
      mx = fmaxf(mx, __shfl_xor(mx, 2, 64));
      mx = fmaxf(mx, __shfl_xor(mx, 4, 64));
      mx = fmaxf(mx, __shfl_xor(mx, 8, 64));
      float mnew = fmaxf(m4[r], mx);
      float alpha = (mnew == -INFINITY) ? 1.f : __expf(m4[r] - mnew);
      float ps = 0.f;
      #pragma unroll
      for (int nt=0;nt<4;nt++){
        float p = (sm[nt] == -INFINITY) ? 0.f : __expf(sm[nt] - mnew);
        pv[nt][r] = p;
        ps += p;
      }
      ps += __shfl_xor(ps, 1, 64);
      ps += __shfl_xor(ps, 2, 64);
      ps += __shfl_xor(ps, 4, 64);
      ps += __shfl_xor(ps, 8, 64);
      l4[r] = l4[r]*alpha + ps;
      m4[r] = mnew;
      #pragma unroll
      for (int ct=0;ct<8;ct++) Ot[ct][r] *= alpha;
    }

    #pragma unroll
    for (int r=0;r<4;r++){
      int row = wm + rbase + r;
      #pragma unroll
      for (int nt=0;nt<4;nt++)
        Ps[row*PSP + nt*16 + fr] = (bft)pv[nt][r];
    }
    bf16x8 af[2];
    #pragma unroll
    for (int kk=0;kk<2;kk++){
      const bft* pp = Ps + (wm+fr)*PSP + kk*32 + fko;
      bf16x4 lo = *(const bf16x4*)pp;
      bf16x4 hi = *(const bf16x4*)(pp+4);
      bf16x8 a;
      #pragma unroll
      for (int j=0;j<4;j++){ a[j]=lo[j]; a[j+4]=hi[j]; }
      af[kk]=a;
    }
    #pragma unroll
    for (int ct=0;ct<8;ct++)
      #pragma unroll
      for (int kk=0;kk<2;kk++){
        bf16x8 bv = *(const bf16x8*)(Vs + (ct*16+fr)*VSP + kk*32 + fko);
        Ot[ct] = __builtin_amdgcn_mfma_f32_16x16x32_bf16(af[kk], bv, Ot[ct], 0, 0, 0);
      }
  }

  #pragma unroll
  for (int r=0;r<4;r++){
    float invl = 1.f / l4[r];
    int qpos = Q0 + wm + rbase + r;
    size_t ob = (size_t)qpos*HID + hb;
    #pragma unroll
    for (int ct=0;ct<8;ct++)
      attn[ob + ct*16 + fr] = Ot[ct][r] * invl;
  }
}

// ---------------------------------------------------------------------------
// TTT elementwise fwd on FUSED buffers:
// gh = [z][ci][ g(0:512) | hm(512:1024) ], qgm = [z][ci][ qg | qm ].
// hid = silu(g)*hm (separate [z][ci][512]); opre = silu(qg)*qm -> qgm col 0.
// ---------------------------------------------------------------------------
__global__ __launch_bounds__(256) void e3f_k(
    bft* __restrict__ gh, bft* __restrict__ qgm, bft* __restrict__ hid)
{
  size_t idx = (size_t)blockIdx.x*256 + threadIdx.x;   // over NFW*CHUNK*FD
  int z  = (int)(idx >> 20);
  int ci = (int)((idx >> 9) & 2047);
  int d  = (int)(idx & 511);
  size_t b = ((size_t)z*CHUNK_LEN + ci)*1024 + d;
  float opre = siluf((float)qgm[b]) * (float)qgm[b + 512];
  hid[idx] = (bft)(siluf((float)gh[b]) * (float)gh[b + 512]);
  qgm[b]   = (bft)opre;
}

// ---------------------------------------------------------------------------
// TTT backprop elementwise on fused buffers (in place):
// gh col0 -> dgp*l0 (a0), gh col512 -> dhm*l2 (a2), qgm col512 -> fv*l1 (a1).
// dhid was written into qgm col512 by the fv@w1tb GEMM.
// ---------------------------------------------------------------------------
__global__ __launch_bounds__(256) void e4f_k(
    bft* __restrict__ gh, bft* __restrict__ qgm,
    const bf16* __restrict__ qkv, const float* __restrict__ lrb, int cbase)
{
  size_t idx = (size_t)blockIdx.x*256 + threadIdx.x;
  int z  = (int)(idx >> 20);
  int ci = (int)((idx >> 9) & 2047);
  int d  = (int)(idx & 511);
  int s  = cbase + ci;
  float l0  = lrb[s*12 + z];
  float l1  = lrb[s*12 + 4 + z];
  float l2v = lrb[s*12 + 8 + z];
  size_t b = ((size_t)z*CHUNK_LEN + ci)*1024 + d;
  float gg = (float)gh[b], hv = (float)gh[b + 512], dh = (float)qgm[b + 512];
  float sg = sigm(gg);
  float silu_g = gg * sg;
  float dhm = dh * silu_g;
  float dg  = dh * hv;
  float dgp = dg * (sg * (1.f + gg * (1.f - sg)));
  float fvv = bf2f(qkv[(size_t)s*QKV3 + 2*HID + z*FD + d]);
  gh[b]        = (bft)(dgp * l0);
  gh[b + 512]  = (bft)(dhm * l2v);
  qgm[b + 512] = (bft)(fvv * l1);
}

// ---------------------------------------------------------------------------
// E5 (per chunk): X = attn + rmsnorm(ofc)*ttt_norm_w -> q region of qkv
// ---------------------------------------------------------------------------
__global__ __launch_bounds__(256) void e5_k(const float* __restrict__ attn,
    const bf16* __restrict__ ofc, const float* __restrict__ tnw,
    bf16* __restrict__ qkv, int cbase)
{
  int ci = blockIdx.x, tid = threadIdx.x;
  int s = cbase + ci;
  int lane = tid & 63, w = tid >> 6;
  float o[8]; float ss = 0.f;
  size_t ob = ((size_t)w*CHUNK_LEN + ci)*FD + (size_t)lane*8;
  #pragma unroll
  for(int i=0;i<8;i++){ o[i] = bf2f(ofc[ob+i]); ss += o[i]*o[i]; }
  ss = wave_sum(ss);
  float inv = rsqrtf(ss*(1.f/FD) + 1e-6f);
  size_t xb = (size_t)s*QKV3 + w*FD + (size_t)lane*8;
  size_t ab = (size_t)s*HID  + w*FD + (size_t)lane*8;
  #pragma unroll
  for(int i=0;i<8;i++){
    int d = lane*8 + i;
    qkv[xb+i] = f2bf(attn[ab+i] + o[i]*inv*tnw[d]);
  }
}

// ---------------------------------------------------------------------------
extern "C" void kernel_launch(void* const* d_in, const int* in_sizes, int n_in,
                              void* d_out, int out_size, void* d_ws, size_t ws_size,
                              hipStream_t stream)
{
  (void)in_sizes; (void)n_in; (void)out_size;
  const float* hidden   = (const float*)d_in[0];
  const float* qkv_w    = (const float*)d_in[1];
  const float* q_norm_w = (const float*)d_in[2];
  const float* k_norm_w = (const float*)d_in[3];
  const float* qk_scale = (const float*)d_in[4];
  const float* qk_off   = (const float*)d_in[5];
  const float* lr_w     = (const float*)d_in[6];
  const float* lr_b     = (const float*)d_in[7];
  const float* w0_in    = (const float*)d_in[8];
  const float* w1_in    = (const float*)d_in[9];
  const float* w2_in    = (const float*)d_in[10];
  const float* ttt_nw   = (const float*)d_in[11];
  const float* o_proj   = (const float*)d_in[12];
  float* out = (float*)d_out;

  char* p = (char*)d_ws;
  auto alloc = [&](size_t n){ char* r = p; p += (n + 255) & ~(size_t)255; return (void*)r; };

  bf16*  qkv   = (bf16*) alloc((size_t)S_LEN*QKV3*sizeof(bf16));
  float* lrb   = (float*)alloc((size_t)S_LEN*12*sizeof(float));
  float* rc    = (float*)alloc((size_t)S_LEN*64*sizeof(float));
  float* rs    = (float*)alloc((size_t)S_LEN*64*sizeof(float));
  float* w0s   = (float*)alloc((size_t)NFW*FD*FD*sizeof(float));
  float* w1s   = (float*)alloc((size_t)NFW*FD*FD*sizeof(float));
  float* w2s   = (float*)alloc((size_t)NFW*FD*FD*sizeof(float));
  bft*   w1tb  = (bft*)  alloc((size_t)NFW*FD*FD*sizeof(bft));
  bft*   w02b  = (bft*)  alloc((size_t)NFW*1024*FD*sizeof(bft));  // w0 rows 0-511, w2 rows 512-1023
  bft*   w1b   = (bft*)  alloc((size_t)NFW*FD*FD*sizeof(bft));
  bf16*  gb    = (bf16*) alloc((size_t)NFW*CHUNK_LEN*FD*sizeof(bf16));
  bf16*  hmb   = (bf16*) alloc((size_t)NFW*CHUNK_LEN*FD*sizeof(bf16));
  bf16*  qgb   = (bf16*) alloc((size_t)NFW*CHUNK_LEN*FD*sizeof(bf16));
  bf16*  qmb   = (bf16*) alloc((size_t)NFW*CHUNK_LEN*FD*sizeof(bf16));
  bf16*  hidb  = (bf16*) alloc((size_t)NFW*CHUNK_LEN*FD*sizeof(bf16));
  bf16*  ofc   = (bf16*) alloc((size_t)NFW*CHUNK_LEN*FD*sizeof(bf16));
  bft*   fkT   = (bft*)  alloc((size_t)NFW*FD*CHUNK_LEN*sizeof(bft));
  bft*   hidT  = (bft*)  alloc((size_t)NFW*FD*CHUNK_LEN*sizeof(bft));
  bft*   a2T   = (bft*)  alloc((size_t)NFW*FD*CHUNK_LEN*sizeof(bft));

  if ((size_t)(p - (char*)d_ws) > ws_size) return;

  // Fused-buffer views (gb..qmb contiguous):
  //   ghb = gb..hmb  : [z][ci][ g | hm ]  (16 MB)
  //   qgm = qgb..qmb : [z][ci][ qg | qm ] (16 MB)
  bft* ghb = (bft*)gb;
  bft* qgm = (bft*)qgb;
  // Liveness aliases:
  //   hidden_bf (33.55 MB) = gb..qmb  — dead before chunk loop.
  //   qkvw_bf   (25.17 MB) = fkT..hidT — dead before vt_k writes vT.
  //   vT        (33.55 MB) = fkT..a2T — dead before chunk loop's tr_k.
  //   opw_bf    ( 8.39 MB) = hidb     — converted after last e5.
  bft* hidden_bf = (bft*)gb;
  bft* qkvw_bf   = (bft*)fkT;
  bft* vT        = (bft*)fkT;
  bft* opw_bf    = (bft*)hidb;

  float* attn = out;   // attn lives in d_out until the final projection

  const long sW  = (long)FD*FD;
  const long sW2 = (long)1024*FD;
  const long sCh = (long)CHUNK_LEN*FD;
  const long sGH = (long)CHUNK_LEN*1024;
  const long sT  = (long)FD*CHUNK_LEN;

  hipMemcpyAsync(w0s, w0_in, (size_t)NFW*FD*FD*sizeof(float), hipMemcpyDeviceToDevice, stream);
  hipMemcpyAsync(w1s, w1_in, (size_t)NFW*FD*FD*sizeof(float), hipMemcpyDeviceToDevice, stream);
  hipMemcpyAsync(w2s, w2_in, (size_t)NFW*FD*FD*sizeof(float), hipMemcpyDeviceToDevice, stream);

  rope_k<<<S_LEN, 64, 0, stream>>>(rc, rs);
  lr_k<<<S_LEN, 256, 0, stream>>>(hidden, lr_w, lr_b, lrb);
  tcw1_k<<<NFW*FD*FD/256, 256, 0, stream>>>(w1_in, w1tb);
  cvt_k<<<(NFW*FD*FD)/2048, 256, 0, stream>>>(w1_in, w1b);
  for (int z = 0; z < NFW; ++z) {
    cvt_k<<<(FD*FD)/2048, 256, 0, stream>>>(w0_in + (size_t)z*sW, w02b + (size_t)z*sW2);
    cvt_k<<<(FD*FD)/2048, 256, 0, stream>>>(w2_in + (size_t)z*sW, w02b + (size_t)z*sW2 + (size_t)512*FD);
  }
  cvt_k<<<(S_LEN*HID)/2048, 256, 0, stream>>>(hidden, hidden_bf);
  cvt_k<<<(QKV3*HID)/2048, 256, 0, stream>>>(qkv_w, qkvw_bf);

  // qkv = hidden @ qkv_w^T -> bf16   (256^2 pipelined GEMM)
  mgemm8<0>(stream, hidden_bf, qkvw_bf, (void*)qkv, S_LEN, QKV3, HID, HID, HID, QKV3);

  e2a_k<<<S_LEN, 256, 0, stream>>>(qkv, q_norm_w, k_norm_w);
  vt_k<<<dim3(S_LEN/64, NH), 256, 0, stream>>>(qkv, vT);
  attn_k<<<NH*128, 256, 0, stream>>>(qkv, vT, rc, rs, attn);
  e2b_k<<<S_LEN, 256, 0, stream>>>(qkv, qk_scale, qk_off);

  const int  NEL = NFW*CHUNK_LEN*FD/256;
  const dim3 tg(FD/64, CHUNK_LEN/64, NFW);

  for(int c=0; c<NCHUNK; c++){
    const bft* fqc = (const bft*)qkv + (size_t)c*CHUNK_LEN*QKV3;
    const bft* fkc = fqc + HID;
    const bft* fvc = fqc + 2*HID;
    // fused forward: [g|hm] = fk @ [w0|w2]^T ; [qg|qm] = fq @ [w0|w2]^T
    mgemm<128,128,0>(stream, fkc, w02b, ghb, nullptr, nullptr,
        CHUNK_LEN, 1024, FD, QKV3, FD, 1024, NFW, FD, sW2, sGH, 0);
    mgemm<128,128,0>(stream, fqc, w02b, qgm, nullptr, nullptr,
        CHUNK_LEN, 1024, FD, QKV3, FD, 1024, NFW, FD, sW2, sGH, 0);
    e3f_k<<<NEL, 256, 0, stream>>>(ghb, qgm, (bft*)hidb);
    // ofc = opre @ w1^T   (opre = qgm col 0-511, lda=1024)
    mgemm<128,128,0>(stream, (const bft*)qgm, w1b, ofc, nullptr, nullptr,
        CHUNK_LEN, FD, FD, 1024, FD, FD, NFW, sGH, sW, sCh, 0);
    // dhid = fv @ w1  (-> qgm col 512-1023; qm is dead after e3f)
    mgemm<128,128,0>(stream, fvc, (const bft*)w1tb, qgm + 512, nullptr, nullptr,
        CHUNK_LEN, FD, FD, QKV3, FD, 1024, NFW, FD, sW, sGH, 0);
    e4f_k<<<NEL, 256, 0, stream>>>(ghb, qgm, qkv, lrb, c*CHUNK_LEN);
    tr_k<<<tg, 256, 0, stream>>>(fkc,              fkT,  QKV3, FD,  sT);
    tr_k<<<tg, 256, 0, stream>>>((const bft*)hidb, hidT, FD,   sCh, sT);
    // interleave transpose -> update (a2T reused as the scratch T buffer)
    tr_k<<<tg, 256, 0, stream>>>(ghb,       a2T, 1024, sGH, sT);   // a0^T
    mgemm<64,64,2>(stream, a2T, fkT,  w0s, w02b, nullptr,
        FD, FD, CHUNK_LEN, CHUNK_LEN, CHUNK_LEN, FD, NFW, sT, sT, sW, sW2);
    tr_k<<<tg, 256, 0, stream>>>(ghb + 512, a2T, 1024, sGH, sT);   // a2^T
    mgemm<64,64,2>(stream, a2T, fkT,  w2s, w02b + (size_t)512*FD, nullptr,
        FD, FD, CHUNK_LEN, CHUNK_LEN, CHUNK_LEN, FD, NFW, sT, sT, sW, sW2);
    tr_k<<<tg, 256, 0, stream>>>(qgm + 512, a2T, 1024, sGH, sT);   // a1^T
    mgemm<64,64,2>(stream, a2T, hidT, w1s, w1b, w1tb,
        FD, FD, CHUNK_LEN, CHUNK_LEN, CHUNK_LEN, FD, NFW, sT, sT, sW, sW);
    e5_k<<<CHUNK_LEN, 256, 0, stream>>>(attn, ofc, ttt_nw, qkv, c*CHUNK_LEN);
  }

  // bf16 copy of o_proj (hidb/ofc are dead now), then final projection
  cvt_k<<<(HID*HID)/2048, 256, 0, stream>>>(o_proj, opw_bf);
  mgemm8<1>(stream, (const bft*)qkv, opw_bf, out, S_LEN, HID, HID, QKV3, HID, HID);
}

// Round 8
// 1428.351 us; speedup vs baseline: 1.2550x; 1.0496x over previous
//
#include <hip/hip_runtime.h>
#include <hip/hip_bf16.h>

typedef __hip_bfloat16 bf16;
typedef __bf16 bft;
typedef bft bf16x8 __attribute__((ext_vector_type(8)));
typedef bft bf16x4 __attribute__((ext_vector_type(4)));
typedef float f32x4 __attribute__((ext_vector_type(4)));

#define S_LEN 8192
#define HID   2048
#define QKV3  6144
#define NH    16
#define HD    128
#define NFW   4
#define FD    512
#define CHUNK_LEN 2048
#define NCHUNK 4
#define BASE_LR_INV (-6.9072552f)   // log(expm1(0.001))
#define QKP 136                     // attn Q/K LDS stride (128 + 8)
#define VSP 72                      // attn V^T LDS stride (64 + 8)
#define PSP 76                      // attn P LDS stride (64 + 12)

__device__ __forceinline__ float bf2f(bf16 x){ return __bfloat162float(x); }
__device__ __forceinline__ bf16  f2bf(float x){ return __float2bfloat16(x); }
__device__ __forceinline__ float sigm(float x){ return 1.f/(1.f+__expf(-x)); }
__device__ __forceinline__ float siluf(float x){ return x/(1.f+__expf(-x)); }
__device__ __forceinline__ float wave_sum(float v){
  #pragma unroll
  for(int off=32; off; off>>=1) v += __shfl_xor(v, off, 64);
  return v;
}

template<int N>
__device__ __forceinline__ void waitcnt_vm(){
  static_assert(N==0||N==2||N==4||N==8, "unsupported vmcnt");
  if constexpr (N==0)      asm volatile("s_waitcnt vmcnt(0)" ::: "memory");
  else if constexpr (N==2) asm volatile("s_waitcnt vmcnt(2)" ::: "memory");
  else if constexpr (N==4) asm volatile("s_waitcnt vmcnt(4)" ::: "memory");
  else                     asm volatile("s_waitcnt vmcnt(8)" ::: "memory");
}

// Raw barrier, NO sched_barrier pinning (m141; also A/B round6-vs-7: a
// single fence before the MFMA cluster cost 6% -- compiler interleave wins).
__device__ __forceinline__ void bar(){
  __builtin_amdgcn_s_barrier();
  asm volatile("" ::: "memory");
}

// ---------------------------------------------------------------------------
// GEMM LDS tile staging (bf16 only), swizzled layout.
// Tile: ROWS x 32 bf16, unpadded [row][32]; physical col-slot c (8 elems)
// holds logical col-group g = c ^ ((row>>1)&3).
// global_load_lds 16B/lane; LDS dest = wave-uniform base + lane*16.
// ---------------------------------------------------------------------------
template<int ROWS>
__device__ __forceinline__ void stage(const bft* __restrict__ src, long ld,
                                      bft* dst, int tid)
{
  const int lane = tid & 63, wv = tid >> 6;
  #pragma unroll
  for (int i = 0; i < ROWS/64; ++i) {
    const int r0 = wv*16 + i*64;               // wave-uniform
    const int row = r0 + (lane >> 2);
    const int g = (lane & 3) ^ ((row >> 1) & 3);
    const bft* gp = src + (size_t)row*ld + g*8;
    bft* lp = dst + (size_t)r0*32;
    __builtin_amdgcn_global_load_lds(
        (const __attribute__((address_space(1))) void*)gp,
        (__attribute__((address_space(3))) void*)lp, 16, 0, 0);
  }
}

// ---------------------------------------------------------------------------
// MFMA NT GEMM: C[M,N] (+)= A[M,K] * B[N,K]^T, fp32 accumulate, 256 threads.
// 4-slot circular LDS pipeline (BK=32), counted vmcnt (never drained to 0
// in steady state), m201-style phase skeleton (keeps VGPR ~100 so 512-block
// chunk grids stay 2-blocks/CU co-resident).
// Race-freedom: slot written at iter s is (s+2)&3; concurrent readers touch
// s&3 (distinct mod 4); reads of the overwritten buffer finished >=1 barrier
// earlier. vmcnt ladder leaves slot s+2's LPT loads in flight.
// EPI: 0 = store bf16, 1 = store fp32, 2 = fp32 C += acc, bf16 direct shadow
// Cd (z-stride sCd, row stride ldc), optional transposed shadow Ct.
// ---------------------------------------------------------------------------
template<int BM,int BN,int EPI>
__global__ __launch_bounds__(256) void mgemm_k(
    const bft* __restrict__ A, const bft* __restrict__ B, void* __restrict__ Cv,
    bft* __restrict__ Cd, bft* __restrict__ Ct, int K,
    long lda, long ldb, long ldc, long sA, long sB, long sC, long sCd)
{
  constexpr int AM = BM/32, AN = BN/32;
  constexpr int LPT = BM/64 + BN/64;           // global_load_lds per wave/slot
  constexpr int NPH = (AM >= 4) ? 2 : 1;       // compute phases per slot
  constexpr int MH  = AM / NPH;                // mi rows per phase
  __shared__ __align__(16) bft As[4][BM*32];
  __shared__ __align__(16) bft Bs[4][BN*32];
  const int tid = threadIdx.x;
  const int z = blockIdx.z;
  A += (size_t)z * sA;
  B += (size_t)z * sB;
  const size_t m0 = (size_t)blockIdx.y * BM, n0 = (size_t)blockIdx.x * BN;
  const int wv = tid >> 6, lane = tid & 63;
  const int wm = (wv & 1) * (BM/2), wn = (wv >> 1) * (BN/2);
  const int fr = lane & 15;
  const int fsw = ((lane >> 4) ^ ((fr >> 1) & 3)) * 8;   // swizzled frag col

  f32x4 acc[AM][AN];
  #pragma unroll
  for (int i=0;i<AM;i++)
    #pragma unroll
    for (int j=0;j<AN;j++) acc[i][j] = (f32x4){0.f,0.f,0.f,0.f};

  const bft* Ab = A + m0*lda;
  const bft* Bb = B + n0*ldb;
  const int NS = K >> 5;

  stage<BM>(Ab,      lda, As[0], tid);
  stage<BN>(Bb,      ldb, Bs[0], tid);
  stage<BM>(Ab + 32, lda, As[1], tid);
  stage<BN>(Bb + 32, ldb, Bs[1], tid);
  waitcnt_vm<LPT>();
  bar();

  for (int s = 0; s < NS; ++s) {
    const bft* Ap = As[s & 3];
    const bft* Bp = Bs[s & 3];
    const int kt = (s + 2) * 32;
    const bool st = (s + 2 < NS);

    bf16x8 bvv[AN], afv[MH];
    // ---- phase A: all B-frags + first mi half; stage next A-tile ----
    #pragma unroll
    for (int ni=0; ni<AN; ni++)
      bvv[ni] = *(const bf16x8*)(Bp + (size_t)(wn + ni*16 + fr)*32 + fsw);
    #pragma unroll
    for (int i=0; i<MH; i++)
      afv[i] = *(const bf16x8*)(Ap + (size_t)(wm + i*16 + fr)*32 + fsw);
    if (st) stage<BM>(Ab + kt, lda, As[(s+2)&3], tid);
    if constexpr (NPH == 1) {
      if (st) { stage<BN>(Bb + kt, ldb, Bs[(s+2)&3], tid); waitcnt_vm<LPT>(); }
      else waitcnt_vm<0>();
    }
    bar();
    __builtin_amdgcn_s_setprio(1);
    #pragma unroll
    for (int i=0; i<MH; i++)
      #pragma unroll
      for (int ni=0; ni<AN; ni++)
        acc[i][ni] = __builtin_amdgcn_mfma_f32_16x16x32_bf16(afv[i], bvv[ni], acc[i][ni], 0, 0, 0);
    __builtin_amdgcn_s_setprio(0);

    if constexpr (NPH == 2) {
      bar();
      // ---- phase B: second mi half; stage next B-tile; vm ladder ----
      #pragma unroll
      for (int i=0; i<MH; i++)
        afv[i] = *(const bf16x8*)(Ap + (size_t)(wm + (MH+i)*16 + fr)*32 + fsw);
      if (st) { stage<BN>(Bb + kt, ldb, Bs[(s+2)&3], tid); waitcnt_vm<LPT>(); }
      else waitcnt_vm<0>();
      bar();
      __builtin_amdgcn_s_setprio(1);
      #pragma unroll
      for (int i=0; i<MH; i++)
        #pragma unroll
        for (int ni=0; ni<AN; ni++)
          acc[MH+i][ni] = __builtin_amdgcn_mfma_f32_16x16x32_bf16(afv[i], bvv[ni], acc[MH+i][ni], 0, 0, 0);
      __builtin_amdgcn_s_setprio(0);
      bar();
    }
  }

  const int er = (lane >> 4) * 4;   // C/D: row=(lane>>4)*4+reg, col=lane&15
  const int ec = lane & 15;
  #pragma unroll
  for (int mi=0; mi<AM; mi++){
    #pragma unroll
    for (int ni=0; ni<AN; ni++){
      #pragma unroll
      for (int r=0; r<4; r++){
        size_t row = m0 + wm + mi*16 + er + r;
        size_t col = n0 + wn + ni*16 + ec;
        size_t idx = (size_t)z*sC + row*ldc + col;
        float v = acc[mi][ni][r];
        if constexpr (EPI == 0){
          ((bft*)Cv)[idx] = (bft)v;
        } else if constexpr (EPI == 1){
          ((float*)Cv)[idx] = v;
        } else {
          float nv = ((float*)Cv)[idx] + v;
          ((float*)Cv)[idx] = nv;
          Cd[(size_t)z*sCd + row*ldc + col] = (bft)nv;
          if (Ct) Ct[(size_t)z*FD*FD + col*FD + row] = (bft)nv;
        }
      }
    }
  }
}

template<int BM,int BN,int EPI>
static inline void mgemm(hipStream_t st, const bft* A, const bft* B, void* C,
    bft* Cd, bft* Ct, int M, int N, int K, long lda, long ldb, long ldc,
    int batch, long sA, long sB, long sC, long sCd)
{
  dim3 g(N/BN, M/BM, batch);
  mgemm_k<BM,BN,EPI><<<g, 256, 0, st>>>(A, B, C, Cd, Ct, K, lda, ldb, ldc, sA, sB, sC, sCd);
}

// ---------------------------------------------------------------------------
// 256x256 MFMA NT GEMM, 4-slot ring, 512 threads = 8 waves (2Mx4N),
// per-wave 128x64 output, cross-slot register double-buffer (round-6 form:
// no scheduling fence; compiler interleaves next-slot reads with MFMAs).
// Race proof: 1 barrier/slot; stage at iter s targets buffer (s+2)&3 whose
// last reads drained >=1 barrier earlier; vmcnt(4)+barrier guarantee slot
// s+1 landed before its reads. LDS = 128 KiB. XCD-aware bijective swizzle.
// ---------------------------------------------------------------------------
__device__ __forceinline__ void stage8(const bft* __restrict__ src, long ld,
                                       bft* dst, int tid)
{
  const int lane = tid & 63, wv = tid >> 6;      // 8 waves
  #pragma unroll
  for (int i = 0; i < 2; ++i) {
    const int r0 = wv*16 + i*128;                // wave-uniform
    const int row = r0 + (lane >> 2);
    const int g = (lane & 3) ^ ((row >> 1) & 3);
    const bft* gp = src + (size_t)row*ld + g*8;
    bft* lp = dst + (size_t)r0*32;
    __builtin_amdgcn_global_load_lds(
        (const __attribute__((address_space(1))) void*)gp,
        (__attribute__((address_space(3))) void*)lp, 16, 0, 0);
  }
}

template<int EPI>
__global__ __launch_bounds__(512, 2) void mgemm8_k(
    const bft* __restrict__ A, const bft* __restrict__ B, void* __restrict__ Cv,
    int K, long lda, long ldb, long ldc)
{
  __shared__ __align__(16) bft As[4][256*32];
  __shared__ __align__(16) bft Bs[4][256*32];
  const int tid = threadIdx.x;

  const int gx = (int)gridDim.x;
  const int nwg = (int)(gridDim.x * gridDim.y);
  int lin = (int)(blockIdx.y * gridDim.x + blockIdx.x);
  if ((nwg & 7) == 0) lin = (lin & 7) * (nwg >> 3) + (lin >> 3);
  const size_t m0 = (size_t)(lin / gx) * 256;
  const size_t n0 = (size_t)(lin % gx) * 256;

  const int wv = tid >> 6, lane = tid & 63;
  const int wm = (wv & 1) * 128, wn = (wv >> 1) * 64;
  const int fr = lane & 15;
  const int fsw = ((lane >> 4) ^ ((fr >> 1) & 3)) * 8;

  f32x4 acc[8][4];
  #pragma unroll
  for (int i=0;i<8;i++)
    #pragma unroll
    for (int j=0;j<4;j++) acc[i][j] = (f32x4){0.f,0.f,0.f,0.f};

  const bft* Ab = A + m0*lda;
  const bft* Bb = B + n0*ldb;
  const int NS = K >> 5;

  stage8(Ab,      lda, As[0], tid);
  stage8(Bb,      ldb, Bs[0], tid);
  stage8(Ab + 32, lda, As[1], tid);
  stage8(Bb + 32, ldb, Bs[1], tid);
  waitcnt_vm<4>();
  bar();

  bf16x8 aP[8], bP[4], aQ[8], bQ[4];
  #pragma unroll
  for (int mi=0; mi<8; mi++)
    aP[mi] = *(const bf16x8*)(As[0] + (size_t)(wm + mi*16 + fr)*32 + fsw);
  #pragma unroll
  for (int ni=0; ni<4; ni++)
    bP[ni] = *(const bf16x8*)(Bs[0] + (size_t)(wn + ni*16 + fr)*32 + fsw);

  auto body = [&](bf16x8 (&ac)[8], bf16x8 (&bc)[4],
                  bf16x8 (&an)[8], bf16x8 (&bn)[4], int s){
    const int kt = (s + 2) * 32;
    const bool st2 = (s + 2 < NS);
    const bool rd  = (s + 1 < NS);
    if (st2) {
      stage8(Ab + kt, lda, As[(s+2)&3], tid);
      stage8(Bb + kt, ldb, Bs[(s+2)&3], tid);
    }
    if (rd) {
      if (st2) waitcnt_vm<4>(); else waitcnt_vm<0>();
      bar();
      const bft* An = As[(s+1)&3];
      const bft* Bn = Bs[(s+1)&3];
      #pragma unroll
      for (int mi=0; mi<8; mi++)
        an[mi] = *(const bf16x8*)(An + (size_t)(wm + mi*16 + fr)*32 + fsw);
      #pragma unroll
      for (int ni=0; ni<4; ni++)
        bn[ni] = *(const bf16x8*)(Bn + (size_t)(wn + ni*16 + fr)*32 + fsw);
    }
    __builtin_amdgcn_s_setprio(1);
    #pragma unroll
    for (int mi=0; mi<8; mi++)
      #pragma unroll
      for (int ni=0; ni<4; ni++)
        acc[mi][ni] = __builtin_amdgcn_mfma_f32_16x16x32_bf16(ac[mi], bc[ni], acc[mi][ni], 0, 0, 0);
    __builtin_amdgcn_s_setprio(0);
  };

  for (int s = 0; s < NS; s += 2) {
    body(aP, bP, aQ, bQ, s);
    body(aQ, bQ, aP, bP, s + 1);
  }

  const int er = (lane >> 4) * 4;
  const int ec = lane & 15;
  #pragma unroll
  for (int mi=0; mi<8; mi++){
    #pragma unroll
    for (int ni=0; ni<4; ni++){
      #pragma unroll
      for (int r=0; r<4; r++){
        size_t row = m0 + wm + mi*16 + er + r;
        size_t col = n0 + wn + ni*16 + ec;
        size_t idx = row*ldc + col;
        float v = acc[mi][ni][r];
        if constexpr (EPI == 0) ((bft*)Cv)[idx] = (bft)v;
        else                    ((float*)Cv)[idx] = v;
      }
    }
  }
}

template<int EPI>
static inline void mgemm8(hipStream_t st, const bft* A, const bft* B, void* C,
                          int M, int N, int K, long lda, long ldb, long ldc)
{
  dim3 g(N/256, M/256, 1);
  mgemm8_k<EPI><<<g, 512, 0, st>>>(A, B, C, K, lda, ldb, ldc);
}

// ---------------------------------------------------------------------------
// fp32 -> bf16 bulk convert (8 elems/thread); n must divide 2048.
// ---------------------------------------------------------------------------
__global__ __launch_bounds__(256) void cvt_k(const float* __restrict__ s,
    bft* __restrict__ d)
{
  size_t i = ((size_t)blockIdx.x*256 + threadIdx.x) * 8;
  const float4 v0 = *(const float4*)(s + i);
  const float4 v1 = *(const float4*)(s + i + 4);
  bf16x8 b;
  b[0]=(bft)v0.x; b[1]=(bft)v0.y; b[2]=(bft)v0.z; b[3]=(bft)v0.w;
  b[4]=(bft)v1.x; b[5]=(bft)v1.y; b[6]=(bft)v1.z; b[7]=(bft)v1.w;
  *(bf16x8*)(d + i) = b;
}

// ---------------------------------------------------------------------------
// Batched bf16 transpose: out[z][c][r] = in[z][r][c]; arbitrary ldin/sIn.
// ---------------------------------------------------------------------------
__global__ __launch_bounds__(256) void tr_k(const bft* __restrict__ in,
    bft* __restrict__ out, long ldin, long sIn, long sOut)
{
  __shared__ __align__(16) bft t[64][72];
  const int c0 = blockIdx.x*64, r0 = blockIdx.y*64;
  in  += (size_t)blockIdx.z * sIn;
  out += (size_t)blockIdx.z * sOut;
  const int tid = threadIdx.x;
  #pragma unroll
  for (int i=0;i<2;i++){
    int e = tid + i*256;
    int r = e >> 3, c8 = (e & 7) * 8;
    *(bf16x8*)&t[r][c8] = *(const bf16x8*)(in + (size_t)(r0+r)*ldin + c0 + c8);
  }
  __syncthreads();
  #pragma unroll
  for (int i=0;i<2;i++){
    int e = tid + i*256;
    int c = e >> 3, r8 = (e & 7) * 8;
    bf16x8 v;
    #pragma unroll
    for (int j=0;j<8;j++) v[j] = t[r8+j][c];
    *(bf16x8*)(out + (size_t)(c0+c)*CHUNK_LEN + r0 + r8) = v;
  }
}

// initial w1^T bf16 shadow: w1tb[z][h][o] = (bf16)w1[z][o][h]
__global__ __launch_bounds__(256) void tcw1_k(const float* __restrict__ w1,
    bft* __restrict__ w1tb)
{
  size_t idx = (size_t)blockIdx.x*256 + threadIdx.x;
  int z = (int)(idx >> 18);
  int h = (int)((idx >> 9) & 511);
  int o = (int)(idx & 511);
  w1tb[idx] = (bft)w1[(size_t)z*FD*FD + (size_t)o*FD + h];
}

// ---------------------------------------------------------------------------
// v^T for attention PV: vT[h][d][s] = v[s][h*128+d] (raw v region of qkv).
// ---------------------------------------------------------------------------
__global__ __launch_bounds__(256) void vt_k(const bf16* __restrict__ qkv,
    bft* __restrict__ vT)
{
  __shared__ __align__(16) bft t[64*QKP];   // [s][d]
  const int s0 = blockIdx.x * 64;
  const int h  = blockIdx.y;
  const int tid = threadIdx.x;
  #pragma unroll
  for (int i=0;i<4;i++){
    int e = tid + i*256;
    int rr = e >> 4, doff = (e & 15) * 8;
    *(bf16x8*)(t + rr*QKP + doff) =
        *(const bf16x8*)((const bft*)qkv + (size_t)(s0+rr)*QKV3 + 2*HID + h*HD + doff);
  }
  __syncthreads();
  #pragma unroll
  for (int it=0; it<4; it++){
    int d = (tid >> 3) + it*32;
    int so8 = (tid & 7) * 8;
    bf16x8 v;
    #pragma unroll
    for (int j=0;j<8;j++) v[j] = t[(so8+j)*QKP + d];
    *(bf16x8*)(vT + ((size_t)(h*HD + d))*S_LEN + s0 + so8) = v;
  }
}

// ---------------------------------------------------------------------------
// RoPE cos/sin tables
// ---------------------------------------------------------------------------
__global__ void rope_k(float* __restrict__ rc, float* __restrict__ rs){
  int pos = blockIdx.x, d = threadIdx.x;
  float inv = 1.f / powf(500000.0f, (float)d * (1.0f/64.0f));
  float ang = (float)pos * inv;
  rc[pos*64+d] = cosf(ang);
  rs[pos*64+d] = sinf(ang);
}

// ---------------------------------------------------------------------------
// per-token learning rates
// ---------------------------------------------------------------------------
__global__ __launch_bounds__(256) void lr_k(const float* __restrict__ hidden,
    const float* __restrict__ lr_w, const float* __restrict__ lr_b,
    float* __restrict__ lro)
{
  __shared__ float hrow[HID];
  __shared__ float red[4][12];
  int s = blockIdx.x, tid = threadIdx.x;
  for(int i=0;i<HID/256;i++) hrow[tid+256*i] = hidden[(size_t)s*HID + tid + 256*i];
  __syncthreads();
  float part[12];
  #pragma unroll
  for(int o=0;o<12;o++) part[o]=0.f;
  for(int i=0;i<HID/256;i++){
    int j = tid + 256*i;
    float h = hrow[j];
    #pragma unroll
    for(int o=0;o<12;o++) part[o] += h * lr_w[o*HID + j];
  }
  int lane = tid & 63, w = tid >> 6;
  #pragma unroll
  for(int o=0;o<12;o++){
    float v = wave_sum(part[o]);
    if(lane==0) red[w][o] = v;
  }
  __syncthreads();
  if(tid < 12){
    float v = red[0][tid]+red[1][tid]+red[2][tid]+red[3][tid] + lr_b[tid] + BASE_LR_INV;
    float sp = (v > 20.f) ? v : log1pf(expf(v));
    lro[s*12 + tid] = sp;
  }
}

// ---------------------------------------------------------------------------
// E2a: per-token rmsnorm(q), rmsnorm(k), in place in qkv (bf16).
// ---------------------------------------------------------------------------
__global__ __launch_bounds__(256) void e2a_k(
    bf16* __restrict__ qkv,
    const float* __restrict__ qnw, const float* __restrict__ knw)
{
  __shared__ float red[8];
  int s = blockIdx.x, tid = threadIdx.x;
  int lane = tid & 63, w = tid >> 6;
  float qv[8], kv[8];
  float sq = 0.f, sk = 0.f;
  size_t base = (size_t)s*QKV3;
  #pragma unroll
  for(int i=0;i<8;i++){
    int j = tid*8 + i;
    qv[i] = bf2f(qkv[base + j]);
    kv[i] = bf2f(qkv[base + HID + j]);
    sq += qv[i]*qv[i]; sk += kv[i]*kv[i];
  }
  sq = wave_sum(sq); sk = wave_sum(sk);
  if(lane==0){ red[w] = sq; red[4+w] = sk; }
  __syncthreads();
  float rq = rsqrtf((red[0]+red[1]+red[2]+red[3])*(1.f/HID) + 1e-6f);
  float rk = rsqrtf((red[4]+red[5]+red[6]+red[7])*(1.f/HID) + 1e-6f);
  #pragma unroll
  for(int i=0;i<8;i++){
    int j = tid*8 + i;
    qkv[base + j]       = f2bf(qv[i]*rq*qnw[j]);
    qkv[base + HID + j] = f2bf(kv[i]*rk*knw[j]);
  }
}

// ---------------------------------------------------------------------------
// E2b (after attention): overwrite q/k/v regions with fq/fk/fv.
// ---------------------------------------------------------------------------
__global__ __launch_bounds__(256) void e2b_k(
    bf16* __restrict__ qkv,
    const float* __restrict__ qks, const float* __restrict__ qko)
{
  int s = blockIdx.x, tid = threadIdx.x;
  size_t base = (size_t)s*QKV3;
  float a[8], b[8], vv[8];
  float ga = 0.f, gb2 = 0.f;
  #pragma unroll
  for(int i=0;i<8;i++){
    int j = tid*8 + i;
    float qn = bf2f(qkv[base + j]);
    float kn = bf2f(qkv[base + HID + j]);
    float v  = bf2f(qkv[base + 2*HID + j]);
    a[i] = siluf(qn*qks[2*j]   + qko[2*j]);
    b[i] = siluf(kn*qks[2*j+1] + qko[2*j+1]);
    vv[i] = siluf(v);
    ga += a[i]*a[i]; gb2 += b[i]*b[i];
  }
  ga = wave_sum(ga); gb2 = wave_sum(gb2);
  float iq = 1.f / fmaxf(sqrtf(ga), 1e-12f);
  float ik = 1.f / fmaxf(sqrtf(gb2), 1e-12f);
  #pragma unroll
  for(int i=0;i<8;i++){
    int j = tid*8 + i;
    qkv[base + j]         = f2bf(a[i]*iq);
    qkv[base + HID + j]   = f2bf(b[i]*ik);
    qkv[base + 2*HID + j] = f2bf(vv[i]);
  }
}

// ---------------------------------------------------------------------------
// MFMA sliding-window attention (window 256 incl self).
// ---------------------------------------------------------------------------
__global__ __launch_bounds__(256) void attn_k(
    const bf16* __restrict__ qkv, const bft* __restrict__ vT,
    const float* __restrict__ rc, const float* __restrict__ rs,
    float* __restrict__ attn)
{
  __shared__ __align__(16) bft Qs[64*QKP];
  __shared__ __align__(16) bft Ks[64*QKP];
  __shared__ __align__(16) bft Vs[128*VSP];
  __shared__ __align__(16) bft Ps[64*PSP];
  const int head = blockIdx.x >> 7;
  const int Q0 = (blockIdx.x & 127) * 64;
  const int tid = threadIdx.x;
  const int hb = head * HD;
  const int lane = tid & 63;
  const int wm = (tid >> 6) * 16;
  const int fr = lane & 15, fko = (lane >> 4) * 8;
  const int rbase = (lane >> 4) * 4;

  #pragma unroll
  for(int i=0;i<16;i++){
    int e = tid + i*256;
    int rr = e >> 6, d = e & 63;
    int qpos = Q0 + rr;
    size_t b = (size_t)qpos*QKV3 + hb;
    float x1 = bf2f(qkv[b + d]);
    float x2 = bf2f(qkv[b + d + 64]);
    float c = rc[qpos*64 + d], sn = rs[qpos*64 + d];
    Qs[rr*QKP + d]      = (bft)(x1*c - x2*sn);
    Qs[rr*QKP + d + 64] = (bft)(x2*c + x1*sn);
  }
  __syncthreads();
  bf16x8 qf[4];
  #pragma unroll
  for (int kk=0;kk<4;kk++)
    qf[kk] = *(const bf16x8*)(Qs + (wm+fr)*QKP + kk*32 + fko);

  f32x4 Ot[8];
  #pragma unroll
  for (int i=0;i<8;i++) Ot[i] = (f32x4){0.f,0.f,0.f,0.f};
  float m4[4], l4[4];
  #pragma unroll
  for (int r=0;r<4;r++){ m4[r] = -INFINITY; l4[r] = 0.f; }

  for (int kt=0; kt<5; kt++){
    const int kb = Q0 - 256 + kt*64;
    if (kb < 0) continue;
    __syncthreads();
    #pragma unroll
    for(int i=0;i<16;i++){
      int e = tid + i*256;
      int rr = e >> 6, d = e & 63;
      int kpos = kb + rr;
      size_t b = (size_t)kpos*QKV3 + HID + hb;
      float x1 = bf2f(qkv[b + d]);
      float x2 = bf2f(qkv[b + d + 64]);
      float c = rc[kpos*64 + d], sn = rs[kpos*64 + d];
      Ks[rr*QKP + d]      = (bft)(x1*c - x2*sn);
      Ks[rr*QKP + d + 64] = (bft)(x2*c + x1*sn);
    }
    {
      int d = tid >> 1, koff = (tid & 1) * 32;
      const bft* vrow = vT + ((size_t)(hb + d))*S_LEN + kb + koff;
      bft* lrow = Vs + d*VSP + koff;
      #pragma unroll
      for (int j8=0;j8<4;j8++)
        *(bf16x8*)(lrow + j8*8) = *(const bf16x8*)(vrow + j8*8);
    }
    __syncthreads();

    f32x4 st[4];
    #pragma unroll
    for (int nt=0;nt<4;nt++){
      f32x4 acc = (f32x4){0.f,0.f,0.f,0.f};
      #pragma unroll
      for (int kk=0;kk<4;kk++){
        bf16x8 kf = *(const bf16x8*)(Ks + (nt*16+fr)*QKP + kk*32 + fko);
        acc = __builtin_amdgcn_mfma_f32_16x16x32_bf16(qf[kk], kf, acc, 0, 0, 0);
      }
      st[nt] = acc;
    }

    float pv[4][4];
    #pragma unroll
    for (int r=0;r<4;r++){
      int qpos = Q0 + wm + rbase + r;
      float sm[4];
      float mx = -INFINITY;
      #pragma unroll
      for (int nt=0;nt<4;nt++){
        int kpos = kb + nt*16 + fr;
        bool valid = (kpos > qpos - 256) && (kpos <= qpos);
        float s = valid ? st[nt][r] * 0.088388347648318447f : -INFINITY;
        sm[nt] = s;
        mx = fmaxf(mx, s);
      }
      mx = fmaxf(mx, __shfl_xor(mx, 1, 64));
      mx = fmaxf(mx, __shfl_xor(mx, 2, 64));
      mx = fmaxf(mx, __shfl_xor(mx, 4, 64));
      mx = fmaxf(mx, __shfl_xor(mx, 8, 64));
      float mnew = fmaxf(m4[r], mx);
      float alpha = (mnew == -INFINITY) ? 1.f : __expf(m4[r] - mnew);
      float ps = 0.f;
      #pragma unroll
      for (int nt=0;nt<4;nt++){
        float p = (sm[nt] == -INFINITY) ? 0.f : __expf(sm[nt] - mnew);
        pv[nt][r] = p;
        ps += p;
      }
      ps += __shfl_xor(ps, 1, 64);
      ps += __shfl_xor(ps, 2, 64);
      ps += __shfl_xor(ps, 4, 64);
      ps += __shfl_xor(ps, 8, 64);
      l4[r] = l4[r]*alpha + ps;
      m4[r] = mnew;
      #pragma unroll
      for (int ct=0;ct<8;ct++) Ot[ct][r] *= alpha;
    }

    #pragma unroll
    for (int r=0;r<4;r++){
      int row = wm + rbase + r;
      #pragma unroll
      for (int nt=0;nt<4;nt++)
        Ps[row*PSP + nt*16 + fr] = (bft)pv[nt][r];
    }
    bf16x8 af[2];
    #pragma unroll
    for (int kk=0;kk<2;kk++){
      const bft* pp = Ps + (wm+fr)*PSP + kk*32 + fko;
      bf16x4 lo = *(const bf16x4*)pp;
      bf16x4 hi = *(const bf16x4*)(pp+4);
      bf16x8 a;
      #pragma unroll
      for (int j=0;j<4;j++){ a[j]=lo[j]; a[j+4]=hi[j]; }
      af[kk]=a;
    }
    #pragma unroll
    for (int ct=0;ct<8;ct++)
      #pragma unroll
      for (int kk=0;kk<2;kk++){
        bf16x8 bv = *(const bf16x8*)(Vs + (ct*16+fr)*VSP + kk*32 + fko);
        Ot[ct] = __builtin_amdgcn_mfma_f32_16x16x32_bf16(af[kk], bv, Ot[ct], 0, 0, 0);
      }
  }

  #pragma unroll
  for (int r=0;r<4;r++){
    float invl = 1.f / l4[r];
    int qpos = Q0 + wm + rbase + r;
    size_t ob = (size_t)qpos*HID + hb;
    #pragma unroll
    for (int ct=0;ct<8;ct++)
      attn[ob + ct*16 + fr] = Ot[ct][r] * invl;
  }
}

// ---------------------------------------------------------------------------
// TTT elementwise fwd on FUSED buffers:
// gh = [z][ci][ g(0:512) | hm(512:1024) ], qgm = [z][ci][ qg | qm ].
// hid = silu(g)*hm (separate [z][ci][512]); opre = silu(qg)*qm -> qgm col 0.
// ---------------------------------------------------------------------------
__global__ __launch_bounds__(256) void e3f_k(
    bft* __restrict__ gh, bft* __restrict__ qgm, bft* __restrict__ hid)
{
  size_t idx = (size_t)blockIdx.x*256 + threadIdx.x;   // over NFW*CHUNK*FD
  int z  = (int)(idx >> 20);
  int ci = (int)((idx >> 9) & 2047);
  int d  = (int)(idx & 511);
  size_t b = ((size_t)z*CHUNK_LEN + ci)*1024 + d;
  float opre = siluf((float)qgm[b]) * (float)qgm[b + 512];
  hid[idx] = (bft)(siluf((float)gh[b]) * (float)gh[b + 512]);
  qgm[b]   = (bft)opre;
}

// ---------------------------------------------------------------------------
// TTT backprop elementwise on fused buffers (in place):
// gh col0 -> dgp*l0 (a0), gh col512 -> dhm*l2 (a2), qgm col512 -> fv*l1 (a1).
// dhid was written into qgm col512 by the fv@w1tb GEMM.
// ---------------------------------------------------------------------------
__global__ __launch_bounds__(256) void e4f_k(
    bft* __restrict__ gh, bft* __restrict__ qgm,
    const bf16* __restrict__ qkv, const float* __restrict__ lrb, int cbase)
{
  size_t idx = (size_t)blockIdx.x*256 + threadIdx.x;
  int z  = (int)(idx >> 20);
  int ci = (int)((idx >> 9) & 2047);
  int d  = (int)(idx & 511);
  int s  = cbase + ci;
  float l0  = lrb[s*12 + z];
  float l1  = lrb[s*12 + 4 + z];
  float l2v = lrb[s*12 + 8 + z];
  size_t b = ((size_t)z*CHUNK_LEN + ci)*1024 + d;
  float gg = (float)gh[b], hv = (float)gh[b + 512], dh = (float)qgm[b + 512];
  float sg = sigm(gg);
  float silu_g = gg * sg;
  float dhm = dh * silu_g;
  float dg  = dh * hv;
  float dgp = dg * (sg * (1.f + gg * (1.f - sg)));
  float fvv = bf2f(qkv[(size_t)s*QKV3 + 2*HID + z*FD + d]);
  gh[b]        = (bft)(dgp * l0);
  gh[b + 512]  = (bft)(dhm * l2v);
  qgm[b + 512] = (bft)(fvv * l1);
}

// ---------------------------------------------------------------------------
// E5 (per chunk): X = attn + rmsnorm(ofc)*ttt_norm_w -> q region of qkv
// ---------------------------------------------------------------------------
__global__ __launch_bounds__(256) void e5_k(const float* __restrict__ attn,
    const bf16* __restrict__ ofc, const float* __restrict__ tnw,
    bf16* __restrict__ qkv, int cbase)
{
  int ci = blockIdx.x, tid = threadIdx.x;
  int s = cbase + ci;
  int lane = tid & 63, w = tid >> 6;
  float o[8]; float ss = 0.f;
  size_t ob = ((size_t)w*CHUNK_LEN + ci)*FD + (size_t)lane*8;
  #pragma unroll
  for(int i=0;i<8;i++){ o[i] = bf2f(ofc[ob+i]); ss += o[i]*o[i]; }
  ss = wave_sum(ss);
  float inv = rsqrtf(ss*(1.f/FD) + 1e-6f);
  size_t xb = (size_t)s*QKV3 + w*FD + (size_t)lane*8;
  size_t ab = (size_t)s*HID  + w*FD + (size_t)lane*8;
  #pragma unroll
  for(int i=0;i<8;i++){
    int d = lane*8 + i;
    qkv[xb+i] = f2bf(attn[ab+i] + o[i]*inv*tnw[d]);
  }
}

// ---------------------------------------------------------------------------
extern "C" void kernel_launch(void* const* d_in, const int* in_sizes, int n_in,
                              void* d_out, int out_size, void* d_ws, size_t ws_size,
                              hipStream_t stream)
{
  (void)in_sizes; (void)n_in; (void)out_size;
  const float* hidden   = (const float*)d_in[0];
  const float* qkv_w    = (const float*)d_in[1];
  const float* q_norm_w = (const float*)d_in[2];
  const float* k_norm_w = (const float*)d_in[3];
  const float* qk_scale = (const float*)d_in[4];
  const float* qk_off   = (const float*)d_in[5];
  const float* lr_w     = (const float*)d_in[6];
  const float* lr_b     = (const float*)d_in[7];
  const float* w0_in    = (const float*)d_in[8];
  const float* w1_in    = (const float*)d_in[9];
  const float* w2_in    = (const float*)d_in[10];
  const float* ttt_nw   = (const float*)d_in[11];
  const float* o_proj   = (const float*)d_in[12];
  float* out = (float*)d_out;

  char* p = (char*)d_ws;
  auto alloc = [&](size_t n){ char* r = p; p += (n + 255) & ~(size_t)255; return (void*)r; };

  bf16*  qkv   = (bf16*) alloc((size_t)S_LEN*QKV3*sizeof(bf16));
  float* lrb   = (float*)alloc((size_t)S_LEN*12*sizeof(float));
  float* rc    = (float*)alloc((size_t)S_LEN*64*sizeof(float));
  float* rs    = (float*)alloc((size_t)S_LEN*64*sizeof(float));
  float* w02s  = (float*)alloc((size_t)NFW*1024*FD*sizeof(float)); // fp32 master [w0; w2]
  float* w1s   = (float*)alloc((size_t)NFW*FD*FD*sizeof(float));
  bft*   w1tb  = (bft*)  alloc((size_t)NFW*FD*FD*sizeof(bft));
  bft*   w02b  = (bft*)  alloc((size_t)NFW*1024*FD*sizeof(bft));   // bf16 shadow [w0; w2]
  bft*   w1b   = (bft*)  alloc((size_t)NFW*FD*FD*sizeof(bft));
  bf16*  gb    = (bf16*) alloc((size_t)NFW*CHUNK_LEN*FD*sizeof(bf16));
  bf16*  hmb   = (bf16*) alloc((size_t)NFW*CHUNK_LEN*FD*sizeof(bf16));
  bf16*  qgb   = (bf16*) alloc((size_t)NFW*CHUNK_LEN*FD*sizeof(bf16));
  bf16*  qmb   = (bf16*) alloc((size_t)NFW*CHUNK_LEN*FD*sizeof(bf16));
  bf16*  hidb  = (bf16*) alloc((size_t)NFW*CHUNK_LEN*FD*sizeof(bf16));
  bf16*  ofc   = (bf16*) alloc((size_t)NFW*CHUNK_LEN*FD*sizeof(bf16));
  bft*   fkT   = (bft*)  alloc((size_t)NFW*FD*CHUNK_LEN*sizeof(bft));
  bft*   hidT  = (bft*)  alloc((size_t)NFW*FD*CHUNK_LEN*sizeof(bft));
  bft*   aT    = (bft*)  alloc((size_t)NFW*1024*CHUNK_LEN*sizeof(bft)); // [a0T;a2T] scratch
  (void)alloc((size_t)4 << 20);   // tail pad: vT alias extends past aT

  if ((size_t)(p - (char*)d_ws) > ws_size) return;

  // Fused-buffer views (gb..qmb contiguous):
  //   ghb = gb..hmb  : [z][ci][ g | hm ]  (16 MB)
  //   qgm = qgb..qmb : [z][ci][ qg | qm ] (16 MB)
  bft* ghb = (bft*)gb;
  bft* qgm = (bft*)qgb;
  // Liveness aliases:
  //   hidden_bf (33.55 MB) = gb..hidb — dead before chunk loop.
  //   qkvw_bf   (25.17 MB) = fkT..aT  — dead before vt_k writes vT.
  //   vT        (33.55 MB) = fkT..aT+pad — dead before chunk loop's tr_k.
  //   opw_bf    ( 8.39 MB) = hidb     — converted after last e5.
  bft* hidden_bf = (bft*)gb;
  bft* qkvw_bf   = (bft*)fkT;
  bft* vT        = (bft*)fkT;
  bft* opw_bf    = (bft*)hidb;

  float* attn = out;   // attn lives in d_out until the final projection

  const long sW  = (long)FD*FD;
  const long sW2 = (long)1024*FD;
  const long sCh = (long)CHUNK_LEN*FD;
  const long sGH = (long)CHUNK_LEN*1024;
  const long sT  = (long)FD*CHUNK_LEN;
  const long sT2 = (long)1024*CHUNK_LEN;

  // fp32 masters: w02s = [w0; w2] per z, w1s = w1.
  for (int z = 0; z < NFW; ++z) {
    hipMemcpyAsync(w02s + (size_t)z*sW2,            w0_in + (size_t)z*sW,
                   (size_t)FD*FD*sizeof(float), hipMemcpyDeviceToDevice, stream);
    hipMemcpyAsync(w02s + (size_t)z*sW2 + (size_t)512*FD, w2_in + (size_t)z*sW,
                   (size_t)FD*FD*sizeof(float), hipMemcpyDeviceToDevice, stream);
  }
  hipMemcpyAsync(w1s, w1_in, (size_t)NFW*FD*FD*sizeof(float), hipMemcpyDeviceToDevice, stream);

  rope_k<<<S_LEN, 64, 0, stream>>>(rc, rs);
  lr_k<<<S_LEN, 256, 0, stream>>>(hidden, lr_w, lr_b, lrb);
  tcw1_k<<<NFW*FD*FD/256, 256, 0, stream>>>(w1_in, w1tb);
  cvt_k<<<(NFW*FD*FD)/2048, 256, 0, stream>>>(w1_in, w1b);
  for (int z = 0; z < NFW; ++z) {
    cvt_k<<<(FD*FD)/2048, 256, 0, stream>>>(w0_in + (size_t)z*sW, w02b + (size_t)z*sW2);
    cvt_k<<<(FD*FD)/2048, 256, 0, stream>>>(w2_in + (size_t)z*sW, w02b + (size_t)z*sW2 + (size_t)512*FD);
  }
  cvt_k<<<(S_LEN*HID)/2048, 256, 0, stream>>>(hidden, hidden_bf);
  cvt_k<<<(QKV3*HID)/2048, 256, 0, stream>>>(qkv_w, qkvw_bf);

  // qkv = hidden @ qkv_w^T -> bf16   (256^2 pipelined GEMM)
  mgemm8<0>(stream, hidden_bf, qkvw_bf, (void*)qkv, S_LEN, QKV3, HID, HID, HID, QKV3);

  e2a_k<<<S_LEN, 256, 0, stream>>>(qkv, q_norm_w, k_norm_w);
  vt_k<<<dim3(S_LEN/64, NH), 256, 0, stream>>>(qkv, vT);
  attn_k<<<NH*128, 256, 0, stream>>>(qkv, vT, rc, rs, attn);
  e2b_k<<<S_LEN, 256, 0, stream>>>(qkv, qk_scale, qk_off);

  const int  NEL = NFW*CHUNK_LEN*FD/256;
  const dim3 tg (FD/64,   CHUNK_LEN/64, NFW);
  const dim3 tg2(1024/64, CHUNK_LEN/64, NFW);

  for(int c=0; c<NCHUNK; c++){
    const bft* fqc = (const bft*)qkv + (size_t)c*CHUNK_LEN*QKV3;
    const bft* fkc = fqc + HID;
    const bft* fvc = fqc + 2*HID;
    // fused forward: [g|hm] = fk @ [w0|w2]^T ; [qg|qm] = fq @ [w0|w2]^T
    mgemm<128,128,0>(stream, fkc, w02b, ghb, nullptr, nullptr,
        CHUNK_LEN, 1024, FD, QKV3, FD, 1024, NFW, FD, sW2, sGH, 0);
    mgemm<128,128,0>(stream, fqc, w02b, qgm, nullptr, nullptr,
        CHUNK_LEN, 1024, FD, QKV3, FD, 1024, NFW, FD, sW2, sGH, 0);
    e3f_k<<<NEL, 256, 0, stream>>>(ghb, qgm, (bft*)hidb);
    // ofc = opre @ w1^T   (opre = qgm col 0-511, lda=1024)
    mgemm<128,128,0>(stream, (const bft*)qgm, w1b, ofc, nullptr, nullptr,
        CHUNK_LEN, FD, FD, 1024, FD, FD, NFW, sGH, sW, sCh, 0);
    // dhid = fv @ w1  (-> qgm col 512-1023; qm is dead after e3f)
    mgemm<128,128,0>(stream, fvc, (const bft*)w1tb, qgm + 512, nullptr, nullptr,
        CHUNK_LEN, FD, FD, QKV3, FD, 1024, NFW, FD, sW, sGH, 0);
    e4f_k<<<NEL, 256, 0, stream>>>(ghb, qgm, qkv, lrb, c*CHUNK_LEN);
    tr_k<<<tg, 256, 0, stream>>>(fkc,              fkT,  QKV3, FD,  sT);
    tr_k<<<tg, 256, 0, stream>>>((const bft*)hidb, hidT, FD,   sCh, sT);
    // one transpose of the full gh buffer -> [a0T; a2T] stacked (M=1024)
    tr_k<<<tg2, 256, 0, stream>>>(ghb, aT, 1024, sGH, sT2);
    // fused w0+w2 update: [w0; w2] += [a0T; a2T] @ fkT   (M=1024 -> 2 blk/CU)
    mgemm<64,64,2>(stream, aT, fkT, w02s, w02b, nullptr,
        1024, FD, CHUNK_LEN, CHUNK_LEN, CHUNK_LEN, FD, NFW, sT2, sT, sW2, sW2);
    // a1T -> first half of aT (GEMM above already consumed it; stream-serial)
    tr_k<<<tg, 256, 0, stream>>>(qgm + 512, aT, 1024, sGH, sT);
    mgemm<64,64,2>(stream, aT, hidT, w1s, w1b, w1tb,
        FD, FD, CHUNK_LEN, CHUNK_LEN, CHUNK_LEN, FD, NFW, sT, sT, sW, sW);
    e5_k<<<CHUNK_LEN, 256, 0, stream>>>(attn, ofc, ttt_nw, qkv, c*CHUNK_LEN);
  }

  // bf16 copy of o_proj (hidb/ofc are dead now), then final projection
  cvt_k<<<(HID*HID)/2048, 256, 0, stream>>>(o_proj, opw_bf);
  mgemm8<1>(stream, (const bft*)qkv, opw_bf, out, S_LEN, HID, HID, QKV3, HID, HID);
}

// Round 9
// 1415.755 us; speedup vs baseline: 1.2662x; 1.0089x over previous
//
#include <hip/hip_runtime.h>
#include <hip/hip_bf16.h>

typedef __hip_bfloat16 bf16;
typedef __bf16 bft;
typedef bft bf16x8 __attribute__((ext_vector_type(8)));
typedef bft bf16x4 __attribute__((ext_vector_type(4)));
typedef float f32x4 __attribute__((ext_vector_type(4)));

#define S_LEN 8192
#define HID   2048
#define QKV3  6144
#define NH    16
#define HD    128
#define NFW   4
#define FD    512
#define CHUNK_LEN 2048
#define NCHUNK 4
#define BASE_LR_INV (-6.9072552f)   // log(expm1(0.001))
#define QKP 136                     // attn Q/K LDS stride (128 + 8)
#define VSP 72                      // attn V^T LDS stride (64 + 8)
#define PSP 76                      // attn P LDS stride (64 + 12)

__device__ __forceinline__ float bf2f(bf16 x){ return __bfloat162float(x); }
__device__ __forceinline__ bf16  f2bf(float x){ return __float2bfloat16(x); }
__device__ __forceinline__ float sigm(float x){ return 1.f/(1.f+__expf(-x)); }
__device__ __forceinline__ float siluf(float x){ return x/(1.f+__expf(-x)); }
__device__ __forceinline__ float wave_sum(float v){
  #pragma unroll
  for(int off=32; off; off>>=1) v += __shfl_xor(v, off, 64);
  return v;
}

template<int N>
__device__ __forceinline__ void waitcnt_vm(){
  static_assert(N==0||N==2||N==4||N==8, "unsupported vmcnt");
  if constexpr (N==0)      asm volatile("s_waitcnt vmcnt(0)" ::: "memory");
  else if constexpr (N==2) asm volatile("s_waitcnt vmcnt(2)" ::: "memory");
  else if constexpr (N==4) asm volatile("s_waitcnt vmcnt(4)" ::: "memory");
  else                     asm volatile("s_waitcnt vmcnt(8)" ::: "memory");
}

// Raw barrier, NO sched_barrier pinning (m141; A/B round6-vs-7 confirmed).
__device__ __forceinline__ void bar(){
  __builtin_amdgcn_s_barrier();
  asm volatile("" ::: "memory");
}

// ---------------------------------------------------------------------------
// GEMM LDS tile staging (bf16 only), swizzled layout.
// Tile: ROWS x 32 bf16, unpadded [row][32]; physical col-slot c (8 elems)
// holds logical col-group g = c ^ ((row>>1)&3).
// global_load_lds 16B/lane; LDS dest = wave-uniform base + lane*16.
// ---------------------------------------------------------------------------
template<int ROWS>
__device__ __forceinline__ void stage(const bft* __restrict__ src, long ld,
                                      bft* dst, int tid)
{
  const int lane = tid & 63, wv = tid >> 6;
  #pragma unroll
  for (int i = 0; i < ROWS/64; ++i) {
    const int r0 = wv*16 + i*64;               // wave-uniform
    const int row = r0 + (lane >> 2);
    const int g = (lane & 3) ^ ((row >> 1) & 3);
    const bft* gp = src + (size_t)row*ld + g*8;
    bft* lp = dst + (size_t)r0*32;
    __builtin_amdgcn_global_load_lds(
        (const __attribute__((address_space(1))) void*)gp,
        (__attribute__((address_space(3))) void*)lp, 16, 0, 0);
  }
}

// ---------------------------------------------------------------------------
// MFMA NT GEMM: C[M,N] (+)= A[M,K] * B[N,K]^T, fp32 accumulate, 256 threads.
// 4-slot circular LDS pipeline (BK=32), counted vmcnt, m201-style phase
// skeleton (VGPR ~100 so 512-block chunk grids stay 2-blocks/CU).
// Race-freedom: slot written at iter s is (s+2)&3; concurrent readers touch
// s&3 (distinct mod 4); reads of the overwritten buffer finished >=1 barrier
// earlier. vmcnt ladder leaves slot s+2's LPT loads in flight.
// EPI: 0 = store bf16, 1 = store fp32, 2 = fp32 C += acc with bf16 shadow Cd
//      (z-stride sCd) + optional transposed shadow Ct,
//      3 = fused TTT-backprop epilogue: acc = dhid; Cd = gh base (z-stride
//      sCd, cols [d | 512+d]), Ct = fv base (row stride QKV3, z*FD col
//      offset), LRB/cb = per-token lr table. Writes:
//        gh[d]     = dgp*l0,  gh[512+d] = dhm*l2,  Cv[d] = fv*l1
//      (Cv base pre-offset to qgm+512, ldc=1024, z-stride sC).
// ---------------------------------------------------------------------------
template<int BM,int BN,int EPI>
__global__ __launch_bounds__(256) void mgemm_k(
    const bft* __restrict__ A, const bft* __restrict__ B, void* __restrict__ Cv,
    bft* __restrict__ Cd, bft* __restrict__ Ct, int K,
    long lda, long ldb, long ldc, long sA, long sB, long sC, long sCd,
    const float* __restrict__ LRB, int cb)
{
  constexpr int AM = BM/32, AN = BN/32;
  constexpr int LPT = BM/64 + BN/64;           // global_load_lds per wave/slot
  constexpr int NPH = (AM >= 4) ? 2 : 1;       // compute phases per slot
  constexpr int MH  = AM / NPH;                // mi rows per phase
  __shared__ __align__(16) bft As[4][BM*32];
  __shared__ __align__(16) bft Bs[4][BN*32];
  const int tid = threadIdx.x;
  const int z = blockIdx.z;
  A += (size_t)z * sA;
  B += (size_t)z * sB;
  const size_t m0 = (size_t)blockIdx.y * BM, n0 = (size_t)blockIdx.x * BN;
  const int wv = tid >> 6, lane = tid & 63;
  const int wm = (wv & 1) * (BM/2), wn = (wv >> 1) * (BN/2);
  const int fr = lane & 15;
  const int fsw = ((lane >> 4) ^ ((fr >> 1) & 3)) * 8;   // swizzled frag col

  f32x4 acc[AM][AN];
  #pragma unroll
  for (int i=0;i<AM;i++)
    #pragma unroll
    for (int j=0;j<AN;j++) acc[i][j] = (f32x4){0.f,0.f,0.f,0.f};

  const bft* Ab = A + m0*lda;
  const bft* Bb = B + n0*ldb;
  const int NS = K >> 5;

  stage<BM>(Ab,      lda, As[0], tid);
  stage<BN>(Bb,      ldb, Bs[0], tid);
  stage<BM>(Ab + 32, lda, As[1], tid);
  stage<BN>(Bb + 32, ldb, Bs[1], tid);
  waitcnt_vm<LPT>();
  bar();

  for (int s = 0; s < NS; ++s) {
    const bft* Ap = As[s & 3];
    const bft* Bp = Bs[s & 3];
    const int kt = (s + 2) * 32;
    const bool st = (s + 2 < NS);

    bf16x8 bvv[AN], afv[MH];
    // ---- phase A: all B-frags + first mi half; stage next A-tile ----
    #pragma unroll
    for (int ni=0; ni<AN; ni++)
      bvv[ni] = *(const bf16x8*)(Bp + (size_t)(wn + ni*16 + fr)*32 + fsw);
    #pragma unroll
    for (int i=0; i<MH; i++)
      afv[i] = *(const bf16x8*)(Ap + (size_t)(wm + i*16 + fr)*32 + fsw);
    if (st) stage<BM>(Ab + kt, lda, As[(s+2)&3], tid);
    if constexpr (NPH == 1) {
      if (st) { stage<BN>(Bb + kt, ldb, Bs[(s+2)&3], tid); waitcnt_vm<LPT>(); }
      else waitcnt_vm<0>();
    }
    bar();
    __builtin_amdgcn_s_setprio(1);
    #pragma unroll
    for (int i=0; i<MH; i++)
      #pragma unroll
      for (int ni=0; ni<AN; ni++)
        acc[i][ni] = __builtin_amdgcn_mfma_f32_16x16x32_bf16(afv[i], bvv[ni], acc[i][ni], 0, 0, 0);
    __builtin_amdgcn_s_setprio(0);

    if constexpr (NPH == 2) {
      bar();
      // ---- phase B: second mi half; stage next B-tile; vm ladder ----
      #pragma unroll
      for (int i=0; i<MH; i++)
        afv[i] = *(const bf16x8*)(Ap + (size_t)(wm + (MH+i)*16 + fr)*32 + fsw);
      if (st) { stage<BN>(Bb + kt, ldb, Bs[(s+2)&3], tid); waitcnt_vm<LPT>(); }
      else waitcnt_vm<0>();
      bar();
      __builtin_amdgcn_s_setprio(1);
      #pragma unroll
      for (int i=0; i<MH; i++)
        #pragma unroll
        for (int ni=0; ni<AN; ni++)
          acc[MH+i][ni] = __builtin_amdgcn_mfma_f32_16x16x32_bf16(afv[i], bvv[ni], acc[MH+i][ni], 0, 0, 0);
      __builtin_amdgcn_s_setprio(0);
      bar();
    }
  }

  const int er = (lane >> 4) * 4;   // C/D: row=(lane>>4)*4+reg, col=lane&15
  const int ec = lane & 15;
  #pragma unroll
  for (int mi=0; mi<AM; mi++){
    #pragma unroll
    for (int ni=0; ni<AN; ni++){
      #pragma unroll
      for (int r=0; r<4; r++){
        size_t row = m0 + wm + mi*16 + er + r;
        size_t col = n0 + wn + ni*16 + ec;
        size_t idx = (size_t)z*sC + row*ldc + col;
        float v = acc[mi][ni][r];
        if constexpr (EPI == 0){
          ((bft*)Cv)[idx] = (bft)v;
        } else if constexpr (EPI == 1){
          ((float*)Cv)[idx] = v;
        } else if constexpr (EPI == 2){
          float nv = ((float*)Cv)[idx] + v;
          ((float*)Cv)[idx] = nv;
          Cd[(size_t)z*sCd + row*ldc + col] = (bft)nv;
          if (Ct) Ct[(size_t)z*FD*FD + col*FD + row] = (bft)nv;
        } else {
          // fused TTT backprop (was e4f): v = dhid element
          size_t bg = (size_t)z*sCd + row*ldc + col;
          float gg = (float)Cd[bg];
          float hv = (float)Cd[bg + 512];
          float sg = sigm(gg);
          float silu_g = gg * sg;
          float dhm = v * silu_g;
          float dgp = v * hv * (sg * (1.f + gg * (1.f - sg)));
          int stok = cb + (int)row;
          float l0  = LRB[stok*12 + z];
          float l1  = LRB[stok*12 + 4 + z];
          float l2v = LRB[stok*12 + 8 + z];
          float fvv = (float)Ct[row*QKV3 + (size_t)z*FD + col];
          Cd[bg]       = (bft)(dgp * l0);
          Cd[bg + 512] = (bft)(dhm * l2v);
          ((bft*)Cv)[idx] = (bft)(fvv * l1);
        }
      }
    }
  }
}

template<int BM,int BN,int EPI>
static inline void mgemm(hipStream_t st, const bft* A, const bft* B, void* C,
    bft* Cd, bft* Ct, int M, int N, int K, long lda, long ldb, long ldc,
    int batch, long sA, long sB, long sC, long sCd,
    const float* LRB = nullptr, int cb = 0)
{
  dim3 g(N/BN, M/BM, batch);
  mgemm_k<BM,BN,EPI><<<g, 256, 0, st>>>(A, B, C, Cd, Ct, K, lda, ldb, ldc,
                                        sA, sB, sC, sCd, LRB, cb);
}

// ---------------------------------------------------------------------------
// 256x256 MFMA NT GEMM, 4-slot ring, 512 threads = 8 waves (2Mx4N),
// per-wave 128x64 output, cross-slot register double-buffer (round-6 form:
// no scheduling fence; compiler interleaves next-slot reads with MFMAs).
// Race proof: 1 barrier/slot; stage at iter s targets buffer (s+2)&3 whose
// last reads drained >=1 barrier earlier; vmcnt(4)+barrier guarantee slot
// s+1 landed before its reads. LDS = 128 KiB. XCD-aware bijective swizzle.
// ---------------------------------------------------------------------------
__device__ __forceinline__ void stage8(const bft* __restrict__ src, long ld,
                                       bft* dst, int tid)
{
  const int lane = tid & 63, wv = tid >> 6;      // 8 waves
  #pragma unroll
  for (int i = 0; i < 2; ++i) {
    const int r0 = wv*16 + i*128;                // wave-uniform
    const int row = r0 + (lane >> 2);
    const int g = (lane & 3) ^ ((row >> 1) & 3);
    const bft* gp = src + (size_t)row*ld + g*8;
    bft* lp = dst + (size_t)r0*32;
    __builtin_amdgcn_global_load_lds(
        (const __attribute__((address_space(1))) void*)gp,
        (__attribute__((address_space(3))) void*)lp, 16, 0, 0);
  }
}

template<int EPI>
__global__ __launch_bounds__(512, 2) void mgemm8_k(
    const bft* __restrict__ A, const bft* __restrict__ B, void* __restrict__ Cv,
    int K, long lda, long ldb, long ldc)
{
  __shared__ __align__(16) bft As[4][256*32];
  __shared__ __align__(16) bft Bs[4][256*32];
  const int tid = threadIdx.x;

  const int gx = (int)gridDim.x;
  const int nwg = (int)(gridDim.x * gridDim.y);
  int lin = (int)(blockIdx.y * gridDim.x + blockIdx.x);
  if ((nwg & 7) == 0) lin = (lin & 7) * (nwg >> 3) + (lin >> 3);
  const size_t m0 = (size_t)(lin / gx) * 256;
  const size_t n0 = (size_t)(lin % gx) * 256;

  const int wv = tid >> 6, lane = tid & 63;
  const int wm = (wv & 1) * 128, wn = (wv >> 1) * 64;
  const int fr = lane & 15;
  const int fsw = ((lane >> 4) ^ ((fr >> 1) & 3)) * 8;

  f32x4 acc[8][4];
  #pragma unroll
  for (int i=0;i<8;i++)
    #pragma unroll
    for (int j=0;j<4;j++) acc[i][j] = (f32x4){0.f,0.f,0.f,0.f};

  const bft* Ab = A + m0*lda;
  const bft* Bb = B + n0*ldb;
  const int NS = K >> 5;

  stage8(Ab,      lda, As[0], tid);
  stage8(Bb,      ldb, Bs[0], tid);
  stage8(Ab + 32, lda, As[1], tid);
  stage8(Bb + 32, ldb, Bs[1], tid);
  waitcnt_vm<4>();
  bar();

  bf16x8 aP[8], bP[4], aQ[8], bQ[4];
  #pragma unroll
  for (int mi=0; mi<8; mi++)
    aP[mi] = *(const bf16x8*)(As[0] + (size_t)(wm + mi*16 + fr)*32 + fsw);
  #pragma unroll
  for (int ni=0; ni<4; ni++)
    bP[ni] = *(const bf16x8*)(Bs[0] + (size_t)(wn + ni*16 + fr)*32 + fsw);

  auto body = [&](bf16x8 (&ac)[8], bf16x8 (&bc)[4],
                  bf16x8 (&an)[8], bf16x8 (&bn)[4], int s){
    const int kt = (s + 2) * 32;
    const bool st2 = (s + 2 < NS);
    const bool rd  = (s + 1 < NS);
    if (st2) {
      stage8(Ab + kt, lda, As[(s+2)&3], tid);
      stage8(Bb + kt, ldb, Bs[(s+2)&3], tid);
    }
    if (rd) {
      if (st2) waitcnt_vm<4>(); else waitcnt_vm<0>();
      bar();
      const bft* An = As[(s+1)&3];
      const bft* Bn = Bs[(s+1)&3];
      #pragma unroll
      for (int mi=0; mi<8; mi++)
        an[mi] = *(const bf16x8*)(An + (size_t)(wm + mi*16 + fr)*32 + fsw);
      #pragma unroll
      for (int ni=0; ni<4; ni++)
        bn[ni] = *(const bf16x8*)(Bn + (size_t)(wn + ni*16 + fr)*32 + fsw);
    }
    __builtin_amdgcn_s_setprio(1);
    #pragma unroll
    for (int mi=0; mi<8; mi++)
      #pragma unroll
      for (int ni=0; ni<4; ni++)
        acc[mi][ni] = __builtin_amdgcn_mfma_f32_16x16x32_bf16(ac[mi], bc[ni], acc[mi][ni], 0, 0, 0);
    __builtin_amdgcn_s_setprio(0);
  };

  for (int s = 0; s < NS; s += 2) {
    body(aP, bP, aQ, bQ, s);
    body(aQ, bQ, aP, bP, s + 1);
  }

  const int er = (lane >> 4) * 4;
  const int ec = lane & 15;
  #pragma unroll
  for (int mi=0; mi<8; mi++){
    #pragma unroll
    for (int ni=0; ni<4; ni++){
      #pragma unroll
      for (int r=0; r<4; r++){
        size_t row = m0 + wm + mi*16 + er + r;
        size_t col = n0 + wn + ni*16 + ec;
        size_t idx = row*ldc + col;
        float v = acc[mi][ni][r];
        if constexpr (EPI == 0) ((bft*)Cv)[idx] = (bft)v;
        else                    ((float*)Cv)[idx] = v;
      }
    }
  }
}

template<int EPI>
static inline void mgemm8(hipStream_t st, const bft* A, const bft* B, void* C,
                          int M, int N, int K, long lda, long ldb, long ldc)
{
  dim3 g(N/256, M/256, 1);
  mgemm8_k<EPI><<<g, 512, 0, st>>>(A, B, C, K, lda, ldb, ldc);
}

// ---------------------------------------------------------------------------
// fp32 -> bf16 bulk convert (8 elems/thread); n must divide 2048.
// ---------------------------------------------------------------------------
__global__ __launch_bounds__(256) void cvt_k(const float* __restrict__ s,
    bft* __restrict__ d)
{
  size_t i = ((size_t)blockIdx.x*256 + threadIdx.x) * 8;
  const float4 v0 = *(const float4*)(s + i);
  const float4 v1 = *(const float4*)(s + i + 4);
  bf16x8 b;
  b[0]=(bft)v0.x; b[1]=(bft)v0.y; b[2]=(bft)v0.z; b[3]=(bft)v0.w;
  b[4]=(bft)v1.x; b[5]=(bft)v1.y; b[6]=(bft)v1.z; b[7]=(bft)v1.w;
  *(bf16x8*)(d + i) = b;
}

// ---------------------------------------------------------------------------
// w0/w2 -> stacked [w0; w2] fp32 master + bf16 shadow, one pass.
// idx space: NFW*FD*FD elems, 8/thread.
// ---------------------------------------------------------------------------
__global__ __launch_bounds__(256) void cvtw02_k(
    const float* __restrict__ w0, const float* __restrict__ w2,
    float* __restrict__ w02s, bft* __restrict__ w02b)
{
  size_t i = ((size_t)blockIdx.x*256 + threadIdx.x) * 8;
  int z = (int)(i / ((size_t)FD*FD));
  size_t rem = i - (size_t)z*FD*FD;
  size_t o0 = (size_t)z*1024*FD + rem;
  size_t o2 = o0 + (size_t)512*FD;
  const float4 a0 = *(const float4*)(w0 + i);
  const float4 a1 = *(const float4*)(w0 + i + 4);
  const float4 b0 = *(const float4*)(w2 + i);
  const float4 b1 = *(const float4*)(w2 + i + 4);
  *(float4*)(w02s + o0)     = a0;
  *(float4*)(w02s + o0 + 4) = a1;
  *(float4*)(w02s + o2)     = b0;
  *(float4*)(w02s + o2 + 4) = b1;
  bf16x8 ba, bb;
  ba[0]=(bft)a0.x; ba[1]=(bft)a0.y; ba[2]=(bft)a0.z; ba[3]=(bft)a0.w;
  ba[4]=(bft)a1.x; ba[5]=(bft)a1.y; ba[6]=(bft)a1.z; ba[7]=(bft)a1.w;
  bb[0]=(bft)b0.x; bb[1]=(bft)b0.y; bb[2]=(bft)b0.z; bb[3]=(bft)b0.w;
  bb[4]=(bft)b1.x; bb[5]=(bft)b1.y; bb[6]=(bft)b1.z; bb[7]=(bft)b1.w;
  *(bf16x8*)(w02b + o0) = ba;
  *(bf16x8*)(w02b + o2) = bb;
}

// ---------------------------------------------------------------------------
// Batched bf16 transpose: out[z][c][r] = in[z][r][c]; arbitrary ldin/sIn.
// ---------------------------------------------------------------------------
__global__ __launch_bounds__(256) void tr_k(const bft* __restrict__ in,
    bft* __restrict__ out, long ldin, long sIn, long sOut)
{
  __shared__ __align__(16) bft t[64][72];
  const int c0 = blockIdx.x*64, r0 = blockIdx.y*64;
  in  += (size_t)blockIdx.z * sIn;
  out += (size_t)blockIdx.z * sOut;
  const int tid = threadIdx.x;
  #pragma unroll
  for (int i=0;i<2;i++){
    int e = tid + i*256;
    int r = e >> 3, c8 = (e & 7) * 8;
    *(bf16x8*)&t[r][c8] = *(const bf16x8*)(in + (size_t)(r0+r)*ldin + c0 + c8);
  }
  __syncthreads();
  #pragma unroll
  for (int i=0;i<2;i++){
    int e = tid + i*256;
    int c = e >> 3, r8 = (e & 7) * 8;
    bf16x8 v;
    #pragma unroll
    for (int j=0;j<8;j++) v[j] = t[r8+j][c];
    *(bf16x8*)(out + (size_t)(c0+c)*CHUNK_LEN + r0 + r8) = v;
  }
}

// initial w1^T bf16 shadow: w1tb[z][h][o] = (bf16)w1[z][o][h]
__global__ __launch_bounds__(256) void tcw1_k(const float* __restrict__ w1,
    bft* __restrict__ w1tb)
{
  size_t idx = (size_t)blockIdx.x*256 + threadIdx.x;
  int z = (int)(idx >> 18);
  int h = (int)((idx >> 9) & 511);
  int o = (int)(idx & 511);
  w1tb[idx] = (bft)w1[(size_t)z*FD*FD + (size_t)o*FD + h];
}

// ---------------------------------------------------------------------------
// v^T for attention PV: vT[h][d][s] = v[s][h*128+d] (raw v region of qkv).
// ---------------------------------------------------------------------------
__global__ __launch_bounds__(256) void vt_k(const bf16* __restrict__ qkv,
    bft* __restrict__ vT)
{
  __shared__ __align__(16) bft t[64*QKP];   // [s][d]
  const int s0 = blockIdx.x * 64;
  const int h  = blockIdx.y;
  const int tid = threadIdx.x;
  #pragma unroll
  for (int i=0;i<4;i++){
    int e = tid + i*256;
    int rr = e >> 4, doff = (e & 15) * 8;
    *(bf16x8*)(t + rr*QKP + doff) =
        *(const bf16x8*)((const bft*)qkv + (size_t)(s0+rr)*QKV3 + 2*HID + h*HD + doff);
  }
  __syncthreads();
  #pragma unroll
  for (int it=0; it<4; it++){
    int d = (tid >> 3) + it*32;
    int so8 = (tid & 7) * 8;
    bf16x8 v;
    #pragma unroll
    for (int j=0;j<8;j++) v[j] = t[(so8+j)*QKP + d];
    *(bf16x8*)(vT + ((size_t)(h*HD + d))*S_LEN + s0 + so8) = v;
  }
}

// ---------------------------------------------------------------------------
// RoPE cos/sin tables
// ---------------------------------------------------------------------------
__global__ void rope_k(float* __restrict__ rc, float* __restrict__ rs){
  int pos = blockIdx.x, d = threadIdx.x;
  float inv = 1.f / powf(500000.0f, (float)d * (1.0f/64.0f));
  float ang = (float)pos * inv;
  rc[pos*64+d] = cosf(ang);
  rs[pos*64+d] = sinf(ang);
}

// ---------------------------------------------------------------------------
// per-token learning rates
// ---------------------------------------------------------------------------
__global__ __launch_bounds__(256) void lr_k(const float* __restrict__ hidden,
    const float* __restrict__ lr_w, const float* __restrict__ lr_b,
    float* __restrict__ lro)
{
  __shared__ float hrow[HID];
  __shared__ float red[4][12];
  int s = blockIdx.x, tid = threadIdx.x;
  for(int i=0;i<HID/256;i++) hrow[tid+256*i] = hidden[(size_t)s*HID + tid + 256*i];
  __syncthreads();
  float part[12];
  #pragma unroll
  for(int o=0;o<12;o++) part[o]=0.f;
  for(int i=0;i<HID/256;i++){
    int j = tid + 256*i;
    float h = hrow[j];
    #pragma unroll
    for(int o=0;o<12;o++) part[o] += h * lr_w[o*HID + j];
  }
  int lane = tid & 63, w = tid >> 6;
  #pragma unroll
  for(int o=0;o<12;o++){
    float v = wave_sum(part[o]);
    if(lane==0) red[w][o] = v;
  }
  __syncthreads();
  if(tid < 12){
    float v = red[0][tid]+red[1][tid]+red[2][tid]+red[3][tid] + lr_b[tid] + BASE_LR_INV;
    float sp = (v > 20.f) ? v : log1pf(expf(v));
    lro[s*12 + tid] = sp;
  }
}

// ---------------------------------------------------------------------------
// E2a: per-token rmsnorm(q), rmsnorm(k), in place in qkv (bf16).
// ---------------------------------------------------------------------------
__global__ __launch_bounds__(256) void e2a_k(
    bf16* __restrict__ qkv,
    const float* __restrict__ qnw, const float* __restrict__ knw)
{
  __shared__ float red[8];
  int s = blockIdx.x, tid = threadIdx.x;
  int lane = tid & 63, w = tid >> 6;
  float qv[8], kv[8];
  float sq = 0.f, sk = 0.f;
  size_t base = (size_t)s*QKV3;
  #pragma unroll
  for(int i=0;i<8;i++){
    int j = tid*8 + i;
    qv[i] = bf2f(qkv[base + j]);
    kv[i] = bf2f(qkv[base + HID + j]);
    sq += qv[i]*qv[i]; sk += kv[i]*kv[i];
  }
  sq = wave_sum(sq); sk = wave_sum(sk);
  if(lane==0){ red[w] = sq; red[4+w] = sk; }
  __syncthreads();
  float rq = rsqrtf((red[0]+red[1]+red[2]+red[3])*(1.f/HID) + 1e-6f);
  float rk = rsqrtf((red[4]+red[5]+red[6]+red[7])*(1.f/HID) + 1e-6f);
  #pragma unroll
  for(int i=0;i<8;i++){
    int j = tid*8 + i;
    qkv[base + j]       = f2bf(qv[i]*rq*qnw[j]);
    qkv[base + HID + j] = f2bf(kv[i]*rk*knw[j]);
  }
}

// ---------------------------------------------------------------------------
// E2b (after attention): overwrite q/k/v regions with fq/fk/fv.
// ---------------------------------------------------------------------------
__global__ __launch_bounds__(256) void e2b_k(
    bf16* __restrict__ qkv,
    const float* __restrict__ qks, const float* __restrict__ qko)
{
  int s = blockIdx.x, tid = threadIdx.x;
  size_t base = (size_t)s*QKV3;
  float a[8], b[8], vv[8];
  float ga = 0.f, gb2 = 0.f;
  #pragma unroll
  for(int i=0;i<8;i++){
    int j = tid*8 + i;
    float qn = bf2f(qkv[base + j]);
    float kn = bf2f(qkv[base + HID + j]);
    float v  = bf2f(qkv[base + 2*HID + j]);
    a[i] = siluf(qn*qks[2*j]   + qko[2*j]);
    b[i] = siluf(kn*qks[2*j+1] + qko[2*j+1]);
    vv[i] = siluf(v);
    ga += a[i]*a[i]; gb2 += b[i]*b[i];
  }
  ga = wave_sum(ga); gb2 = wave_sum(gb2);
  float iq = 1.f / fmaxf(sqrtf(ga), 1e-12f);
  float ik = 1.f / fmaxf(sqrtf(gb2), 1e-12f);
  #pragma unroll
  for(int i=0;i<8;i++){
    int j = tid*8 + i;
    qkv[base + j]         = f2bf(a[i]*iq);
    qkv[base + HID + j]   = f2bf(b[i]*ik);
    qkv[base + 2*HID + j] = f2bf(vv[i]);
  }
}

// ---------------------------------------------------------------------------
// MFMA sliding-window attention (window 256 incl self).
// ---------------------------------------------------------------------------
__global__ __launch_bounds__(256) void attn_k(
    const bf16* __restrict__ qkv, const bft* __restrict__ vT,
    const float* __restrict__ rc, const float* __restrict__ rs,
    float* __restrict__ attn)
{
  __shared__ __align__(16) bft Qs[64*QKP];
  __shared__ __align__(16) bft Ks[64*QKP];
  __shared__ __align__(16) bft Vs[128*VSP];
  __shared__ __align__(16) bft Ps[64*PSP];
  const int head = blockIdx.x >> 7;
  const int Q0 = (blockIdx.x & 127) * 64;
  const int tid = threadIdx.x;
  const int hb = head * HD;
  const int lane = tid & 63;
  const int wm = (tid >> 6) * 16;
  const int fr = lane & 15, fko = (lane >> 4) * 8;
  const int rbase = (lane >> 4) * 4;

  #pragma unroll
  for(int i=0;i<16;i++){
    int e = tid + i*256;
    int rr = e >> 6, d = e & 63;
    int qpos = Q0 + rr;
    size_t b = (size_t)qpos*QKV3 + hb;
    float x1 = bf2f(qkv[b + d]);
    float x2 = bf2f(qkv[b + d + 64]);
    float c = rc[qpos*64 + d], sn = rs[qpos*64 + d];
    Qs[rr*QKP + d]      = (bft)(x1*c - x2*sn);
    Qs[rr*QKP + d + 64] = (bft)(x2*c + x1*sn);
  }
  __syncthreads();
  bf16x8 qf[4];
  #pragma unroll
  for (int kk=0;kk<4;kk++)
    qf[kk] = *(const bf16x8*)(Qs + (wm+fr)*QKP + kk*32 + fko);

  f32x4 Ot[8];
  #pragma unroll
  for (int i=0;i<8;i++) Ot[i] = (f32x4){0.f,0.f,0.f,0.f};
  float m4[4], l4[4];
  #pragma unroll
  for (int r=0;r<4;r++){ m4[r] = -INFINITY; l4[r] = 0.f; }

  for (int kt=0; kt<5; kt++){
    const int kb = Q0 - 256 + kt*64;
    if (kb < 0) continue;
    __syncthreads();
    #pragma unroll
    for(int i=0;i<16;i++){
      int e = tid + i*256;
      int rr = e >> 6, d = e & 63;
      int kpos = kb + rr;
      size_t b = (size_t)kpos*QKV3 + HID + hb;
      float x1 = bf2f(qkv[b + d]);
      float x2 = bf2f(qkv[b + d + 64]);
      float c = rc[kpos*64 + d], sn = rs[kpos*64 + d];
      Ks[rr*QKP + d]      = (bft)(x1*c - x2*sn);
      Ks[rr*QKP + d + 64] = (bft)(x2*c + x1*sn);
    }
    {
      int d = tid >> 1, koff = (tid & 1) * 32;
      const bft* vrow = vT + ((size_t)(hb + d))*S_LEN + kb + koff;
      bft* lrow = Vs + d*VSP + koff;
      #pragma unroll
      for (int j8=0;j8<4;j8++)
        *(bf16x8*)(lrow + j8*8) = *(const bf16x8*)(vrow + j8*8);
    }
    __syncthreads();

    f32x4 st[4];
    #pragma unroll
    for (int nt=0;nt<4;nt++){
      f32x4 acc = (f32x4){0.f,0.f,0.f,0.f};
      #pragma unroll
      for (int kk=0;kk<4;kk++){
        bf16x8 kf = *(const bf16x8*)(Ks + (nt*16+fr)*QKP + kk*32 + fko);
        acc = __builtin_amdgcn_mfma_f32_16x16x32_bf16(qf[kk], kf, acc, 0, 0, 0);
      }
      st[nt] = acc;
    }

    float pv[4][4];
    #pragma unroll
    for (int r=0;r<4;r++){
      int qpos = Q0 + wm + rbase + r;
      float sm[4];
      float mx = -INFINITY;
      #pragma unroll
      for (int nt=0;nt<4;nt++){
        int kpos = kb + nt*16 + fr;
        bool valid = (kpos > qpos - 256) && (kpos <= qpos);
        float s = valid ? st[nt][r] * 0.088388347648318447f : -INFINITY;
        sm[nt] = s;
        mx = fmaxf(mx, s);
      }
      mx = fmaxf(mx, __shfl_xor(mx, 1, 64));
      mx = fmaxf(mx, __shfl_xor(mx, 2, 64));
      mx = fmaxf(mx, __shfl_xor(mx, 4, 64));
      mx = fmaxf(mx, __shfl_xor(mx, 8, 64));
      float mnew = fmaxf(m4[r], mx);
      float alpha = (mnew == -INFINITY) ? 1.f : __expf(m4[r] - mnew);
      float ps = 0.f;
      #pragma unroll
      for (int nt=0;nt<4;nt++){
        float p = (sm[nt] == -INFINITY) ? 0.f : __expf(sm[nt] - mnew);
        pv[nt][r] = p;
        ps += p;
      }
      ps += __shfl_xor(ps, 1, 64);
      ps += __shfl_xor(ps, 2, 64);
      ps += __shfl_xor(ps, 4, 64);
      ps += __shfl_xor(ps, 8, 64);
      l4[r] = l4[r]*alpha + ps;
      m4[r] = mnew;
      #pragma unroll
      for (int ct=0;ct<8;ct++) Ot[ct][r] *= alpha;
    }

    #pragma unroll
    for (int r=0;r<4;r++){
      int row = wm + rbase + r;
      #pragma unroll
      for (int nt=0;nt<4;nt++)
        Ps[row*PSP + nt*16 + fr] = (bft)pv[nt][r];
    }
    bf16x8 af[2];
    #pragma unroll
    for (int kk=0;kk<2;kk++){
      const bft* pp = Ps + (wm+fr)*PSP + kk*32 + fko;
      bf16x4 lo = *(const bf16x4*)pp;
      bf16x4 hi = *(const bf16x4*)(pp+4);
      bf16x8 a;
      #pragma unroll
      for (int j=0;j<4;j++){ a[j]=lo[j]; a[j+4]=hi[j]; }
      af[kk]=a;
    }
    #pragma unroll
    for (int ct=0;ct<8;ct++)
      #pragma unroll
      for (int kk=0;kk<2;kk++){
        bf16x8 bv = *(const bf16x8*)(Vs + (ct*16+fr)*VSP + kk*32 + fko);
        Ot[ct] = __builtin_amdgcn_mfma_f32_16x16x32_bf16(af[kk], bv, Ot[ct], 0, 0, 0);
      }
  }

  #pragma unroll
  for (int r=0;r<4;r++){
    float invl = 1.f / l4[r];
    int qpos = Q0 + wm + rbase + r;
    size_t ob = (size_t)qpos*HID + hb;
    #pragma unroll
    for (int ct=0;ct<8;ct++)
      attn[ob + ct*16 + fr] = Ot[ct][r] * invl;
  }
}

// ---------------------------------------------------------------------------
// TTT elementwise fwd on FUSED buffers:
// gh = [z][ci][ g(0:512) | hm(512:1024) ], qgm = [z][ci][ qg | qm ].
// hid = silu(g)*hm (separate [z][ci][512]); opre = silu(qg)*qm -> qgm col 0.
// ---------------------------------------------------------------------------
__global__ __launch_bounds__(256) void e3f_k(
    bft* __restrict__ gh, bft* __restrict__ qgm, bft* __restrict__ hid)
{
  size_t idx = (size_t)blockIdx.x*256 + threadIdx.x;   // over NFW*CHUNK*FD
  int z  = (int)(idx >> 20);
  int ci = (int)((idx >> 9) & 2047);
  int d  = (int)(idx & 511);
  size_t b = ((size_t)z*CHUNK_LEN + ci)*1024 + d;
  float opre = siluf((float)qgm[b]) * (float)qgm[b + 512];
  hid[idx] = (bft)(siluf((float)gh[b]) * (float)gh[b + 512]);
  qgm[b]   = (bft)opre;
}

// ---------------------------------------------------------------------------
// E5 (per chunk): X = attn + rmsnorm(ofc)*ttt_norm_w -> q region of qkv
// ---------------------------------------------------------------------------
__global__ __launch_bounds__(256) void e5_k(const float* __restrict__ attn,
    const bf16* __restrict__ ofc, const float* __restrict__ tnw,
    bf16* __restrict__ qkv, int cbase)
{
  int ci = blockIdx.x, tid = threadIdx.x;
  int s = cbase + ci;
  int lane = tid & 63, w = tid >> 6;
  float o[8]; float ss = 0.f;
  size_t ob = ((size_t)w*CHUNK_LEN + ci)*FD + (size_t)lane*8;
  #pragma unroll
  for(int i=0;i<8;i++){ o[i] = bf2f(ofc[ob+i]); ss += o[i]*o[i]; }
  ss = wave_sum(ss);
  float inv = rsqrtf(ss*(1.f/FD) + 1e-6f);
  size_t xb = (size_t)s*QKV3 + w*FD + (size_t)lane*8;
  size_t ab = (size_t)s*HID  + w*FD + (size_t)lane*8;
  #pragma unroll
  for(int i=0;i<8;i++){
    int d = lane*8 + i;
    qkv[xb+i] = f2bf(attn[ab+i] + o[i]*inv*tnw[d]);
  }
}

// ---------------------------------------------------------------------------
extern "C" void kernel_launch(void* const* d_in, const int* in_sizes, int n_in,
                              void* d_out, int out_size, void* d_ws, size_t ws_size,
                              hipStream_t stream)
{
  (void)in_sizes; (void)n_in; (void)out_size;
  const float* hidden   = (const float*)d_in[0];
  const float* qkv_w    = (const float*)d_in[1];
  const float* q_norm_w = (const float*)d_in[2];
  const float* k_norm_w = (const float*)d_in[3];
  const float* qk_scale = (const float*)d_in[4];
  const float* qk_off   = (const float*)d_in[5];
  const float* lr_w     = (const float*)d_in[6];
  const float* lr_b     = (const float*)d_in[7];
  const float* w0_in    = (const float*)d_in[8];
  const float* w1_in    = (const float*)d_in[9];
  const float* w2_in    = (const float*)d_in[10];
  const float* ttt_nw   = (const float*)d_in[11];
  const float* o_proj   = (const float*)d_in[12];
  float* out = (float*)d_out;

  char* p = (char*)d_ws;
  auto alloc = [&](size_t n){ char* r = p; p += (n + 255) & ~(size_t)255; return (void*)r; };

  bf16*  qkv   = (bf16*) alloc((size_t)S_LEN*QKV3*sizeof(bf16));
  float* lrb   = (float*)alloc((size_t)S_LEN*12*sizeof(float));
  float* rc    = (float*)alloc((size_t)S_LEN*64*sizeof(float));
  float* rs    = (float*)alloc((size_t)S_LEN*64*sizeof(float));
  float* w02s  = (float*)alloc((size_t)NFW*1024*FD*sizeof(float)); // fp32 master [w0; w2]
  float* w1s   = (float*)alloc((size_t)NFW*FD*FD*sizeof(float));
  bft*   w1tb  = (bft*)  alloc((size_t)NFW*FD*FD*sizeof(bft));
  bft*   w02b  = (bft*)  alloc((size_t)NFW*1024*FD*sizeof(bft));   // bf16 shadow [w0; w2]
  bft*   w1b   = (bft*)  alloc((size_t)NFW*FD*FD*sizeof(bft));
  bf16*  gb    = (bf16*) alloc((size_t)NFW*CHUNK_LEN*FD*sizeof(bf16));
  bf16*  hmb   = (bf16*) alloc((size_t)NFW*CHUNK_LEN*FD*sizeof(bf16));
  bf16*  qgb   = (bf16*) alloc((size_t)NFW*CHUNK_LEN*FD*sizeof(bf16));
  bf16*  qmb   = (bf16*) alloc((size_t)NFW*CHUNK_LEN*FD*sizeof(bf16));
  bf16*  hidb  = (bf16*) alloc((size_t)NFW*CHUNK_LEN*FD*sizeof(bf16));
  bf16*  ofc   = (bf16*) alloc((size_t)NFW*CHUNK_LEN*FD*sizeof(bf16));
  bft*   fkT   = (bft*)  alloc((size_t)NFW*FD*CHUNK_LEN*sizeof(bft));
  bft*   hidT  = (bft*)  alloc((size_t)NFW*FD*CHUNK_LEN*sizeof(bft));
  bft*   aT    = (bft*)  alloc((size_t)NFW*1024*CHUNK_LEN*sizeof(bft)); // [a0T;a2T] scratch
  (void)alloc((size_t)4 << 20);   // tail pad: vT alias extends past aT

  if ((size_t)(p - (char*)d_ws) > ws_size) return;

  // Fused-buffer views (gb..qmb contiguous):
  //   ghb = gb..hmb  : [z][ci][ g | hm ]  (16 MB)
  //   qgm = qgb..qmb : [z][ci][ qg | qm ] (16 MB)
  bft* ghb = (bft*)gb;
  bft* qgm = (bft*)qgb;
  // Liveness aliases:
  //   hidden_bf (33.55 MB) = gb..hidb — dead before chunk loop.
  //   qkvw_bf   (25.17 MB) = fkT..aT  — dead before vt_k writes vT.
  //   vT        (33.55 MB) = fkT..aT+pad — dead before chunk loop's tr_k.
  //   opw_bf    ( 8.39 MB) = hidb     — converted after last e5.
  bft* hidden_bf = (bft*)gb;
  bft* qkvw_bf   = (bft*)fkT;
  bft* vT        = (bft*)fkT;
  bft* opw_bf    = (bft*)hidb;

  float* attn = out;   // attn lives in d_out until the final projection

  const long sW  = (long)FD*FD;
  const long sW2 = (long)1024*FD;
  const long sCh = (long)CHUNK_LEN*FD;
  const long sGH = (long)CHUNK_LEN*1024;
  const long sT  = (long)FD*CHUNK_LEN;
  const long sT2 = (long)1024*CHUNK_LEN;

  hipMemcpyAsync(w1s, w1_in, (size_t)NFW*FD*FD*sizeof(float), hipMemcpyDeviceToDevice, stream);

  rope_k<<<S_LEN, 64, 0, stream>>>(rc, rs);
  lr_k<<<S_LEN, 256, 0, stream>>>(hidden, lr_w, lr_b, lrb);
  tcw1_k<<<NFW*FD*FD/256, 256, 0, stream>>>(w1_in, w1tb);
  cvt_k<<<(NFW*FD*FD)/2048, 256, 0, stream>>>(w1_in, w1b);
  cvtw02_k<<<(NFW*FD*FD)/2048, 256, 0, stream>>>(w0_in, w2_in, w02s, w02b);
  cvt_k<<<(S_LEN*HID)/2048, 256, 0, stream>>>(hidden, hidden_bf);
  cvt_k<<<(QKV3*HID)/2048, 256, 0, stream>>>(qkv_w, qkvw_bf);

  // qkv = hidden @ qkv_w^T -> bf16   (256^2 pipelined GEMM)
  mgemm8<0>(stream, hidden_bf, qkvw_bf, (void*)qkv, S_LEN, QKV3, HID, HID, HID, QKV3);

  e2a_k<<<S_LEN, 256, 0, stream>>>(qkv, q_norm_w, k_norm_w);
  vt_k<<<dim3(S_LEN/64, NH), 256, 0, stream>>>(qkv, vT);
  attn_k<<<NH*128, 256, 0, stream>>>(qkv, vT, rc, rs, attn);
  e2b_k<<<S_LEN, 256, 0, stream>>>(qkv, qk_scale, qk_off);

  const int  NEL = NFW*CHUNK_LEN*FD/256;
  const dim3 tg (FD/64,   CHUNK_LEN/64, NFW);
  const dim3 tg2(1024/64, CHUNK_LEN/64, NFW);

  for(int c=0; c<NCHUNK; c++){
    const bft* fqc = (const bft*)qkv + (size_t)c*CHUNK_LEN*QKV3;
    const bft* fkc = fqc + HID;
    const bft* fvc = fqc + 2*HID;
    // fused forward: [g|hm] = fk @ [w0|w2]^T ; [qg|qm] = fq @ [w0|w2]^T
    mgemm<128,128,0>(stream, fkc, w02b, ghb, nullptr, nullptr,
        CHUNK_LEN, 1024, FD, QKV3, FD, 1024, NFW, FD, sW2, sGH, 0);
    mgemm<128,128,0>(stream, fqc, w02b, qgm, nullptr, nullptr,
        CHUNK_LEN, 1024, FD, QKV3, FD, 1024, NFW, FD, sW2, sGH, 0);
    e3f_k<<<NEL, 256, 0, stream>>>(ghb, qgm, (bft*)hidb);
    // ofc = opre @ w1^T   (opre = qgm col 0-511, lda=1024)
    mgemm<128,128,0>(stream, (const bft*)qgm, w1b, ofc, nullptr, nullptr,
        CHUNK_LEN, FD, FD, 1024, FD, FD, NFW, sGH, sW, sCh, 0);
    // dhid = fv @ w1 with FUSED e4f epilogue (EPI=3):
    //   gh col d   <- dgp*l0, gh col 512+d <- dhm*l2, qgm col 512+d <- fv*l1
    mgemm<128,128,3>(stream, fvc, (const bft*)w1tb, qgm + 512, ghb, (bft*)fvc,
        CHUNK_LEN, FD, FD, QKV3, FD, 1024, NFW, FD, sW, sGH, sGH,
        lrb, c*CHUNK_LEN);
    tr_k<<<tg, 256, 0, stream>>>(fkc,              fkT,  QKV3, FD,  sT);
    tr_k<<<tg, 256, 0, stream>>>((const bft*)hidb, hidT, FD,   sCh, sT);
    // one transpose of the full gh buffer -> [a0T; a2T] stacked (M=1024)
    tr_k<<<tg2, 256, 0, stream>>>(ghb, aT, 1024, sGH, sT2);
    // fused w0+w2 update: [w0; w2] += [a0T; a2T] @ fkT   (M=1024 -> 2 blk/CU)
    mgemm<64,64,2>(stream, aT, fkT, w02s, w02b, nullptr,
        1024, FD, CHUNK_LEN, CHUNK_LEN, CHUNK_LEN, FD, NFW, sT2, sT, sW2, sW2);
    // a1T -> first half of aT (GEMM above already consumed it; stream-serial)
    tr_k<<<tg, 256, 0, stream>>>(qgm + 512, aT, 1024, sGH, sT);
    mgemm<64,64,2>(stream, aT, hidT, w1s, w1b, w1tb,
        FD, FD, CHUNK_LEN, CHUNK_LEN, CHUNK_LEN, FD, NFW, sT, sT, sW, sW);
    e5_k<<<CHUNK_LEN, 256, 0, stream>>>(attn, ofc, ttt_nw, qkv, c*CHUNK_LEN);
  }

  // bf16 copy of o_proj (hidb/ofc are dead now), then final projection
  cvt_k<<<(HID*HID)/2048, 256, 0, stream>>>(o_proj, opw_bf);
  mgemm8<1>(stream, (const bft*)qkv, opw_bf, out, S_LEN, HID, HID, QKV3, HID, HID);
}